// Round 1
// baseline (4077.861 us; speedup 1.0000x reference)
//
#include <hip/hip_runtime.h>
#include <hip/hip_bf16.h>

#define DEV static __device__ __forceinline__

constexpr int N_SEQ = 1024;
constexpr int N_HEADS = 16;
constexpr float SM_SCALE = 0.125f;   // hd^-0.5, hd=64

// ---- bf16 helpers (use ushort to keep LDS arrays POD) ----
DEV float bf2f(unsigned short u) {
  union { unsigned int i; float f; } v; v.i = ((unsigned int)u) << 16; return v.f;
}
DEV unsigned short f2bf(float f) {
  union { float f; unsigned int i; } v; v.f = f;
  unsigned int r = v.i + 0x7fffu + ((v.i >> 16) & 1u);
  return (unsigned short)(r >> 16);
}

// ---------- workspace layout ----------
constexpr size_t SZ_MAT  = (size_t)2048 * 1024 * 4;       // 8 MB fp32 2048x1024
constexpr size_t OFF_Q   = 0;
constexpr size_t OFF_K   = 1 * SZ_MAT;
constexpr size_t OFF_V   = 2 * SZ_MAT;
constexpr size_t OFF_W   = 3 * SZ_MAT;
constexpr size_t OFF_O   = 4 * SZ_MAT;
constexpr size_t OFF_WPRE= 5 * SZ_MAT;                    // 2048x64 f32
constexpr size_t OFF_BETA= OFF_WPRE + (size_t)2048*64*4;  // 2048x16 f32 (b,n,h)
constexpr size_t OFF_LF  = OFF_BETA + (size_t)2048*16*4;  // 2048x16 f32
constexpr size_t OFF_FC  = OFF_LF   + (size_t)2048*16*4;  // 32x1024 f32 (bh,n)
constexpr size_t OFF_L   = OFF_FC   + (size_t)32*1024*4;  // bf16 32x1024x1024 (reused as S)
constexpr size_t SZ_TRI  = (size_t)32*1024*1024*2;        // 64 MB
constexpr size_t OFF_C   = OFF_L + SZ_TRI;
constexpr size_t OFF_G   = OFF_C + SZ_TRI;
// total ~233 MB

// ---------- generic f32 GEMM: C = A(MxK) @ B(KxN), all row-major ----------
__global__ __launch_bounds__(256) void gemm_f32(const float* __restrict__ A,
    const float* __restrict__ Bm, float* __restrict__ Cm, int M, int N, int K) {
  __shared__ float As[16][65];
  __shared__ float Bs[16][65];
  int t = threadIdx.x;
  int bm = blockIdx.y * 64, bn = blockIdx.x * 64;
  int tx = t & 15, ty = t >> 4;
  float acc[4][4] = {};
  for (int k0 = 0; k0 < K; k0 += 16) {
#pragma unroll
    for (int i = 0; i < 4; ++i) {
      int lin = t + i * 256;
      int m = lin >> 4, kk = lin & 15;
      float v = 0.f;
      if (bm + m < M && k0 + kk < K) v = A[(size_t)(bm + m) * K + k0 + kk];
      As[kk][m] = v;
    }
#pragma unroll
    for (int i = 0; i < 4; ++i) {
      int lin = t + i * 256;
      int kk = lin >> 6, nn = lin & 63;
      float v = 0.f;
      if (k0 + kk < K && bn + nn < N) v = Bm[(size_t)(k0 + kk) * N + bn + nn];
      Bs[kk][nn] = v;
    }
    __syncthreads();
#pragma unroll
    for (int kk = 0; kk < 16; ++kk) {
      float a[4], bv[4];
#pragma unroll
      for (int i = 0; i < 4; ++i) a[i] = As[kk][ty * 4 + i];
#pragma unroll
      for (int j = 0; j < 4; ++j) bv[j] = Bs[kk][tx * 4 + j];
#pragma unroll
      for (int i = 0; i < 4; ++i)
#pragma unroll
        for (int j = 0; j < 4; ++j) acc[i][j] += a[i] * bv[j];
    }
    __syncthreads();
  }
#pragma unroll
  for (int i = 0; i < 4; ++i) {
    int m = bm + ty * 4 + i;
    if (m >= M) continue;
#pragma unroll
    for (int j = 0; j < 4; ++j) {
      int nn = bn + tx * 4 + j;
      if (nn < N) Cm[(size_t)m * N + nn] = acc[i][j];
    }
  }
}

// ---------- l2-normalize w per (row, head) ----------
__global__ __launch_bounds__(256) void wnorm_kernel(float* __restrict__ Wg) {
  int row = blockIdx.x;            // 0..2047
  int wave = threadIdx.x >> 6, lane = threadIdx.x & 63;
#pragma unroll
  for (int i = 0; i < 4; ++i) {
    int hh = wave * 4 + i;
    size_t idx = ((size_t)row << 10) + hh * 64 + lane;
    float v = Wg[idx];
    float ss = v * v;
#pragma unroll
    for (int off = 1; off < 64; off <<= 1) ss += __shfl_xor(ss, off);
    Wg[idx] = v * rsqrtf(ss + 1e-6f);
  }
}

// ---------- beta = 2*sigmoid(.), logf = log_sigmoid(.+delta) in place ----------
__global__ __launch_bounds__(256) void bg_kernel(float* __restrict__ beta,
    float* __restrict__ lf, const float* __restrict__ delta) {
  int idx = blockIdx.x * 256 + threadIdx.x;
  if (idx >= 2048 * 16) return;
  int hh = idx & 15;
  float braw = beta[idx];
  beta[idx] = 2.f / (1.f + __expf(-braw));
  float x = lf[idx] + delta[hh];
  float ls = (x >= 0.f) ? -log1pf(__expf(-x)) : (x - log1pf(__expf(x)));
  lf[idx] = ls;
}

// ---------- Fc = cumsum of logf over t, per (b,h) ----------
__global__ __launch_bounds__(256) void fc_kernel(const float* __restrict__ lf,
                                                 float* __restrict__ Fc) {
  int bh = blockIdx.x;             // 0..31
  int b = bh >> 4, h = bh & 15;
  int t = threadIdx.x;
  __shared__ float buf[1024];
  __shared__ float tsum[256];
#pragma unroll
  for (int i = 0; i < 4; ++i) {
    int tt = t + i * 256;
    buf[tt] = lf[((size_t)((b << 10) + tt) << 4) + h];
  }
  __syncthreads();
  float loc[4]; float run = 0.f;
#pragma unroll
  for (int i = 0; i < 4; ++i) { run += buf[t * 4 + i]; loc[i] = run; }
  tsum[t] = run;
  __syncthreads();
  for (int off = 1; off < 256; off <<= 1) {
    float add = (t >= off) ? tsum[t - off] : 0.f;
    __syncthreads();
    tsum[t] += add;
    __syncthreads();
  }
  float excl = tsum[t] - run;
#pragma unroll
  for (int i = 0; i < 4; ++i) Fc[bh * 1024 + t * 4 + i] = excl + loc[i];
}

// ---------- dst[bh][i][j] = mask * beta_j * (A_i . B_j), bf16 out ----------
// strict=1: keep j<i (L);  strict=0: keep j<=i (G)
__global__ __launch_bounds__(256) void pair_dots_kernel(
    const float* __restrict__ Ag, const float* __restrict__ Bg,
    const float* __restrict__ betaG, unsigned short* __restrict__ dst, int strict) {
  int jb = blockIdx.x, ibk = blockIdx.y, bh = blockIdx.z;
  if (jb > ibk) return;
  int b = bh >> 4, h = bh & 15;
  int i0 = ibk * 64, j0 = jb * 64;
  int t = threadIdx.x, tx = t & 15, ty = t >> 4;
  __shared__ float Ab[64][65], Bb2[64][65];
  __shared__ float bet[64];
  size_t rowbase = (size_t)b * N_SEQ;
#pragma unroll
  for (int i = 0; i < 16; ++i) {
    int lin = t + i * 256; int r = lin >> 6, dd = lin & 63;
    Ab[r][dd]  = Ag[((rowbase + i0 + r) << 10) + (h << 6) + dd];
    Bb2[r][dd] = Bg[((rowbase + j0 + r) << 10) + (h << 6) + dd];
  }
  if (t < 64) bet[t] = betaG[((size_t)((b << 10) + j0 + t) << 4) + h];
  __syncthreads();
  float acc[4][4] = {};
  for (int dd = 0; dd < 64; ++dd) {
    float a[4], bv[4];
#pragma unroll
    for (int i = 0; i < 4; ++i) a[i] = Ab[ty * 4 + i][dd];
#pragma unroll
    for (int j = 0; j < 4; ++j) bv[j] = Bb2[tx * 4 + j][dd];
#pragma unroll
    for (int i = 0; i < 4; ++i)
#pragma unroll
      for (int j = 0; j < 4; ++j) acc[i][j] += a[i] * bv[j];
  }
  size_t base = (size_t)bh << 20;
#pragma unroll
  for (int i = 0; i < 4; ++i) {
#pragma unroll
    for (int j = 0; j < 4; ++j) {
      int gi = i0 + ty * 4 + i, gj = j0 + tx * 4 + j;
      bool keep = strict ? (gj < gi) : (gj <= gi);
      float v = keep ? acc[i][j] * bet[tx * 4 + j] : 0.f;
      dst[base + ((size_t)gi << 10) + gj] = f2bf(v);
    }
  }
}

// ---------- blocked unit-lower triangular solve (I+L) C = tril(W K^T, -1) ----------
// one WG per (bh, 64-column slab); forward substitution over 64-row blocks
__global__ __launch_bounds__(256) void solve_kernel(
    const float* __restrict__ Kg, const float* __restrict__ Wg,
    const unsigned short* __restrict__ Lg, unsigned short* __restrict__ Cg) {
  int js = blockIdx.x;             // 0..15 column slab
  int bh = blockIdx.y;             // 0..31
  int b = bh >> 4, h = bh & 15;
  int j0 = js * 64;
  int t = threadIdx.x;
  int colg = t & 31;               // 32 col groups x 2 cols
  int rowg = t >> 5;               // 8 row groups x 8 rows
  __shared__ unsigned short Ks[64][66];   // k_j vectors (bf16)
  __shared__ unsigned short CS[64][66];   // Cprev stage / C broadcast (bf16)
  __shared__ float WL[64][65];            // Wb (M init) or L tile (f32)
  size_t rowbase = (size_t)b * N_SEQ;
  size_t base = (size_t)bh << 20;
#pragma unroll
  for (int i = 0; i < 16; ++i) {
    int lin = t + i * 256; int c = lin >> 6, dd = lin & 63;
    Ks[c][dd] = f2bf(Kg[((rowbase + j0 + c) << 10) + (h << 6) + dd]);
  }
  float acc[8][2];
  for (int ib = js; ib < 16; ++ib) {
    int s0 = ib * 64;
    __syncthreads();
#pragma unroll
    for (int i = 0; i < 16; ++i) {     // load w_s block
      int lin = t + i * 256; int sl = lin >> 6, dd = lin & 63;
      WL[sl][dd] = Wg[((rowbase + s0 + sl) << 10) + (h << 6) + dd];
    }
    __syncthreads();
    // M init: acc = w_s . k_j  (strict lower)
#pragma unroll
    for (int r = 0; r < 8; ++r) { acc[r][0] = 0.f; acc[r][1] = 0.f; }
    for (int dd = 0; dd < 64; ++dd) {
      float kv0 = bf2f(Ks[colg * 2 + 0][dd]);
      float kv1 = bf2f(Ks[colg * 2 + 1][dd]);
#pragma unroll
      for (int r = 0; r < 8; ++r) {
        float wv = WL[rowg * 8 + r][dd];
        acc[r][0] += wv * kv0;
        acc[r][1] += wv * kv1;
      }
    }
    if (ib == js) {                  // diagonal block: zero j >= s
#pragma unroll
      for (int r = 0; r < 8; ++r) {
        int sl = rowg * 8 + r;
        if (colg * 2 + 0 >= sl) acc[r][0] = 0.f;
        if (colg * 2 + 1 >= sl) acc[r][1] = 0.f;
      }
    }
    __syncthreads();
    // off-block updates: acc -= L[s, rb] * C[rb, j]
    for (int rb = js; rb < ib; ++rb) {
      int r0 = rb * 64;
#pragma unroll
      for (int i = 0; i < 16; ++i) {
        int lin = t + i * 256; int a = lin >> 6, c = lin & 63;
        WL[a][c] = bf2f(Lg[base + ((size_t)(s0 + a) << 10) + r0 + c]);
        CS[a][c] = Cg[base + ((size_t)(r0 + a) << 10) + j0 + c];
      }
      __syncthreads();
      for (int rl = 0; rl < 64; ++rl) {
        float cv0 = bf2f(CS[rl][colg * 2 + 0]);
        float cv1 = bf2f(CS[rl][colg * 2 + 1]);
#pragma unroll
        for (int r = 0; r < 8; ++r) {
          float lv = WL[rowg * 8 + r][rl];
          acc[r][0] -= lv * cv0;
          acc[r][1] -= lv * cv1;
        }
      }
      __syncthreads();
    }
    // diagonal L tile
#pragma unroll
    for (int i = 0; i < 16; ++i) {
      int lin = t + i * 256; int a = lin >> 6, c = lin & 63;
      WL[a][c] = bf2f(Lg[base + ((size_t)(s0 + a) << 10) + s0 + c]);
    }
    __syncthreads();
    // in-block forward substitution
    for (int r = 0; r < 64; ++r) {
      if (rowg == (r >> 3)) {        // owners of row r broadcast it
        int rr = r & 7;
#pragma unroll
        for (int c = 0; c < 2; ++c) {
          int cl = colg * 2 + c;
          float v = acc[rr][c];
          if (ib == js && cl >= r) v = 0.f;
          CS[r][cl] = f2bf(v);
        }
      }
      __syncthreads();
      float cb0 = bf2f(CS[r][colg * 2 + 0]);
      float cb1 = bf2f(CS[r][colg * 2 + 1]);
#pragma unroll
      for (int rr = 0; rr < 8; ++rr) {
        int sl = rowg * 8 + rr;
        if (sl > r) {
          float lv = WL[sl][r];
          acc[rr][0] -= lv * cb0;
          acc[rr][1] -= lv * cb1;
        }
      }
    }
    __syncthreads();
    // write block (zeros included in diagonal block upper part)
#pragma unroll
    for (int rr = 0; rr < 8; ++rr) {
      int sl = rowg * 8 + rr;
#pragma unroll
      for (int c = 0; c < 2; ++c) {
        int cl = colg * 2 + c;
        float v = acc[rr][c];
        if (ib == js && cl >= sl) v = 0.f;
        Cg[base + ((size_t)(s0 + sl) << 10) + j0 + cl] = f2bf(v);
      }
    }
  }
}

// ---------- S tile = Q K^T - sum_sb G(t,sb) C(sb,j), bf16 out ----------
__global__ __launch_bounds__(256) void score_kernel(
    const float* __restrict__ Qg, const float* __restrict__ Kg,
    const unsigned short* __restrict__ Gg, const unsigned short* __restrict__ Cg,
    unsigned short* __restrict__ Sg) {
  int jb = blockIdx.x, tb = blockIdx.y, bh = blockIdx.z;
  if (jb > tb) return;
  int b = bh >> 4, h = bh & 15;
  int t0 = tb * 64, j0 = jb * 64;
  int t = threadIdx.x, tx = t & 15, ty = t >> 4;
  __shared__ float Qb[64][65], Kb[64][65];
  __shared__ unsigned short Gt[64][66], Ct[64][66];
  size_t rowbase = (size_t)b * N_SEQ;
#pragma unroll
  for (int i = 0; i < 16; ++i) {
    int lin = t + i * 256; int r = lin >> 6, dd = lin & 63;
    Qb[r][dd] = Qg[((rowbase + t0 + r) << 10) + (h << 6) + dd];
    Kb[r][dd] = Kg[((rowbase + j0 + r) << 10) + (h << 6) + dd];
  }
  __syncthreads();
  float acc[4][4] = {};
  for (int dd = 0; dd < 64; ++dd) {
    float a[4], bv[4];
#pragma unroll
    for (int i = 0; i < 4; ++i) a[i] = Qb[ty * 4 + i][dd];
#pragma unroll
    for (int j = 0; j < 4; ++j) bv[j] = Kb[tx * 4 + j][dd];
#pragma unroll
    for (int i = 0; i < 4; ++i)
#pragma unroll
      for (int j = 0; j < 4; ++j) acc[i][j] += a[i] * bv[j];
  }
  size_t base = (size_t)bh << 20;
  for (int sb = jb; sb <= tb; ++sb) {
    int s0 = sb * 64;
    __syncthreads();
#pragma unroll
    for (int i = 0; i < 16; ++i) {
      int lin = t + i * 256; int r = lin >> 6, c = lin & 63;
      Gt[r][c] = Gg[base + ((size_t)(t0 + r) << 10) + s0 + c];
      Ct[r][c] = Cg[base + ((size_t)(s0 + r) << 10) + j0 + c];
    }
    __syncthreads();
    for (int sl = 0; sl < 64; ++sl) {
      float a[4], bv[4];
#pragma unroll
      for (int i = 0; i < 4; ++i) a[i] = bf2f(Gt[ty * 4 + i][sl]);
#pragma unroll
      for (int j = 0; j < 4; ++j) bv[j] = bf2f(Ct[sl][tx * 4 + j]);
#pragma unroll
      for (int i = 0; i < 4; ++i)
#pragma unroll
        for (int j = 0; j < 4; ++j) acc[i][j] -= a[i] * bv[j];
    }
  }
#pragma unroll
  for (int i = 0; i < 4; ++i)
#pragma unroll
    for (int j = 0; j < 4; ++j)
      Sg[base + ((size_t)(t0 + ty * 4 + i) << 10) + j0 + tx * 4 + j] = f2bf(acc[i][j]);
}

// ---------- online softmax (with decay) + P@V ----------
__global__ __launch_bounds__(256) void softpv_kernel(
    const unsigned short* __restrict__ Sg, const float* __restrict__ Vg,
    const float* __restrict__ FcG, float* __restrict__ Og) {
  int tb = blockIdx.x, bh = blockIdx.y;
  int b = bh >> 4, h = bh & 15;
  int t0 = tb * 64;
  int t = threadIdx.x, tx = t & 15, ty = t >> 4;
  int rrow = t >> 2, rq = t & 3;
  __shared__ float Pt[64][65];
  __shared__ float Vt[64][65];
  __shared__ float mrow[64], lrow[64], crow[64], fct[64];
  if (t < 64) {
    mrow[t] = -1e30f; lrow[t] = 0.f;
    fct[t] = FcG[bh * 1024 + t0 + t];
  }
  float oacc[4][4] = {};
  size_t base = (size_t)bh << 20;
  size_t rowbase = (size_t)b * N_SEQ;
  for (int jb = 0; jb <= tb; ++jb) {
    int j0 = jb * 64;
    __syncthreads();
#pragma unroll
    for (int i = 0; i < 16; ++i) {
      int lin = t + i * 256; int r = lin >> 6, c = lin & 63;
      float sv = bf2f(Sg[base + ((size_t)(t0 + r) << 10) + j0 + c]);
      float lg = sv * SM_SCALE + fct[r] - FcG[bh * 1024 + j0 + c];
      if (jb == tb && c > r) lg = -1e30f;
      Pt[r][c] = lg;
      Vt[r][c] = Vg[((rowbase + j0 + r) << 10) + (h << 6) + c];
    }
    __syncthreads();
    float tm = -1e30f;
#pragma unroll
    for (int c = 0; c < 16; ++c) tm = fmaxf(tm, Pt[rrow][rq * 16 + c]);
    tm = fmaxf(tm, __shfl_xor(tm, 1));
    tm = fmaxf(tm, __shfl_xor(tm, 2));
    float mold = mrow[rrow];
    float mnew = fmaxf(mold, tm);
    float corr = __expf(mold - mnew);
    float psum = 0.f;
#pragma unroll
    for (int c = 0; c < 16; ++c) {
      float p = __expf(Pt[rrow][rq * 16 + c] - mnew);
      Pt[rrow][rq * 16 + c] = p;
      psum += p;
    }
    psum += __shfl_xor(psum, 1);
    psum += __shfl_xor(psum, 2);
    if (rq == 0) {
      lrow[rrow] = lrow[rrow] * corr + psum;
      crow[rrow] = corr;
      mrow[rrow] = mnew;
    }
    __syncthreads();
#pragma unroll
    for (int i = 0; i < 4; ++i) {
      float cr = crow[ty * 4 + i];
#pragma unroll
      for (int j = 0; j < 4; ++j) oacc[i][j] *= cr;
    }
    for (int jj = 0; jj < 64; ++jj) {
      float a[4], vv[4];
#pragma unroll
      for (int i = 0; i < 4; ++i) a[i] = Pt[ty * 4 + i][jj];
#pragma unroll
      for (int j = 0; j < 4; ++j) vv[j] = Vt[jj][tx * 4 + j];
#pragma unroll
      for (int i = 0; i < 4; ++i)
#pragma unroll
        for (int j = 0; j < 4; ++j) oacc[i][j] += a[i] * vv[j];
    }
  }
  __syncthreads();
#pragma unroll
  for (int i = 0; i < 4; ++i) {
    float inv = 1.f / lrow[ty * 4 + i];
#pragma unroll
    for (int j = 0; j < 4; ++j)
      Og[((rowbase + t0 + ty * 4 + i) << 10) + (h << 6) + tx * 4 + j] = oacc[i][j] * inv;
  }
}

extern "C" void kernel_launch(void* const* d_in, const int* in_sizes, int n_in,
                              void* d_out, int out_size, void* d_ws, size_t ws_size,
                              hipStream_t stream) {
  const float* x    = (const float*)d_in[0];
  const float* Wq   = (const float*)d_in[1];
  const float* Wk   = (const float*)d_in[2];
  const float* Wv   = (const float*)d_in[3];
  const float* Wo   = (const float*)d_in[4];
  const float* Ww1  = (const float*)d_in[5];
  const float* Ww2  = (const float*)d_in[6];
  const float* Wb   = (const float*)d_in[7];
  const float* Wf   = (const float*)d_in[8];
  const float* delta= (const float*)d_in[9];

  char* ws = (char*)d_ws;
  float* Qb   = (float*)(ws + OFF_Q);
  float* Kb   = (float*)(ws + OFF_K);
  float* Vb   = (float*)(ws + OFF_V);
  float* Wn   = (float*)(ws + OFF_W);
  float* Ob   = (float*)(ws + OFF_O);
  float* Wpre = (float*)(ws + OFF_WPRE);
  float* Beta = (float*)(ws + OFF_BETA);
  float* Lf   = (float*)(ws + OFF_LF);
  float* Fc   = (float*)(ws + OFF_FC);
  unsigned short* Lbuf = (unsigned short*)(ws + OFF_L);
  unsigned short* Cbuf = (unsigned short*)(ws + OFF_C);
  unsigned short* Gbuf = (unsigned short*)(ws + OFF_G);
  unsigned short* Sbuf = Lbuf;   // reuse: L dead after solve

  dim3 blk(256);
  // projections
  gemm_f32<<<dim3(16, 32), blk, 0, stream>>>(x, Wq, Qb, 2048, 1024, 1024);
  gemm_f32<<<dim3(16, 32), blk, 0, stream>>>(x, Wk, Kb, 2048, 1024, 1024);
  gemm_f32<<<dim3(16, 32), blk, 0, stream>>>(x, Wv, Vb, 2048, 1024, 1024);
  gemm_f32<<<dim3(1, 32),  blk, 0, stream>>>(x, Ww1, Wpre, 2048, 64, 1024);
  gemm_f32<<<dim3(16, 32), blk, 0, stream>>>(Wpre, Ww2, Wn, 2048, 1024, 64);
  gemm_f32<<<dim3(1, 32),  blk, 0, stream>>>(x, Wb, Beta, 2048, 16, 1024);
  gemm_f32<<<dim3(1, 32),  blk, 0, stream>>>(x, Wf, Lf, 2048, 16, 1024);
  // elementwise prep
  wnorm_kernel<<<2048, blk, 0, stream>>>(Wn);
  bg_kernel<<<128, blk, 0, stream>>>(Beta, Lf, delta);
  fc_kernel<<<32, blk, 0, stream>>>(Lf, Fc);
  // L and G (bf16)
  pair_dots_kernel<<<dim3(16, 16, 32), blk, 0, stream>>>(Wn, Wn, Beta, Lbuf, 1);
  pair_dots_kernel<<<dim3(16, 16, 32), blk, 0, stream>>>(Qb, Wn, Beta, Gbuf, 0);
  // triangular solve -> C
  solve_kernel<<<dim3(16, 32), blk, 0, stream>>>(Kb, Wn, Lbuf, Cbuf);
  // scores S = QK^T - G C   (S reuses L region)
  score_kernel<<<dim3(16, 16, 32), blk, 0, stream>>>(Qb, Kb, Gbuf, Cbuf, Sbuf);
  // softmax + PV
  softpv_kernel<<<dim3(16, 32), blk, 0, stream>>>(Sbuf, Vb, Fc, Ob);
  // output projection
  gemm_f32<<<dim3(16, 32), blk, 0, stream>>>(Ob, Wo, (float*)d_out, 2048, 1024, 1024);
}

// Round 2
// 1357.979 us; speedup vs baseline: 3.0029x; 3.0029x over previous
//
#include <hip/hip_runtime.h>
#include <hip/hip_bf16.h>

#define DEV static __device__ __forceinline__

constexpr float SM_SCALE = 0.125f;   // hd^-0.5, hd=64

typedef __attribute__((ext_vector_type(8))) short s16x8;
typedef __attribute__((ext_vector_type(8))) unsigned short u16x8;
typedef __attribute__((ext_vector_type(4))) float f32x4;

DEV float bf2f(unsigned short u) {
  union { unsigned int i; float f; } v; v.i = ((unsigned int)u) << 16; return v.f;
}
DEV unsigned short f2bf(float f) {
  union { float f; unsigned int i; } v; v.f = f;
  unsigned int r = v.i + 0x7fffu + ((v.i >> 16) & 1u);
  return (unsigned short)(r >> 16);
}

// ---------- workspace layout (bytes) ----------
constexpr size_t OFF_XB   = 0;                       // 4,194,304  xb bf16; VT reuses after projections
constexpr size_t OFF_VT   = 0;
constexpr size_t OFF_WQT  = 4194304;                 // 2MB each
constexpr size_t OFF_WKT  = 6291456;
constexpr size_t OFF_WVT  = 8388608;
constexpr size_t OFF_WOT  = 10485760;
constexpr size_t OFF_W1T  = 12582912;                // 131072 (reused as Beta f32)
constexpr size_t OFF_W2T  = 12713984;                // 131072 (reused as Lf f32)
constexpr size_t OFF_Q16  = 12845056;                // 4MB each bf16 2048x1024
constexpr size_t OFF_K16  = 17039360;
constexpr size_t OFF_V16  = 21233664;
constexpr size_t OFF_WN16 = 25427968;
constexpr size_t OFF_WB16 = 29622272;
constexpr size_t OFF_WNF  = 33816576;                // 4MB (reused as Ob)
constexpr size_t OFF_OB   = 33816576;
constexpr size_t OFF_WPRE = 38010880;                // 262144
constexpr size_t OFF_FC   = 38273024;                // 131072
constexpr size_t OFF_L    = 38404096;                // 64MB (reused as S)
constexpr size_t OFF_CT   = 105512960;               // 64MB
constexpr size_t OFF_G    = 172621824;               // 64MB  -> end 239,730,688

// ================= round-1 fp32 helpers (small mats only) =================
__global__ __launch_bounds__(256) void gemm_f32(const float* __restrict__ A,
    const float* __restrict__ Bm, float* __restrict__ Cm, int M, int N, int K) {
  __shared__ float As[16][65];
  __shared__ float Bs[16][65];
  int t = threadIdx.x;
  int bm = blockIdx.y * 64, bn = blockIdx.x * 64;
  int tx = t & 15, ty = t >> 4;
  float acc[4][4] = {};
  for (int k0 = 0; k0 < K; k0 += 16) {
#pragma unroll
    for (int i = 0; i < 4; ++i) {
      int lin = t + i * 256;
      int m = lin >> 4, kk = lin & 15;
      float v = 0.f;
      if (bm + m < M && k0 + kk < K) v = A[(size_t)(bm + m) * K + k0 + kk];
      As[kk][m] = v;
    }
#pragma unroll
    for (int i = 0; i < 4; ++i) {
      int lin = t + i * 256;
      int kk = lin >> 6, nn = lin & 63;
      float v = 0.f;
      if (k0 + kk < K && bn + nn < N) v = Bm[(size_t)(k0 + kk) * N + bn + nn];
      Bs[kk][nn] = v;
    }
    __syncthreads();
#pragma unroll
    for (int kk = 0; kk < 16; ++kk) {
      float a[4], bv[4];
#pragma unroll
      for (int i = 0; i < 4; ++i) a[i] = As[kk][ty * 4 + i];
#pragma unroll
      for (int j = 0; j < 4; ++j) bv[j] = Bs[kk][tx * 4 + j];
#pragma unroll
      for (int i = 0; i < 4; ++i)
#pragma unroll
        for (int j = 0; j < 4; ++j) acc[i][j] += a[i] * bv[j];
    }
    __syncthreads();
  }
#pragma unroll
  for (int i = 0; i < 4; ++i) {
    int m = bm + ty * 4 + i;
    if (m >= M) continue;
#pragma unroll
    for (int j = 0; j < 4; ++j) {
      int nn = bn + tx * 4 + j;
      if (nn < N) Cm[(size_t)m * N + nn] = acc[i][j];
    }
  }
}

__global__ __launch_bounds__(256) void bg_kernel(float* __restrict__ beta,
    float* __restrict__ lf, const float* __restrict__ delta) {
  int idx = blockIdx.x * 256 + threadIdx.x;
  if (idx >= 2048 * 16) return;
  int hh = idx & 15;
  float braw = beta[idx];
  beta[idx] = 2.f / (1.f + __expf(-braw));
  float x = lf[idx] + delta[hh];
  float ls = (x >= 0.f) ? -log1pf(__expf(-x)) : (x - log1pf(__expf(x)));
  lf[idx] = ls;
}

__global__ __launch_bounds__(256) void fc_kernel(const float* __restrict__ lf,
                                                 float* __restrict__ Fc) {
  int bh = blockIdx.x;
  int b = bh >> 4, h = bh & 15;
  int t = threadIdx.x;
  __shared__ float buf[1024];
  __shared__ float tsum[256];
#pragma unroll
  for (int i = 0; i < 4; ++i) {
    int tt = t + i * 256;
    buf[tt] = lf[((size_t)((b << 10) + tt) << 4) + h];
  }
  __syncthreads();
  float loc[4]; float run = 0.f;
#pragma unroll
  for (int i = 0; i < 4; ++i) { run += buf[t * 4 + i]; loc[i] = run; }
  tsum[t] = run;
  __syncthreads();
  for (int off = 1; off < 256; off <<= 1) {
    float add = (t >= off) ? tsum[t - off] : 0.f;
    __syncthreads();
    tsum[t] += add;
    __syncthreads();
  }
  float excl = tsum[t] - run;
#pragma unroll
  for (int i = 0; i < 4; ++i) Fc[bh * 1024 + t * 4 + i] = excl + loc[i];
}

// ================= casts / transposes =================
__global__ __launch_bounds__(256) void cast_bf16(const float* __restrict__ src,
    unsigned short* __restrict__ dst, int n) {
  int i = (blockIdx.x * 256 + threadIdx.x) * 8;
  if (i >= n) return;
  float4 a = *(const float4*)(src + i);
  float4 b = *(const float4*)(src + i + 4);
  u16x8 o;
  o[0] = f2bf(a.x); o[1] = f2bf(a.y); o[2] = f2bf(a.z); o[3] = f2bf(a.w);
  o[4] = f2bf(b.x); o[5] = f2bf(b.y); o[6] = f2bf(b.z); o[7] = f2bf(b.w);
  *(u16x8*)(dst + i) = o;
}

// dst[c][r] = bf16(src[r][c]);  grid (C/64, R/64)
__global__ __launch_bounds__(256) void transpose_cast(const float* __restrict__ src,
    unsigned short* __restrict__ dst, int R, int C) {
  __shared__ float tile[64 * 65];
  int c0 = blockIdx.x * 64, r0 = blockIdx.y * 64;
  int t = threadIdx.x;
#pragma unroll
  for (int i = 0; i < 16; ++i) {
    int lin = t + i * 256; int r = lin >> 6, c = lin & 63;
    tile[r * 65 + c] = src[(size_t)(r0 + r) * C + c0 + c];
  }
  __syncthreads();
#pragma unroll
  for (int i = 0; i < 16; ++i) {
    int lin = t + i * 256; int c = lin >> 6, r = lin & 63;
    dst[(size_t)(c0 + c) * R + r0 + r] = f2bf(tile[r * 65 + c]);
  }
}

// V16 (2048x1024 bf16, head cols) -> VT[bh][64][1024]
__global__ __launch_bounds__(256) void vtrans(const unsigned short* __restrict__ V,
    unsigned short* __restrict__ VT) {
  int tbb = blockIdx.x, bh = blockIdx.y;
  int b = bh >> 4, h = bh & 15;
  __shared__ unsigned short tile[64 * 65];
  int t = threadIdx.x;
#pragma unroll
  for (int i = 0; i < 16; ++i) {
    int lin = t + i * 256; int r = lin >> 6, c = lin & 63;
    tile[r * 65 + c] = V[(size_t)(b * 1024 + tbb * 64 + r) * 1024 + h * 64 + c];
  }
  __syncthreads();
#pragma unroll
  for (int i = 0; i < 16; ++i) {
    int lin = t + i * 256; int dd = lin >> 6, r = lin & 63;
    VT[((size_t)bh * 64 + dd) * 1024 + tbb * 64 + r] = tile[r * 65 + dd];
  }
}

// ================= bf16 NT MFMA GEMM: out = A(MxK) @ BT(NxK)^T =================
template<int F32OUT>
__global__ __launch_bounds__(256) void gemm_nt(const unsigned short* __restrict__ A,
    const unsigned short* __restrict__ BT, void* __restrict__ out,
    int M, int N, int K) {
  __shared__ unsigned short As[64 * 64];
  __shared__ unsigned short Bs[64 * 64];
  int m0 = blockIdx.y * 64, n0 = blockIdx.x * 64;
  int t = threadIdx.x;
  int w = t >> 6, l = t & 63, fr = l & 15;
  int koB = (l >> 4) * 16;                  // byte offset of 8-elem k-chunk
  f32x4 acc[4];
#pragma unroll
  for (int c = 0; c < 4; ++c) acc[c] = (f32x4){0.f, 0.f, 0.f, 0.f};
  for (int k0 = 0; k0 < K; k0 += 64) {
    __syncthreads();
#pragma unroll
    for (int i = 0; i < 2; ++i) {
      int cid = t + i * 256;
      int row = cid >> 3, ch = cid & 7;
      int byt = ((row << 7) + (ch << 4)) ^ ((row & 7) << 4);
      *(u16x8*)((char*)As + byt) = *(const u16x8*)(A + (size_t)(m0 + row) * K + k0 + ch * 8);
      *(u16x8*)((char*)Bs + byt) = *(const u16x8*)(BT + (size_t)(n0 + row) * K + k0 + ch * 8);
    }
    __syncthreads();
#pragma unroll
    for (int kh = 0; kh < 2; ++kh) {
      int ra = 16 * w + fr;
      s16x8 a = *(const s16x8*)((char*)As + (((ra << 7) + (kh << 6) + koB) ^ ((ra & 7) << 4)));
#pragma unroll
      for (int c = 0; c < 4; ++c) {
        int rb = 16 * c + fr;
        s16x8 bb = *(const s16x8*)((char*)Bs + (((rb << 7) + (kh << 6) + koB) ^ ((rb & 7) << 4)));
        acc[c] = __builtin_amdgcn_mfma_f32_16x16x32_bf16(a, bb, acc[c], 0, 0, 0);
      }
    }
  }
  int rbase = m0 + 16 * w + ((l >> 4) << 2);
#pragma unroll
  for (int c = 0; c < 4; ++c) {
    int col = n0 + 16 * c + fr;
#pragma unroll
    for (int r = 0; r < 4; ++r) {
      if (F32OUT) ((float*)out)[(size_t)(rbase + r) * N + col] = acc[c][r];
      else ((unsigned short*)out)[(size_t)(rbase + r) * N + col] = f2bf(acc[c][r]);
    }
  }
}

// ================= w normalize + beta-scale =================
__global__ __launch_bounds__(256) void wnorm2(const unsigned short* __restrict__ WNF,
    const float* __restrict__ Beta, unsigned short* __restrict__ WN,
    unsigned short* __restrict__ WB) {
  int row = blockIdx.x;
  int wave = threadIdx.x >> 6, lane = threadIdx.x & 63;
#pragma unroll
  for (int i = 0; i < 4; ++i) {
    int hh = wave * 4 + i;
    size_t idx = ((size_t)row << 10) + hh * 64 + lane;
    float v = bf2f(WNF[idx]);
    float ss = v * v;
#pragma unroll
    for (int off = 1; off < 64; off <<= 1) ss += __shfl_xor(ss, off);
    float wn = v * rsqrtf(ss + 1e-6f);
    WN[idx] = f2bf(wn);
    WB[idx] = f2bf(wn * Beta[row * 16 + hh]);
  }
}

// ================= masked pair NT: dst[bh][i][j] = mask * (A_i . B_j) =================
// B rows are beta-prescaled. STRICT=1: j<i (L); STRICT=0: j<=i (G)
template<int STRICT>
__global__ __launch_bounds__(256) void pair_nt(const unsigned short* __restrict__ Ar,
    const unsigned short* __restrict__ Br, unsigned short* __restrict__ dst) {
  int jb = blockIdx.x, ib = blockIdx.y, bh = blockIdx.z;
  if (jb > ib) return;
  int b = bh >> 4, h = bh & 15;
  int t = threadIdx.x, w = t >> 6, l = t & 63, fr = l & 15;
  int ko = (l >> 4) * 8;
  const unsigned short* Ab = Ar + ((size_t)b * 1024) * 1024 + h * 64;
  const unsigned short* Bb = Br + ((size_t)b * 1024) * 1024 + h * 64;
  int ar = ib * 64 + 16 * w + fr;
  f32x4 acc[4];
#pragma unroll
  for (int c = 0; c < 4; ++c) acc[c] = (f32x4){0.f, 0.f, 0.f, 0.f};
#pragma unroll
  for (int kh = 0; kh < 2; ++kh) {
    s16x8 a = *(const s16x8*)(Ab + (size_t)ar * 1024 + kh * 32 + ko);
#pragma unroll
    for (int c = 0; c < 4; ++c) {
      s16x8 bb = *(const s16x8*)(Bb + (size_t)(jb * 64 + 16 * c + fr) * 1024 + kh * 32 + ko);
      acc[c] = __builtin_amdgcn_mfma_f32_16x16x32_bf16(a, bb, acc[c], 0, 0, 0);
    }
  }
  size_t base = (size_t)bh << 20;
#pragma unroll
  for (int c = 0; c < 4; ++c) {
#pragma unroll
    for (int r = 0; r < 4; ++r) {
      int gi = ib * 64 + 16 * w + ((l >> 4) << 2) + r;
      int gj = jb * 64 + 16 * c + fr;
      bool keep = STRICT ? (gj < gi) : (gj <= gi);
      dst[base + (size_t)gi * 1024 + gj] = f2bf(keep ? acc[c][r] : 0.f);
    }
  }
}

// ================= solve step ib: rect = W K^T - L C, then in-block substitution =================
__global__ __launch_bounds__(256) void solve_step(const unsigned short* __restrict__ WN,
    const unsigned short* __restrict__ Kk, const unsigned short* __restrict__ Lb,
    unsigned short* __restrict__ CT, int ib) {
  int jb = blockIdx.x, bh = blockIdx.y;
  int b = bh >> 4, h = bh & 15;
  int t = threadIdx.x, w = t >> 6, l = t & 63, fr = l & 15;
  int ko = (l >> 4) * 8;
  size_t base = (size_t)bh << 20;
  int s0 = ib * 64, j0 = jb * 64;
  __shared__ float rect[64 * 68];
  __shared__ float LD[64 * 65];
  const unsigned short* Wb_ = WN + ((size_t)b * 1024) * 1024 + h * 64;
  const unsigned short* Kb_ = Kk + ((size_t)b * 1024) * 1024 + h * 64;
  int ar = s0 + 16 * w + fr;
  f32x4 am[4], al[4];
#pragma unroll
  for (int c = 0; c < 4; ++c) { am[c] = (f32x4){0.f,0.f,0.f,0.f}; al[c] = (f32x4){0.f,0.f,0.f,0.f}; }
  // M init: w_s . k_j
#pragma unroll
  for (int kh = 0; kh < 2; ++kh) {
    s16x8 a = *(const s16x8*)(Wb_ + (size_t)ar * 1024 + kh * 32 + ko);
#pragma unroll
    for (int c = 0; c < 4; ++c) {
      s16x8 bb = *(const s16x8*)(Kb_ + (size_t)(j0 + 16 * c + fr) * 1024 + kh * 32 + ko);
      am[c] = __builtin_amdgcn_mfma_f32_16x16x32_bf16(a, bb, am[c], 0, 0, 0);
    }
  }
  // minus L[ib][rb] @ C[rb]  (only rb >= jb have nonzero C)
  for (int rb = jb; rb < ib; ++rb) {
#pragma unroll
    for (int kh = 0; kh < 2; ++kh) {
      s16x8 a = *(const s16x8*)(Lb + base + (size_t)ar * 1024 + rb * 64 + kh * 32 + ko);
#pragma unroll
      for (int c = 0; c < 4; ++c) {
        s16x8 bb = *(const s16x8*)(CT + base + (size_t)(j0 + 16 * c + fr) * 1024 + rb * 64 + kh * 32 + ko);
        al[c] = __builtin_amdgcn_mfma_f32_16x16x32_bf16(a, bb, al[c], 0, 0, 0);
      }
    }
  }
  // stage diagonal L tile (f32) for substitution
#pragma unroll
  for (int i = 0; i < 16; ++i) {
    int lin = t + i * 256; int s = lin >> 6, r = lin & 63;
    LD[s * 65 + r] = bf2f(Lb[base + (size_t)(s0 + s) * 1024 + s0 + r]);
  }
  // rect[j][s]
#pragma unroll
  for (int c = 0; c < 4; ++c) {
#pragma unroll
    for (int r = 0; r < 4; ++r) {
      int jl = 16 * c + fr, sl = 16 * w + ((l >> 4) << 2) + r;
      rect[jl * 68 + sl] = am[c][r] - al[c][r];
    }
  }
  __syncthreads();
  if (w == 0) {                       // lane l = local column j
    float cc[64];
#pragma unroll
    for (int s = 0; s < 64; ++s) cc[s] = rect[l * 68 + s];
    if (jb == ib) {
#pragma unroll
      for (int s = 0; s < 64; ++s) if (s <= l) cc[s] = 0.f;
    }
#pragma unroll
    for (int r = 0; r < 63; ++r) {
      float val = cc[r];
#pragma unroll
      for (int s = r + 1; s < 64; ++s) cc[s] -= LD[s * 65 + r] * val;
    }
#pragma unroll
    for (int s = 0; s < 64; ++s) rect[l * 68 + s] = cc[s];
  }
  __syncthreads();
#pragma unroll
  for (int i = 0; i < 16; ++i) {
    int lin = t + i * 256; int jl = lin >> 6, sl = lin & 63;
    CT[base + (size_t)(j0 + jl) * 1024 + s0 + sl] = f2bf(rect[jl * 68 + sl]);
  }
}

// ================= S = Q K^T - G @ C =================
__global__ __launch_bounds__(256) void score_mfma(const unsigned short* __restrict__ Q,
    const unsigned short* __restrict__ Kk, const unsigned short* __restrict__ G,
    const unsigned short* __restrict__ CT, unsigned short* __restrict__ Sg) {
  int jb = blockIdx.x, tb = blockIdx.y, bh = blockIdx.z;
  if (jb > tb) return;
  int b = bh >> 4, h = bh & 15;
  int t = threadIdx.x, w = t >> 6, l = t & 63, fr = l & 15;
  int ko = (l >> 4) * 8;
  size_t base = (size_t)bh << 20;
  int t0 = tb * 64, j0 = jb * 64;
  const unsigned short* Qb_ = Q + ((size_t)b * 1024) * 1024 + h * 64;
  const unsigned short* Kb_ = Kk + ((size_t)b * 1024) * 1024 + h * 64;
  int ar = t0 + 16 * w + fr;
  f32x4 aq[4], ag[4];
#pragma unroll
  for (int c = 0; c < 4; ++c) { aq[c] = (f32x4){0.f,0.f,0.f,0.f}; ag[c] = (f32x4){0.f,0.f,0.f,0.f}; }
#pragma unroll
  for (int kh = 0; kh < 2; ++kh) {
    s16x8 a = *(const s16x8*)(Qb_ + (size_t)ar * 1024 + kh * 32 + ko);
#pragma unroll
    for (int c = 0; c < 4; ++c) {
      s16x8 bb = *(const s16x8*)(Kb_ + (size_t)(j0 + 16 * c + fr) * 1024 + kh * 32 + ko);
      aq[c] = __builtin_amdgcn_mfma_f32_16x16x32_bf16(a, bb, aq[c], 0, 0, 0);
    }
  }
  for (int sb = jb; sb <= tb; ++sb) {
#pragma unroll
    for (int kh = 0; kh < 2; ++kh) {
      s16x8 a = *(const s16x8*)(G + base + (size_t)ar * 1024 + sb * 64 + kh * 32 + ko);
#pragma unroll
      for (int c = 0; c < 4; ++c) {
        s16x8 bb = *(const s16x8*)(CT + base + (size_t)(j0 + 16 * c + fr) * 1024 + sb * 64 + kh * 32 + ko);
        ag[c] = __builtin_amdgcn_mfma_f32_16x16x32_bf16(a, bb, ag[c], 0, 0, 0);
      }
    }
  }
#pragma unroll
  for (int c = 0; c < 4; ++c) {
#pragma unroll
    for (int r = 0; r < 4; ++r) {
      int gi = t0 + 16 * w + ((l >> 4) << 2) + r;
      int gj = j0 + 16 * c + fr;
      Sg[base + (size_t)gi * 1024 + gj] = f2bf(aq[c][r] - ag[c][r]);
    }
  }
}

// ================= softmax (decay + causal) + P@V via MFMA =================
__global__ __launch_bounds__(256) void softpv(const unsigned short* __restrict__ S,
    const unsigned short* __restrict__ VT, const float* __restrict__ Fc,
    unsigned short* __restrict__ Ob) {
  int tb = blockIdx.x, bh = blockIdx.y;
  int b = bh >> 4, h = bh & 15;
  int t0 = tb * 64;
  int t = threadIdx.x, w = t >> 6, l = t & 63, fr = l & 15;
  int koB = (l >> 4) * 16;
  __shared__ unsigned short Pl[64 * 64];
  __shared__ float fcj[64], smax[4][64], ssum[4][64];
  __shared__ float mrow[64], lrow[64], crow[64], fct[64];
  if (t < 64) { mrow[t] = -1e30f; lrow[t] = 0.f; fct[t] = Fc[bh * 1024 + t0 + t]; }
  f32x4 accO[4];
#pragma unroll
  for (int c = 0; c < 4; ++c) accO[c] = (f32x4){0.f,0.f,0.f,0.f};
  size_t base = (size_t)bh << 20;
  int row = t & 63, cg = t >> 6;
  for (int jb = 0; jb <= tb; ++jb) {
    int j0 = jb * 64;
    if (t < 64) fcj[t] = Fc[bh * 1024 + j0 + t];
    __syncthreads();                               // (A)
    float lg[16];
    const unsigned short* srow = S + base + (size_t)(t0 + row) * 1024 + j0 + cg * 16;
    u16x8 sv0 = *(const u16x8*)(srow);
    u16x8 sv1 = *(const u16x8*)(srow + 8);
    float pm = -1e30f;
#pragma unroll
    for (int c = 0; c < 16; ++c) {
      float sv = bf2f(c < 8 ? sv0[c] : sv1[c - 8]);
      float v = sv * SM_SCALE + fct[row] - fcj[cg * 16 + c];
      if (jb == tb && cg * 16 + c > row) v = -1e30f;
      lg[c] = v; pm = fmaxf(pm, v);
    }
    smax[cg][row] = pm;
    __syncthreads();                               // (B)
    if (t < 64) {
      float m4 = fmaxf(fmaxf(smax[0][t], smax[1][t]), fmaxf(smax[2][t], smax[3][t]));
      float mn = fmaxf(mrow[t], m4);
      crow[t] = __expf(mrow[t] - mn);
      mrow[t] = mn;
    }
    __syncthreads();                               // (C)
    float mn = mrow[row];
    float ps = 0.f;
#pragma unroll
    for (int cp = 0; cp < 8; ++cp) {
      float p0 = __expf(lg[2 * cp] - mn), p1 = __expf(lg[2 * cp + 1] - mn);
      ps += p0 + p1;
      unsigned int packed = (unsigned)f2bf(p0) | ((unsigned)f2bf(p1) << 16);
      int byt = ((row << 7) + (cg << 5) + (cp << 2)) ^ ((row & 7) << 4);
      *(unsigned int*)((char*)Pl + byt) = packed;
    }
    ssum[cg][row] = ps;
    __syncthreads();                               // (D)
    if (t < 64) lrow[t] = lrow[t] * crow[t] + ssum[0][t] + ssum[1][t] + ssum[2][t] + ssum[3][t];
    int ra = 16 * w + fr;
    float cr[4];
#pragma unroll
    for (int r = 0; r < 4; ++r) cr[r] = crow[16 * w + ((l >> 4) << 2) + r];
#pragma unroll
    for (int c = 0; c < 4; ++c)
#pragma unroll
      for (int r = 0; r < 4; ++r) accO[c][r] *= cr[r];
#pragma unroll
    for (int kh = 0; kh < 2; ++kh) {
      s16x8 a = *(const s16x8*)((char*)Pl + (((ra << 7) + (kh << 6) + koB) ^ ((ra & 7) << 4)));
#pragma unroll
      for (int c = 0; c < 4; ++c) {
        const unsigned short* vrow = VT + ((size_t)bh * 64 + 16 * c + fr) * 1024 + j0 + kh * 32 + (l >> 4) * 8;
        s16x8 bb = *(const s16x8*)vrow;
        accO[c] = __builtin_amdgcn_mfma_f32_16x16x32_bf16(a, bb, accO[c], 0, 0, 0);
      }
    }
    __syncthreads();                               // (E)
  }
  float inv[4];
#pragma unroll
  for (int r = 0; r < 4; ++r) inv[r] = 1.f / lrow[16 * w + ((l >> 4) << 2) + r];
#pragma unroll
  for (int c = 0; c < 4; ++c) {
#pragma unroll
    for (int r = 0; r < 4; ++r) {
      int grow = t0 + 16 * w + ((l >> 4) << 2) + r;
      Ob[((size_t)(b * 1024) + grow) * 1024 + h * 64 + 16 * c + fr] = f2bf(accO[c][r] * inv[r]);
    }
  }
}

extern "C" void kernel_launch(void* const* d_in, const int* in_sizes, int n_in,
                              void* d_out, int out_size, void* d_ws, size_t ws_size,
                              hipStream_t stream) {
  const float* x    = (const float*)d_in[0];
  const float* Wq   = (const float*)d_in[1];
  const float* Wk   = (const float*)d_in[2];
  const float* Wv   = (const float*)d_in[3];
  const float* Wo   = (const float*)d_in[4];
  const float* Ww1  = (const float*)d_in[5];
  const float* Ww2  = (const float*)d_in[6];
  const float* Wb   = (const float*)d_in[7];
  const float* Wf   = (const float*)d_in[8];
  const float* delta= (const float*)d_in[9];

  char* ws = (char*)d_ws;
  unsigned short* xb   = (unsigned short*)(ws + OFF_XB);
  unsigned short* VT   = (unsigned short*)(ws + OFF_VT);
  unsigned short* WqT  = (unsigned short*)(ws + OFF_WQT);
  unsigned short* WkT  = (unsigned short*)(ws + OFF_WKT);
  unsigned short* WvT  = (unsigned short*)(ws + OFF_WVT);
  unsigned short* WoT  = (unsigned short*)(ws + OFF_WOT);
  unsigned short* W1T  = (unsigned short*)(ws + OFF_W1T);
  unsigned short* W2T  = (unsigned short*)(ws + OFF_W2T);
  float*          Beta = (float*)(ws + OFF_W1T);
  float*          Lf   = (float*)(ws + OFF_W2T);
  unsigned short* Q16  = (unsigned short*)(ws + OFF_Q16);
  unsigned short* K16  = (unsigned short*)(ws + OFF_K16);
  unsigned short* V16  = (unsigned short*)(ws + OFF_V16);
  unsigned short* WN16 = (unsigned short*)(ws + OFF_WN16);
  unsigned short* WB16 = (unsigned short*)(ws + OFF_WB16);
  unsigned short* WNF16= (unsigned short*)(ws + OFF_WNF);
  unsigned short* ObB  = (unsigned short*)(ws + OFF_OB);
  unsigned short* Wpre = (unsigned short*)(ws + OFF_WPRE);
  float*          Fc   = (float*)(ws + OFF_FC);
  unsigned short* Lbuf = (unsigned short*)(ws + OFF_L);
  unsigned short* Sbuf = (unsigned short*)(ws + OFF_L);
  unsigned short* CT   = (unsigned short*)(ws + OFF_CT);
  unsigned short* Gbuf = (unsigned short*)(ws + OFF_G);

  dim3 blk(256);
  // weight transposes + x cast
  transpose_cast<<<dim3(16,16), blk, 0, stream>>>(Wq, WqT, 1024, 1024);
  transpose_cast<<<dim3(16,16), blk, 0, stream>>>(Wk, WkT, 1024, 1024);
  transpose_cast<<<dim3(16,16), blk, 0, stream>>>(Wv, WvT, 1024, 1024);
  transpose_cast<<<dim3(16,16), blk, 0, stream>>>(Wo, WoT, 1024, 1024);
  transpose_cast<<<dim3(1,16),  blk, 0, stream>>>(Ww1, W1T, 1024, 64);
  transpose_cast<<<dim3(16,1),  blk, 0, stream>>>(Ww2, W2T, 64, 1024);
  cast_bf16<<<1024, blk, 0, stream>>>(x, xb, 2048 * 1024);
  // projections (MFMA)
  gemm_nt<0><<<dim3(16,32), blk, 0, stream>>>(xb, WqT, Q16, 2048, 1024, 1024);
  gemm_nt<0><<<dim3(16,32), blk, 0, stream>>>(xb, WkT, K16, 2048, 1024, 1024);
  gemm_nt<0><<<dim3(16,32), blk, 0, stream>>>(xb, WvT, V16, 2048, 1024, 1024);
  gemm_nt<0><<<dim3(1,32),  blk, 0, stream>>>(xb, W1T, Wpre, 2048, 64, 1024);
  gemm_nt<0><<<dim3(16,32), blk, 0, stream>>>(Wpre, W2T, WNF16, 2048, 1024, 64);
  // beta / log_f (fp32, tiny) -- overwrite W1T/W2T region AFTER they are consumed
  gemm_f32<<<dim3(1,32), blk, 0, stream>>>(x, Wb, Beta, 2048, 16, 1024);
  gemm_f32<<<dim3(1,32), blk, 0, stream>>>(x, Wf, Lf, 2048, 16, 1024);
  bg_kernel<<<128, blk, 0, stream>>>(Beta, Lf, delta);
  fc_kernel<<<32, blk, 0, stream>>>(Lf, Fc);
  wnorm2<<<2048, blk, 0, stream>>>(WNF16, Beta, WN16, WB16);
  vtrans<<<dim3(16,32), blk, 0, stream>>>(V16, VT);
  // L and G
  pair_nt<1><<<dim3(16,16,32), blk, 0, stream>>>(WN16, WB16, Lbuf);
  pair_nt<0><<<dim3(16,16,32), blk, 0, stream>>>(Q16, WB16, Gbuf);
  // blocked triangular solve -> CT (transposed store)
  for (int ib = 0; ib < 16; ++ib)
    solve_step<<<dim3(ib + 1, 32), blk, 0, stream>>>(WN16, K16, Lbuf, CT, ib);
  // S = QK^T - G C   (reuses L region)
  score_mfma<<<dim3(16,16,32), blk, 0, stream>>>(Q16, K16, Gbuf, CT, Sbuf);
  // softmax + PV
  softpv<<<dim3(16,32), blk, 0, stream>>>(Sbuf, VT, Fc, ObB);
  // output projection (f32 out)
  gemm_nt<1><<<dim3(16,32), blk, 0, stream>>>(ObB, WoT, d_out, 2048, 1024, 1024);
}

// Round 3
// 776.926 us; speedup vs baseline: 5.2487x; 1.7479x over previous
//
#include <hip/hip_runtime.h>
#include <hip/hip_bf16.h>

#define DEV static __device__ __forceinline__

constexpr float SM_SCALE = 0.125f;   // hd^-0.5, hd=64

typedef __attribute__((ext_vector_type(8))) short s16x8;
typedef __attribute__((ext_vector_type(8))) unsigned short u16x8;
typedef __attribute__((ext_vector_type(4))) float f32x4;

DEV float bf2f(unsigned short u) {
  union { unsigned int i; float f; } v; v.i = ((unsigned int)u) << 16; return v.f;
}
DEV unsigned short f2bf(float f) {
  union { float f; unsigned int i; } v; v.f = f;
  unsigned int r = v.i + 0x7fffu + ((v.i >> 16) & 1u);
  return (unsigned short)(r >> 16);
}

// ---------- workspace layout (bytes) ----------
constexpr size_t OFF_XB   = 0;                       // 4MB xb bf16 [2048][1024]
constexpr size_t OFF_WQT  = 4194304;                 // 2MB; reused as BL (f32 2048x64) after Q proj
constexpr size_t OFF_BL   = 4194304;
constexpr size_t OFF_WKT  = 6291456;                 // 2MB; reused as BFT (bf16 64x1024) after K proj
constexpr size_t OFF_BFT  = 6291456;
constexpr size_t OFF_WVT  = 8388608;
constexpr size_t OFF_WOT  = 10485760;
constexpr size_t OFF_W1T  = 12582912;                // 128KB (reused as Beta f32)
constexpr size_t OFF_W2T  = 12713984;                // 128KB (reused as Lf f32)
constexpr size_t OFF_Q16  = 12845056;                // 4MB bf16 2048x1024
constexpr size_t OFF_K16  = 17039360;                // 4MB
constexpr size_t OFF_VT   = 21233664;                // 4MB  VT[b][64h*d][1024n]
constexpr size_t OFF_WN16 = 25427968;                // 4MB
constexpr size_t OFF_WB16 = 29622272;                // 4MB
constexpr size_t OFF_WNF  = 33816576;                // 4MB (reused as Ob)
constexpr size_t OFF_OB   = 33816576;
constexpr size_t OFF_WPRE = 38010880;                // 256KB
constexpr size_t OFF_FC   = 38273024;                // 128KB
constexpr size_t OFF_L    = 38404096;                // 64MB (reused as S)
constexpr size_t OFF_CT   = 105512960;               // 64MB
constexpr size_t OFF_G    = 172621824;               // 64MB  -> end 239,730,688

// ================= elementwise / prep =================
__global__ __launch_bounds__(256) void bg_kernel2(const float* __restrict__ BL,
    float* __restrict__ beta, float* __restrict__ lf, const float* __restrict__ delta) {
  int idx = blockIdx.x * 256 + threadIdx.x;
  if (idx >= 2048 * 16) return;
  int row = idx >> 4, hh = idx & 15;
  float braw = BL[row * 64 + hh];
  float lraw = BL[row * 64 + 16 + hh] + delta[hh];
  beta[idx] = 2.f / (1.f + __expf(-braw));
  lf[idx] = (lraw >= 0.f) ? -log1pf(__expf(-lraw)) : (lraw - log1pf(__expf(lraw)));
}

__global__ __launch_bounds__(256) void fc_kernel(const float* __restrict__ lf,
                                                 float* __restrict__ Fc) {
  int bh = blockIdx.x;
  int b = bh >> 4, h = bh & 15;
  int t = threadIdx.x;
  __shared__ float buf[1024];
  __shared__ float tsum[256];
#pragma unroll
  for (int i = 0; i < 4; ++i) {
    int tt = t + i * 256;
    buf[tt] = lf[((size_t)((b << 10) + tt) << 4) + h];
  }
  __syncthreads();
  float loc[4]; float run = 0.f;
#pragma unroll
  for (int i = 0; i < 4; ++i) { run += buf[t * 4 + i]; loc[i] = run; }
  tsum[t] = run;
  __syncthreads();
  for (int off = 1; off < 256; off <<= 1) {
    float add = (t >= off) ? tsum[t - off] : 0.f;
    __syncthreads();
    tsum[t] += add;
    __syncthreads();
  }
  float excl = tsum[t] - run;
#pragma unroll
  for (int i = 0; i < 4; ++i) Fc[bh * 1024 + t * 4 + i] = excl + loc[i];
}

__global__ __launch_bounds__(256) void cast_bf16(const float* __restrict__ src,
    unsigned short* __restrict__ dst, int n) {
  int i = (blockIdx.x * 256 + threadIdx.x) * 8;
  if (i >= n) return;
  float4 a = *(const float4*)(src + i);
  float4 b = *(const float4*)(src + i + 4);
  u16x8 o;
  o[0] = f2bf(a.x); o[1] = f2bf(a.y); o[2] = f2bf(a.z); o[3] = f2bf(a.w);
  o[4] = f2bf(b.x); o[5] = f2bf(b.y); o[6] = f2bf(b.z); o[7] = f2bf(b.w);
  *(u16x8*)(dst + i) = o;
}

// dst[c][r] = bf16(src[r][c]);  grid (C/64, R/64)
__global__ __launch_bounds__(256) void transpose_cast(const float* __restrict__ src,
    unsigned short* __restrict__ dst, int R, int C) {
  __shared__ float tile[64 * 65];
  int c0 = blockIdx.x * 64, r0 = blockIdx.y * 64;
  int t = threadIdx.x;
#pragma unroll
  for (int i = 0; i < 16; ++i) {
    int lin = t + i * 256; int r = lin >> 6, c = lin & 63;
    tile[r * 65 + c] = src[(size_t)(r0 + r) * C + c0 + c];
  }
  __syncthreads();
#pragma unroll
  for (int i = 0; i < 16; ++i) {
    int lin = t + i * 256; int c = lin >> 6, r = lin & 63;
    dst[(size_t)(c0 + c) * R + r0 + r] = f2bf(tile[r * 65 + c]);
  }
}

// src [1024][16] f32 -> dst rows [ofs..ofs+15] of [64][1024] bf16 (transposed)
__global__ __launch_bounds__(256) void padT16(const float* __restrict__ src,
    unsigned short* __restrict__ dst, int ofs) {
  int idx = blockIdx.x * 256 + threadIdx.x;   // 16384
  int i = idx >> 4, j = idx & 15;
  dst[((size_t)(ofs + j) << 10) + i] = f2bf(src[idx]);
}

__global__ __launch_bounds__(256) void zero_u16(unsigned short* __restrict__ dst, int n) {
  int i = blockIdx.x * 256 + threadIdx.x;
  if (i < n) dst[i] = 0;
}

// zero the never-solved CT blocks (j-slab 2m+1, s-block 2m)
__global__ __launch_bounds__(256) void zeroCT(unsigned short* __restrict__ CT) {
  int m = blockIdx.x, bh = blockIdx.y;
  int t = threadIdx.x;
  size_t base = (size_t)bh << 20;
  int j0 = (2 * m + 1) * 64, s0 = 2 * m * 64;
#pragma unroll
  for (int i = 0; i < 16; ++i) {
    int lin = t + i * 256; int jl = lin >> 6, sl = lin & 63;
    CT[base + ((size_t)(j0 + jl) << 10) + s0 + sl] = 0;
  }
}

// ================= 64-tile bf16 NT GEMM (narrow N=64 cases) =================
template<int F32OUT>
__global__ __launch_bounds__(256) void gemm_nt(const unsigned short* __restrict__ A,
    const unsigned short* __restrict__ BT, void* __restrict__ out,
    int M, int N, int K) {
  __shared__ unsigned short As[64 * 64];
  __shared__ unsigned short Bs[64 * 64];
  int m0 = blockIdx.y * 64, n0 = blockIdx.x * 64;
  int t = threadIdx.x;
  int w = t >> 6, l = t & 63, fr = l & 15;
  int koB = (l >> 4) * 16;
  f32x4 acc[4];
#pragma unroll
  for (int c = 0; c < 4; ++c) acc[c] = (f32x4){0.f, 0.f, 0.f, 0.f};
  for (int k0 = 0; k0 < K; k0 += 64) {
    __syncthreads();
#pragma unroll
    for (int i = 0; i < 2; ++i) {
      int cid = t + i * 256;
      int row = cid >> 3, ch = cid & 7;
      int byt = ((row << 7) + (ch << 4)) ^ ((row & 7) << 4);
      *(u16x8*)((char*)As + byt) = *(const u16x8*)(A + (size_t)(m0 + row) * K + k0 + ch * 8);
      *(u16x8*)((char*)Bs + byt) = *(const u16x8*)(BT + (size_t)(n0 + row) * K + k0 + ch * 8);
    }
    __syncthreads();
#pragma unroll
    for (int kh = 0; kh < 2; ++kh) {
      int ra = 16 * w + fr;
      s16x8 a = *(const s16x8*)((char*)As + (((ra << 7) + (kh << 6) + koB) ^ ((ra & 7) << 4)));
#pragma unroll
      for (int c = 0; c < 4; ++c) {
        int rb = 16 * c + fr;
        s16x8 bb = *(const s16x8*)((char*)Bs + (((rb << 7) + (kh << 6) + koB) ^ ((rb & 7) << 4)));
        acc[c] = __builtin_amdgcn_mfma_f32_16x16x32_bf16(a, bb, acc[c], 0, 0, 0);
      }
    }
  }
  int rbase = m0 + 16 * w + ((l >> 4) << 2);
#pragma unroll
  for (int c = 0; c < 4; ++c) {
    int col = n0 + 16 * c + fr;
#pragma unroll
    for (int r = 0; r < 4; ++r) {
      if (F32OUT) ((float*)out)[(size_t)(rbase + r) * N + col] = acc[c][r];
      else ((unsigned short*)out)[(size_t)(rbase + r) * N + col] = f2bf(acc[c][r]);
    }
  }
}

// ================= 128-tile bf16 NT GEMM: out = A(MxK) @ BT(NxK)^T =================
template<int F32OUT>
__global__ __launch_bounds__(256) void gemm_nt128(const unsigned short* __restrict__ A,
    const unsigned short* __restrict__ BT, void* __restrict__ out,
    int M, int N, int K) {
  __shared__ unsigned short As[128 * 64];
  __shared__ unsigned short Bs[128 * 64];
  int m0 = blockIdx.y * 128, n0 = blockIdx.x * 128;
  int t = threadIdx.x;
  int w = t >> 6, l = t & 63;
  int wr = w >> 1, wc = w & 1;
  int fr = l & 15, fq = l >> 4;
  f32x4 acc[4][4];
#pragma unroll
  for (int m = 0; m < 4; ++m)
#pragma unroll
    for (int c = 0; c < 4; ++c) acc[m][c] = (f32x4){0.f, 0.f, 0.f, 0.f};
  for (int k0 = 0; k0 < K; k0 += 64) {
    __syncthreads();
#pragma unroll
    for (int i = 0; i < 4; ++i) {
      int cid = t + i * 256;
      int row = cid >> 3, ch = cid & 7;
      int byt = ((row << 7) + (ch << 4)) ^ ((row & 7) << 4);
      *(u16x8*)((char*)As + byt) = *(const u16x8*)(A + (size_t)(m0 + row) * K + k0 + ch * 8);
      *(u16x8*)((char*)Bs + byt) = *(const u16x8*)(BT + (size_t)(n0 + row) * K + k0 + ch * 8);
    }
    __syncthreads();
#pragma unroll
    for (int kh = 0; kh < 2; ++kh) {
      s16x8 af[4], bfv[4];
#pragma unroll
      for (int m = 0; m < 4; ++m) {
        int ra = wr * 64 + 16 * m + fr;
        af[m] = *(const s16x8*)((char*)As + (((ra << 7) + (kh << 6) + (fq << 4)) ^ ((ra & 7) << 4)));
      }
#pragma unroll
      for (int c = 0; c < 4; ++c) {
        int rb = wc * 64 + 16 * c + fr;
        bfv[c] = *(const s16x8*)((char*)Bs + (((rb << 7) + (kh << 6) + (fq << 4)) ^ ((rb & 7) << 4)));
      }
#pragma unroll
      for (int m = 0; m < 4; ++m)
#pragma unroll
        for (int c = 0; c < 4; ++c)
          acc[m][c] = __builtin_amdgcn_mfma_f32_16x16x32_bf16(af[m], bfv[c], acc[m][c], 0, 0, 0);
    }
  }
#pragma unroll
  for (int m = 0; m < 4; ++m) {
#pragma unroll
    for (int c = 0; c < 4; ++c) {
      int col = n0 + wc * 64 + 16 * c + fr;
#pragma unroll
      for (int r = 0; r < 4; ++r) {
        int grow = m0 + wr * 64 + 16 * m + fq * 4 + r;
        if (F32OUT) ((float*)out)[(size_t)grow * N + col] = acc[m][c][r];
        else ((unsigned short*)out)[(size_t)grow * N + col] = f2bf(acc[m][c][r]);
      }
    }
  }
}

// ================= pair (L/G): dst[bh][i][j] = mask * (A_i . Bbeta_j), 128-tile =================
template<int STRICT>
__global__ __launch_bounds__(256) void pair128(const unsigned short* __restrict__ Ar,
    const unsigned short* __restrict__ Br, unsigned short* __restrict__ dst) {
  int jb2 = blockIdx.x, tb2 = blockIdx.y, bh = blockIdx.z;
  if (jb2 > tb2) return;
  int b = bh >> 4, h = bh & 15;
  int m0 = tb2 * 128, n0 = jb2 * 128;
  int t = threadIdx.x;
  int w = t >> 6, l = t & 63;
  int wr = w >> 1, wc = w & 1;
  int fr = l & 15, fq = l >> 4;
  __shared__ unsigned short As[128 * 64];
  __shared__ unsigned short Bs[128 * 64];
  const unsigned short* Ab = Ar + ((size_t)b << 20) + h * 64;
  const unsigned short* Bb = Br + ((size_t)b << 20) + h * 64;
  f32x4 acc[4][4];
#pragma unroll
  for (int m = 0; m < 4; ++m)
#pragma unroll
    for (int c = 0; c < 4; ++c) acc[m][c] = (f32x4){0.f, 0.f, 0.f, 0.f};
#pragma unroll
  for (int i = 0; i < 4; ++i) {
    int cid = t + i * 256;
    int row = cid >> 3, ch = cid & 7;
    int byt = ((row << 7) + (ch << 4)) ^ ((row & 7) << 4);
    *(u16x8*)((char*)As + byt) = *(const u16x8*)(Ab + ((size_t)(m0 + row) << 10) + ch * 8);
    *(u16x8*)((char*)Bs + byt) = *(const u16x8*)(Bb + ((size_t)(n0 + row) << 10) + ch * 8);
  }
  __syncthreads();
#pragma unroll
  for (int kh = 0; kh < 2; ++kh) {
    s16x8 af[4], bfv[4];
#pragma unroll
    for (int m = 0; m < 4; ++m) {
      int ra = wr * 64 + 16 * m + fr;
      af[m] = *(const s16x8*)((char*)As + (((ra << 7) + (kh << 6) + (fq << 4)) ^ ((ra & 7) << 4)));
    }
#pragma unroll
    for (int c = 0; c < 4; ++c) {
      int rb = wc * 64 + 16 * c + fr;
      bfv[c] = *(const s16x8*)((char*)Bs + (((rb << 7) + (kh << 6) + (fq << 4)) ^ ((rb & 7) << 4)));
    }
#pragma unroll
    for (int m = 0; m < 4; ++m)
#pragma unroll
      for (int c = 0; c < 4; ++c)
        acc[m][c] = __builtin_amdgcn_mfma_f32_16x16x32_bf16(af[m], bfv[c], acc[m][c], 0, 0, 0);
  }
  size_t base = (size_t)bh << 20;
#pragma unroll
  for (int m = 0; m < 4; ++m) {
#pragma unroll
    for (int c = 0; c < 4; ++c) {
      int gj = n0 + wc * 64 + 16 * c + fr;
#pragma unroll
      for (int r = 0; r < 4; ++r) {
        int gi = m0 + wr * 64 + 16 * m + fq * 4 + r;
        bool keep = STRICT ? (gj < gi) : (gj <= gi);
        dst[base + ((size_t)gi << 10) + gj] = f2bf(keep ? acc[m][c][r] : 0.f);
      }
    }
  }
}

// ================= score: S = Q K^T - G @ C, 128-tile band GEMM =================
__global__ __launch_bounds__(256) void score128(const unsigned short* __restrict__ Q,
    const unsigned short* __restrict__ Kk, const unsigned short* __restrict__ G,
    const unsigned short* __restrict__ CT, unsigned short* __restrict__ Sg) {
  int jb2 = blockIdx.x, tb2 = blockIdx.y, bh = blockIdx.z;
  if (jb2 > tb2) return;
  int b = bh >> 4, h = bh & 15;
  int m0 = tb2 * 128, n0 = jb2 * 128;
  int t = threadIdx.x;
  int w = t >> 6, l = t & 63;
  int wr = w >> 1, wc = w & 1;
  int fr = l & 15, fq = l >> 4;
  __shared__ unsigned short As[128 * 64];
  __shared__ unsigned short Bs[128 * 64];
  size_t base = (size_t)bh << 20;
  const unsigned short* Qb_ = Q + ((size_t)b << 20) + h * 64;
  const unsigned short* Kb_ = Kk + ((size_t)b << 20) + h * 64;
  const unsigned short* Gb_ = G + base;
  const unsigned short* Cb_ = CT + base;
  int kbase = jb2 * 128;
  int nsteps = 1 + (tb2 - jb2 + 1) * 2;
  f32x4 acc[4][4];
#pragma unroll
  for (int m = 0; m < 4; ++m)
#pragma unroll
    for (int c = 0; c < 4; ++c) acc[m][c] = (f32x4){0.f, 0.f, 0.f, 0.f};
  for (int step = 0; step < nsteps; ++step) {
    const unsigned short* pa; const unsigned short* pb; int koff; bool neg;
    if (step == 0) { pa = Qb_; pb = Kb_; koff = 0; neg = false; }
    else { pa = Gb_; pb = Cb_; koff = kbase + (step - 1) * 64; neg = true; }
    __syncthreads();
#pragma unroll
    for (int i = 0; i < 4; ++i) {
      int cid = t + i * 256;
      int row = cid >> 3, ch = cid & 7;
      int byt = ((row << 7) + (ch << 4)) ^ ((row & 7) << 4);
      u16x8 av = *(const u16x8*)(pa + ((size_t)(m0 + row) << 10) + koff + ch * 8);
      if (neg) av ^= (unsigned short)0x8000;
      *(u16x8*)((char*)As + byt) = av;
      *(u16x8*)((char*)Bs + byt) = *(const u16x8*)(pb + ((size_t)(n0 + row) << 10) + koff + ch * 8);
    }
    __syncthreads();
#pragma unroll
    for (int kh = 0; kh < 2; ++kh) {
      s16x8 af[4], bfv[4];
#pragma unroll
      for (int m = 0; m < 4; ++m) {
        int ra = wr * 64 + 16 * m + fr;
        af[m] = *(const s16x8*)((char*)As + (((ra << 7) + (kh << 6) + (fq << 4)) ^ ((ra & 7) << 4)));
      }
#pragma unroll
      for (int c = 0; c < 4; ++c) {
        int rb = wc * 64 + 16 * c + fr;
        bfv[c] = *(const s16x8*)((char*)Bs + (((rb << 7) + (kh << 6) + (fq << 4)) ^ ((rb & 7) << 4)));
      }
#pragma unroll
      for (int m = 0; m < 4; ++m)
#pragma unroll
        for (int c = 0; c < 4; ++c)
          acc[m][c] = __builtin_amdgcn_mfma_f32_16x16x32_bf16(af[m], bfv[c], acc[m][c], 0, 0, 0);
    }
  }
#pragma unroll
  for (int m = 0; m < 4; ++m) {
#pragma unroll
    for (int c = 0; c < 4; ++c) {
      int gj = n0 + wc * 64 + 16 * c + fr;
#pragma unroll
      for (int r = 0; r < 4; ++r) {
        int gi = m0 + wr * 64 + 16 * m + fq * 4 + r;
        Sg[base + ((size_t)gi << 10) + gj] = f2bf(acc[m][c][r]);
      }
    }
  }
}

// ================= w normalize + beta-scale =================
__global__ __launch_bounds__(256) void wnorm2(const unsigned short* __restrict__ WNF,
    const float* __restrict__ Beta, unsigned short* __restrict__ WN,
    unsigned short* __restrict__ WB) {
  int row = blockIdx.x;
  int wave = threadIdx.x >> 6, lane = threadIdx.x & 63;
#pragma unroll
  for (int i = 0; i < 4; ++i) {
    int hh = wave * 4 + i;
    size_t idx = ((size_t)row << 10) + hh * 64 + lane;
    float v = bf2f(WNF[idx]);
    float ss = v * v;
#pragma unroll
    for (int off = 1; off < 64; off <<= 1) ss += __shfl_xor(ss, off);
    float wn = v * rsqrtf(ss + 1e-6f);
    WN[idx] = f2bf(wn);
    WB[idx] = f2bf(wn * Beta[row * 16 + hh]);
  }
}

// ================= solve step ib: rect = W K^T - L C, then in-block substitution =================
__global__ __launch_bounds__(256) void solve_step(const unsigned short* __restrict__ WN,
    const unsigned short* __restrict__ Kk, const unsigned short* __restrict__ Lb,
    unsigned short* __restrict__ CT, int ib) {
  int jb = blockIdx.x, bh = blockIdx.y;
  int b = bh >> 4, h = bh & 15;
  int t = threadIdx.x, w = t >> 6, l = t & 63, fr = l & 15;
  int ko = (l >> 4) * 8;
  size_t base = (size_t)bh << 20;
  int s0 = ib * 64, j0 = jb * 64;
  __shared__ float rect[64 * 68];
  __shared__ float LD[64 * 65];
  const unsigned short* Wb_ = WN + ((size_t)b << 20) + h * 64;
  const unsigned short* Kb_ = Kk + ((size_t)b << 20) + h * 64;
  int ar = s0 + 16 * w + fr;
  f32x4 am[4], al[4];
#pragma unroll
  for (int c = 0; c < 4; ++c) { am[c] = (f32x4){0.f,0.f,0.f,0.f}; al[c] = (f32x4){0.f,0.f,0.f,0.f}; }
#pragma unroll
  for (int kh = 0; kh < 2; ++kh) {
    s16x8 a = *(const s16x8*)(Wb_ + ((size_t)ar << 10) + kh * 32 + ko);
#pragma unroll
    for (int c = 0; c < 4; ++c) {
      s16x8 bb = *(const s16x8*)(Kb_ + ((size_t)(j0 + 16 * c + fr) << 10) + kh * 32 + ko);
      am[c] = __builtin_amdgcn_mfma_f32_16x16x32_bf16(a, bb, am[c], 0, 0, 0);
    }
  }
  for (int rb = jb; rb < ib; ++rb) {
#pragma unroll
    for (int kh = 0; kh < 2; ++kh) {
      s16x8 a = *(const s16x8*)(Lb + base + ((size_t)ar << 10) + rb * 64 + kh * 32 + ko);
#pragma unroll
      for (int c = 0; c < 4; ++c) {
        s16x8 bb = *(const s16x8*)(CT + base + ((size_t)(j0 + 16 * c + fr) << 10) + rb * 64 + kh * 32 + ko);
        al[c] = __builtin_amdgcn_mfma_f32_16x16x32_bf16(a, bb, al[c], 0, 0, 0);
      }
    }
  }
#pragma unroll
  for (int i = 0; i < 16; ++i) {
    int lin = t + i * 256; int s = lin >> 6, r = lin & 63;
    LD[s * 65 + r] = bf2f(Lb[base + ((size_t)(s0 + s) << 10) + s0 + r]);
  }
#pragma unroll
  for (int c = 0; c < 4; ++c) {
#pragma unroll
    for (int r = 0; r < 4; ++r) {
      int jl = 16 * c + fr, sl = 16 * w + ((l >> 4) << 2) + r;
      rect[jl * 68 + sl] = am[c][r] - al[c][r];
    }
  }
  __syncthreads();
  if (w == 0) {
    float cc[64];
#pragma unroll
    for (int s = 0; s < 64; ++s) cc[s] = rect[l * 68 + s];
    if (jb == ib) {
#pragma unroll
      for (int s = 0; s < 64; ++s) if (s <= l) cc[s] = 0.f;
    }
#pragma unroll
    for (int r = 0; r < 63; ++r) {
      float val = cc[r];
#pragma unroll
      for (int s = r + 1; s < 64; ++s) cc[s] -= LD[s * 65 + r] * val;
    }
#pragma unroll
    for (int s = 0; s < 64; ++s) rect[l * 68 + s] = cc[s];
  }
  __syncthreads();
#pragma unroll
  for (int i = 0; i < 16; ++i) {
    int lin = t + i * 256; int jl = lin >> 6, sl = lin & 63;
    CT[base + ((size_t)(j0 + jl) << 10) + s0 + sl] = f2bf(rect[jl * 68 + sl]);
  }
}

// ================= softmax (decay + causal) + P@V via MFMA =================
__global__ __launch_bounds__(256) void softpv(const unsigned short* __restrict__ S,
    const unsigned short* __restrict__ VT, const float* __restrict__ Fc,
    unsigned short* __restrict__ Ob) {
  int tb = blockIdx.x, bh = blockIdx.y;
  int b = bh >> 4, h = bh & 15;
  int t0 = tb * 64;
  int t = threadIdx.x, w = t >> 6, l = t & 63, fr = l & 15;
  int koB = (l >> 4) * 16;
  __shared__ unsigned short Pl[64 * 64];
  __shared__ float fcj[64], smax[4][64], ssum[4][64];
  __shared__ float mrow[64], lrow[64], crow[64], fct[64];
  if (t < 64) { mrow[t] = -1e30f; lrow[t] = 0.f; fct[t] = Fc[bh * 1024 + t0 + t]; }
  f32x4 accO[4];
#pragma unroll
  for (int c = 0; c < 4; ++c) accO[c] = (f32x4){0.f,0.f,0.f,0.f};
  size_t base = (size_t)bh << 20;
  int row = t & 63, cg = t >> 6;
  for (int jb = 0; jb <= tb; ++jb) {
    int j0 = jb * 64;
    if (t < 64) fcj[t] = Fc[bh * 1024 + j0 + t];
    __syncthreads();
    float lg[16];
    const unsigned short* srow = S + base + ((size_t)(t0 + row) << 10) + j0 + cg * 16;
    u16x8 sv0 = *(const u16x8*)(srow);
    u16x8 sv1 = *(const u16x8*)(srow + 8);
    float pm = -1e30f;
#pragma unroll
    for (int c = 0; c < 16; ++c) {
      float sv = bf2f(c < 8 ? sv0[c] : sv1[c - 8]);
      float v = sv * SM_SCALE + fct[row] - fcj[cg * 16 + c];
      if (jb == tb && cg * 16 + c > row) v = -1e30f;
      lg[c] = v; pm = fmaxf(pm, v);
    }
    smax[cg][row] = pm;
    __syncthreads();
    if (t < 64) {
      float m4 = fmaxf(fmaxf(smax[0][t], smax[1][t]), fmaxf(smax[2][t], smax[3][t]));
      float mn = fmaxf(mrow[t], m4);
      crow[t] = __expf(mrow[t] - mn);
      mrow[t] = mn;
    }
    __syncthreads();
    float mn = mrow[row];
    float ps = 0.f;
#pragma unroll
    for (int cp = 0; cp < 8; ++cp) {
      float p0 = __expf(lg[2 * cp] - mn), p1 = __expf(lg[2 * cp + 1] - mn);
      ps += p0 + p1;
      unsigned int packed = (unsigned)f2bf(p0) | ((unsigned)f2bf(p1) << 16);
      int byt = ((row << 7) + (cg << 5) + (cp << 2)) ^ ((row & 7) << 4);
      *(unsigned int*)((char*)Pl + byt) = packed;
    }
    ssum[cg][row] = ps;
    __syncthreads();
    if (t < 64) lrow[t] = lrow[t] * crow[t] + ssum[0][t] + ssum[1][t] + ssum[2][t] + ssum[3][t];
    int ra = 16 * w + fr;
    float cr[4];
#pragma unroll
    for (int r = 0; r < 4; ++r) cr[r] = crow[16 * w + ((l >> 4) << 2) + r];
#pragma unroll
    for (int c = 0; c < 4; ++c)
#pragma unroll
      for (int r = 0; r < 4; ++r) accO[c][r] *= cr[r];
#pragma unroll
    for (int kh = 0; kh < 2; ++kh) {
      s16x8 a = *(const s16x8*)((char*)Pl + (((ra << 7) + (kh << 6) + koB) ^ ((ra & 7) << 4)));
#pragma unroll
      for (int c = 0; c < 4; ++c) {
        const unsigned short* vrow = VT + ((size_t)bh * 64 + 16 * c + fr) * 1024 + j0 + kh * 32 + (l >> 4) * 8;
        s16x8 bb = *(const s16x8*)vrow;
        accO[c] = __builtin_amdgcn_mfma_f32_16x16x32_bf16(a, bb, accO[c], 0, 0, 0);
      }
    }
    __syncthreads();
  }
  float inv[4];
#pragma unroll
  for (int r = 0; r < 4; ++r) inv[r] = 1.f / lrow[16 * w + ((l >> 4) << 2) + r];
#pragma unroll
  for (int c = 0; c < 4; ++c) {
#pragma unroll
    for (int r = 0; r < 4; ++r) {
      int grow = t0 + 16 * w + ((l >> 4) << 2) + r;
      Ob[((size_t)(b * 1024) + grow) * 1024 + h * 64 + 16 * c + fr] = f2bf(accO[c][r] * inv[r]);
    }
  }
}

extern "C" void kernel_launch(void* const* d_in, const int* in_sizes, int n_in,
                              void* d_out, int out_size, void* d_ws, size_t ws_size,
                              hipStream_t stream) {
  const float* x    = (const float*)d_in[0];
  const float* Wq   = (const float*)d_in[1];
  const float* Wk   = (const float*)d_in[2];
  const float* Wv   = (const float*)d_in[3];
  const float* Wo   = (const float*)d_in[4];
  const float* Ww1  = (const float*)d_in[5];
  const float* Ww2  = (const float*)d_in[6];
  const float* Wb   = (const float*)d_in[7];
  const float* Wf   = (const float*)d_in[8];
  const float* delta= (const float*)d_in[9];

  char* ws = (char*)d_ws;
  unsigned short* xb   = (unsigned short*)(ws + OFF_XB);
  unsigned short* WqT  = (unsigned short*)(ws + OFF_WQT);
  float*          BL   = (float*)(ws + OFF_BL);
  unsigned short* WkT  = (unsigned short*)(ws + OFF_WKT);
  unsigned short* BFT  = (unsigned short*)(ws + OFF_BFT);
  unsigned short* WvT  = (unsigned short*)(ws + OFF_WVT);
  unsigned short* WoT  = (unsigned short*)(ws + OFF_WOT);
  unsigned short* W1T  = (unsigned short*)(ws + OFF_W1T);
  unsigned short* W2T  = (unsigned short*)(ws + OFF_W2T);
  float*          Beta = (float*)(ws + OFF_W1T);
  float*          Lf   = (float*)(ws + OFF_W2T);
  unsigned short* Q16  = (unsigned short*)(ws + OFF_Q16);
  unsigned short* K16  = (unsigned short*)(ws + OFF_K16);
  unsigned short* VT   = (unsigned short*)(ws + OFF_VT);
  unsigned short* WN16 = (unsigned short*)(ws + OFF_WN16);
  unsigned short* WB16 = (unsigned short*)(ws + OFF_WB16);
  unsigned short* WNF16= (unsigned short*)(ws + OFF_WNF);
  unsigned short* ObB  = (unsigned short*)(ws + OFF_OB);
  unsigned short* Wpre = (unsigned short*)(ws + OFF_WPRE);
  float*          Fc   = (float*)(ws + OFF_FC);
  unsigned short* Lbuf = (unsigned short*)(ws + OFF_L);
  unsigned short* Sbuf = (unsigned short*)(ws + OFF_L);
  unsigned short* CT   = (unsigned short*)(ws + OFF_CT);
  unsigned short* Gbuf = (unsigned short*)(ws + OFF_G);

  dim3 blk(256);
  // weight transposes + x cast
  transpose_cast<<<dim3(16,16), blk, 0, stream>>>(Wq, WqT, 1024, 1024);
  transpose_cast<<<dim3(16,16), blk, 0, stream>>>(Wk, WkT, 1024, 1024);
  transpose_cast<<<dim3(16,16), blk, 0, stream>>>(Wv, WvT, 1024, 1024);
  transpose_cast<<<dim3(16,16), blk, 0, stream>>>(Wo, WoT, 1024, 1024);
  transpose_cast<<<dim3(1,16),  blk, 0, stream>>>(Ww1, W1T, 1024, 64);
  transpose_cast<<<dim3(16,1),  blk, 0, stream>>>(Ww2, W2T, 64, 1024);
  cast_bf16<<<1024, blk, 0, stream>>>(x, xb, 2048 * 1024);
  // projections (MFMA) -- Q and K consume WqT/WkT before those regions are reused
  gemm_nt128<0><<<dim3(8,16), blk, 0, stream>>>(xb, WqT, Q16, 2048, 1024, 1024);
  gemm_nt128<0><<<dim3(8,16), blk, 0, stream>>>(xb, WkT, K16, 2048, 1024, 1024);
  // V directly transposed: VT[b] = WvT @ xb[b]^T
  gemm_nt128<0><<<dim3(8,8), blk, 0, stream>>>(WvT, xb, VT, 1024, 1024, 1024);
  gemm_nt128<0><<<dim3(8,8), blk, 0, stream>>>(WvT, xb + (size_t)1024*1024, VT + (size_t)1024*1024, 1024, 1024, 1024);
  gemm_nt<0><<<dim3(1,32), blk, 0, stream>>>(xb, W1T, Wpre, 2048, 64, 1024);
  gemm_nt128<0><<<dim3(8,16), blk, 0, stream>>>(Wpre, W2T, WNF16, 2048, 1024, 64);
  // beta / log_f via MFMA: BFT = [Wb^T ; Wf^T ; 0] (64x1024), BL = xb @ BFT^T (f32)
  padT16<<<64, blk, 0, stream>>>(Wb, BFT, 0);
  padT16<<<64, blk, 0, stream>>>(Wf, BFT, 16);
  zero_u16<<<128, blk, 0, stream>>>(BFT + 32 * 1024, 32 * 1024);
  gemm_nt<1><<<dim3(1,32), blk, 0, stream>>>(xb, BFT, BL, 2048, 64, 1024);
  bg_kernel2<<<128, blk, 0, stream>>>(BL, Beta, Lf, delta);
  fc_kernel<<<32, blk, 0, stream>>>(Lf, Fc);
  wnorm2<<<2048, blk, 0, stream>>>(WNF16, Beta, WN16, WB16);
  // L and G
  pair128<1><<<dim3(8,8,32), blk, 0, stream>>>(WN16, WB16, Lbuf);
  pair128<0><<<dim3(8,8,32), blk, 0, stream>>>(Q16, WB16, Gbuf);
  // zero never-written CT blocks, then blocked triangular solve -> CT
  zeroCT<<<dim3(16,32), blk, 0, stream>>>(CT);
  for (int ib = 0; ib < 16; ++ib)
    solve_step<<<dim3(ib + 1, 32), blk, 0, stream>>>(WN16, K16, Lbuf, CT, ib);
  // S = QK^T - G C (reuses L region)
  score128<<<dim3(8,8,32), blk, 0, stream>>>(Q16, K16, Gbuf, CT, Sbuf);
  // softmax + PV
  softpv<<<dim3(16,32), blk, 0, stream>>>(Sbuf, VT, Fc, ObB);
  // output projection (f32 out)
  gemm_nt128<1><<<dim3(8,16), blk, 0, stream>>>(ObB, WoT, d_out, 2048, 1024, 1024);
}

// Round 4
// 660.171 us; speedup vs baseline: 6.1770x; 1.1769x over previous
//
#include <hip/hip_runtime.h>
#include <hip/hip_bf16.h>

#define DEV static __device__ __forceinline__

constexpr float SM_SCALE = 0.125f;   // hd^-0.5, hd=64

typedef __attribute__((ext_vector_type(8))) short s16x8;
typedef __attribute__((ext_vector_type(8))) unsigned short u16x8;
typedef __attribute__((ext_vector_type(4))) float f32x4;

DEV float bf2f(unsigned short u) {
  union { unsigned int i; float f; } v; v.i = ((unsigned int)u) << 16; return v.f;
}
DEV unsigned short f2bf(float f) {
  union { float f; unsigned int i; } v; v.f = f;
  unsigned int r = v.i + 0x7fffu + ((v.i >> 16) & 1u);
  return (unsigned short)(r >> 16);
}

// ---------- workspace layout (bytes) ----------
constexpr size_t OFF_XB   = 0;                       // 4MB xb bf16 [2048][1024]
constexpr size_t OFF_WQT  = 4194304;                 // 2MB; reused as BL (f32 2048x64) after Q proj
constexpr size_t OFF_BL   = 4194304;
constexpr size_t OFF_WKT  = 6291456;                 // 2MB; reused as BFT (bf16 64x1024) after K proj
constexpr size_t OFF_BFT  = 6291456;
constexpr size_t OFF_WVT  = 8388608;
constexpr size_t OFF_WOT  = 10485760;
constexpr size_t OFF_W1T  = 12582912;                // 128KB (reused as Beta f32)
constexpr size_t OFF_W2T  = 12713984;                // 128KB (reused as Lf f32)
constexpr size_t OFF_Q16  = 12845056;                // 4MB bf16 2048x1024
constexpr size_t OFF_K16  = 17039360;                // 4MB
constexpr size_t OFF_VT   = 21233664;                // 4MB  VT[b][64h*d][1024n]
constexpr size_t OFF_WN16 = 25427968;                // 4MB
constexpr size_t OFF_WB16 = 29622272;                // 4MB
constexpr size_t OFF_WNF  = 33816576;                // 4MB (reused as Ob)
constexpr size_t OFF_OB   = 33816576;
constexpr size_t OFF_WPRE = 38010880;                // 256KB
constexpr size_t OFF_FC   = 38273024;                // 128KB
constexpr size_t OFF_L    = 38404096;                // 64MB (reused as S)
constexpr size_t OFF_CT   = 105512960;               // 64MB
constexpr size_t OFF_G    = 172621824;               // 64MB
constexpr size_t OFF_MR   = 239730688;               // 128KB f32 [32][1024]
constexpr size_t OFF_LR   = 239861760;               // 128KB
constexpr size_t OFF_UI   = 239992832;               // 4MB bf16 [32][16][64][64]  -> end 244,187,136

// ================= elementwise / prep =================
__global__ __launch_bounds__(256) void bg_kernel2(const float* __restrict__ BL,
    float* __restrict__ beta, float* __restrict__ lf, const float* __restrict__ delta) {
  int idx = blockIdx.x * 256 + threadIdx.x;
  if (idx >= 2048 * 16) return;
  int row = idx >> 4, hh = idx & 15;
  float braw = BL[row * 64 + hh];
  float lraw = BL[row * 64 + 16 + hh] + delta[hh];
  beta[idx] = 2.f / (1.f + __expf(-braw));
  lf[idx] = (lraw >= 0.f) ? -log1pf(__expf(-lraw)) : (lraw - log1pf(__expf(lraw)));
}

__global__ __launch_bounds__(256) void fc_kernel(const float* __restrict__ lf,
                                                 float* __restrict__ Fc) {
  int bh = blockIdx.x;
  int b = bh >> 4, h = bh & 15;
  int t = threadIdx.x;
  __shared__ float buf[1024];
  __shared__ float tsum[256];
#pragma unroll
  for (int i = 0; i < 4; ++i) {
    int tt = t + i * 256;
    buf[tt] = lf[((size_t)((b << 10) + tt) << 4) + h];
  }
  __syncthreads();
  float loc[4]; float run = 0.f;
#pragma unroll
  for (int i = 0; i < 4; ++i) { run += buf[t * 4 + i]; loc[i] = run; }
  tsum[t] = run;
  __syncthreads();
  for (int off = 1; off < 256; off <<= 1) {
    float add = (t >= off) ? tsum[t - off] : 0.f;
    __syncthreads();
    tsum[t] += add;
    __syncthreads();
  }
  float excl = tsum[t] - run;
#pragma unroll
  for (int i = 0; i < 4; ++i) Fc[bh * 1024 + t * 4 + i] = excl + loc[i];
}

__global__ __launch_bounds__(256) void cast_bf16(const float* __restrict__ src,
    unsigned short* __restrict__ dst, int n) {
  int i = (blockIdx.x * 256 + threadIdx.x) * 8;
  if (i >= n) return;
  float4 a = *(const float4*)(src + i);
  float4 b = *(const float4*)(src + i + 4);
  u16x8 o;
  o[0] = f2bf(a.x); o[1] = f2bf(a.y); o[2] = f2bf(a.z); o[3] = f2bf(a.w);
  o[4] = f2bf(b.x); o[5] = f2bf(b.y); o[6] = f2bf(b.z); o[7] = f2bf(b.w);
  *(u16x8*)(dst + i) = o;
}

// dst[c][r] = bf16(src[r][c]);  grid (C/64, R/64)
__global__ __launch_bounds__(256) void transpose_cast(const float* __restrict__ src,
    unsigned short* __restrict__ dst, int R, int C) {
  __shared__ float tile[64 * 65];
  int c0 = blockIdx.x * 64, r0 = blockIdx.y * 64;
  int t = threadIdx.x;
#pragma unroll
  for (int i = 0; i < 16; ++i) {
    int lin = t + i * 256; int r = lin >> 6, c = lin & 63;
    tile[r * 65 + c] = src[(size_t)(r0 + r) * C + c0 + c];
  }
  __syncthreads();
#pragma unroll
  for (int i = 0; i < 16; ++i) {
    int lin = t + i * 256; int c = lin >> 6, r = lin & 63;
    dst[(size_t)(c0 + c) * R + r0 + r] = f2bf(tile[r * 65 + c]);
  }
}

// fused 4x 1024x1024 weight transpose: grid (16,16,4)
__global__ __launch_bounds__(256) void transpose4(
    const float* __restrict__ W0, const float* __restrict__ W1,
    const float* __restrict__ W2, const float* __restrict__ W3,
    unsigned short* __restrict__ D0, unsigned short* __restrict__ D1,
    unsigned short* __restrict__ D2, unsigned short* __restrict__ D3) {
  int z = blockIdx.z;
  const float* src = z == 0 ? W0 : z == 1 ? W1 : z == 2 ? W2 : W3;
  unsigned short* dst = z == 0 ? D0 : z == 1 ? D1 : z == 2 ? D2 : D3;
  __shared__ float tile[64 * 65];
  int c0 = blockIdx.x * 64, r0 = blockIdx.y * 64;
  int t = threadIdx.x;
#pragma unroll
  for (int i = 0; i < 16; ++i) {
    int lin = t + i * 256; int r = lin >> 6, c = lin & 63;
    tile[r * 65 + c] = src[(size_t)(r0 + r) * 1024 + c0 + c];
  }
  __syncthreads();
#pragma unroll
  for (int i = 0; i < 16; ++i) {
    int lin = t + i * 256; int c = lin >> 6, r = lin & 63;
    dst[(size_t)(c0 + c) * 1024 + r0 + r] = f2bf(tile[r * 65 + c]);
  }
}

// BFT (64x1024) = [Wb^T ; Wf^T ; 0]; grid 256
__global__ __launch_bounds__(256) void bfprep(const float* __restrict__ Wb,
    const float* __restrict__ Wf, unsigned short* __restrict__ BFT) {
  int idx = blockIdx.x * 256 + threadIdx.x;   // 65536
  int j = idx >> 10, i = idx & 1023;
  float v = 0.f;
  if (j < 16) v = Wb[i * 16 + j];
  else if (j < 32) v = Wf[i * 16 + (j - 16)];
  BFT[idx] = f2bf(v);
}

// zero the never-solved CT blocks (j-slab 2m+1, s-block 2m)
__global__ __launch_bounds__(256) void zeroCT(unsigned short* __restrict__ CT) {
  int m = blockIdx.x, bh = blockIdx.y;
  int t = threadIdx.x;
  size_t base = (size_t)bh << 20;
  int j0 = (2 * m + 1) * 64, s0 = 2 * m * 64;
#pragma unroll
  for (int i = 0; i < 16; ++i) {
    int lin = t + i * 256; int jl = lin >> 6, sl = lin & 63;
    CT[base + ((size_t)(j0 + jl) << 10) + s0 + sl] = 0;
  }
}

// ================= 64-tile bf16 NT GEMM with batch strides =================
template<int F32OUT>
__global__ __launch_bounds__(256) void gemm_nt(const unsigned short* __restrict__ A,
    const unsigned short* __restrict__ BT, void* __restrict__ out,
    int M, int N, int K, size_t zA, size_t zB, size_t zC) {
  A += zA * blockIdx.z; BT += zB * blockIdx.z;
  __shared__ unsigned short As[64 * 64];
  __shared__ unsigned short Bs[64 * 64];
  int m0 = blockIdx.y * 64, n0 = blockIdx.x * 64;
  int t = threadIdx.x;
  int w = t >> 6, l = t & 63, fr = l & 15;
  int koB = (l >> 4) * 16;
  f32x4 acc[4];
#pragma unroll
  for (int c = 0; c < 4; ++c) acc[c] = (f32x4){0.f, 0.f, 0.f, 0.f};
  for (int k0 = 0; k0 < K; k0 += 64) {
    __syncthreads();
#pragma unroll
    for (int i = 0; i < 2; ++i) {
      int cid = t + i * 256;
      int row = cid >> 3, ch = cid & 7;
      int byt = ((row << 7) + (ch << 4)) ^ ((row & 7) << 4);
      *(u16x8*)((char*)As + byt) = *(const u16x8*)(A + (size_t)(m0 + row) * K + k0 + ch * 8);
      *(u16x8*)((char*)Bs + byt) = *(const u16x8*)(BT + (size_t)(n0 + row) * K + k0 + ch * 8);
    }
    __syncthreads();
#pragma unroll
    for (int kh = 0; kh < 2; ++kh) {
      int ra = 16 * w + fr;
      s16x8 a = *(const s16x8*)((char*)As + (((ra << 7) + (kh << 6) + koB) ^ ((ra & 7) << 4)));
#pragma unroll
      for (int c = 0; c < 4; ++c) {
        int rb = 16 * c + fr;
        s16x8 bb = *(const s16x8*)((char*)Bs + (((rb << 7) + (kh << 6) + koB) ^ ((rb & 7) << 4)));
        acc[c] = __builtin_amdgcn_mfma_f32_16x16x32_bf16(a, bb, acc[c], 0, 0, 0);
      }
    }
  }
  int rbase = m0 + 16 * w + ((l >> 4) << 2);
#pragma unroll
  for (int c = 0; c < 4; ++c) {
    int col = n0 + 16 * c + fr;
#pragma unroll
    for (int r = 0; r < 4; ++r) {
      if (F32OUT) ((float*)out + zC * blockIdx.z)[(size_t)(rbase + r) * N + col] = acc[c][r];
      else ((unsigned short*)out + zC * blockIdx.z)[(size_t)(rbase + r) * N + col] = f2bf(acc[c][r]);
    }
  }
}

// ================= pair (L/G): dst[bh][i][j] = mask * (A_i . Bbeta_j), 128-tile =================
template<int STRICT>
__global__ __launch_bounds__(256) void pair128(const unsigned short* __restrict__ Ar,
    const unsigned short* __restrict__ Br, unsigned short* __restrict__ dst) {
  int jb2 = blockIdx.x, tb2 = blockIdx.y, bh = blockIdx.z;
  if (jb2 > tb2) return;
  int b = bh >> 4, h = bh & 15;
  int m0 = tb2 * 128, n0 = jb2 * 128;
  int t = threadIdx.x;
  int w = t >> 6, l = t & 63;
  int wr = w >> 1, wc = w & 1;
  int fr = l & 15, fq = l >> 4;
  __shared__ unsigned short As[128 * 64];
  __shared__ unsigned short Bs[128 * 64];
  const unsigned short* Ab = Ar + ((size_t)b << 20) + h * 64;
  const unsigned short* Bb = Br + ((size_t)b << 20) + h * 64;
  f32x4 acc[4][4];
#pragma unroll
  for (int m = 0; m < 4; ++m)
#pragma unroll
    for (int c = 0; c < 4; ++c) acc[m][c] = (f32x4){0.f, 0.f, 0.f, 0.f};
#pragma unroll
  for (int i = 0; i < 4; ++i) {
    int cid = t + i * 256;
    int row = cid >> 3, ch = cid & 7;
    int byt = ((row << 7) + (ch << 4)) ^ ((row & 7) << 4);
    *(u16x8*)((char*)As + byt) = *(const u16x8*)(Ab + ((size_t)(m0 + row) << 10) + ch * 8);
    *(u16x8*)((char*)Bs + byt) = *(const u16x8*)(Bb + ((size_t)(n0 + row) << 10) + ch * 8);
  }
  __syncthreads();
#pragma unroll
  for (int kh = 0; kh < 2; ++kh) {
    s16x8 af[4], bfv[4];
#pragma unroll
    for (int m = 0; m < 4; ++m) {
      int ra = wr * 64 + 16 * m + fr;
      af[m] = *(const s16x8*)((char*)As + (((ra << 7) + (kh << 6) + (fq << 4)) ^ ((ra & 7) << 4)));
    }
#pragma unroll
    for (int c = 0; c < 4; ++c) {
      int rb = wc * 64 + 16 * c + fr;
      bfv[c] = *(const s16x8*)((char*)Bs + (((rb << 7) + (kh << 6) + (fq << 4)) ^ ((rb & 7) << 4)));
    }
#pragma unroll
    for (int m = 0; m < 4; ++m)
#pragma unroll
      for (int c = 0; c < 4; ++c)
        acc[m][c] = __builtin_amdgcn_mfma_f32_16x16x32_bf16(af[m], bfv[c], acc[m][c], 0, 0, 0);
  }
  size_t base = (size_t)bh << 20;
#pragma unroll
  for (int m = 0; m < 4; ++m) {
#pragma unroll
    for (int c = 0; c < 4; ++c) {
      int gj = n0 + wc * 64 + 16 * c + fr;
#pragma unroll
      for (int r = 0; r < 4; ++r) {
        int gi = m0 + wr * 64 + 16 * m + fq * 4 + r;
        bool keep = STRICT ? (gj < gi) : (gj <= gi);
        dst[base + ((size_t)gi << 10) + gj] = f2bf(keep ? acc[m][c][r] : 0.f);
      }
    }
  }
}

// ================= score: S = Q K^T - G @ C, sorted 1D grid =================
__global__ __launch_bounds__(256) void score128s(const unsigned short* __restrict__ Q,
    const unsigned short* __restrict__ Kk, const unsigned short* __restrict__ G,
    const unsigned short* __restrict__ CT, unsigned short* __restrict__ Sg) {
  int idx = blockIdx.x;
  int bh = idx & 31, r0r = idx >> 5;
  int k = (int)((sqrtf(8.f * r0r + 1.f) - 1.f) * 0.5f);
  while (k * (k + 1) / 2 > r0r) --k;
  while ((k + 1) * (k + 2) / 2 <= r0r) ++k;
  int i = r0r - k * (k + 1) / 2;
  int tb2 = (7 - k) + i, jb2 = i;
  int b = bh >> 4, h = bh & 15;
  int m0 = tb2 * 128, n0 = jb2 * 128;
  int t = threadIdx.x;
  int w = t >> 6, l = t & 63;
  int wr = w >> 1, wc = w & 1;
  int fr = l & 15, fq = l >> 4;
  __shared__ unsigned short As[128 * 64];
  __shared__ unsigned short Bs[128 * 64];
  size_t base = (size_t)bh << 20;
  const unsigned short* Qb_ = Q + ((size_t)b << 20) + h * 64;
  const unsigned short* Kb_ = Kk + ((size_t)b << 20) + h * 64;
  const unsigned short* Gb_ = G + base;
  const unsigned short* Cb_ = CT + base;
  int kbase = jb2 * 128;
  int nsteps = 1 + (tb2 - jb2 + 1) * 2;
  f32x4 acc[4][4];
#pragma unroll
  for (int m = 0; m < 4; ++m)
#pragma unroll
    for (int c = 0; c < 4; ++c) acc[m][c] = (f32x4){0.f, 0.f, 0.f, 0.f};
  for (int step = 0; step < nsteps; ++step) {
    const unsigned short* pa; const unsigned short* pb; int koff; bool neg;
    if (step == 0) { pa = Qb_; pb = Kb_; koff = 0; neg = false; }
    else { pa = Gb_; pb = Cb_; koff = kbase + (step - 1) * 64; neg = true; }
    __syncthreads();
#pragma unroll
    for (int i2 = 0; i2 < 4; ++i2) {
      int cid = t + i2 * 256;
      int row = cid >> 3, ch = cid & 7;
      int byt = ((row << 7) + (ch << 4)) ^ ((row & 7) << 4);
      u16x8 av = *(const u16x8*)(pa + ((size_t)(m0 + row) << 10) + koff + ch * 8);
      if (neg) av ^= (unsigned short)0x8000;
      *(u16x8*)((char*)As + byt) = av;
      *(u16x8*)((char*)Bs + byt) = *(const u16x8*)(pb + ((size_t)(n0 + row) << 10) + koff + ch * 8);
    }
    __syncthreads();
#pragma unroll
    for (int kh = 0; kh < 2; ++kh) {
      s16x8 af[4], bfv[4];
#pragma unroll
      for (int m = 0; m < 4; ++m) {
        int ra = wr * 64 + 16 * m + fr;
        af[m] = *(const s16x8*)((char*)As + (((ra << 7) + (kh << 6) + (fq << 4)) ^ ((ra & 7) << 4)));
      }
#pragma unroll
      for (int c = 0; c < 4; ++c) {
        int rb = wc * 64 + 16 * c + fr;
        bfv[c] = *(const s16x8*)((char*)Bs + (((rb << 7) + (kh << 6) + (fq << 4)) ^ ((rb & 7) << 4)));
      }
#pragma unroll
      for (int m = 0; m < 4; ++m)
#pragma unroll
        for (int c = 0; c < 4; ++c)
          acc[m][c] = __builtin_amdgcn_mfma_f32_16x16x32_bf16(af[m], bfv[c], acc[m][c], 0, 0, 0);
    }
  }
#pragma unroll
  for (int m = 0; m < 4; ++m) {
#pragma unroll
    for (int c = 0; c < 4; ++c) {
      int gj = n0 + wc * 64 + 16 * c + fr;
#pragma unroll
      for (int r = 0; r < 4; ++r) {
        int gi = m0 + wr * 64 + 16 * m + fq * 4 + r;
        Sg[base + ((size_t)gi << 10) + gj] = f2bf(acc[m][c][r]);
      }
    }
  }
}

// ================= w normalize + beta-scale =================
__global__ __launch_bounds__(256) void wnorm2(const unsigned short* __restrict__ WNF,
    const float* __restrict__ Beta, unsigned short* __restrict__ WN,
    unsigned short* __restrict__ WB) {
  int row = blockIdx.x;
  int wave = threadIdx.x >> 6, lane = threadIdx.x & 63;
#pragma unroll
  for (int i = 0; i < 4; ++i) {
    int hh = wave * 4 + i;
    size_t idx = ((size_t)row << 10) + hh * 64 + lane;
    float v = bf2f(WNF[idx]);
    float ss = v * v;
#pragma unroll
    for (int off = 1; off < 64; off <<= 1) ss += __shfl_xor(ss, off);
    float wn = v * rsqrtf(ss + 1e-6f);
    WN[idx] = f2bf(wn);
    WB[idx] = f2bf(wn * Beta[row * 16 + hh]);
  }
}

// ================= inv64: U = (I + Ldiag)^-1 per (bh, ib); grid (16,32) =================
__global__ __launch_bounds__(256) void inv64(const unsigned short* __restrict__ Lb,
    unsigned short* __restrict__ UI) {
  int ib = blockIdx.x, bh = blockIdx.y;
  int t = threadIdx.x;
  int s0 = ib * 64;
  size_t base = (size_t)bh << 20;
  __shared__ float LD[64 * 65];
  __shared__ unsigned short us[64 * 66];
#pragma unroll
  for (int i = 0; i < 16; ++i) {
    int lin = t + i * 256; int s = lin >> 6, r = lin & 63;
    LD[s * 65 + r] = bf2f(Lb[base + ((size_t)(s0 + s) << 10) + s0 + r]);
  }
  __syncthreads();
  if (t < 64) {                      // lane j = column j of inverse
    float cc[64];
#pragma unroll
    for (int s = 0; s < 64; ++s) cc[s] = (s == t) ? 1.f : 0.f;
#pragma unroll
    for (int r = 0; r < 63; ++r) {
      float val = cc[r];
#pragma unroll
      for (int s = r + 1; s < 64; ++s) cc[s] -= LD[s * 65 + r] * val;
    }
#pragma unroll
    for (int s = 0; s < 64; ++s) us[s * 66 + t] = f2bf(cc[s]);
  }
  __syncthreads();
  size_t ubase = ((size_t)(bh * 16 + ib)) << 12;
#pragma unroll
  for (int i = 0; i < 16; ++i) {
    int lin = t + i * 256; int s = lin >> 6, j = lin & 63;
    UI[ubase + s * 64 + j] = us[s * 66 + j];
  }
}

// ================= solve step ib: rect = W K^T - L C, then C = U @ rect (MFMA) =================
__global__ __launch_bounds__(256) void solve_step2(const unsigned short* __restrict__ WN,
    const unsigned short* __restrict__ Kk, const unsigned short* __restrict__ Lb,
    const unsigned short* __restrict__ UI, unsigned short* __restrict__ CT, int ib) {
  int jb = blockIdx.x, bh = blockIdx.y;
  int b = bh >> 4, h = bh & 15;
  int t = threadIdx.x, w = t >> 6, l = t & 63, fr = l & 15, fq = l >> 4;
  int ko = fq * 8;
  size_t base = (size_t)bh << 20;
  int s0 = ib * 64, j0 = jb * 64;
  __shared__ float rect[64 * 68];
  const unsigned short* Wb_ = WN + ((size_t)b << 20) + h * 64;
  const unsigned short* Kb_ = Kk + ((size_t)b << 20) + h * 64;
  int ar = s0 + 16 * w + fr;
  f32x4 am[4];
#pragma unroll
  for (int c = 0; c < 4; ++c) am[c] = (f32x4){0.f,0.f,0.f,0.f};
#pragma unroll
  for (int kh = 0; kh < 2; ++kh) {
    s16x8 a = *(const s16x8*)(Wb_ + ((size_t)ar << 10) + kh * 32 + ko);
#pragma unroll
    for (int c = 0; c < 4; ++c) {
      s16x8 bb = *(const s16x8*)(Kb_ + ((size_t)(j0 + 16 * c + fr) << 10) + kh * 32 + ko);
      am[c] = __builtin_amdgcn_mfma_f32_16x16x32_bf16(a, bb, am[c], 0, 0, 0);
    }
  }
  for (int rb = jb; rb < ib; ++rb) {
#pragma unroll
    for (int kh = 0; kh < 2; ++kh) {
      s16x8 a = *(const s16x8*)(Lb + base + ((size_t)ar << 10) + rb * 64 + kh * 32 + ko);
      a ^= (short)0x8000;   // negate L so mfma accumulates -L*C
#pragma unroll
      for (int c = 0; c < 4; ++c) {
        s16x8 bb = *(const s16x8*)(CT + base + ((size_t)(j0 + 16 * c + fr) << 10) + rb * 64 + kh * 32 + ko);
        am[c] = __builtin_amdgcn_mfma_f32_16x16x32_bf16(a, bb, am[c], 0, 0, 0);
      }
    }
  }
  // rect[j][s] (diag slab: zero j >= s)
#pragma unroll
  for (int c = 0; c < 4; ++c) {
#pragma unroll
    for (int r = 0; r < 4; ++r) {
      int jl = 16 * c + fr, sl = 16 * w + fq * 4 + r;
      float v = am[c][r];
      if (jb == ib && jl >= sl) v = 0.f;
      rect[jl * 68 + sl] = v;
    }
  }
  __syncthreads();
  // C = U @ rect  (output rows s from U, cols j from rect rows)
  const unsigned short* Ug = UI + (((size_t)(bh * 16 + ib)) << 12);
  f32x4 accc[4];
#pragma unroll
  for (int c = 0; c < 4; ++c) accc[c] = (f32x4){0.f,0.f,0.f,0.f};
#pragma unroll
  for (int kh = 0; kh < 2; ++kh) {
    s16x8 a = *(const s16x8*)(Ug + (16 * w + fr) * 64 + kh * 32 + ko);
#pragma unroll
    for (int c = 0; c < 4; ++c) {
      const float* rp = rect + (16 * c + fr) * 68 + kh * 32 + ko;
      f32x4 b0 = *(const f32x4*)(rp);
      f32x4 b1 = *(const f32x4*)(rp + 4);
      s16x8 bb;
#pragma unroll
      for (int e = 0; e < 4; ++e) { bb[e] = (short)f2bf(b0[e]); bb[4 + e] = (short)f2bf(b1[e]); }
      accc[c] = __builtin_amdgcn_mfma_f32_16x16x32_bf16(a, bb, accc[c], 0, 0, 0);
    }
  }
  __syncthreads();
#pragma unroll
  for (int c = 0; c < 4; ++c) {
#pragma unroll
    for (int r = 0; r < 4; ++r) {
      int jl = 16 * c + fr, sl = 16 * w + fq * 4 + r;
      rect[jl * 68 + sl] = accc[c][r];
    }
  }
  __syncthreads();
#pragma unroll
  for (int i = 0; i < 16; ++i) {
    int lin = t + i * 256; int jl = lin >> 6, sl = lin & 63;
    CT[base + ((size_t)(j0 + jl) << 10) + s0 + sl] = f2bf(rect[jl * 68 + sl]);
  }
}

// ================= rowstat: m,l per row (Fc_t cancels in softmax) =================
__global__ __launch_bounds__(256) void rowstat(const unsigned short* __restrict__ S,
    const float* __restrict__ Fc, float* __restrict__ MR, float* __restrict__ LR) {
  int bh = blockIdx.y;
  int t = blockIdx.x * 4 + (threadIdx.x >> 6);
  int l = threadIdx.x & 63;
  size_t base = (size_t)bh << 20;
  const unsigned short* srow = S + base + ((size_t)t << 10);
  float vals[16]; float vmax = -1e30f;
#pragma unroll
  for (int i = 0; i < 2; ++i) {
    int c0 = i * 512 + l * 8;
    u16x8 sv = *(const u16x8*)(srow + c0);
    float4 f0 = *(const float4*)(Fc + bh * 1024 + c0);
    float4 f1 = *(const float4*)(Fc + bh * 1024 + c0 + 4);
#pragma unroll
    for (int e = 0; e < 8; ++e) {
      float fc = e < 4 ? ((const float*)&f0)[e] : ((const float*)&f1)[e - 4];
      float v = (c0 + e <= t) ? bf2f(sv[e]) * SM_SCALE - fc : -1e30f;
      vals[i * 8 + e] = v; vmax = fmaxf(vmax, v);
    }
  }
#pragma unroll
  for (int o = 1; o < 64; o <<= 1) vmax = fmaxf(vmax, __shfl_xor(vmax, o));
  float sum = 0.f;
#pragma unroll
  for (int e = 0; e < 16; ++e) sum += __expf(vals[e] - vmax);
#pragma unroll
  for (int o = 1; o < 64; o <<= 1) sum += __shfl_xor(sum, o);
  if (l == 0) { MR[bh * 1024 + t] = vmax; LR[bh * 1024 + t] = sum; }
}

// ================= pv: O = P @ V with on-the-fly P; sorted 1D grid (512) =================
__global__ __launch_bounds__(256) void pv_kernel(const unsigned short* __restrict__ S,
    const unsigned short* __restrict__ VT, const float* __restrict__ Fc,
    const float* __restrict__ MR, const float* __restrict__ LR,
    unsigned short* __restrict__ Ob) {
  int idx = blockIdx.x;
  int bh = idx & 31, rank = idx >> 5;
  int tb = 15 - rank;
  int b = bh >> 4, h = bh & 15;
  int t0 = tb * 64;
  int t = threadIdx.x, w = t >> 6, l = t & 63, fr = l & 15, fq = l >> 4;
  __shared__ unsigned short Pl[64 * 64];
  size_t base = (size_t)bh << 20;
  f32x4 acc[4];
#pragma unroll
  for (int c = 0; c < 4; ++c) acc[c] = (f32x4){0.f,0.f,0.f,0.f};
  for (int jb = 0; jb <= tb; ++jb) {
    int j0 = jb * 64;
    __syncthreads();
#pragma unroll
    for (int i = 0; i < 2; ++i) {
      int cid = t + i * 256;
      int row = cid >> 3, ch = cid & 7;
      int grow = t0 + row;
      u16x8 sv = *(const u16x8*)(S + base + ((size_t)grow << 10) + j0 + ch * 8);
      float4 f0 = *(const float4*)(Fc + bh * 1024 + j0 + ch * 8);
      float4 f1 = *(const float4*)(Fc + bh * 1024 + j0 + ch * 8 + 4);
      float m = MR[bh * 1024 + grow];
      u16x8 pv;
#pragma unroll
      for (int e = 0; e < 8; ++e) {
        float fc = e < 4 ? ((const float*)&f0)[e] : ((const float*)&f1)[e - 4];
        float p = __expf(bf2f(sv[e]) * SM_SCALE - fc - m);
        if (jb == tb && ch * 8 + e > row) p = 0.f;
        pv[e] = f2bf(p);
      }
      int byt = ((row << 7) + (ch << 4)) ^ ((row & 7) << 4);
      *(u16x8*)((char*)Pl + byt) = pv;
    }
    __syncthreads();
#pragma unroll
    for (int kh = 0; kh < 2; ++kh) {
      int ra = 16 * w + fr;
      s16x8 a = *(const s16x8*)((char*)Pl + (((ra << 7) + (kh << 6) + (fq << 4)) ^ ((ra & 7) << 4)));
#pragma unroll
      for (int c = 0; c < 4; ++c) {
        s16x8 bb = *(const s16x8*)(VT + ((size_t)bh * 64 + 16 * c + fr) * 1024 + j0 + kh * 32 + fq * 8);
        acc[c] = __builtin_amdgcn_mfma_f32_16x16x32_bf16(a, bb, acc[c], 0, 0, 0);
      }
    }
  }
  float inv[4];
#pragma unroll
  for (int r = 0; r < 4; ++r) inv[r] = 1.f / LR[bh * 1024 + t0 + 16 * w + fq * 4 + r];
#pragma unroll
  for (int c = 0; c < 4; ++c) {
#pragma unroll
    for (int r = 0; r < 4; ++r) {
      int grow = t0 + 16 * w + fq * 4 + r;
      Ob[((size_t)(b * 1024) + grow) * 1024 + h * 64 + 16 * c + fr] = f2bf(acc[c][r] * inv[r]);
    }
  }
}

extern "C" void kernel_launch(void* const* d_in, const int* in_sizes, int n_in,
                              void* d_out, int out_size, void* d_ws, size_t ws_size,
                              hipStream_t stream) {
  const float* x    = (const float*)d_in[0];
  const float* Wq   = (const float*)d_in[1];
  const float* Wk   = (const float*)d_in[2];
  const float* Wv   = (const float*)d_in[3];
  const float* Wo   = (const float*)d_in[4];
  const float* Ww1  = (const float*)d_in[5];
  const float* Ww2  = (const float*)d_in[6];
  const float* Wb   = (const float*)d_in[7];
  const float* Wf   = (const float*)d_in[8];
  const float* delta= (const float*)d_in[9];

  char* ws = (char*)d_ws;
  unsigned short* xb   = (unsigned short*)(ws + OFF_XB);
  unsigned short* WqT  = (unsigned short*)(ws + OFF_WQT);
  float*          BL   = (float*)(ws + OFF_BL);
  unsigned short* WkT  = (unsigned short*)(ws + OFF_WKT);
  unsigned short* BFT  = (unsigned short*)(ws + OFF_BFT);
  unsigned short* WvT  = (unsigned short*)(ws + OFF_WVT);
  unsigned short* WoT  = (unsigned short*)(ws + OFF_WOT);
  unsigned short* W1T  = (unsigned short*)(ws + OFF_W1T);
  unsigned short* W2T  = (unsigned short*)(ws + OFF_W2T);
  float*          Beta = (float*)(ws + OFF_W1T);
  float*          Lf   = (float*)(ws + OFF_W2T);
  unsigned short* Q16  = (unsigned short*)(ws + OFF_Q16);
  unsigned short* K16  = (unsigned short*)(ws + OFF_K16);
  unsigned short* VT   = (unsigned short*)(ws + OFF_VT);
  unsigned short* WN16 = (unsigned short*)(ws + OFF_WN16);
  unsigned short* WB16 = (unsigned short*)(ws + OFF_WB16);
  unsigned short* WNF16= (unsigned short*)(ws + OFF_WNF);
  unsigned short* ObB  = (unsigned short*)(ws + OFF_OB);
  unsigned short* Wpre = (unsigned short*)(ws + OFF_WPRE);
  float*          Fc   = (float*)(ws + OFF_FC);
  unsigned short* Lbuf = (unsigned short*)(ws + OFF_L);
  unsigned short* Sbuf = (unsigned short*)(ws + OFF_L);
  unsigned short* CT   = (unsigned short*)(ws + OFF_CT);
  unsigned short* Gbuf = (unsigned short*)(ws + OFF_G);
  float*          MR   = (float*)(ws + OFF_MR);
  float*          LR   = (float*)(ws + OFF_LR);
  unsigned short* UI   = (unsigned short*)(ws + OFF_UI);

  dim3 blk(256);
  // weight transposes + x cast
  transpose4<<<dim3(16,16,4), blk, 0, stream>>>(Wq, Wk, Wv, Wo, WqT, WkT, WvT, WoT);
  transpose_cast<<<dim3(1,16),  blk, 0, stream>>>(Ww1, W1T, 1024, 64);
  transpose_cast<<<dim3(16,1),  blk, 0, stream>>>(Ww2, W2T, 64, 1024);
  cast_bf16<<<1024, blk, 0, stream>>>(x, xb, 2048 * 1024);
  // projections (64-tile grids for occupancy)
  gemm_nt<0><<<dim3(16,32,1), blk, 0, stream>>>(xb, WqT, Q16, 2048, 1024, 1024, 0, 0, 0);
  gemm_nt<0><<<dim3(16,32,1), blk, 0, stream>>>(xb, WkT, K16, 2048, 1024, 1024, 0, 0, 0);
  gemm_nt<0><<<dim3(16,16,2), blk, 0, stream>>>(WvT, xb, VT, 1024, 1024, 1024,
                                                0, (size_t)1 << 20, (size_t)1 << 20);
  gemm_nt<0><<<dim3(1,32,1),  blk, 0, stream>>>(xb, W1T, Wpre, 2048, 64, 1024, 0, 0, 0);
  gemm_nt<0><<<dim3(16,32,1), blk, 0, stream>>>(Wpre, W2T, WNF16, 2048, 1024, 64, 0, 0, 0);
  // beta / log_f via MFMA (BFT overlays WkT -> after K proj)
  bfprep<<<256, blk, 0, stream>>>(Wb, Wf, BFT);
  gemm_nt<1><<<dim3(1,32,1), blk, 0, stream>>>(xb, BFT, BL, 2048, 64, 1024, 0, 0, 0);
  bg_kernel2<<<128, blk, 0, stream>>>(BL, Beta, Lf, delta);
  fc_kernel<<<32, blk, 0, stream>>>(Lf, Fc);
  wnorm2<<<2048, blk, 0, stream>>>(WNF16, Beta, WN16, WB16);
  // L and G
  pair128<1><<<dim3(8,8,32), blk, 0, stream>>>(WN16, WB16, Lbuf);
  pair128<0><<<dim3(8,8,32), blk, 0, stream>>>(Q16, WB16, Gbuf);
  // triangular solve: block inverses + 16 MFMA steps
  zeroCT<<<dim3(16,32), blk, 0, stream>>>(CT);
  inv64<<<dim3(16,32), blk, 0, stream>>>(Lbuf, UI);
  for (int ib = 0; ib < 16; ++ib)
    solve_step2<<<dim3(ib + 1, 32), blk, 0, stream>>>(WN16, K16, Lbuf, UI, CT, ib);
  // S = QK^T - G C (sorted band grid; reuses L region)
  score128s<<<dim3(36 * 32), blk, 0, stream>>>(Q16, K16, Gbuf, CT, Sbuf);
  // softmax stats + PV
  rowstat<<<dim3(256,32), blk, 0, stream>>>(Sbuf, Fc, MR, LR);
  pv_kernel<<<dim3(512), blk, 0, stream>>>(Sbuf, VT, Fc, MR, LR, ObB);
  // output projection (f32 out)
  gemm_nt<1><<<dim3(16,32,1), blk, 0, stream>>>(ObB, WoT, d_out, 2048, 1024, 1024, 0, 0, 0);
}

// Round 5
// 434.967 us; speedup vs baseline: 9.3751x; 1.5177x over previous
//
#include <hip/hip_runtime.h>
#include <hip/hip_bf16.h>

#define DEV static __device__ __forceinline__

constexpr float SM_SCALE = 0.125f;   // hd^-0.5, hd=64

typedef __attribute__((ext_vector_type(8))) short s16x8;
typedef __attribute__((ext_vector_type(8))) unsigned short u16x8;
typedef __attribute__((ext_vector_type(4))) unsigned short u16x4;
typedef __attribute__((ext_vector_type(4))) float f32x4;

DEV float bf2f(unsigned short u) {
  union { unsigned int i; float f; } v; v.i = ((unsigned int)u) << 16; return v.f;
}
DEV unsigned short f2bf(float f) {
  union { float f; unsigned int i; } v; v.f = f;
  unsigned int r = v.i + 0x7fffu + ((v.i >> 16) & 1u);
  return (unsigned short)(r >> 16);
}
DEV void tri_unrank(int r, int& k, int& i) {
  k = (int)((sqrtf(8.f * r + 1.f) - 1.f) * 0.5f);
  while (k * (k + 1) / 2 > r) --k;
  while ((k + 1) * (k + 2) / 2 <= r) ++k;
  i = r - k * (k + 1) / 2;
}

// ---------- workspace layout (bytes) ----------
constexpr size_t OFF_XB   = 0;                       // 4MB xb bf16 [2048][1024]
constexpr size_t OFF_WQT  = 4194304;                 // 2MB; reused as BL (f32 2048x64) after Q proj
constexpr size_t OFF_BL   = 4194304;
constexpr size_t OFF_WKT  = 6291456;                 // 2MB; reused as BFT (bf16 64x1024) after K proj
constexpr size_t OFF_BFT  = 6291456;
constexpr size_t OFF_WVT  = 8388608;
constexpr size_t OFF_WOT  = 10485760;
constexpr size_t OFF_W1T  = 12582912;                // 128KB (reused as Beta f32)
constexpr size_t OFF_W2T  = 12713984;                // 128KB (reused as Lf f32)
constexpr size_t OFF_Q16  = 12845056;                // 4MB bf16 2048x1024
constexpr size_t OFF_K16  = 17039360;                // 4MB
constexpr size_t OFF_VT   = 21233664;                // 4MB  VT[b][64h*d][1024n]
constexpr size_t OFF_WN16 = 25427968;                // 4MB
constexpr size_t OFF_WB16 = 29622272;                // 4MB
constexpr size_t OFF_WNF  = 33816576;                // 4MB (reused as Ob)
constexpr size_t OFF_OB   = 33816576;
constexpr size_t OFF_WPRE = 38010880;                // 256KB
constexpr size_t OFF_FC   = 38273024;                // 128KB
constexpr size_t OFF_L    = 38404096;                // 64MB (reused as S)
constexpr size_t OFF_CT   = 105512960;               // 64MB
constexpr size_t OFF_G    = 172621824;               // 64MB
constexpr size_t OFF_MR   = 239730688;               // 128KB f32 [32][1024]
constexpr size_t OFF_LR   = 239861760;               // 128KB
constexpr size_t OFF_UI   = 239992832;               // 4MB bf16 [32][16][64][64]  -> end 244,187,136

// ================= elementwise / prep =================
__global__ __launch_bounds__(256) void bg_kernel2(const float* __restrict__ BL,
    float* __restrict__ beta, float* __restrict__ lf, const float* __restrict__ delta) {
  int idx = blockIdx.x * 256 + threadIdx.x;
  if (idx >= 2048 * 16) return;
  int row = idx >> 4, hh = idx & 15;
  float braw = BL[row * 64 + hh];
  float lraw = BL[row * 64 + 16 + hh] + delta[hh];
  beta[idx] = 2.f / (1.f + __expf(-braw));
  lf[idx] = (lraw >= 0.f) ? -log1pf(__expf(-lraw)) : (lraw - log1pf(__expf(lraw)));
}

__global__ __launch_bounds__(256) void fc_kernel(const float* __restrict__ lf,
                                                 float* __restrict__ Fc) {
  int bh = blockIdx.x;
  int b = bh >> 4, h = bh & 15;
  int t = threadIdx.x;
  __shared__ float buf[1024];
  __shared__ float tsum[256];
#pragma unroll
  for (int i = 0; i < 4; ++i) {
    int tt = t + i * 256;
    buf[tt] = lf[((size_t)((b << 10) + tt) << 4) + h];
  }
  __syncthreads();
  float loc[4]; float run = 0.f;
#pragma unroll
  for (int i = 0; i < 4; ++i) { run += buf[t * 4 + i]; loc[i] = run; }
  tsum[t] = run;
  __syncthreads();
  for (int off = 1; off < 256; off <<= 1) {
    float add = (t >= off) ? tsum[t - off] : 0.f;
    __syncthreads();
    tsum[t] += add;
    __syncthreads();
  }
  float excl = tsum[t] - run;
#pragma unroll
  for (int i = 0; i < 4; ++i) Fc[bh * 1024 + t * 4 + i] = excl + loc[i];
}

__global__ __launch_bounds__(256) void cast_bf16(const float* __restrict__ src,
    unsigned short* __restrict__ dst, int n) {
  int i = (blockIdx.x * 256 + threadIdx.x) * 8;
  if (i >= n) return;
  float4 a = *(const float4*)(src + i);
  float4 b = *(const float4*)(src + i + 4);
  u16x8 o;
  o[0] = f2bf(a.x); o[1] = f2bf(a.y); o[2] = f2bf(a.z); o[3] = f2bf(a.w);
  o[4] = f2bf(b.x); o[5] = f2bf(b.y); o[6] = f2bf(b.z); o[7] = f2bf(b.w);
  *(u16x8*)(dst + i) = o;
}

// dst[c][r] = bf16(src[r][c]);  grid (C/64, R/64)
__global__ __launch_bounds__(256) void transpose_cast(const float* __restrict__ src,
    unsigned short* __restrict__ dst, int R, int C) {
  __shared__ float tile[64 * 65];
  int c0 = blockIdx.x * 64, r0 = blockIdx.y * 64;
  int t = threadIdx.x;
#pragma unroll
  for (int i = 0; i < 16; ++i) {
    int lin = t + i * 256; int r = lin >> 6, c = lin & 63;
    tile[r * 65 + c] = src[(size_t)(r0 + r) * C + c0 + c];
  }
  __syncthreads();
#pragma unroll
  for (int i = 0; i < 16; ++i) {
    int lin = t + i * 256; int c = lin >> 6, r = lin & 63;
    dst[(size_t)(c0 + c) * R + r0 + r] = f2bf(tile[r * 65 + c]);
  }
}

// fused 4x 1024x1024 weight transpose: grid (16,16,4)
__global__ __launch_bounds__(256) void transpose4(
    const float* __restrict__ W0, const float* __restrict__ W1,
    const float* __restrict__ W2, const float* __restrict__ W3,
    unsigned short* __restrict__ D0, unsigned short* __restrict__ D1,
    unsigned short* __restrict__ D2, unsigned short* __restrict__ D3) {
  int z = blockIdx.z;
  const float* src = z == 0 ? W0 : z == 1 ? W1 : z == 2 ? W2 : W3;
  unsigned short* dst = z == 0 ? D0 : z == 1 ? D1 : z == 2 ? D2 : D3;
  __shared__ float tile[64 * 65];
  int c0 = blockIdx.x * 64, r0 = blockIdx.y * 64;
  int t = threadIdx.x;
#pragma unroll
  for (int i = 0; i < 16; ++i) {
    int lin = t + i * 256; int r = lin >> 6, c = lin & 63;
    tile[r * 65 + c] = src[(size_t)(r0 + r) * 1024 + c0 + c];
  }
  __syncthreads();
#pragma unroll
  for (int i = 0; i < 16; ++i) {
    int lin = t + i * 256; int c = lin >> 6, r = lin & 63;
    dst[(size_t)(c0 + c) * 1024 + r0 + r] = f2bf(tile[r * 65 + c]);
  }
}

// BFT (64x1024) = [Wb^T ; Wf^T ; 0]; grid 256
__global__ __launch_bounds__(256) void bfprep(const float* __restrict__ Wb,
    const float* __restrict__ Wf, unsigned short* __restrict__ BFT) {
  int idx = blockIdx.x * 256 + threadIdx.x;   // 65536
  int j = idx >> 10, i = idx & 1023;
  float v = 0.f;
  if (j < 16) v = Wb[i * 16 + j];
  else if (j < 32) v = Wf[i * 16 + (j - 16)];
  BFT[idx] = f2bf(v);
}

// ================= 64-tile bf16 NT GEMM with batch strides =================
template<int F32OUT>
__global__ __launch_bounds__(256) void gemm_nt(const unsigned short* __restrict__ A,
    const unsigned short* __restrict__ BT, void* __restrict__ out,
    int M, int N, int K, size_t zA, size_t zB, size_t zC) {
  A += zA * blockIdx.z; BT += zB * blockIdx.z;
  __shared__ unsigned short As[64 * 64];
  __shared__ unsigned short Bs[64 * 64];
  int m0 = blockIdx.y * 64, n0 = blockIdx.x * 64;
  int t = threadIdx.x;
  int w = t >> 6, l = t & 63, fr = l & 15;
  int koB = (l >> 4) * 16;
  f32x4 acc[4];
#pragma unroll
  for (int c = 0; c < 4; ++c) acc[c] = (f32x4){0.f, 0.f, 0.f, 0.f};
  for (int k0 = 0; k0 < K; k0 += 64) {
    __syncthreads();
#pragma unroll
    for (int i = 0; i < 2; ++i) {
      int cid = t + i * 256;
      int row = cid >> 3, ch = cid & 7;
      int byt = ((row << 7) + (ch << 4)) ^ ((row & 7) << 4);
      *(u16x8*)((char*)As + byt) = *(const u16x8*)(A + (size_t)(m0 + row) * K + k0 + ch * 8);
      *(u16x8*)((char*)Bs + byt) = *(const u16x8*)(BT + (size_t)(n0 + row) * K + k0 + ch * 8);
    }
    __syncthreads();
#pragma unroll
    for (int kh = 0; kh < 2; ++kh) {
      int ra = 16 * w + fr;
      s16x8 a = *(const s16x8*)((char*)As + (((ra << 7) + (kh << 6) + koB) ^ ((ra & 7) << 4)));
#pragma unroll
      for (int c = 0; c < 4; ++c) {
        int rb = 16 * c + fr;
        s16x8 bb = *(const s16x8*)((char*)Bs + (((rb << 7) + (kh << 6) + koB) ^ ((rb & 7) << 4)));
        acc[c] = __builtin_amdgcn_mfma_f32_16x16x32_bf16(a, bb, acc[c], 0, 0, 0);
      }
    }
  }
  int rbase = m0 + 16 * w + ((l >> 4) << 2);
#pragma unroll
  for (int c = 0; c < 4; ++c) {
    int col = n0 + 16 * c + fr;
#pragma unroll
    for (int r = 0; r < 4; ++r) {
      if (F32OUT) ((float*)out + zC * blockIdx.z)[(size_t)(rbase + r) * N + col] = acc[c][r];
      else ((unsigned short*)out + zC * blockIdx.z)[(size_t)(rbase + r) * N + col] = f2bf(acc[c][r]);
    }
  }
}

// ================= pair (L/G): dst[bh][i][j] = mask * (A_i . Bbeta_j), dense 1D grid =================
template<int STRICT>
__global__ __launch_bounds__(256) void pair128s(const unsigned short* __restrict__ Ar,
    const unsigned short* __restrict__ Br, unsigned short* __restrict__ dst) {
  int idx = blockIdx.x;
  int bh = idx & 31, r0r = idx >> 5;
  int tb2, jb2; tri_unrank(r0r, tb2, jb2);
  int b = bh >> 4, h = bh & 15;
  int m0 = tb2 * 128, n0 = jb2 * 128;
  int t = threadIdx.x;
  int w = t >> 6, l = t & 63;
  int wr = w >> 1, wc = w & 1;
  int fr = l & 15, fq = l >> 4;
  __shared__ unsigned short As[128 * 64];
  __shared__ unsigned short Bs[128 * 64];
  const unsigned short* Ab = Ar + ((size_t)b << 20) + h * 64;
  const unsigned short* Bb = Br + ((size_t)b << 20) + h * 64;
  f32x4 acc[4][4];
#pragma unroll
  for (int m = 0; m < 4; ++m)
#pragma unroll
    for (int c = 0; c < 4; ++c) acc[m][c] = (f32x4){0.f, 0.f, 0.f, 0.f};
#pragma unroll
  for (int i = 0; i < 4; ++i) {
    int cid = t + i * 256;
    int row = cid >> 3, ch = cid & 7;
    int byt = ((row << 7) + (ch << 4)) ^ ((row & 7) << 4);
    *(u16x8*)((char*)As + byt) = *(const u16x8*)(Ab + ((size_t)(m0 + row) << 10) + ch * 8);
    *(u16x8*)((char*)Bs + byt) = *(const u16x8*)(Bb + ((size_t)(n0 + row) << 10) + ch * 8);
  }
  __syncthreads();
#pragma unroll
  for (int kh = 0; kh < 2; ++kh) {
    s16x8 af[4], bfv[4];
#pragma unroll
    for (int m = 0; m < 4; ++m) {
      int ra = wr * 64 + 16 * m + fr;
      af[m] = *(const s16x8*)((char*)As + (((ra << 7) + (kh << 6) + (fq << 4)) ^ ((ra & 7) << 4)));
    }
#pragma unroll
    for (int c = 0; c < 4; ++c) {
      int rb = wc * 64 + 16 * c + fr;
      bfv[c] = *(const s16x8*)((char*)Bs + (((rb << 7) + (kh << 6) + (fq << 4)) ^ ((rb & 7) << 4)));
    }
#pragma unroll
    for (int m = 0; m < 4; ++m)
#pragma unroll
      for (int c = 0; c < 4; ++c)
        acc[m][c] = __builtin_amdgcn_mfma_f32_16x16x32_bf16(af[m], bfv[c], acc[m][c], 0, 0, 0);
  }
  size_t base = (size_t)bh << 20;
#pragma unroll
  for (int m = 0; m < 4; ++m) {
#pragma unroll
    for (int c = 0; c < 4; ++c) {
      int gj = n0 + wc * 64 + 16 * c + fr;
#pragma unroll
      for (int r = 0; r < 4; ++r) {
        int gi = m0 + wr * 64 + 16 * m + fq * 4 + r;
        bool keep = STRICT ? (gj < gi) : (gj <= gi);
        dst[base + ((size_t)gi << 10) + gj] = f2bf(keep ? acc[m][c][r] : 0.f);
      }
    }
  }
}

// ================= score: S = Q K^T - G @ C, sorted 1D grid =================
__global__ __launch_bounds__(256) void score128s(const unsigned short* __restrict__ Q,
    const unsigned short* __restrict__ Kk, const unsigned short* __restrict__ G,
    const unsigned short* __restrict__ CT, unsigned short* __restrict__ Sg) {
  int idx = blockIdx.x;
  int bh = idx & 31, r0r = idx >> 5;
  int k, i; tri_unrank(r0r, k, i);
  int tb2 = (7 - k) + i, jb2 = i;
  int b = bh >> 4, h = bh & 15;
  int m0 = tb2 * 128, n0 = jb2 * 128;
  int t = threadIdx.x;
  int w = t >> 6, l = t & 63;
  int wr = w >> 1, wc = w & 1;
  int fr = l & 15, fq = l >> 4;
  __shared__ unsigned short As[128 * 64];
  __shared__ unsigned short Bs[128 * 64];
  size_t base = (size_t)bh << 20;
  const unsigned short* Qb_ = Q + ((size_t)b << 20) + h * 64;
  const unsigned short* Kb_ = Kk + ((size_t)b << 20) + h * 64;
  const unsigned short* Gb_ = G + base;
  const unsigned short* Cb_ = CT + base;
  int kbase = jb2 * 128;
  int nsteps = 1 + (tb2 - jb2 + 1) * 2;
  f32x4 acc[4][4];
#pragma unroll
  for (int m = 0; m < 4; ++m)
#pragma unroll
    for (int c = 0; c < 4; ++c) acc[m][c] = (f32x4){0.f, 0.f, 0.f, 0.f};
  for (int step = 0; step < nsteps; ++step) {
    const unsigned short* pa; const unsigned short* pb; int koff; bool neg;
    if (step == 0) { pa = Qb_; pb = Kb_; koff = 0; neg = false; }
    else { pa = Gb_; pb = Cb_; koff = kbase + (step - 1) * 64; neg = true; }
    __syncthreads();
#pragma unroll
    for (int i2 = 0; i2 < 4; ++i2) {
      int cid = t + i2 * 256;
      int row = cid >> 3, ch = cid & 7;
      int byt = ((row << 7) + (ch << 4)) ^ ((row & 7) << 4);
      u16x8 av = *(const u16x8*)(pa + ((size_t)(m0 + row) << 10) + koff + ch * 8);
      if (neg) av ^= (unsigned short)0x8000;
      *(u16x8*)((char*)As + byt) = av;
      *(u16x8*)((char*)Bs + byt) = *(const u16x8*)(pb + ((size_t)(n0 + row) << 10) + koff + ch * 8);
    }
    __syncthreads();
#pragma unroll
    for (int kh = 0; kh < 2; ++kh) {
      s16x8 af[4], bfv[4];
#pragma unroll
      for (int m = 0; m < 4; ++m) {
        int ra = wr * 64 + 16 * m + fr;
        af[m] = *(const s16x8*)((char*)As + (((ra << 7) + (kh << 6) + (fq << 4)) ^ ((ra & 7) << 4)));
      }
#pragma unroll
      for (int c = 0; c < 4; ++c) {
        int rb = wc * 64 + 16 * c + fr;
        bfv[c] = *(const s16x8*)((char*)Bs + (((rb << 7) + (kh << 6) + (fq << 4)) ^ ((rb & 7) << 4)));
      }
#pragma unroll
      for (int m = 0; m < 4; ++m)
#pragma unroll
        for (int c = 0; c < 4; ++c)
          acc[m][c] = __builtin_amdgcn_mfma_f32_16x16x32_bf16(af[m], bfv[c], acc[m][c], 0, 0, 0);
    }
  }
#pragma unroll
  for (int m = 0; m < 4; ++m) {
#pragma unroll
    for (int c = 0; c < 4; ++c) {
      int gj = n0 + wc * 64 + 16 * c + fr;
#pragma unroll
      for (int r = 0; r < 4; ++r) {
        int gi = m0 + wr * 64 + 16 * m + fq * 4 + r;
        Sg[base + ((size_t)gi << 10) + gj] = f2bf(acc[m][c][r]);
      }
    }
  }
}

// ================= w normalize + beta-scale =================
__global__ __launch_bounds__(256) void wnorm2(const unsigned short* __restrict__ WNF,
    const float* __restrict__ Beta, unsigned short* __restrict__ WN,
    unsigned short* __restrict__ WB) {
  int row = blockIdx.x;
  int wave = threadIdx.x >> 6, lane = threadIdx.x & 63;
#pragma unroll
  for (int i = 0; i < 4; ++i) {
    int hh = wave * 4 + i;
    size_t idx = ((size_t)row << 10) + hh * 64 + lane;
    float v = bf2f(WNF[idx]);
    float ss = v * v;
#pragma unroll
    for (int off = 1; off < 64; off <<= 1) ss += __shfl_xor(ss, off);
    float wn = v * rsqrtf(ss + 1e-6f);
    WN[idx] = f2bf(wn);
    WB[idx] = f2bf(wn * Beta[row * 16 + hh]);
  }
}

// ================= inv64: U = (I + Ldiag)^-1 per (bh, ib64); grid (16,32) =================
__global__ __launch_bounds__(256) void inv64(const unsigned short* __restrict__ Lb,
    unsigned short* __restrict__ UI) {
  int ib = blockIdx.x, bh = blockIdx.y;
  int t = threadIdx.x;
  int s0 = ib * 64;
  size_t base = (size_t)bh << 20;
  __shared__ float LD[64 * 65];
  __shared__ unsigned short us[64 * 66];
#pragma unroll
  for (int i = 0; i < 16; ++i) {
    int lin = t + i * 256; int s = lin >> 6, r = lin & 63;
    LD[s * 65 + r] = bf2f(Lb[base + ((size_t)(s0 + s) << 10) + s0 + r]);
  }
  __syncthreads();
  if (t < 64) {                      // lane j = column j of inverse
    float cc[64];
#pragma unroll
    for (int s = 0; s < 64; ++s) cc[s] = (s == t) ? 1.f : 0.f;
#pragma unroll
    for (int r = 0; r < 63; ++r) {
      float val = cc[r];
#pragma unroll
      for (int s = r + 1; s < 64; ++s) cc[s] -= LD[s * 65 + r] * val;
    }
#pragma unroll
    for (int s = 0; s < 64; ++s) us[s * 66 + t] = f2bf(cc[s]);
  }
  __syncthreads();
  size_t ubase = ((size_t)(bh * 16 + ib)) << 12;
#pragma unroll
  for (int i = 0; i < 16; ++i) {
    int lin = t + i * 256; int s = lin >> 6, j = lin & 63;
    UI[ubase + s * 64 + j] = us[s * 66 + j];
  }
}

// ================= solve128: 128-row block step; band GEMM + MFMA substitution =================
__global__ __launch_bounds__(256) void solve128(const unsigned short* __restrict__ WN,
    const unsigned short* __restrict__ Kk, const unsigned short* __restrict__ Lb,
    const unsigned short* __restrict__ UI, unsigned short* __restrict__ CT, int ib) {
  int jb = blockIdx.x, bh = blockIdx.y;     // jb: 128-wide col slab, 0..ib
  int b = bh >> 4, h = bh & 15;
  int t = threadIdx.x, w = t >> 6, l = t & 63;
  int wr = w >> 1, wc = w & 1, fr = l & 15, fq = l >> 4;
  int s0 = ib * 128, j0 = jb * 128;
  size_t base = (size_t)bh << 20;
  __shared__ unsigned short sh[128 * 192];  // 48KB
  unsigned short* As = sh;
  unsigned short* Bs = sh + 128 * 64;
  unsigned short* rT = sh;                  // [128 j][128 s] bf16, overlays As+Bs
  unsigned short* Ctp = sh + 128 * 128;     // CtopT [128 j][64 s']
  const unsigned short* Wb_ = WN + ((size_t)b << 20) + h * 64;
  const unsigned short* Kb_ = Kk + ((size_t)b << 20) + h * 64;

  // ---- band: rect = W K^T - sum L*C  (128x128, acc in regs) ----
  f32x4 acc[4][4];
#pragma unroll
  for (int m = 0; m < 4; ++m)
#pragma unroll
    for (int c = 0; c < 4; ++c) acc[m][c] = (f32x4){0.f, 0.f, 0.f, 0.f};
  int nst = (jb == ib) ? 1 : 1 + 2 * (ib - jb);
  for (int st = 0; st < nst; ++st) {
    __syncthreads();
#pragma unroll
    for (int i = 0; i < 4; ++i) {
      int cid = t + i * 256;
      int row = cid >> 3, ch = cid & 7;
      int byt = ((row << 7) + (ch << 4)) ^ ((row & 7) << 4);
      u16x8 av, bv;
      if (st == 0) {
        av = *(const u16x8*)(Wb_ + ((size_t)(s0 + row) << 10) + ch * 8);
        bv = *(const u16x8*)(Kb_ + ((size_t)(j0 + row) << 10) + ch * 8);
      } else {
        int rb = 2 * jb + st - 1;
        av = *(const u16x8*)(Lb + base + ((size_t)(s0 + row) << 10) + rb * 64 + ch * 8);
        av ^= (unsigned short)0x8000;
        bv = *(const u16x8*)(CT + base + ((size_t)(j0 + row) << 10) + rb * 64 + ch * 8);
      }
      *(u16x8*)((char*)As + byt) = av;
      *(u16x8*)((char*)Bs + byt) = bv;
    }
    __syncthreads();
#pragma unroll
    for (int kh = 0; kh < 2; ++kh) {
      s16x8 af[4], bfv[4];
#pragma unroll
      for (int m = 0; m < 4; ++m) {
        int ra = wr * 64 + 16 * m + fr;
        af[m] = *(const s16x8*)((char*)As + (((ra << 7) + (kh << 6) + (fq << 4)) ^ ((ra & 7) << 4)));
      }
#pragma unroll
      for (int c = 0; c < 4; ++c) {
        int rb2 = wc * 64 + 16 * c + fr;
        bfv[c] = *(const s16x8*)((char*)Bs + (((rb2 << 7) + (kh << 6) + (fq << 4)) ^ ((rb2 & 7) << 4)));
      }
#pragma unroll
      for (int m = 0; m < 4; ++m)
#pragma unroll
        for (int c = 0; c < 4; ++c)
          acc[m][c] = __builtin_amdgcn_mfma_f32_16x16x32_bf16(af[m], bfv[c], acc[m][c], 0, 0, 0);
    }
  }
  __syncthreads();
  // ---- write rectT [j][s] bf16 (256B rows, XOR (j&15)<<4), mask diag slab ----
#pragma unroll
  for (int m = 0; m < 4; ++m) {
#pragma unroll
    for (int c = 0; c < 4; ++c) {
      int jl = wc * 64 + 16 * c + fr;
      int sb = wr * 64 + 16 * m + fq * 4;
      u16x4 pk;
#pragma unroll
      for (int r = 0; r < 4; ++r) {
        float v = acc[m][c][r];
        if (jb == ib && jl >= sb + r) v = 0.f;
        pk[r] = f2bf(v);
      }
      int byt = ((jl << 8) + (sb << 1)) ^ ((jl & 15) << 4);
      *(u16x4*)((char*)rT + byt) = pk;
    }
  }
  __syncthreads();
  // ---- (a) C_top = Ua @ rect_top : wave w owns cols jc=w*32 ----
  const unsigned short* Ua = UI + (((size_t)(bh * 16 + 2 * ib)) << 12);
  const unsigned short* Uc = UI + (((size_t)(bh * 16 + 2 * ib + 1)) << 12);
  int jc = w * 32;
  f32x4 a2[4][2];
#pragma unroll
  for (int m = 0; m < 4; ++m) { a2[m][0] = (f32x4){0.f,0.f,0.f,0.f}; a2[m][1] = (f32x4){0.f,0.f,0.f,0.f}; }
#pragma unroll
  for (int kh = 0; kh < 2; ++kh) {
    s16x8 ua[4];
#pragma unroll
    for (int m = 0; m < 4; ++m)
      ua[m] = *(const s16x8*)(Ua + (16 * m + fr) * 64 + kh * 32 + fq * 8);
#pragma unroll
    for (int c2 = 0; c2 < 2; ++c2) {
      int jl = jc + 16 * c2 + fr;
      int byt = ((jl << 8) + (kh << 6) + (fq << 4)) ^ ((jl & 15) << 4);
      s16x8 bb = *(const s16x8*)((char*)rT + byt);
#pragma unroll
      for (int m = 0; m < 4; ++m)
        a2[m][c2] = __builtin_amdgcn_mfma_f32_16x16x32_bf16(ua[m], bb, a2[m][c2], 0, 0, 0);
    }
  }
  // ---- (b) write CtopT [j][s'] (128B rows, XOR (j&7)<<4) ----
#pragma unroll
  for (int m = 0; m < 4; ++m) {
#pragma unroll
    for (int c2 = 0; c2 < 2; ++c2) {
      int jl = jc + 16 * c2 + fr;
      int sb = 16 * m + fq * 4;
      u16x4 pk;
#pragma unroll
      for (int r = 0; r < 4; ++r) pk[r] = f2bf(a2[m][c2][r]);
      int byt = ((jl << 7) + (sb << 1)) ^ ((jl & 7) << 4);
      *(u16x4*)((char*)Ctp + byt) = pk;
    }
  }
  __syncthreads();
  // ---- (c) rect_bot' = rect_bot - L_BA @ C_top ----
  f32x4 a3[4][2];
#pragma unroll
  for (int m = 0; m < 4; ++m) { a3[m][0] = (f32x4){0.f,0.f,0.f,0.f}; a3[m][1] = (f32x4){0.f,0.f,0.f,0.f}; }
#pragma unroll
  for (int kh = 0; kh < 2; ++kh) {
    s16x8 la[4];
#pragma unroll
    for (int m = 0; m < 4; ++m) {
      la[m] = *(const s16x8*)(Lb + base + ((size_t)(s0 + 64 + 16 * m + fr) << 10) + s0 + kh * 32 + fq * 8);
      la[m] ^= (short)0x8000;
    }
#pragma unroll
    for (int c2 = 0; c2 < 2; ++c2) {
      int jl = jc + 16 * c2 + fr;
      int byt = ((jl << 7) + (kh << 6) + (fq << 4)) ^ ((jl & 7) << 4);
      s16x8 bb = *(const s16x8*)((char*)Ctp + byt);
#pragma unroll
      for (int m = 0; m < 4; ++m)
        a3[m][c2] = __builtin_amdgcn_mfma_f32_16x16x32_bf16(la[m], bb, a3[m][c2], 0, 0, 0);
    }
  }
#pragma unroll
  for (int m = 0; m < 4; ++m) {
#pragma unroll
    for (int c2 = 0; c2 < 2; ++c2) {
      int jl = jc + 16 * c2 + fr;
      int sb = 64 + 16 * m + fq * 4;
      int byt = ((jl << 8) + (sb << 1)) ^ ((jl & 15) << 4);
      u16x4 old = *(const u16x4*)((char*)rT + byt);
      u16x4 pk;
#pragma unroll
      for (int r = 0; r < 4; ++r) pk[r] = f2bf(bf2f(old[r]) + a3[m][c2][r]);
      *(u16x4*)((char*)rT + byt) = pk;
    }
  }
  __syncthreads();
  // ---- (d) C_bot = Uc @ rect_bot' ; write straight to CT ----
  f32x4 a4[4][2];
#pragma unroll
  for (int m = 0; m < 4; ++m) { a4[m][0] = (f32x4){0.f,0.f,0.f,0.f}; a4[m][1] = (f32x4){0.f,0.f,0.f,0.f}; }
#pragma unroll
  for (int kh = 0; kh < 2; ++kh) {
    s16x8 ua[4];
#pragma unroll
    for (int m = 0; m < 4; ++m)
      ua[m] = *(const s16x8*)(Uc + (16 * m + fr) * 64 + kh * 32 + fq * 8);
#pragma unroll
    for (int c2 = 0; c2 < 2; ++c2) {
      int jl = jc + 16 * c2 + fr;
      int byt = ((jl << 8) + 128 + (kh << 6) + (fq << 4)) ^ ((jl & 15) << 4);
      s16x8 bb = *(const s16x8*)((char*)rT + byt);
#pragma unroll
      for (int m = 0; m < 4; ++m)
        a4[m][c2] = __builtin_amdgcn_mfma_f32_16x16x32_bf16(ua[m], bb, a4[m][c2], 0, 0, 0);
    }
  }
#pragma unroll
  for (int m = 0; m < 4; ++m) {
#pragma unroll
    for (int c2 = 0; c2 < 2; ++c2) {
      int jl = jc + 16 * c2 + fr;
      int sb = 64 + 16 * m + fq * 4;
      u16x4 pk;
#pragma unroll
      for (int r = 0; r < 4; ++r) pk[r] = f2bf(a4[m][c2][r]);
      *(u16x4*)(CT + base + ((size_t)(j0 + jl) << 10) + s0 + sb) = pk;
    }
  }
  // ---- write C_top from CtopT ----
#pragma unroll
  for (int i = 0; i < 4; ++i) {
    int lin = t + i * 256;
    int jl = lin >> 3, ch = lin & 7;
    int byt = ((jl << 7) + (ch << 4)) ^ ((jl & 7) << 4);
    u16x8 v = *(const u16x8*)((char*)Ctp + byt);
    *(u16x8*)(CT + base + ((size_t)(j0 + jl) << 10) + s0 + ch * 8) = v;
  }
}

// ================= rowstat: m,l per row (Fc_t cancels in softmax) =================
__global__ __launch_bounds__(256) void rowstat(const unsigned short* __restrict__ S,
    const float* __restrict__ Fc, float* __restrict__ MR, float* __restrict__ LR) {
  int bh = blockIdx.y;
  int t = blockIdx.x * 4 + (threadIdx.x >> 6);
  int l = threadIdx.x & 63;
  size_t base = (size_t)bh << 20;
  const unsigned short* srow = S + base + ((size_t)t << 10);
  float vals[16]; float vmax = -1e30f;
#pragma unroll
  for (int i = 0; i < 2; ++i) {
    int c0 = i * 512 + l * 8;
    u16x8 sv = *(const u16x8*)(srow + c0);
    float4 f0 = *(const float4*)(Fc + bh * 1024 + c0);
    float4 f1 = *(const float4*)(Fc + bh * 1024 + c0 + 4);
#pragma unroll
    for (int e = 0; e < 8; ++e) {
      float fc = e < 4 ? ((const float*)&f0)[e] : ((const float*)&f1)[e - 4];
      float v = (c0 + e <= t) ? bf2f(sv[e]) * SM_SCALE - fc : -1e30f;
      vals[i * 8 + e] = v; vmax = fmaxf(vmax, v);
    }
  }
#pragma unroll
  for (int o = 1; o < 64; o <<= 1) vmax = fmaxf(vmax, __shfl_xor(vmax, o));
  float sum = 0.f;
#pragma unroll
  for (int e = 0; e < 16; ++e) sum += __expf(vals[e] - vmax);
#pragma unroll
  for (int o = 1; o < 64; o <<= 1) sum += __shfl_xor(sum, o);
  if (l == 0) { MR[bh * 1024 + t] = vmax; LR[bh * 1024 + t] = sum; }
}

// ================= pv: O = P @ V with on-the-fly P; sorted 1D grid (512) =================
__global__ __launch_bounds__(256) void pv_kernel(const unsigned short* __restrict__ S,
    const unsigned short* __restrict__ VT, const float* __restrict__ Fc,
    const float* __restrict__ MR, const float* __restrict__ LR,
    unsigned short* __restrict__ Ob) {
  int idx = blockIdx.x;
  int bh = idx & 31, rank = idx >> 5;
  int tb = 15 - rank;
  int b = bh >> 4, h = bh & 15;
  int t0 = tb * 64;
  int t = threadIdx.x, w = t >> 6, l = t & 63, fr = l & 15, fq = l >> 4;
  __shared__ unsigned short Pl[64 * 64];
  size_t base = (size_t)bh << 20;
  f32x4 acc[4];
#pragma unroll
  for (int c = 0; c < 4; ++c) acc[c] = (f32x4){0.f,0.f,0.f,0.f};
  for (int jb = 0; jb <= tb; ++jb) {
    int j0 = jb * 64;
    __syncthreads();
#pragma unroll
    for (int i = 0; i < 2; ++i) {
      int cid = t + i * 256;
      int row = cid >> 3, ch = cid & 7;
      int grow = t0 + row;
      u16x8 sv = *(const u16x8*)(S + base + ((size_t)grow << 10) + j0 + ch * 8);
      float4 f0 = *(const float4*)(Fc + bh * 1024 + j0 + ch * 8);
      float4 f1 = *(const float4*)(Fc + bh * 1024 + j0 + ch * 8 + 4);
      float m = MR[bh * 1024 + grow];
      u16x8 pv;
#pragma unroll
      for (int e = 0; e < 8; ++e) {
        float fc = e < 4 ? ((const float*)&f0)[e] : ((const float*)&f1)[e - 4];
        float p = __expf(bf2f(sv[e]) * SM_SCALE - fc - m);
        if (jb == tb && ch * 8 + e > row) p = 0.f;
        pv[e] = f2bf(p);
      }
      int byt = ((row << 7) + (ch << 4)) ^ ((row & 7) << 4);
      *(u16x8*)((char*)Pl + byt) = pv;
    }
    __syncthreads();
#pragma unroll
    for (int kh = 0; kh < 2; ++kh) {
      int ra = 16 * w + fr;
      s16x8 a = *(const s16x8*)((char*)Pl + (((ra << 7) + (kh << 6) + (fq << 4)) ^ ((ra & 7) << 4)));
#pragma unroll
      for (int c = 0; c < 4; ++c) {
        s16x8 bb = *(const s16x8*)(VT + ((size_t)bh * 64 + 16 * c + fr) * 1024 + j0 + kh * 32 + fq * 8);
        acc[c] = __builtin_amdgcn_mfma_f32_16x16x32_bf16(a, bb, acc[c], 0, 0, 0);
      }
    }
  }
  float inv[4];
#pragma unroll
  for (int r = 0; r < 4; ++r) inv[r] = 1.f / LR[bh * 1024 + t0 + 16 * w + fq * 4 + r];
#pragma unroll
  for (int c = 0; c < 4; ++c) {
#pragma unroll
    for (int r = 0; r < 4; ++r) {
      int grow = t0 + 16 * w + fq * 4 + r;
      Ob[((size_t)(b * 1024) + grow) * 1024 + h * 64 + 16 * c + fr] = f2bf(acc[c][r] * inv[r]);
    }
  }
}

extern "C" void kernel_launch(void* const* d_in, const int* in_sizes, int n_in,
                              void* d_out, int out_size, void* d_ws, size_t ws_size,
                              hipStream_t stream) {
  const float* x    = (const float*)d_in[0];
  const float* Wq   = (const float*)d_in[1];
  const float* Wk   = (const float*)d_in[2];
  const float* Wv   = (const float*)d_in[3];
  const float* Wo   = (const float*)d_in[4];
  const float* Ww1  = (const float*)d_in[5];
  const float* Ww2  = (const float*)d_in[6];
  const float* Wb   = (const float*)d_in[7];
  const float* Wf   = (const float*)d_in[8];
  const float* delta= (const float*)d_in[9];

  char* ws = (char*)d_ws;
  unsigned short* xb   = (unsigned short*)(ws + OFF_XB);
  unsigned short* WqT  = (unsigned short*)(ws + OFF_WQT);
  float*          BL   = (float*)(ws + OFF_BL);
  unsigned short* WkT  = (unsigned short*)(ws + OFF_WKT);
  unsigned short* BFT  = (unsigned short*)(ws + OFF_BFT);
  unsigned short* WvT  = (unsigned short*)(ws + OFF_WVT);
  unsigned short* WoT  = (unsigned short*)(ws + OFF_WOT);
  unsigned short* W1T  = (unsigned short*)(ws + OFF_W1T);
  unsigned short* W2T  = (unsigned short*)(ws + OFF_W2T);
  float*          Beta = (float*)(ws + OFF_W1T);
  float*          Lf   = (float*)(ws + OFF_W2T);
  unsigned short* Q16  = (unsigned short*)(ws + OFF_Q16);
  unsigned short* K16  = (unsigned short*)(ws + OFF_K16);
  unsigned short* VT   = (unsigned short*)(ws + OFF_VT);
  unsigned short* WN16 = (unsigned short*)(ws + OFF_WN16);
  unsigned short* WB16 = (unsigned short*)(ws + OFF_WB16);
  unsigned short* WNF16= (unsigned short*)(ws + OFF_WNF);
  unsigned short* ObB  = (unsigned short*)(ws + OFF_OB);
  unsigned short* Wpre = (unsigned short*)(ws + OFF_WPRE);
  float*          Fc   = (float*)(ws + OFF_FC);
  unsigned short* Lbuf = (unsigned short*)(ws + OFF_L);
  unsigned short* Sbuf = (unsigned short*)(ws + OFF_L);
  unsigned short* CT   = (unsigned short*)(ws + OFF_CT);
  unsigned short* Gbuf = (unsigned short*)(ws + OFF_G);
  float*          MR   = (float*)(ws + OFF_MR);
  float*          LR   = (float*)(ws + OFF_LR);
  unsigned short* UI   = (unsigned short*)(ws + OFF_UI);

  dim3 blk(256);
  // weight transposes + x cast
  transpose4<<<dim3(16,16,4), blk, 0, stream>>>(Wq, Wk, Wv, Wo, WqT, WkT, WvT, WoT);
  transpose_cast<<<dim3(1,16),  blk, 0, stream>>>(Ww1, W1T, 1024, 64);
  transpose_cast<<<dim3(16,1),  blk, 0, stream>>>(Ww2, W2T, 64, 1024);
  cast_bf16<<<1024, blk, 0, stream>>>(x, xb, 2048 * 1024);
  // projections
  gemm_nt<0><<<dim3(16,32,1), blk, 0, stream>>>(xb, WqT, Q16, 2048, 1024, 1024, 0, 0, 0);
  gemm_nt<0><<<dim3(16,32,1), blk, 0, stream>>>(xb, WkT, K16, 2048, 1024, 1024, 0, 0, 0);
  gemm_nt<0><<<dim3(16,16,2), blk, 0, stream>>>(WvT, xb, VT, 1024, 1024, 1024,
                                                0, (size_t)1 << 20, (size_t)1 << 20);
  gemm_nt<0><<<dim3(1,32,1),  blk, 0, stream>>>(xb, W1T, Wpre, 2048, 64, 1024, 0, 0, 0);
  gemm_nt<0><<<dim3(16,32,1), blk, 0, stream>>>(Wpre, W2T, WNF16, 2048, 1024, 64, 0, 0, 0);
  // beta / log_f via MFMA (BFT overlays WkT -> after K proj)
  bfprep<<<256, blk, 0, stream>>>(Wb, Wf, BFT);
  gemm_nt<1><<<dim3(1,32,1), blk, 0, stream>>>(xb, BFT, BL, 2048, 64, 1024, 0, 0, 0);
  bg_kernel2<<<128, blk, 0, stream>>>(BL, Beta, Lf, delta);
  fc_kernel<<<32, blk, 0, stream>>>(Lf, Fc);
  wnorm2<<<2048, blk, 0, stream>>>(WNF16, Beta, WN16, WB16);
  // L and G (dense triangular 1D grids)
  pair128s<1><<<dim3(36 * 32), blk, 0, stream>>>(WN16, WB16, Lbuf);
  pair128s<0><<<dim3(36 * 32), blk, 0, stream>>>(Q16, WB16, Gbuf);
  // triangular solve: 64-block inverses + 8 x 128-block MFMA steps
  inv64<<<dim3(16,32), blk, 0, stream>>>(Lbuf, UI);
  for (int ib = 0; ib < 8; ++ib)
    solve128<<<dim3(ib + 1, 32), blk, 0, stream>>>(WN16, K16, Lbuf, UI, CT, ib);
  // S = QK^T - G C (sorted band grid; reuses L region)
  score128s<<<dim3(36 * 32), blk, 0, stream>>>(Q16, K16, Gbuf, CT, Sbuf);
  // softmax stats + PV
  rowstat<<<dim3(256,32), blk, 0, stream>>>(Sbuf, Fc, MR, LR);
  pv_kernel<<<dim3(512), blk, 0, stream>>>(Sbuf, VT, Fc, MR, LR, ObB);
  // output projection (f32 out)
  gemm_nt<1><<<dim3(16,32,1), blk, 0, stream>>>(ObB, WoT, d_out, 2048, 1024, 1024, 0, 0, 0);
}

// Round 6
// 364.550 us; speedup vs baseline: 11.1860x; 1.1932x over previous
//
#include <hip/hip_runtime.h>
#include <hip/hip_bf16.h>

#define DEV static __device__ __forceinline__

constexpr float SM_SCALE = 0.125f;   // hd^-0.5, hd=64

typedef __attribute__((ext_vector_type(8))) short s16x8;
typedef __attribute__((ext_vector_type(8))) unsigned short u16x8;
typedef __attribute__((ext_vector_type(4))) unsigned short u16x4;
typedef __attribute__((ext_vector_type(4))) float f32x4;

DEV float bf2f(unsigned short u) {
  union { unsigned int i; float f; } v; v.i = ((unsigned int)u) << 16; return v.f;
}
DEV unsigned short f2bf(float f) {
  union { float f; unsigned int i; } v; v.f = f;
  unsigned int r = v.i + 0x7fffu + ((v.i >> 16) & 1u);
  return (unsigned short)(r >> 16);
}
DEV void tri_unrank(int r, int& k, int& i) {
  k = (int)((sqrtf(8.f * r + 1.f) - 1.f) * 0.5f);
  while (k * (k + 1) / 2 > r) --k;
  while ((k + 1) * (k + 2) / 2 <= r) ++k;
  i = r - k * (k + 1) / 2;
}

// ---------- workspace layout (bytes) ----------
constexpr size_t OFF_XB   = 0;                       // 4MB xb bf16 [2048][1024]
constexpr size_t OFF_WQT  = 4194304;                 // 2MB; reused as BL (f32 2048x64)
constexpr size_t OFF_BL   = 4194304;
constexpr size_t OFF_WKT  = 6291456;                 // 2MB; reused as BFT (bf16 64x1024)
constexpr size_t OFF_BFT  = 6291456;
constexpr size_t OFF_WVT  = 8388608;
constexpr size_t OFF_WOT  = 10485760;
constexpr size_t OFF_W1T  = 12582912;                // 128KB (reused as Beta f32)
constexpr size_t OFF_W2T  = 12713984;                // 128KB
constexpr size_t OFF_Q16  = 12845056;                // 4MB bf16 2048x1024
constexpr size_t OFF_K16  = 17039360;                // 4MB
constexpr size_t OFF_VT   = 21233664;                // 4MB  VT[b][64h*d][1024n]
constexpr size_t OFF_WN16 = 25427968;                // 4MB
constexpr size_t OFF_WB16 = 29622272;                // 4MB
constexpr size_t OFF_WNF  = 33816576;                // 4MB (reused as Ob)
constexpr size_t OFF_OB   = 33816576;
constexpr size_t OFF_WPRE = 38010880;                // 256KB
constexpr size_t OFF_FC   = 38273024;                // 128KB
constexpr size_t OFF_L    = 38404096;                // 64MB (reused as S)
constexpr size_t OFF_CT   = 105512960;               // 64MB
constexpr size_t OFF_G    = 172621824;               // 64MB
constexpr size_t OFF_MR   = 239730688;               // 128KB f32 [32][1024]
constexpr size_t OFF_LR   = 239861760;               // 128KB
constexpr size_t OFF_UI   = 239992832;               // 4MB bf16 [32][16][64][64]
constexpr size_t OFF_U128 = 244187136;               // 8MB bf16 [32][8][128][128] -> end 252,575,744

// ================= prep =================
__global__ __launch_bounds__(256) void cast_bf16(const float* __restrict__ src,
    unsigned short* __restrict__ dst, int n) {
  int i = (blockIdx.x * 256 + threadIdx.x) * 8;
  if (i >= n) return;
  float4 a = *(const float4*)(src + i);
  float4 b = *(const float4*)(src + i + 4);
  u16x8 o;
  o[0] = f2bf(a.x); o[1] = f2bf(a.y); o[2] = f2bf(a.z); o[3] = f2bf(a.w);
  o[4] = f2bf(b.x); o[5] = f2bf(b.y); o[6] = f2bf(b.z); o[7] = f2bf(b.w);
  *(u16x8*)(dst + i) = o;
}

// 6-way fused transpose-cast; grid (16,16,6)
__global__ __launch_bounds__(256) void transpose6(
    const float* __restrict__ W0, const float* __restrict__ W1,
    const float* __restrict__ W2, const float* __restrict__ W3,
    const float* __restrict__ Ww1, const float* __restrict__ Ww2,
    unsigned short* __restrict__ D0, unsigned short* __restrict__ D1,
    unsigned short* __restrict__ D2, unsigned short* __restrict__ D3,
    unsigned short* __restrict__ D4, unsigned short* __restrict__ D5) {
  int z = blockIdx.z;
  const float* src; unsigned short* dst; int R, C;
  if (z == 0) { src = W0; dst = D0; R = 1024; C = 1024; }
  else if (z == 1) { src = W1; dst = D1; R = 1024; C = 1024; }
  else if (z == 2) { src = W2; dst = D2; R = 1024; C = 1024; }
  else if (z == 3) { src = W3; dst = D3; R = 1024; C = 1024; }
  else if (z == 4) { src = Ww1; dst = D4; R = 1024; C = 64; }
  else { src = Ww2; dst = D5; R = 64; C = 1024; }
  int c0 = blockIdx.x * 64, r0 = blockIdx.y * 64;
  if (c0 >= C || r0 >= R) return;
  __shared__ float tile[64 * 65];
  int t = threadIdx.x;
#pragma unroll
  for (int i = 0; i < 16; ++i) {
    int lin = t + i * 256; int r = lin >> 6, c = lin & 63;
    tile[r * 65 + c] = src[(size_t)(r0 + r) * C + c0 + c];
  }
  __syncthreads();
#pragma unroll
  for (int i = 0; i < 16; ++i) {
    int lin = t + i * 256; int c = lin >> 6, r = lin & 63;
    dst[(size_t)(c0 + c) * R + r0 + r] = f2bf(tile[r * 65 + c]);
  }
}

// BFT (64x1024) = [Wb^T ; Wf^T ; 0]; grid 256
__global__ __launch_bounds__(256) void bfprep(const float* __restrict__ Wb,
    const float* __restrict__ Wf, unsigned short* __restrict__ BFT) {
  int idx = blockIdx.x * 256 + threadIdx.x;   // 65536
  int j = idx >> 10, i = idx & 1023;
  float v = 0.f;
  if (j < 16) v = Wb[i * 16 + j];
  else if (j < 32) v = Wf[i * 16 + (j - 16)];
  BFT[idx] = f2bf(v);
}

// beta + log_sigmoid + cumsum fused; grid 32 (bh)
__global__ __launch_bounds__(256) void bgfc(const float* __restrict__ BL,
    const float* __restrict__ delta, float* __restrict__ Beta, float* __restrict__ Fc) {
  int bh = blockIdx.x;
  int b = bh >> 4, h = bh & 15;
  int t = threadIdx.x;
  __shared__ float buf[1024];
  __shared__ float tsum[256];
  float dh = delta[h];
#pragma unroll
  for (int i = 0; i < 4; ++i) {
    int n = t + i * 256;
    int row = (b << 10) + n;
    float braw = BL[row * 64 + h];
    Beta[row * 16 + h] = 2.f / (1.f + __expf(-braw));
    float lraw = BL[row * 64 + 16 + h] + dh;
    buf[n] = (lraw >= 0.f) ? -log1pf(__expf(-lraw)) : (lraw - log1pf(__expf(lraw)));
  }
  __syncthreads();
  float loc[4]; float run = 0.f;
#pragma unroll
  for (int i = 0; i < 4; ++i) { run += buf[t * 4 + i]; loc[i] = run; }
  tsum[t] = run;
  __syncthreads();
  for (int off = 1; off < 256; off <<= 1) {
    float add = (t >= off) ? tsum[t - off] : 0.f;
    __syncthreads();
    tsum[t] += add;
    __syncthreads();
  }
  float excl = tsum[t] - run;
#pragma unroll
  for (int i = 0; i < 4; ++i) Fc[bh * 1024 + t * 4 + i] = excl + loc[i];
}

// ================= mega projection: Q,K (128^2) + VT (2 batches), 384 blocks =================
__global__ __launch_bounds__(256) void proj_big(const unsigned short* __restrict__ xb,
    const unsigned short* __restrict__ WqT, const unsigned short* __restrict__ WkT,
    const unsigned short* __restrict__ WvT, unsigned short* __restrict__ Q16,
    unsigned short* __restrict__ K16, unsigned short* __restrict__ VT) {
  int idx = blockIdx.x;
  const unsigned short *A, *BT; unsigned short* out; int m0, n0;
  if (idx < 256) {
    int my = idx >> 4, nx = idx & 15;
    m0 = my * 128; A = xb;
    if (nx < 8) { BT = WqT; out = Q16; n0 = nx * 128; }
    else { BT = WkT; out = K16; n0 = (nx - 8) * 128; }
  } else {
    int r = idx - 256; int bz = r >> 6; int rem = r & 63;
    m0 = (rem >> 3) * 128; n0 = (rem & 7) * 128;
    A = WvT; BT = xb + ((size_t)bz << 20); out = VT + ((size_t)bz << 20);
  }
  int t = threadIdx.x;
  int w = t >> 6, l = t & 63;
  int wr = w >> 1, wc = w & 1;
  int fr = l & 15, fq = l >> 4;
  __shared__ unsigned short As[128 * 64];
  __shared__ unsigned short Bs[128 * 64];
  f32x4 acc[4][4];
#pragma unroll
  for (int m = 0; m < 4; ++m)
#pragma unroll
    for (int c = 0; c < 4; ++c) acc[m][c] = (f32x4){0.f, 0.f, 0.f, 0.f};
  for (int k0 = 0; k0 < 1024; k0 += 64) {
    __syncthreads();
#pragma unroll
    for (int i = 0; i < 4; ++i) {
      int cid = t + i * 256;
      int row = cid >> 3, ch = cid & 7;
      int byt = ((row << 7) + (ch << 4)) ^ ((row & 7) << 4);
      *(u16x8*)((char*)As + byt) = *(const u16x8*)(A + (size_t)(m0 + row) * 1024 + k0 + ch * 8);
      *(u16x8*)((char*)Bs + byt) = *(const u16x8*)(BT + (size_t)(n0 + row) * 1024 + k0 + ch * 8);
    }
    __syncthreads();
#pragma unroll
    for (int kh = 0; kh < 2; ++kh) {
      s16x8 af[4], bfv[4];
#pragma unroll
      for (int m = 0; m < 4; ++m) {
        int ra = wr * 64 + 16 * m + fr;
        af[m] = *(const s16x8*)((char*)As + (((ra << 7) + (kh << 6) + (fq << 4)) ^ ((ra & 7) << 4)));
      }
#pragma unroll
      for (int c = 0; c < 4; ++c) {
        int rb = wc * 64 + 16 * c + fr;
        bfv[c] = *(const s16x8*)((char*)Bs + (((rb << 7) + (kh << 6) + (fq << 4)) ^ ((rb & 7) << 4)));
      }
#pragma unroll
      for (int m = 0; m < 4; ++m)
#pragma unroll
        for (int c = 0; c < 4; ++c)
          acc[m][c] = __builtin_amdgcn_mfma_f32_16x16x32_bf16(af[m], bfv[c], acc[m][c], 0, 0, 0);
    }
  }
#pragma unroll
  for (int m = 0; m < 4; ++m) {
#pragma unroll
    for (int c = 0; c < 4; ++c) {
      int col = n0 + wc * 64 + 16 * c + fr;
#pragma unroll
      for (int r = 0; r < 4; ++r) {
        int grow = m0 + wr * 64 + 16 * m + fq * 4 + r;
        out[(size_t)grow * 1024 + col] = f2bf(acc[m][c][r]);
      }
    }
  }
}

// dual small projection: nt=0 -> Wpre (bf16), nt=1 -> BL (f32); grid (2,32)
__global__ __launch_bounds__(256) void proj_small(const unsigned short* __restrict__ A,
    const unsigned short* __restrict__ W1T, const unsigned short* __restrict__ BFT,
    unsigned short* __restrict__ Wpre, float* __restrict__ BL) {
  int nt = blockIdx.x;
  const unsigned short* BT = nt ? BFT : W1T;
  __shared__ unsigned short As[64 * 64];
  __shared__ unsigned short Bs[64 * 64];
  int m0 = blockIdx.y * 64;
  int t = threadIdx.x;
  int w = t >> 6, l = t & 63, fr = l & 15;
  int koB = (l >> 4) * 16;
  f32x4 acc[4];
#pragma unroll
  for (int c = 0; c < 4; ++c) acc[c] = (f32x4){0.f, 0.f, 0.f, 0.f};
  for (int k0 = 0; k0 < 1024; k0 += 64) {
    __syncthreads();
#pragma unroll
    for (int i = 0; i < 2; ++i) {
      int cid = t + i * 256;
      int row = cid >> 3, ch = cid & 7;
      int byt = ((row << 7) + (ch << 4)) ^ ((row & 7) << 4);
      *(u16x8*)((char*)As + byt) = *(const u16x8*)(A + (size_t)(m0 + row) * 1024 + k0 + ch * 8);
      *(u16x8*)((char*)Bs + byt) = *(const u16x8*)(BT + (size_t)row * 1024 + k0 + ch * 8);
    }
    __syncthreads();
#pragma unroll
    for (int kh = 0; kh < 2; ++kh) {
      int ra = 16 * w + fr;
      s16x8 a = *(const s16x8*)((char*)As + (((ra << 7) + (kh << 6) + koB) ^ ((ra & 7) << 4)));
#pragma unroll
      for (int c = 0; c < 4; ++c) {
        int rb = 16 * c + fr;
        s16x8 bb = *(const s16x8*)((char*)Bs + (((rb << 7) + (kh << 6) + koB) ^ ((rb & 7) << 4)));
        acc[c] = __builtin_amdgcn_mfma_f32_16x16x32_bf16(a, bb, acc[c], 0, 0, 0);
      }
    }
  }
  int rbase = m0 + 16 * w + ((l >> 4) << 2);
#pragma unroll
  for (int c = 0; c < 4; ++c) {
    int col = 16 * c + fr;
#pragma unroll
    for (int r = 0; r < 4; ++r) {
      if (nt) BL[(size_t)(rbase + r) * 64 + col] = acc[c][r];
      else Wpre[(size_t)(rbase + r) * 64 + col] = f2bf(acc[c][r]);
    }
  }
}

// ================= 64-tile bf16 NT GEMM (WNF and output projection) =================
template<int F32OUT>
__global__ __launch_bounds__(256) void gemm_nt(const unsigned short* __restrict__ A,
    const unsigned short* __restrict__ BT, void* __restrict__ out,
    int M, int N, int K) {
  __shared__ unsigned short As[64 * 64];
  __shared__ unsigned short Bs[64 * 64];
  int m0 = blockIdx.y * 64, n0 = blockIdx.x * 64;
  int t = threadIdx.x;
  int w = t >> 6, l = t & 63, fr = l & 15;
  int koB = (l >> 4) * 16;
  f32x4 acc[4];
#pragma unroll
  for (int c = 0; c < 4; ++c) acc[c] = (f32x4){0.f, 0.f, 0.f, 0.f};
  for (int k0 = 0; k0 < K; k0 += 64) {
    __syncthreads();
#pragma unroll
    for (int i = 0; i < 2; ++i) {
      int cid = t + i * 256;
      int row = cid >> 3, ch = cid & 7;
      int byt = ((row << 7) + (ch << 4)) ^ ((row & 7) << 4);
      *(u16x8*)((char*)As + byt) = *(const u16x8*)(A + (size_t)(m0 + row) * K + k0 + ch * 8);
      *(u16x8*)((char*)Bs + byt) = *(const u16x8*)(BT + (size_t)(n0 + row) * K + k0 + ch * 8);
    }
    __syncthreads();
#pragma unroll
    for (int kh = 0; kh < 2; ++kh) {
      int ra = 16 * w + fr;
      s16x8 a = *(const s16x8*)((char*)As + (((ra << 7) + (kh << 6) + koB) ^ ((ra & 7) << 4)));
#pragma unroll
      for (int c = 0; c < 4; ++c) {
        int rb = 16 * c + fr;
        s16x8 bb = *(const s16x8*)((char*)Bs + (((rb << 7) + (kh << 6) + koB) ^ ((rb & 7) << 4)));
        acc[c] = __builtin_amdgcn_mfma_f32_16x16x32_bf16(a, bb, acc[c], 0, 0, 0);
      }
    }
  }
  int rbase = m0 + 16 * w + ((l >> 4) << 2);
#pragma unroll
  for (int c = 0; c < 4; ++c) {
    int col = n0 + 16 * c + fr;
#pragma unroll
    for (int r = 0; r < 4; ++r) {
      if (F32OUT) ((float*)out)[(size_t)(rbase + r) * N + col] = acc[c][r];
      else ((unsigned short*)out)[(size_t)(rbase + r) * N + col] = f2bf(acc[c][r]);
    }
  }
}

// ================= w normalize + beta-scale =================
__global__ __launch_bounds__(256) void wnorm2(const unsigned short* __restrict__ WNF,
    const float* __restrict__ Beta, unsigned short* __restrict__ WN,
    unsigned short* __restrict__ WB) {
  int row = blockIdx.x;
  int wave = threadIdx.x >> 6, lane = threadIdx.x & 63;
#pragma unroll
  for (int i = 0; i < 4; ++i) {
    int hh = wave * 4 + i;
    size_t idx = ((size_t)row << 10) + hh * 64 + lane;
    float v = bf2f(WNF[idx]);
    float ss = v * v;
#pragma unroll
    for (int off = 1; off < 64; off <<= 1) ss += __shfl_xor(ss, off);
    float wn = v * rsqrtf(ss + 1e-6f);
    WN[idx] = f2bf(wn);
    WB[idx] = f2bf(wn * Beta[row * 16 + hh]);
  }
}

// ================= pair fused: L and G in one block =================
__global__ __launch_bounds__(256) void pairLG(const unsigned short* __restrict__ WN,
    const unsigned short* __restrict__ Q, const unsigned short* __restrict__ WB,
    unsigned short* __restrict__ Lg, unsigned short* __restrict__ Gg) {
  int idx = blockIdx.x;
  int bh = idx & 31, r0r = idx >> 5;
  int tb2, jb2; tri_unrank(r0r, tb2, jb2);
  int b = bh >> 4, h = bh & 15;
  int m0 = tb2 * 128, n0 = jb2 * 128;
  int t = threadIdx.x;
  int w = t >> 6, l = t & 63;
  int wr = w >> 1, wc = w & 1;
  int fr = l & 15, fq = l >> 4;
  __shared__ unsigned short As[128 * 64];
  __shared__ unsigned short Bs[128 * 64];
  const unsigned short* WNb = WN + ((size_t)b << 20) + h * 64;
  const unsigned short* Qb  = Q + ((size_t)b << 20) + h * 64;
  const unsigned short* WBb = WB + ((size_t)b << 20) + h * 64;
  size_t base = (size_t)bh << 20;
  // stage WN(m0) + WB(n0)
#pragma unroll
  for (int i = 0; i < 4; ++i) {
    int cid = t + i * 256;
    int row = cid >> 3, ch = cid & 7;
    int byt = ((row << 7) + (ch << 4)) ^ ((row & 7) << 4);
    *(u16x8*)((char*)As + byt) = *(const u16x8*)(WNb + ((size_t)(m0 + row) << 10) + ch * 8);
    *(u16x8*)((char*)Bs + byt) = *(const u16x8*)(WBb + ((size_t)(n0 + row) << 10) + ch * 8);
  }
  __syncthreads();
  for (int pass = 0; pass < 2; ++pass) {
    f32x4 acc[4][4];
#pragma unroll
    for (int m = 0; m < 4; ++m)
#pragma unroll
      for (int c = 0; c < 4; ++c) acc[m][c] = (f32x4){0.f, 0.f, 0.f, 0.f};
#pragma unroll
    for (int kh = 0; kh < 2; ++kh) {
      s16x8 af[4], bfv[4];
#pragma unroll
      for (int m = 0; m < 4; ++m) {
        int ra = wr * 64 + 16 * m + fr;
        af[m] = *(const s16x8*)((char*)As + (((ra << 7) + (kh << 6) + (fq << 4)) ^ ((ra & 7) << 4)));
      }
#pragma unroll
      for (int c = 0; c < 4; ++c) {
        int rb = wc * 64 + 16 * c + fr;
        bfv[c] = *(const s16x8*)((char*)Bs + (((rb << 7) + (kh << 6) + (fq << 4)) ^ ((rb & 7) << 4)));
      }
#pragma unroll
      for (int m = 0; m < 4; ++m)
#pragma unroll
        for (int c = 0; c < 4; ++c)
          acc[m][c] = __builtin_amdgcn_mfma_f32_16x16x32_bf16(af[m], bfv[c], acc[m][c], 0, 0, 0);
    }
    unsigned short* dst = pass ? Gg : Lg;
#pragma unroll
    for (int m = 0; m < 4; ++m) {
#pragma unroll
      for (int c = 0; c < 4; ++c) {
        int gj = n0 + wc * 64 + 16 * c + fr;
#pragma unroll
        for (int r = 0; r < 4; ++r) {
          int gi = m0 + wr * 64 + 16 * m + fq * 4 + r;
          bool keep = pass ? (gj <= gi) : (gj < gi);
          dst[base + ((size_t)gi << 10) + gj] = f2bf(keep ? acc[m][c][r] : 0.f);
        }
      }
    }
    if (pass == 0) {
      __syncthreads();   // all MFMA reads of As done
#pragma unroll
      for (int i = 0; i < 4; ++i) {
        int cid = t + i * 256;
        int row = cid >> 3, ch = cid & 7;
        int byt = ((row << 7) + (ch << 4)) ^ ((row & 7) << 4);
        *(u16x8*)((char*)As + byt) = *(const u16x8*)(Qb + ((size_t)(m0 + row) << 10) + ch * 8);
      }
      __syncthreads();
    }
  }
}

// ================= score: S = Q K^T - G @ C, sorted 1D grid =================
__global__ __launch_bounds__(256) void score128s(const unsigned short* __restrict__ Q,
    const unsigned short* __restrict__ Kk, const unsigned short* __restrict__ G,
    const unsigned short* __restrict__ CT, unsigned short* __restrict__ Sg) {
  int idx = blockIdx.x;
  int bh = idx & 31, r0r = idx >> 5;
  int k, i; tri_unrank(r0r, k, i);
  int tb2 = (7 - k) + i, jb2 = i;
  int b = bh >> 4, h = bh & 15;
  int m0 = tb2 * 128, n0 = jb2 * 128;
  int t = threadIdx.x;
  int w = t >> 6, l = t & 63;
  int wr = w >> 1, wc = w & 1;
  int fr = l & 15, fq = l >> 4;
  __shared__ unsigned short As[128 * 64];
  __shared__ unsigned short Bs[128 * 64];
  size_t base = (size_t)bh << 20;
  const unsigned short* Qb_ = Q + ((size_t)b << 20) + h * 64;
  const unsigned short* Kb_ = Kk + ((size_t)b << 20) + h * 64;
  const unsigned short* Gb_ = G + base;
  const unsigned short* Cb_ = CT + base;
  int kbase = jb2 * 128;
  int nsteps = 1 + (tb2 - jb2 + 1) * 2;
  f32x4 acc[4][4];
#pragma unroll
  for (int m = 0; m < 4; ++m)
#pragma unroll
    for (int c = 0; c < 4; ++c) acc[m][c] = (f32x4){0.f, 0.f, 0.f, 0.f};
  for (int step = 0; step < nsteps; ++step) {
    const unsigned short* pa; const unsigned short* pb; int koff; bool neg;
    if (step == 0) { pa = Qb_; pb = Kb_; koff = 0; neg = false; }
    else { pa = Gb_; pb = Cb_; koff = kbase + (step - 1) * 64; neg = true; }
    __syncthreads();
#pragma unroll
    for (int i2 = 0; i2 < 4; ++i2) {
      int cid = t + i2 * 256;
      int row = cid >> 3, ch = cid & 7;
      int byt = ((row << 7) + (ch << 4)) ^ ((row & 7) << 4);
      u16x8 av = *(const u16x8*)(pa + ((size_t)(m0 + row) << 10) + koff + ch * 8);
      if (neg) av ^= (unsigned short)0x8000;
      *(u16x8*)((char*)As + byt) = av;
      *(u16x8*)((char*)Bs + byt) = *(const u16x8*)(pb + ((size_t)(n0 + row) << 10) + koff + ch * 8);
    }
    __syncthreads();
#pragma unroll
    for (int kh = 0; kh < 2; ++kh) {
      s16x8 af[4], bfv[4];
#pragma unroll
      for (int m = 0; m < 4; ++m) {
        int ra = wr * 64 + 16 * m + fr;
        af[m] = *(const s16x8*)((char*)As + (((ra << 7) + (kh << 6) + (fq << 4)) ^ ((ra & 7) << 4)));
      }
#pragma unroll
      for (int c = 0; c < 4; ++c) {
        int rb = wc * 64 + 16 * c + fr;
        bfv[c] = *(const s16x8*)((char*)Bs + (((rb << 7) + (kh << 6) + (fq << 4)) ^ ((rb & 7) << 4)));
      }
#pragma unroll
      for (int m = 0; m < 4; ++m)
#pragma unroll
        for (int c = 0; c < 4; ++c)
          acc[m][c] = __builtin_amdgcn_mfma_f32_16x16x32_bf16(af[m], bfv[c], acc[m][c], 0, 0, 0);
    }
  }
#pragma unroll
  for (int m = 0; m < 4; ++m) {
#pragma unroll
    for (int c = 0; c < 4; ++c) {
      int gj = n0 + wc * 64 + 16 * c + fr;
#pragma unroll
      for (int r = 0; r < 4; ++r) {
        int gi = m0 + wr * 64 + 16 * m + fq * 4 + r;
        Sg[base + ((size_t)gi << 10) + gj] = f2bf(acc[m][c][r]);
      }
    }
  }
}

// ================= inv64: U = (I + Ldiag)^-1 per (bh, ib64); grid (16,32) =================
__global__ __launch_bounds__(256) void inv64(const unsigned short* __restrict__ Lb,
    unsigned short* __restrict__ UI) {
  int ib = blockIdx.x, bh = blockIdx.y;
  int t = threadIdx.x;
  int s0 = ib * 64;
  size_t base = (size_t)bh << 20;
  __shared__ float LD[64 * 65];
  __shared__ unsigned short us[64 * 66];
#pragma unroll
  for (int i = 0; i < 16; ++i) {
    int lin = t + i * 256; int s = lin >> 6, r = lin & 63;
    LD[s * 65 + r] = bf2f(Lb[base + ((size_t)(s0 + s) << 10) + s0 + r]);
  }
  __syncthreads();
  if (t < 64) {                      // lane j = column j of inverse
    float cc[64];
#pragma unroll
    for (int s = 0; s < 64; ++s) cc[s] = (s == t) ? 1.f : 0.f;
#pragma unroll
    for (int r = 0; r < 63; ++r) {
      float val = cc[r];
#pragma unroll
      for (int s = r + 1; s < 64; ++s) cc[s] -= LD[s * 65 + r] * val;
    }
#pragma unroll
    for (int s = 0; s < 64; ++s) us[s * 66 + t] = f2bf(cc[s]);
  }
  __syncthreads();
  size_t ubase = ((size_t)(bh * 16 + ib)) << 12;
#pragma unroll
  for (int i = 0; i < 16; ++i) {
    int lin = t + i * 256; int s = lin >> 6, j = lin & 63;
    UI[ubase + s * 64 + j] = us[s * 66 + j];
  }
}

// ================= u128build: U128 = [[Ua,0],[-Uc L_BA Ua, Uc]]; grid (8,32) =================
__global__ __launch_bounds__(256) void u128build(const unsigned short* __restrict__ Lb,
    const unsigned short* __restrict__ UI, unsigned short* __restrict__ U128) {
  int ib = blockIdx.x, bh = blockIdx.y;
  int t = threadIdx.x, w = t >> 6, l = t & 63, fr = l & 15, fq = l >> 4;
  int s0 = ib * 128;
  size_t base = (size_t)bh << 20;
  const unsigned short* Ua = UI + (((size_t)(bh * 16 + 2 * ib)) << 12);
  const unsigned short* Uc = UI + (((size_t)(bh * 16 + 2 * ib + 1)) << 12);
  unsigned short* Uo = U128 + (((size_t)(bh * 8 + ib)) << 14);
  __shared__ unsigned short UaT[64 * 64];
  __shared__ unsigned short T1T[64 * 64];
  // stage UaT transposed (swizzled 128B rows)
#pragma unroll
  for (int i = 0; i < 2; ++i) {
    int cid = t + i * 256;
    int s = cid >> 3, ch = cid & 7;
    u16x8 v = *(const u16x8*)(Ua + s * 64 + ch * 8);
#pragma unroll
    for (int e = 0; e < 8; ++e) {
      int j = ch * 8 + e;
      int byt = ((j << 7) + (s << 1)) ^ ((j & 7) << 4);
      *(unsigned short*)((char*)UaT + byt) = v[e];
    }
  }
  // copies: top-left Ua, top-right 0, bottom-right Uc
#pragma unroll
  for (int i = 0; i < 8; ++i) {
    int cid = t + i * 256;            // 0..2047
    int row = cid >> 4, ch = cid & 15;
    if (row < 64) {
      if (ch < 8) *(u16x8*)(Uo + row * 128 + ch * 8) = *(const u16x8*)(Ua + row * 64 + ch * 8);
      else { u16x8 z = {0,0,0,0,0,0,0,0}; *(u16x8*)(Uo + row * 128 + ch * 8) = z; }
    } else if (ch >= 8) {
      *(u16x8*)(Uo + row * 128 + ch * 8) = *(const u16x8*)(Uc + (row - 64) * 64 + (ch - 8) * 8);
    }
  }
  __syncthreads();
  // T1 = L_BA @ Ua  (wave w: rows 16w..16w+15)
  f32x4 a1[4];
#pragma unroll
  for (int c = 0; c < 4; ++c) a1[c] = (f32x4){0.f, 0.f, 0.f, 0.f};
#pragma unroll
  for (int kc = 0; kc < 2; ++kc) {
    s16x8 af = *(const s16x8*)(Lb + base + ((size_t)(s0 + 64 + 16 * w + fr) << 10) + s0 + kc * 32 + fq * 8);
#pragma unroll
    for (int c = 0; c < 4; ++c) {
      int j = 16 * c + fr;
      s16x8 bb = *(const s16x8*)((char*)UaT + (((j << 7) + (kc << 6) + (fq << 4)) ^ ((j & 7) << 4)));
      a1[c] = __builtin_amdgcn_mfma_f32_16x16x32_bf16(af, bb, a1[c], 0, 0, 0);
    }
  }
#pragma unroll
  for (int c = 0; c < 4; ++c) {
    int gj = 16 * c + fr;
    int sb = 16 * w + fq * 4;
    u16x4 pk;
#pragma unroll
    for (int r = 0; r < 4; ++r) pk[r] = f2bf(a1[c][r]);
    *(u16x4*)((char*)T1T + (((gj << 7) + (sb << 1)) ^ ((gj & 7) << 4))) = pk;
  }
  __syncthreads();
  // B128 = -Uc @ T1
  f32x4 a2[4];
#pragma unroll
  for (int c = 0; c < 4; ++c) a2[c] = (f32x4){0.f, 0.f, 0.f, 0.f};
#pragma unroll
  for (int kc = 0; kc < 2; ++kc) {
    s16x8 af = *(const s16x8*)(Uc + (16 * w + fr) * 64 + kc * 32 + fq * 8);
#pragma unroll
    for (int c = 0; c < 4; ++c) {
      int j = 16 * c + fr;
      s16x8 bb = *(const s16x8*)((char*)T1T + (((j << 7) + (kc << 6) + (fq << 4)) ^ ((j & 7) << 4)));
      a2[c] = __builtin_amdgcn_mfma_f32_16x16x32_bf16(af, bb, a2[c], 0, 0, 0);
    }
  }
#pragma unroll
  for (int c = 0; c < 4; ++c) {
    int gj = 16 * c + fr;
#pragma unroll
    for (int r = 0; r < 4; ++r)
      Uo[(64 + 16 * w + fq * 4 + r) * 128 + gj] = f2bf(-a2[c][r]);
  }
}

// ================= solve128 v2: band GEMM + single U128 apply =================
__global__ __launch_bounds__(256) void solve128(const unsigned short* __restrict__ WN,
    const unsigned short* __restrict__ Kk, const unsigned short* __restrict__ Lb,
    const unsigned short* __restrict__ U128, unsigned short* __restrict__ CT, int ib) {
  int jb = blockIdx.x, bh = blockIdx.y;     // jb: 128-wide col slab, 0..ib
  int b = bh >> 4, h = bh & 15;
  int t = threadIdx.x, w = t >> 6, l = t & 63;
  int wr = w >> 1, wc = w & 1, fr = l & 15, fq = l >> 4;
  int s0 = ib * 128, j0 = jb * 128;
  size_t base = (size_t)bh << 20;
  __shared__ unsigned short sh[128 * 128];  // 32KB: As/Bs then rT
  unsigned short* As = sh;
  unsigned short* Bs = sh + 128 * 64;
  unsigned short* rT = sh;                  // [128 j][128 s] bf16
  const unsigned short* Wb_ = WN + ((size_t)b << 20) + h * 64;
  const unsigned short* Kb_ = Kk + ((size_t)b << 20) + h * 64;

  // ---- band: rect = W K^T - sum L*C ----
  f32x4 acc[4][4];
#pragma unroll
  for (int m = 0; m < 4; ++m)
#pragma unroll
    for (int c = 0; c < 4; ++c) acc[m][c] = (f32x4){0.f, 0.f, 0.f, 0.f};
  int nst = (jb == ib) ? 1 : 1 + 2 * (ib - jb);
  for (int st = 0; st < nst; ++st) {
    __syncthreads();
#pragma unroll
    for (int i = 0; i < 4; ++i) {
      int cid = t + i * 256;
      int row = cid >> 3, ch = cid & 7;
      int byt = ((row << 7) + (ch << 4)) ^ ((row & 7) << 4);
      u16x8 av, bv;
      if (st == 0) {
        av = *(const u16x8*)(Wb_ + ((size_t)(s0 + row) << 10) + ch * 8);
        bv = *(const u16x8*)(Kb_ + ((size_t)(j0 + row) << 10) + ch * 8);
      } else {
        int rb = 2 * jb + st - 1;
        av = *(const u16x8*)(Lb + base + ((size_t)(s0 + row) << 10) + rb * 64 + ch * 8);
        av ^= (unsigned short)0x8000;
        bv = *(const u16x8*)(CT + base + ((size_t)(j0 + row) << 10) + rb * 64 + ch * 8);
      }
      *(u16x8*)((char*)As + byt) = av;
      *(u16x8*)((char*)Bs + byt) = bv;
    }
    __syncthreads();
#pragma unroll
    for (int kh = 0; kh < 2; ++kh) {
      s16x8 af[4], bfv[4];
#pragma unroll
      for (int m = 0; m < 4; ++m) {
        int ra = wr * 64 + 16 * m + fr;
        af[m] = *(const s16x8*)((char*)As + (((ra << 7) + (kh << 6) + (fq << 4)) ^ ((ra & 7) << 4)));
      }
#pragma unroll
      for (int c = 0; c < 4; ++c) {
        int rb2 = wc * 64 + 16 * c + fr;
        bfv[c] = *(const s16x8*)((char*)Bs + (((rb2 << 7) + (kh << 6) + (fq << 4)) ^ ((rb2 & 7) << 4)));
      }
#pragma unroll
      for (int m = 0; m < 4; ++m)
#pragma unroll
        for (int c = 0; c < 4; ++c)
          acc[m][c] = __builtin_amdgcn_mfma_f32_16x16x32_bf16(af[m], bfv[c], acc[m][c], 0, 0, 0);
    }
  }
  __syncthreads();
  // ---- write rectT [j][s] bf16 (256B rows, XOR (j&15)<<4), mask diag slab ----
#pragma unroll
  for (int m = 0; m < 4; ++m) {
#pragma unroll
    for (int c = 0; c < 4; ++c) {
      int jl = wc * 64 + 16 * c + fr;
      int sb = wr * 64 + 16 * m + fq * 4;
      u16x4 pk;
#pragma unroll
      for (int r = 0; r < 4; ++r) {
        float v = acc[m][c][r];
        if (jb == ib && jl >= sb + r) v = 0.f;
        pk[r] = f2bf(v);
      }
      int byt = ((jl << 8) + (sb << 1)) ^ ((jl & 15) << 4);
      *(u16x4*)((char*)rT + byt) = pk;
    }
  }
  __syncthreads();
  // ---- C = U128 @ rect, write straight to CT ----
  const unsigned short* U = U128 + (((size_t)(bh * 8 + ib)) << 14);
  f32x4 a2[4][4];
#pragma unroll
  for (int m = 0; m < 4; ++m)
#pragma unroll
    for (int c = 0; c < 4; ++c) a2[m][c] = (f32x4){0.f, 0.f, 0.f, 0.f};
#pragma unroll
  for (int kc = 0; kc < 4; ++kc) {
    s16x8 uf[4], bfv[4];
#pragma unroll
    for (int m = 0; m < 4; ++m)
      uf[m] = *(const s16x8*)(U + (wr * 64 + 16 * m + fr) * 128 + kc * 32 + fq * 8);
#pragma unroll
    for (int c = 0; c < 4; ++c) {
      int jl = wc * 64 + 16 * c + fr;
      bfv[c] = *(const s16x8*)((char*)rT + (((jl << 8) + (kc << 6) + (fq << 4)) ^ ((jl & 15) << 4)));
    }
#pragma unroll
    for (int m = 0; m < 4; ++m)
#pragma unroll
      for (int c = 0; c < 4; ++c)
        a2[m][c] = __builtin_amdgcn_mfma_f32_16x16x32_bf16(uf[m], bfv[c], a2[m][c], 0, 0, 0);
  }
#pragma unroll
  for (int m = 0; m < 4; ++m) {
#pragma unroll
    for (int c = 0; c < 4; ++c) {
      int gj = wc * 64 + 16 * c + fr;
      int sb = wr * 64 + 16 * m + fq * 4;
      u16x4 pk;
#pragma unroll
      for (int r = 0; r < 4; ++r) pk[r] = f2bf(a2[m][c][r]);
      *(u16x4*)(CT + base + ((size_t)(j0 + gj) << 10) + s0 + sb) = pk;
    }
  }
}

// ================= rowstat: m,l per row =================
__global__ __launch_bounds__(256) void rowstat(const unsigned short* __restrict__ S,
    const float* __restrict__ Fc, float* __restrict__ MR, float* __restrict__ LR) {
  int bh = blockIdx.y;
  int t = blockIdx.x * 4 + (threadIdx.x >> 6);
  int l = threadIdx.x & 63;
  size_t base = (size_t)bh << 20;
  const unsigned short* srow = S + base + ((size_t)t << 10);
  float vals[16]; float vmax = -1e30f;
#pragma unroll
  for (int i = 0; i < 2; ++i) {
    int c0 = i * 512 + l * 8;
    u16x8 sv = *(const u16x8*)(srow + c0);
    float4 f0 = *(const float4*)(Fc + bh * 1024 + c0);
    float4 f1 = *(const float4*)(Fc + bh * 1024 + c0 + 4);
#pragma unroll
    for (int e = 0; e < 8; ++e) {
      float fc = e < 4 ? ((const float*)&f0)[e] : ((const float*)&f1)[e - 4];
      float v = (c0 + e <= t) ? bf2f(sv[e]) * SM_SCALE - fc : -1e30f;
      vals[i * 8 + e] = v; vmax = fmaxf(vmax, v);
    }
  }
#pragma unroll
  for (int o = 1; o < 64; o <<= 1) vmax = fmaxf(vmax, __shfl_xor(vmax, o));
  float sum = 0.f;
#pragma unroll
  for (int e = 0; e < 16; ++e) sum += __expf(vals[e] - vmax);
#pragma unroll
  for (int o = 1; o < 64; o <<= 1) sum += __shfl_xor(sum, o);
  if (l == 0) { MR[bh * 1024 + t] = vmax; LR[bh * 1024 + t] = sum; }
}

// ================= pv: O = P @ V with on-the-fly P; sorted 1D grid (512) =================
__global__ __launch_bounds__(256) void pv_kernel(const unsigned short* __restrict__ S,
    const unsigned short* __restrict__ VT, const float* __restrict__ Fc,
    const float* __restrict__ MR, const float* __restrict__ LR,
    unsigned short* __restrict__ Ob) {
  int idx = blockIdx.x;
  int bh = idx & 31, rank = idx >> 5;
  int tb = 15 - rank;
  int b = bh >> 4, h = bh & 15;
  int t0 = tb * 64;
  int t = threadIdx.x, w = t >> 6, l = t & 63, fr = l & 15, fq = l >> 4;
  __shared__ unsigned short Pl[64 * 64];
  size_t base = (size_t)bh << 20;
  f32x4 acc[4];
#pragma unroll
  for (int c = 0; c < 4; ++c) acc[c] = (f32x4){0.f,0.f,0.f,0.f};
  for (int jb = 0; jb <= tb; ++jb) {
    int j0 = jb * 64;
    __syncthreads();
#pragma unroll
    for (int i = 0; i < 2; ++i) {
      int cid = t + i * 256;
      int row = cid >> 3, ch = cid & 7;
      int grow = t0 + row;
      u16x8 sv = *(const u16x8*)(S + base + ((size_t)grow << 10) + j0 + ch * 8);
      float4 f0 = *(const float4*)(Fc + bh * 1024 + j0 + ch * 8);
      float4 f1 = *(const float4*)(Fc + bh * 1024 + j0 + ch * 8 + 4);
      float m = MR[bh * 1024 + grow];
      u16x8 pv;
#pragma unroll
      for (int e = 0; e < 8; ++e) {
        float fc = e < 4 ? ((const float*)&f0)[e] : ((const float*)&f1)[e - 4];
        float p = __expf(bf2f(sv[e]) * SM_SCALE - fc - m);
        if (jb == tb && ch * 8 + e > row) p = 0.f;
        pv[e] = f2bf(p);
      }
      int byt = ((row << 7) + (ch << 4)) ^ ((row & 7) << 4);
      *(u16x8*)((char*)Pl + byt) = pv;
    }
    __syncthreads();
#pragma unroll
    for (int kh = 0; kh < 2; ++kh) {
      int ra = 16 * w + fr;
      s16x8 a = *(const s16x8*)((char*)Pl + (((ra << 7) + (kh << 6) + (fq << 4)) ^ ((ra & 7) << 4)));
#pragma unroll
      for (int c = 0; c < 4; ++c) {
        s16x8 bb = *(const s16x8*)(VT + ((size_t)bh * 64 + 16 * c + fr) * 1024 + j0 + kh * 32 + fq * 8);
        acc[c] = __builtin_amdgcn_mfma_f32_16x16x32_bf16(a, bb, acc[c], 0, 0, 0);
      }
    }
  }
  float inv[4];
#pragma unroll
  for (int r = 0; r < 4; ++r) inv[r] = 1.f / LR[bh * 1024 + t0 + 16 * w + fq * 4 + r];
#pragma unroll
  for (int c = 0; c < 4; ++c) {
#pragma unroll
    for (int r = 0; r < 4; ++r) {
      int grow = t0 + 16 * w + fq * 4 + r;
      Ob[((size_t)(b * 1024) + grow) * 1024 + h * 64 + 16 * c + fr] = f2bf(acc[c][r] * inv[r]);
    }
  }
}

extern "C" void kernel_launch(void* const* d_in, const int* in_sizes, int n_in,
                              void* d_out, int out_size, void* d_ws, size_t ws_size,
                              hipStream_t stream) {
  const float* x    = (const float*)d_in[0];
  const float* Wq   = (const float*)d_in[1];
  const float* Wk   = (const float*)d_in[2];
  const float* Wv   = (const float*)d_in[3];
  const float* Wo   = (const float*)d_in[4];
  const float* Ww1  = (const float*)d_in[5];
  const float* Ww2  = (const float*)d_in[6];
  const float* Wb   = (const float*)d_in[7];
  const float* Wf   = (const float*)d_in[8];
  const float* delta= (const float*)d_in[9];

  char* ws = (char*)d_ws;
  unsigned short* xb   = (unsigned short*)(ws + OFF_XB);
  unsigned short* WqT  = (unsigned short*)(ws + OFF_WQT);
  float*          BL   = (float*)(ws + OFF_BL);
  unsigned short* WkT  = (unsigned short*)(ws + OFF_WKT);
  unsigned short* BFT  = (unsigned short*)(ws + OFF_BFT);
  unsigned short* WvT  = (unsigned short*)(ws + OFF_WVT);
  unsigned short* WoT  = (unsigned short*)(ws + OFF_WOT);
  unsigned short* W1T  = (unsigned short*)(ws + OFF_W1T);
  unsigned short* W2T  = (unsigned short*)(ws + OFF_W2T);
  float*          Beta = (float*)(ws + OFF_W1T);
  unsigned short* Q16  = (unsigned short*)(ws + OFF_Q16);
  unsigned short* K16  = (unsigned short*)(ws + OFF_K16);
  unsigned short* VT   = (unsigned short*)(ws + OFF_VT);
  unsigned short* WN16 = (unsigned short*)(ws + OFF_WN16);
  unsigned short* WB16 = (unsigned short*)(ws + OFF_WB16);
  unsigned short* WNF16= (unsigned short*)(ws + OFF_WNF);
  unsigned short* ObB  = (unsigned short*)(ws + OFF_OB);
  unsigned short* Wpre = (unsigned short*)(ws + OFF_WPRE);
  float*          Fc   = (float*)(ws + OFF_FC);
  unsigned short* Lbuf = (unsigned short*)(ws + OFF_L);
  unsigned short* Sbuf = (unsigned short*)(ws + OFF_L);
  unsigned short* CT   = (unsigned short*)(ws + OFF_CT);
  unsigned short* Gbuf = (unsigned short*)(ws + OFF_G);
  float*          MR   = (float*)(ws + OFF_MR);
  float*          LR   = (float*)(ws + OFF_LR);
  unsigned short* UI   = (unsigned short*)(ws + OFF_UI);
  unsigned short* U128 = (unsigned short*)(ws + OFF_U128);

  dim3 blk(256);
  // prep
  transpose6<<<dim3(16,16,6), blk, 0, stream>>>(Wq, Wk, Wv, Wo, Ww1, Ww2,
                                                WqT, WkT, WvT, WoT, W1T, W2T);
  cast_bf16<<<1024, blk, 0, stream>>>(x, xb, 2048 * 1024);
  // Q,K,VT in one launch (128^2 tiles)
  proj_big<<<384, blk, 0, stream>>>(xb, WqT, WkT, WvT, Q16, K16, VT);
  // beta/log_f operand (overlays WkT -> after proj_big)
  bfprep<<<256, blk, 0, stream>>>(Wb, Wf, BFT);
  // Wpre + BL in one launch (BL overlays WqT -> after proj_big)
  proj_small<<<dim3(2,32), blk, 0, stream>>>(xb, W1T, BFT, Wpre, BL);
  // WNF = Wpre @ W2T
  gemm_nt<0><<<dim3(16,32), blk, 0, stream>>>(Wpre, W2T, WNF16, 2048, 1024, 64);
  // beta/logsigmoid/cumsum fused (Beta overlays W1T -> after proj_small)
  bgfc<<<32, blk, 0, stream>>>(BL, delta, Beta, Fc);
  wnorm2<<<2048, blk, 0, stream>>>(WNF16, Beta, WN16, WB16);
  // L and G in one fused launch
  pairLG<<<dim3(36 * 32), blk, 0, stream>>>(WN16, Q16, WB16, Lbuf, Gbuf);
  // triangular solve: 64-inverses -> 128-inverses -> 8 MFMA band steps
  inv64<<<dim3(16,32), blk, 0, stream>>>(Lbuf, UI);
  u128build<<<dim3(8,32), blk, 0, stream>>>(Lbuf, UI, U128);
  for (int ib = 0; ib < 8; ++ib)
    solve128<<<dim3(ib + 1, 32), blk, 0, stream>>>(WN16, K16, Lbuf, U128, CT, ib);
  // S = QK^T - G C (sorted band grid; reuses L region)
  score128s<<<dim3(36 * 32), blk, 0, stream>>>(Q16, K16, Gbuf, CT, Sbuf);
  // softmax stats + PV
  rowstat<<<dim3(256,32), blk, 0, stream>>>(Sbuf, Fc, MR, LR);
  pv_kernel<<<dim3(512), blk, 0, stream>>>(Sbuf, VT, Fc, MR, LR, ObB);
  // output projection (f32 out)
  gemm_nt<1><<<dim3(16,32), blk, 0, stream>>>(ObB, WoT, d_out, 2048, 1024, 1024);
}

// Round 7
// 337.494 us; speedup vs baseline: 12.0828x; 1.0802x over previous
//
#include <hip/hip_runtime.h>
#include <hip/hip_bf16.h>

#define DEV static __device__ __forceinline__

constexpr float SM_SCALE = 0.125f;   // hd^-0.5, hd=64

typedef __attribute__((ext_vector_type(8))) short s16x8;
typedef __attribute__((ext_vector_type(8))) unsigned short u16x8;
typedef __attribute__((ext_vector_type(4))) unsigned short u16x4;
typedef __attribute__((ext_vector_type(4))) float f32x4;

DEV float bf2f(unsigned short u) {
  union { unsigned int i; float f; } v; v.i = ((unsigned int)u) << 16; return v.f;
}
DEV unsigned short f2bf(float f) {
  union { float f; unsigned int i; } v; v.f = f;
  unsigned int r = v.i + 0x7fffu + ((v.i >> 16) & 1u);
  return (unsigned short)(r >> 16);
}
DEV void tri_unrank(int r, int& k, int& i) {
  k = (int)((sqrtf(8.f * r + 1.f) - 1.f) * 0.5f);
  while (k * (k + 1) / 2 > r) --k;
  while ((k + 1) * (k + 2) / 2 <= r) ++k;
  i = r - k * (k + 1) / 2;
}
// async global->LDS, 16B per lane; dest must be wave-linear (base + lane*16)
DEV void glds16(const void* g, void* l) {
  __builtin_amdgcn_global_load_lds(
      (const __attribute__((address_space(1))) void*)g,
      (__attribute__((address_space(3))) void*)l, 16, 0, 0);
}

// ---------- workspace layout (bytes) ----------
constexpr size_t OFF_XB   = 0;                       // 4MB xb bf16 [2048][1024]
constexpr size_t OFF_WQT  = 4194304;                 // 2MB; reused as BL (f32 2048x64)
constexpr size_t OFF_BL   = 4194304;
constexpr size_t OFF_WKT  = 6291456;                 // 2MB; reused as BFT (bf16 64x1024)
constexpr size_t OFF_BFT  = 6291456;
constexpr size_t OFF_WVT  = 8388608;
constexpr size_t OFF_WOT  = 10485760;
constexpr size_t OFF_W1T  = 12582912;                // 128KB (reused as Beta f32)
constexpr size_t OFF_W2T  = 12713984;                // 128KB
constexpr size_t OFF_Q16  = 12845056;                // 4MB bf16 2048x1024
constexpr size_t OFF_K16  = 17039360;                // 4MB
constexpr size_t OFF_VT   = 21233664;                // 4MB  VT[b][64h*d][1024n]
constexpr size_t OFF_WN16 = 25427968;                // 4MB
constexpr size_t OFF_WB16 = 29622272;                // 4MB
constexpr size_t OFF_WNF  = 33816576;                // 4MB (reused as Ob)
constexpr size_t OFF_OB   = 33816576;
constexpr size_t OFF_WPRE = 38010880;                // 256KB
constexpr size_t OFF_FC   = 38273024;                // 128KB
constexpr size_t OFF_L    = 38404096;                // 64MB, stores -L (reused as S)
constexpr size_t OFF_CT   = 105512960;               // 64MB
constexpr size_t OFF_G    = 172621824;               // 64MB, stores -G
constexpr size_t OFF_MR   = 239730688;               // 128KB f32 [32][1024]
constexpr size_t OFF_LR   = 239861760;               // 128KB
constexpr size_t OFF_UI   = 239992832;               // 4MB bf16 [32][16][64][64]
constexpr size_t OFF_U128 = 244187136;               // 8MB bf16 [32][8][128][128]

// ================= fused prep: 6 transposes + x cast; grid 2560 =================
__global__ __launch_bounds__(256) void prep_all(
    const float* __restrict__ W0, const float* __restrict__ W1,
    const float* __restrict__ W2, const float* __restrict__ W3,
    const float* __restrict__ Ww1, const float* __restrict__ Ww2,
    const float* __restrict__ x,
    unsigned short* __restrict__ D0, unsigned short* __restrict__ D1,
    unsigned short* __restrict__ D2, unsigned short* __restrict__ D3,
    unsigned short* __restrict__ D4, unsigned short* __restrict__ D5,
    unsigned short* __restrict__ xb) {
  int bidx = blockIdx.x;
  int t = threadIdx.x;
  if (bidx >= 1536) {                      // cast x -> bf16
    int i = ((bidx - 1536) * 256 + t) * 8;
    float4 a = *(const float4*)(x + i);
    float4 b = *(const float4*)(x + i + 4);
    u16x8 o;
    o[0] = f2bf(a.x); o[1] = f2bf(a.y); o[2] = f2bf(a.z); o[3] = f2bf(a.w);
    o[4] = f2bf(b.x); o[5] = f2bf(b.y); o[6] = f2bf(b.z); o[7] = f2bf(b.w);
    *(u16x8*)(xb + i) = o;
    return;
  }
  int z = bidx >> 8, xy = bidx & 255;
  int bx = xy & 15, by = xy >> 4;
  const float* src; unsigned short* dst; int R, C;
  if (z == 0) { src = W0; dst = D0; R = 1024; C = 1024; }
  else if (z == 1) { src = W1; dst = D1; R = 1024; C = 1024; }
  else if (z == 2) { src = W2; dst = D2; R = 1024; C = 1024; }
  else if (z == 3) { src = W3; dst = D3; R = 1024; C = 1024; }
  else if (z == 4) { src = Ww1; dst = D4; R = 1024; C = 64; }
  else { src = Ww2; dst = D5; R = 64; C = 1024; }
  int c0 = bx * 64, r0 = by * 64;
  if (c0 >= C || r0 >= R) return;
  __shared__ float tile[64 * 65];
#pragma unroll
  for (int i = 0; i < 16; ++i) {
    int lin = t + i * 256; int r = lin >> 6, c = lin & 63;
    tile[r * 65 + c] = src[(size_t)(r0 + r) * C + c0 + c];
  }
  __syncthreads();
#pragma unroll
  for (int i = 0; i < 16; ++i) {
    int lin = t + i * 256; int c = lin >> 6, r = lin & 63;
    dst[(size_t)(c0 + c) * R + r0 + r] = f2bf(tile[r * 65 + c]);
  }
}

// BFT (64x1024) = [Wb^T ; Wf^T ; 0]; grid 256
__global__ __launch_bounds__(256) void bfprep(const float* __restrict__ Wb,
    const float* __restrict__ Wf, unsigned short* __restrict__ BFT) {
  int idx = blockIdx.x * 256 + threadIdx.x;   // 65536
  int j = idx >> 10, i = idx & 1023;
  float v = 0.f;
  if (j < 16) v = Wb[i * 16 + j];
  else if (j < 32) v = Wf[i * 16 + (j - 16)];
  BFT[idx] = f2bf(v);
}

// beta + log_sigmoid + cumsum fused; grid 32 (bh)
__global__ __launch_bounds__(256) void bgfc(const float* __restrict__ BL,
    const float* __restrict__ delta, float* __restrict__ Beta, float* __restrict__ Fc) {
  int bh = blockIdx.x;
  int b = bh >> 4, h = bh & 15;
  int t = threadIdx.x;
  __shared__ float buf[1024];
  __shared__ float tsum[256];
  float dh = delta[h];
#pragma unroll
  for (int i = 0; i < 4; ++i) {
    int n = t + i * 256;
    int row = (b << 10) + n;
    float braw = BL[row * 64 + h];
    Beta[row * 16 + h] = 2.f / (1.f + __expf(-braw));
    float lraw = BL[row * 64 + 16 + h] + dh;
    buf[n] = (lraw >= 0.f) ? -log1pf(__expf(-lraw)) : (lraw - log1pf(__expf(lraw)));
  }
  __syncthreads();
  float loc[4]; float run = 0.f;
#pragma unroll
  for (int i = 0; i < 4; ++i) { run += buf[t * 4 + i]; loc[i] = run; }
  tsum[t] = run;
  __syncthreads();
  for (int off = 1; off < 256; off <<= 1) {
    float add = (t >= off) ? tsum[t - off] : 0.f;
    __syncthreads();
    tsum[t] += add;
    __syncthreads();
  }
  float excl = tsum[t] - run;
#pragma unroll
  for (int i = 0; i < 4; ++i) Fc[bh * 1024 + t * 4 + i] = excl + loc[i];
}

// ================= mega projection: Q,K (128^2) + VT (2 batches), 384 blocks =================
__global__ __launch_bounds__(256) void proj_big(const unsigned short* __restrict__ xb,
    const unsigned short* __restrict__ WqT, const unsigned short* __restrict__ WkT,
    const unsigned short* __restrict__ WvT, unsigned short* __restrict__ Q16,
    unsigned short* __restrict__ K16, unsigned short* __restrict__ VT) {
  int idx = blockIdx.x;
  const unsigned short *A, *BT; unsigned short* out; int m0, n0;
  if (idx < 256) {
    int my = idx >> 4, nx = idx & 15;
    m0 = my * 128; A = xb;
    if (nx < 8) { BT = WqT; out = Q16; n0 = nx * 128; }
    else { BT = WkT; out = K16; n0 = (nx - 8) * 128; }
  } else {
    int r = idx - 256; int bz = r >> 6; int rem = r & 63;
    m0 = (rem >> 3) * 128; n0 = (rem & 7) * 128;
    A = WvT; BT = xb + ((size_t)bz << 20); out = VT + ((size_t)bz << 20);
  }
  int t = threadIdx.x;
  int w = t >> 6, l = t & 63;
  int wr = w >> 1, wc = w & 1;
  int fr = l & 15, fq = l >> 4;
  __shared__ unsigned short As[128 * 64];
  __shared__ unsigned short Bs[128 * 64];
  f32x4 acc[4][4];
#pragma unroll
  for (int m = 0; m < 4; ++m)
#pragma unroll
    for (int c = 0; c < 4; ++c) acc[m][c] = (f32x4){0.f, 0.f, 0.f, 0.f};
  for (int k0 = 0; k0 < 1024; k0 += 64) {
    __syncthreads();
#pragma unroll
    for (int i = 0; i < 4; ++i) {
      int cid = t + i * 256;
      int row = cid >> 3, ch = cid & 7;
      int chs = ch ^ (row & 7);
      glds16(A + (size_t)(m0 + row) * 1024 + k0 + chs * 8, (char*)As + cid * 16);
      glds16(BT + (size_t)(n0 + row) * 1024 + k0 + chs * 8, (char*)Bs + cid * 16);
    }
    __syncthreads();
#pragma unroll
    for (int kh = 0; kh < 2; ++kh) {
      s16x8 af[4], bfv[4];
#pragma unroll
      for (int m = 0; m < 4; ++m) {
        int ra = wr * 64 + 16 * m + fr;
        af[m] = *(const s16x8*)((char*)As + (((ra << 7) + (kh << 6) + (fq << 4)) ^ ((ra & 7) << 4)));
      }
#pragma unroll
      for (int c = 0; c < 4; ++c) {
        int rb = wc * 64 + 16 * c + fr;
        bfv[c] = *(const s16x8*)((char*)Bs + (((rb << 7) + (kh << 6) + (fq << 4)) ^ ((rb & 7) << 4)));
      }
#pragma unroll
      for (int m = 0; m < 4; ++m)
#pragma unroll
        for (int c = 0; c < 4; ++c)
          acc[m][c] = __builtin_amdgcn_mfma_f32_16x16x32_bf16(af[m], bfv[c], acc[m][c], 0, 0, 0);
    }
  }
#pragma unroll
  for (int m = 0; m < 4; ++m) {
#pragma unroll
    for (int c = 0; c < 4; ++c) {
      int col = n0 + wc * 64 + 16 * c + fr;
#pragma unroll
      for (int r = 0; r < 4; ++r) {
        int grow = m0 + wr * 64 + 16 * m + fq * 4 + r;
        out[(size_t)grow * 1024 + col] = f2bf(acc[m][c][r]);
      }
    }
  }
}

// dual small projection: nt=0 -> Wpre (bf16), nt=1 -> BL (f32); grid (2,32)
__global__ __launch_bounds__(256) void proj_small(const unsigned short* __restrict__ A,
    const unsigned short* __restrict__ W1T, const unsigned short* __restrict__ BFT,
    unsigned short* __restrict__ Wpre, float* __restrict__ BL) {
  int nt = blockIdx.x;
  const unsigned short* BT = nt ? BFT : W1T;
  __shared__ unsigned short As[64 * 64];
  __shared__ unsigned short Bs[64 * 64];
  int m0 = blockIdx.y * 64;
  int t = threadIdx.x;
  int w = t >> 6, l = t & 63, fr = l & 15;
  int koB = (l >> 4) * 16;
  f32x4 acc[4];
#pragma unroll
  for (int c = 0; c < 4; ++c) acc[c] = (f32x4){0.f, 0.f, 0.f, 0.f};
  for (int k0 = 0; k0 < 1024; k0 += 64) {
    __syncthreads();
#pragma unroll
    for (int i = 0; i < 2; ++i) {
      int cid = t + i * 256;
      int row = cid >> 3, ch = cid & 7;
      int chs = ch ^ (row & 7);
      glds16(A + (size_t)(m0 + row) * 1024 + k0 + chs * 8, (char*)As + cid * 16);
      glds16(BT + (size_t)row * 1024 + k0 + chs * 8, (char*)Bs + cid * 16);
    }
    __syncthreads();
#pragma unroll
    for (int kh = 0; kh < 2; ++kh) {
      int ra = 16 * w + fr;
      s16x8 a = *(const s16x8*)((char*)As + (((ra << 7) + (kh << 6) + koB) ^ ((ra & 7) << 4)));
#pragma unroll
      for (int c = 0; c < 4; ++c) {
        int rb = 16 * c + fr;
        s16x8 bb = *(const s16x8*)((char*)Bs + (((rb << 7) + (kh << 6) + koB) ^ ((rb & 7) << 4)));
        acc[c] = __builtin_amdgcn_mfma_f32_16x16x32_bf16(a, bb, acc[c], 0, 0, 0);
      }
    }
  }
  int rbase = m0 + 16 * w + ((l >> 4) << 2);
#pragma unroll
  for (int c = 0; c < 4; ++c) {
    int col = 16 * c + fr;
#pragma unroll
    for (int r = 0; r < 4; ++r) {
      if (nt) BL[(size_t)(rbase + r) * 64 + col] = acc[c][r];
      else Wpre[(size_t)(rbase + r) * 64 + col] = f2bf(acc[c][r]);
    }
  }
}

// ================= 64-tile bf16 NT GEMM (WNF and output projection) =================
template<int F32OUT>
__global__ __launch_bounds__(256) void gemm_nt(const unsigned short* __restrict__ A,
    const unsigned short* __restrict__ BT, void* __restrict__ out,
    int M, int N, int K) {
  __shared__ unsigned short As[64 * 64];
  __shared__ unsigned short Bs[64 * 64];
  int m0 = blockIdx.y * 64, n0 = blockIdx.x * 64;
  int t = threadIdx.x;
  int w = t >> 6, l = t & 63, fr = l & 15;
  int koB = (l >> 4) * 16;
  f32x4 acc[4];
#pragma unroll
  for (int c = 0; c < 4; ++c) acc[c] = (f32x4){0.f, 0.f, 0.f, 0.f};
  for (int k0 = 0; k0 < K; k0 += 64) {
    __syncthreads();
#pragma unroll
    for (int i = 0; i < 2; ++i) {
      int cid = t + i * 256;
      int row = cid >> 3, ch = cid & 7;
      int chs = ch ^ (row & 7);
      glds16(A + (size_t)(m0 + row) * K + k0 + chs * 8, (char*)As + cid * 16);
      glds16(BT + (size_t)(n0 + row) * K + k0 + chs * 8, (char*)Bs + cid * 16);
    }
    __syncthreads();
#pragma unroll
    for (int kh = 0; kh < 2; ++kh) {
      int ra = 16 * w + fr;
      s16x8 a = *(const s16x8*)((char*)As + (((ra << 7) + (kh << 6) + koB) ^ ((ra & 7) << 4)));
#pragma unroll
      for (int c = 0; c < 4; ++c) {
        int rb = 16 * c + fr;
        s16x8 bb = *(const s16x8*)((char*)Bs + (((rb << 7) + (kh << 6) + koB) ^ ((rb & 7) << 4)));
        acc[c] = __builtin_amdgcn_mfma_f32_16x16x32_bf16(a, bb, acc[c], 0, 0, 0);
      }
    }
  }
  int rbase = m0 + 16 * w + ((l >> 4) << 2);
#pragma unroll
  for (int c = 0; c < 4; ++c) {
    int col = n0 + 16 * c + fr;
#pragma unroll
    for (int r = 0; r < 4; ++r) {
      if (F32OUT) ((float*)out)[(size_t)(rbase + r) * N + col] = acc[c][r];
      else ((unsigned short*)out)[(size_t)(rbase + r) * N + col] = f2bf(acc[c][r]);
    }
  }
}

// ================= w normalize + beta-scale =================
__global__ __launch_bounds__(256) void wnorm2(const unsigned short* __restrict__ WNF,
    const float* __restrict__ Beta, unsigned short* __restrict__ WN,
    unsigned short* __restrict__ WB) {
  int row = blockIdx.x;
  int wave = threadIdx.x >> 6, lane = threadIdx.x & 63;
#pragma unroll
  for (int i = 0; i < 4; ++i) {
    int hh = wave * 4 + i;
    size_t idx = ((size_t)row << 10) + hh * 64 + lane;
    float v = bf2f(WNF[idx]);
    float ss = v * v;
#pragma unroll
    for (int off = 1; off < 64; off <<= 1) ss += __shfl_xor(ss, off);
    float wn = v * rsqrtf(ss + 1e-6f);
    WN[idx] = f2bf(wn);
    WB[idx] = f2bf(wn * Beta[row * 16 + hh]);
  }
}

// ================= pair fused: writes NEGATED L and G =================
__global__ __launch_bounds__(256) void pairLG(const unsigned short* __restrict__ WN,
    const unsigned short* __restrict__ Q, const unsigned short* __restrict__ WB,
    unsigned short* __restrict__ Lg, unsigned short* __restrict__ Gg) {
  int idx = blockIdx.x;
  int bh = idx & 31, r0r = idx >> 5;
  int tb2, jb2; tri_unrank(r0r, tb2, jb2);
  int b = bh >> 4, h = bh & 15;
  int m0 = tb2 * 128, n0 = jb2 * 128;
  int t = threadIdx.x;
  int w = t >> 6, l = t & 63;
  int wr = w >> 1, wc = w & 1;
  int fr = l & 15, fq = l >> 4;
  __shared__ unsigned short As[128 * 64];
  __shared__ unsigned short Bs[128 * 64];
  const unsigned short* WNb = WN + ((size_t)b << 20) + h * 64;
  const unsigned short* Qb  = Q + ((size_t)b << 20) + h * 64;
  const unsigned short* WBb = WB + ((size_t)b << 20) + h * 64;
  size_t base = (size_t)bh << 20;
#pragma unroll
  for (int i = 0; i < 4; ++i) {
    int cid = t + i * 256;
    int row = cid >> 3, ch = cid & 7;
    int chs = ch ^ (row & 7);
    glds16(WNb + ((size_t)(m0 + row) << 10) + chs * 8, (char*)As + cid * 16);
    glds16(WBb + ((size_t)(n0 + row) << 10) + chs * 8, (char*)Bs + cid * 16);
  }
  __syncthreads();
  for (int pass = 0; pass < 2; ++pass) {
    f32x4 acc[4][4];
#pragma unroll
    for (int m = 0; m < 4; ++m)
#pragma unroll
      for (int c = 0; c < 4; ++c) acc[m][c] = (f32x4){0.f, 0.f, 0.f, 0.f};
#pragma unroll
    for (int kh = 0; kh < 2; ++kh) {
      s16x8 af[4], bfv[4];
#pragma unroll
      for (int m = 0; m < 4; ++m) {
        int ra = wr * 64 + 16 * m + fr;
        af[m] = *(const s16x8*)((char*)As + (((ra << 7) + (kh << 6) + (fq << 4)) ^ ((ra & 7) << 4)));
      }
#pragma unroll
      for (int c = 0; c < 4; ++c) {
        int rb = wc * 64 + 16 * c + fr;
        bfv[c] = *(const s16x8*)((char*)Bs + (((rb << 7) + (kh << 6) + (fq << 4)) ^ ((rb & 7) << 4)));
      }
#pragma unroll
      for (int m = 0; m < 4; ++m)
#pragma unroll
        for (int c = 0; c < 4; ++c)
          acc[m][c] = __builtin_amdgcn_mfma_f32_16x16x32_bf16(af[m], bfv[c], acc[m][c], 0, 0, 0);
    }
    unsigned short* dst = pass ? Gg : Lg;
#pragma unroll
    for (int m = 0; m < 4; ++m) {
#pragma unroll
      for (int c = 0; c < 4; ++c) {
        int gj = n0 + wc * 64 + 16 * c + fr;
#pragma unroll
        for (int r = 0; r < 4; ++r) {
          int gi = m0 + wr * 64 + 16 * m + fq * 4 + r;
          bool keep = pass ? (gj <= gi) : (gj < gi);
          dst[base + ((size_t)gi << 10) + gj] = f2bf(keep ? -acc[m][c][r] : 0.f);
        }
      }
    }
    if (pass == 0) {
      __syncthreads();   // all MFMA reads of As done
#pragma unroll
      for (int i = 0; i < 4; ++i) {
        int cid = t + i * 256;
        int row = cid >> 3, ch = cid & 7;
        int chs = ch ^ (row & 7);
        glds16(Qb + ((size_t)(m0 + row) << 10) + chs * 8, (char*)As + cid * 16);
      }
      __syncthreads();
    }
  }
}

// ================= score: S = Q K^T + Gneg @ C, sorted 1D grid =================
__global__ __launch_bounds__(256) void score128s(const unsigned short* __restrict__ Q,
    const unsigned short* __restrict__ Kk, const unsigned short* __restrict__ G,
    const unsigned short* __restrict__ CT, unsigned short* __restrict__ Sg) {
  int idx = blockIdx.x;
  int bh = idx & 31, r0r = idx >> 5;
  int k, i; tri_unrank(r0r, k, i);
  int tb2 = (7 - k) + i, jb2 = i;
  int b = bh >> 4, h = bh & 15;
  int m0 = tb2 * 128, n0 = jb2 * 128;
  int t = threadIdx.x;
  int w = t >> 6, l = t & 63;
  int wr = w >> 1, wc = w & 1;
  int fr = l & 15, fq = l >> 4;
  __shared__ unsigned short As[128 * 64];
  __shared__ unsigned short Bs[128 * 64];
  size_t base = (size_t)bh << 20;
  const unsigned short* Qb_ = Q + ((size_t)b << 20) + h * 64;
  const unsigned short* Kb_ = Kk + ((size_t)b << 20) + h * 64;
  const unsigned short* Gb_ = G + base;
  const unsigned short* Cb_ = CT + base;
  int kbase = jb2 * 128;
  int nsteps = 1 + (tb2 - jb2 + 1) * 2;
  f32x4 acc[4][4];
#pragma unroll
  for (int m = 0; m < 4; ++m)
#pragma unroll
    for (int c = 0; c < 4; ++c) acc[m][c] = (f32x4){0.f, 0.f, 0.f, 0.f};
  for (int step = 0; step < nsteps; ++step) {
    const unsigned short* pa; const unsigned short* pb; int koff;
    if (step == 0) { pa = Qb_; pb = Kb_; koff = 0; }
    else { pa = Gb_; pb = Cb_; koff = kbase + (step - 1) * 64; }
    __syncthreads();
#pragma unroll
    for (int i2 = 0; i2 < 4; ++i2) {
      int cid = t + i2 * 256;
      int row = cid >> 3, ch = cid & 7;
      int chs = ch ^ (row & 7);
      glds16(pa + ((size_t)(m0 + row) << 10) + koff + chs * 8, (char*)As + cid * 16);
      glds16(pb + ((size_t)(n0 + row) << 10) + koff + chs * 8, (char*)Bs + cid * 16);
    }
    __syncthreads();
#pragma unroll
    for (int kh = 0; kh < 2; ++kh) {
      s16x8 af[4], bfv[4];
#pragma unroll
      for (int m = 0; m < 4; ++m) {
        int ra = wr * 64 + 16 * m + fr;
        af[m] = *(const s16x8*)((char*)As + (((ra << 7) + (kh << 6) + (fq << 4)) ^ ((ra & 7) << 4)));
      }
#pragma unroll
      for (int c = 0; c < 4; ++c) {
        int rb = wc * 64 + 16 * c + fr;
        bfv[c] = *(const s16x8*)((char*)Bs + (((rb << 7) + (kh << 6) + (fq << 4)) ^ ((rb & 7) << 4)));
      }
#pragma unroll
      for (int m = 0; m < 4; ++m)
#pragma unroll
        for (int c = 0; c < 4; ++c)
          acc[m][c] = __builtin_amdgcn_mfma_f32_16x16x32_bf16(af[m], bfv[c], acc[m][c], 0, 0, 0);
    }
  }
#pragma unroll
  for (int m = 0; m < 4; ++m) {
#pragma unroll
    for (int c = 0; c < 4; ++c) {
      int gj = n0 + wc * 64 + 16 * c + fr;
#pragma unroll
      for (int r = 0; r < 4; ++r) {
        int gi = m0 + wr * 64 + 16 * m + fq * 4 + r;
        Sg[base + ((size_t)gi << 10) + gj] = f2bf(acc[m][c][r]);
      }
    }
  }
}

// ================= inv64: U = (I + Ldiag)^-1 (Lb holds -L); grid (16,32) =================
__global__ __launch_bounds__(256) void inv64(const unsigned short* __restrict__ Lb,
    unsigned short* __restrict__ UI) {
  int ib = blockIdx.x, bh = blockIdx.y;
  int t = threadIdx.x;
  int s0 = ib * 64;
  size_t base = (size_t)bh << 20;
  __shared__ float LD[64 * 65];
  __shared__ unsigned short us[64 * 66];
#pragma unroll
  for (int i = 0; i < 16; ++i) {
    int lin = t + i * 256; int s = lin >> 6, r = lin & 63;
    LD[s * 65 + r] = -bf2f(Lb[base + ((size_t)(s0 + s) << 10) + s0 + r]);   // +L
  }
  __syncthreads();
  if (t < 64) {                      // lane j = column j of inverse
    float cc[64];
#pragma unroll
    for (int s = 0; s < 64; ++s) cc[s] = (s == t) ? 1.f : 0.f;
#pragma unroll
    for (int r = 0; r < 63; ++r) {
      float val = cc[r];
#pragma unroll
      for (int s = r + 1; s < 64; ++s) cc[s] -= LD[s * 65 + r] * val;
    }
#pragma unroll
    for (int s = 0; s < 64; ++s) us[s * 66 + t] = f2bf(cc[s]);
  }
  __syncthreads();
  size_t ubase = ((size_t)(bh * 16 + ib)) << 12;
#pragma unroll
  for (int i = 0; i < 16; ++i) {
    int lin = t + i * 256; int s = lin >> 6, j = lin & 63;
    UI[ubase + s * 64 + j] = us[s * 66 + j];
  }
}

// ================= u128build: U128 = [[Ua,0],[-Uc L_BA Ua, Uc]] (Lb = -L); grid (8,32) =================
__global__ __launch_bounds__(256) void u128build(const unsigned short* __restrict__ Lb,
    const unsigned short* __restrict__ UI, unsigned short* __restrict__ U128) {
  int ib = blockIdx.x, bh = blockIdx.y;
  int t = threadIdx.x, w = t >> 6, l = t & 63, fr = l & 15, fq = l >> 4;
  int s0 = ib * 128;
  size_t base = (size_t)bh << 20;
  const unsigned short* Ua = UI + (((size_t)(bh * 16 + 2 * ib)) << 12);
  const unsigned short* Uc = UI + (((size_t)(bh * 16 + 2 * ib + 1)) << 12);
  unsigned short* Uo = U128 + (((size_t)(bh * 8 + ib)) << 14);
  __shared__ unsigned short UaT[64 * 64];
  __shared__ unsigned short T1T[64 * 64];
  // stage UaT transposed (swizzled 128B rows)
#pragma unroll
  for (int i = 0; i < 2; ++i) {
    int cid = t + i * 256;
    int s = cid >> 3, ch = cid & 7;
    u16x8 v = *(const u16x8*)(Ua + s * 64 + ch * 8);
#pragma unroll
    for (int e = 0; e < 8; ++e) {
      int j = ch * 8 + e;
      int byt = ((j << 7) + (s << 1)) ^ ((j & 7) << 4);
      *(unsigned short*)((char*)UaT + byt) = v[e];
    }
  }
  // copies: top-left Ua, top-right 0, bottom-right Uc
#pragma unroll
  for (int i = 0; i < 8; ++i) {
    int cid = t + i * 256;            // 0..2047
    int row = cid >> 4, ch = cid & 15;
    if (row < 64) {
      if (ch < 8) *(u16x8*)(Uo + row * 128 + ch * 8) = *(const u16x8*)(Ua + row * 64 + ch * 8);
      else { u16x8 z = {0,0,0,0,0,0,0,0}; *(u16x8*)(Uo + row * 128 + ch * 8) = z; }
    } else if (ch >= 8) {
      *(u16x8*)(Uo + row * 128 + ch * 8) = *(const u16x8*)(Uc + (row - 64) * 64 + (ch - 8) * 8);
    }
  }
  __syncthreads();
  // T1n = (-L_BA) @ Ua  (Lb already negated)
  f32x4 a1[4];
#pragma unroll
  for (int c = 0; c < 4; ++c) a1[c] = (f32x4){0.f, 0.f, 0.f, 0.f};
#pragma unroll
  for (int kc = 0; kc < 2; ++kc) {
    s16x8 af = *(const s16x8*)(Lb + base + ((size_t)(s0 + 64 + 16 * w + fr) << 10) + s0 + kc * 32 + fq * 8);
#pragma unroll
    for (int c = 0; c < 4; ++c) {
      int j = 16 * c + fr;
      s16x8 bb = *(const s16x8*)((char*)UaT + (((j << 7) + (kc << 6) + (fq << 4)) ^ ((j & 7) << 4)));
      a1[c] = __builtin_amdgcn_mfma_f32_16x16x32_bf16(af, bb, a1[c], 0, 0, 0);
    }
  }
#pragma unroll
  for (int c = 0; c < 4; ++c) {
    int gj = 16 * c + fr;
    int sb = 16 * w + fq * 4;
    u16x4 pk;
#pragma unroll
    for (int r = 0; r < 4; ++r) pk[r] = f2bf(a1[c][r]);
    *(u16x4*)((char*)T1T + (((gj << 7) + (sb << 1)) ^ ((gj & 7) << 4))) = pk;
  }
  __syncthreads();
  // B128 = Uc @ T1n = -Uc L_BA Ua
  f32x4 a2[4];
#pragma unroll
  for (int c = 0; c < 4; ++c) a2[c] = (f32x4){0.f, 0.f, 0.f, 0.f};
#pragma unroll
  for (int kc = 0; kc < 2; ++kc) {
    s16x8 af = *(const s16x8*)(Uc + (16 * w + fr) * 64 + kc * 32 + fq * 8);
#pragma unroll
    for (int c = 0; c < 4; ++c) {
      int j = 16 * c + fr;
      s16x8 bb = *(const s16x8*)((char*)T1T + (((j << 7) + (kc << 6) + (fq << 4)) ^ ((j & 7) << 4)));
      a2[c] = __builtin_amdgcn_mfma_f32_16x16x32_bf16(af, bb, a2[c], 0, 0, 0);
    }
  }
#pragma unroll
  for (int c = 0; c < 4; ++c) {
    int gj = 16 * c + fr;
#pragma unroll
    for (int r = 0; r < 4; ++r)
      Uo[(64 + 16 * w + fq * 4 + r) * 128 + gj] = f2bf(a2[c][r]);
  }
}

// ================= solve128: band GEMM + single U128 apply (Lb = -L) =================
__global__ __launch_bounds__(256) void solve128(const unsigned short* __restrict__ WN,
    const unsigned short* __restrict__ Kk, const unsigned short* __restrict__ Lb,
    const unsigned short* __restrict__ U128, unsigned short* __restrict__ CT, int ib) {
  int jb = blockIdx.x, bh = blockIdx.y;     // jb: 128-wide col slab, 0..ib
  int b = bh >> 4, h = bh & 15;
  int t = threadIdx.x, w = t >> 6, l = t & 63;
  int wr = w >> 1, wc = w & 1, fr = l & 15, fq = l >> 4;
  int s0 = ib * 128, j0 = jb * 128;
  size_t base = (size_t)bh << 20;
  __shared__ unsigned short sh[128 * 128];  // 32KB: As/Bs then rT
  unsigned short* As = sh;
  unsigned short* Bs = sh + 128 * 64;
  unsigned short* rT = sh;                  // [128 j][128 s] bf16
  const unsigned short* Wb_ = WN + ((size_t)b << 20) + h * 64;
  const unsigned short* Kb_ = Kk + ((size_t)b << 20) + h * 64;

  // ---- band: rect = W K^T - sum L*C ----
  f32x4 acc[4][4];
#pragma unroll
  for (int m = 0; m < 4; ++m)
#pragma unroll
    for (int c = 0; c < 4; ++c) acc[m][c] = (f32x4){0.f, 0.f, 0.f, 0.f};
  int nst = (jb == ib) ? 1 : 1 + 2 * (ib - jb);
  for (int st = 0; st < nst; ++st) {
    __syncthreads();
#pragma unroll
    for (int i = 0; i < 4; ++i) {
      int cid = t + i * 256;
      int row = cid >> 3, ch = cid & 7;
      int chs = ch ^ (row & 7);
      const unsigned short *ga, *gb;
      if (st == 0) {
        ga = Wb_ + ((size_t)(s0 + row) << 10) + chs * 8;
        gb = Kb_ + ((size_t)(j0 + row) << 10) + chs * 8;
      } else {
        int rb = 2 * jb + st - 1;
        ga = Lb + base + ((size_t)(s0 + row) << 10) + rb * 64 + chs * 8;
        gb = CT + base + ((size_t)(j0 + row) << 10) + rb * 64 + chs * 8;
      }
      glds16(ga, (char*)As + cid * 16);
      glds16(gb, (char*)Bs + cid * 16);
    }
    __syncthreads();
#pragma unroll
    for (int kh = 0; kh < 2; ++kh) {
      s16x8 af[4], bfv[4];
#pragma unroll
      for (int m = 0; m < 4; ++m) {
        int ra = wr * 64 + 16 * m + fr;
        af[m] = *(const s16x8*)((char*)As + (((ra << 7) + (kh << 6) + (fq << 4)) ^ ((ra & 7) << 4)));
      }
#pragma unroll
      for (int c = 0; c < 4; ++c) {
        int rb2 = wc * 64 + 16 * c + fr;
        bfv[c] = *(const s16x8*)((char*)Bs + (((rb2 << 7) + (kh << 6) + (fq << 4)) ^ ((rb2 & 7) << 4)));
      }
#pragma unroll
      for (int m = 0; m < 4; ++m)
#pragma unroll
        for (int c = 0; c < 4; ++c)
          acc[m][c] = __builtin_amdgcn_mfma_f32_16x16x32_bf16(af[m], bfv[c], acc[m][c], 0, 0, 0);
    }
  }
  __syncthreads();
  // ---- write rectT [j][s] bf16 (256B rows, XOR (j&15)<<4), mask diag slab ----
#pragma unroll
  for (int m = 0; m < 4; ++m) {
#pragma unroll
    for (int c = 0; c < 4; ++c) {
      int jl = wc * 64 + 16 * c + fr;
      int sb = wr * 64 + 16 * m + fq * 4;
      u16x4 pk;
#pragma unroll
      for (int r = 0; r < 4; ++r) {
        float v = acc[m][c][r];
        if (jb == ib && jl >= sb + r) v = 0.f;
        pk[r] = f2bf(v);
      }
      int byt = ((jl << 8) + (sb << 1)) ^ ((jl & 15) << 4);
      *(u16x4*)((char*)rT + byt) = pk;
    }
  }
  __syncthreads();
  // ---- C = U128 @ rect, write straight to CT ----
  const unsigned short* U = U128 + (((size_t)(bh * 8 + ib)) << 14);
  f32x4 a2[4][4];
#pragma unroll
  for (int m = 0; m < 4; ++m)
#pragma unroll
    for (int c = 0; c < 4; ++c) a2[m][c] = (f32x4){0.f, 0.f, 0.f, 0.f};
#pragma unroll
  for (int kc = 0; kc < 4; ++kc) {
    s16x8 uf[4], bfv[4];
#pragma unroll
    for (int m = 0; m < 4; ++m)
      uf[m] = *(const s16x8*)(U + (wr * 64 + 16 * m + fr) * 128 + kc * 32 + fq * 8);
#pragma unroll
    for (int c = 0; c < 4; ++c) {
      int jl = wc * 64 + 16 * c + fr;
      bfv[c] = *(const s16x8*)((char*)rT + (((jl << 8) + (kc << 6) + (fq << 4)) ^ ((jl & 15) << 4)));
    }
#pragma unroll
    for (int m = 0; m < 4; ++m)
#pragma unroll
      for (int c = 0; c < 4; ++c)
        a2[m][c] = __builtin_amdgcn_mfma_f32_16x16x32_bf16(uf[m], bfv[c], a2[m][c], 0, 0, 0);
  }
#pragma unroll
  for (int m = 0; m < 4; ++m) {
#pragma unroll
    for (int c = 0; c < 4; ++c) {
      int gj = wc * 64 + 16 * c + fr;
      int sb = wr * 64 + 16 * m + fq * 4;
      u16x4 pk;
#pragma unroll
      for (int r = 0; r < 4; ++r) pk[r] = f2bf(a2[m][c][r]);
      *(u16x4*)(CT + base + ((size_t)(j0 + gj) << 10) + s0 + sb) = pk;
    }
  }
}

// ================= rowstat: m,l per row =================
__global__ __launch_bounds__(256) void rowstat(const unsigned short* __restrict__ S,
    const float* __restrict__ Fc, float* __restrict__ MR, float* __restrict__ LR) {
  int bh = blockIdx.y;
  int t = blockIdx.x * 4 + (threadIdx.x >> 6);
  int l = threadIdx.x & 63;
  size_t base = (size_t)bh << 20;
  const unsigned short* srow = S + base + ((size_t)t << 10);
  float vals[16]; float vmax = -1e30f;
#pragma unroll
  for (int i = 0; i < 2; ++i) {
    int c0 = i * 512 + l * 8;
    u16x8 sv = *(const u16x8*)(srow + c0);
    float4 f0 = *(const float4*)(Fc + bh * 1024 + c0);
    float4 f1 = *(const float4*)(Fc + bh * 1024 + c0 + 4);
#pragma unroll
    for (int e = 0; e < 8; ++e) {
      float fc = e < 4 ? ((const float*)&f0)[e] : ((const float*)&f1)[e - 4];
      float v = (c0 + e <= t) ? bf2f(sv[e]) * SM_SCALE - fc : -1e30f;
      vals[i * 8 + e] = v; vmax = fmaxf(vmax, v);
    }
  }
#pragma unroll
  for (int o = 1; o < 64; o <<= 1) vmax = fmaxf(vmax, __shfl_xor(vmax, o));
  float sum = 0.f;
#pragma unroll
  for (int e = 0; e < 16; ++e) sum += __expf(vals[e] - vmax);
#pragma unroll
  for (int o = 1; o < 64; o <<= 1) sum += __shfl_xor(sum, o);
  if (l == 0) { MR[bh * 1024 + t] = vmax; LR[bh * 1024 + t] = sum; }
}

// ================= pv: O = P @ V with on-the-fly P; sorted 1D grid (512) =================
__global__ __launch_bounds__(256) void pv_kernel(const unsigned short* __restrict__ S,
    const unsigned short* __restrict__ VT, const float* __restrict__ Fc,
    const float* __restrict__ MR, const float* __restrict__ LR,
    unsigned short* __restrict__ Ob) {
  int idx = blockIdx.x;
  int bh = idx & 31, rank = idx >> 5;
  int tb = 15 - rank;
  int b = bh >> 4, h = bh & 15;
  int t0 = tb * 64;
  int t = threadIdx.x, w = t >> 6, l = t & 63, fr = l & 15, fq = l >> 4;
  __shared__ unsigned short Pl[64 * 64];
  size_t base = (size_t)bh << 20;
  f32x4 acc[4];
#pragma unroll
  for (int c = 0; c < 4; ++c) acc[c] = (f32x4){0.f,0.f,0.f,0.f};
  for (int jb = 0; jb <= tb; ++jb) {
    int j0 = jb * 64;
    __syncthreads();
#pragma unroll
    for (int i = 0; i < 2; ++i) {
      int cid = t + i * 256;
      int row = cid >> 3, ch = cid & 7;
      int grow = t0 + row;
      u16x8 sv = *(const u16x8*)(S + base + ((size_t)grow << 10) + j0 + ch * 8);
      float4 f0 = *(const float4*)(Fc + bh * 1024 + j0 + ch * 8);
      float4 f1 = *(const float4*)(Fc + bh * 1024 + j0 + ch * 8 + 4);
      float m = MR[bh * 1024 + grow];
      u16x8 pv;
#pragma unroll
      for (int e = 0; e < 8; ++e) {
        float fc = e < 4 ? ((const float*)&f0)[e] : ((const float*)&f1)[e - 4];
        float p = __expf(bf2f(sv[e]) * SM_SCALE - fc - m);
        if (jb == tb && ch * 8 + e > row) p = 0.f;
        pv[e] = f2bf(p);
      }
      int byt = ((row << 7) + (ch << 4)) ^ ((row & 7) << 4);
      *(u16x8*)((char*)Pl + byt) = pv;
    }
    __syncthreads();
#pragma unroll
    for (int kh = 0; kh < 2; ++kh) {
      int ra = 16 * w + fr;
      s16x8 a = *(const s16x8*)((char*)Pl + (((ra << 7) + (kh << 6) + (fq << 4)) ^ ((ra & 7) << 4)));
#pragma unroll
      for (int c = 0; c < 4; ++c) {
        s16x8 bb = *(const s16x8*)(VT + ((size_t)bh * 64 + 16 * c + fr) * 1024 + j0 + kh * 32 + fq * 8);
        acc[c] = __builtin_amdgcn_mfma_f32_16x16x32_bf16(a, bb, acc[c], 0, 0, 0);
      }
    }
  }
  float inv[4];
#pragma unroll
  for (int r = 0; r < 4; ++r) inv[r] = 1.f / LR[bh * 1024 + t0 + 16 * w + fq * 4 + r];
#pragma unroll
  for (int c = 0; c < 4; ++c) {
#pragma unroll
    for (int r = 0; r < 4; ++r) {
      int grow = t0 + 16 * w + fq * 4 + r;
      Ob[((size_t)(b * 1024) + grow) * 1024 + h * 64 + 16 * c + fr] = f2bf(acc[c][r] * inv[r]);
    }
  }
}

extern "C" void kernel_launch(void* const* d_in, const int* in_sizes, int n_in,
                              void* d_out, int out_size, void* d_ws, size_t ws_size,
                              hipStream_t stream) {
  const float* x    = (const float*)d_in[0];
  const float* Wq   = (const float*)d_in[1];
  const float* Wk   = (const float*)d_in[2];
  const float* Wv   = (const float*)d_in[3];
  const float* Wo   = (const float*)d_in[4];
  const float* Ww1  = (const float*)d_in[5];
  const float* Ww2  = (const float*)d_in[6];
  const float* Wb   = (const float*)d_in[7];
  const float* Wf   = (const float*)d_in[8];
  const float* delta= (const float*)d_in[9];

  char* ws = (char*)d_ws;
  unsigned short* xb   = (unsigned short*)(ws + OFF_XB);
  unsigned short* WqT  = (unsigned short*)(ws + OFF_WQT);
  float*          BL   = (float*)(ws + OFF_BL);
  unsigned short* WkT  = (unsigned short*)(ws + OFF_WKT);
  unsigned short* BFT  = (unsigned short*)(ws + OFF_BFT);
  unsigned short* WvT  = (unsigned short*)(ws + OFF_WVT);
  unsigned short* WoT  = (unsigned short*)(ws + OFF_WOT);
  unsigned short* W1T  = (unsigned short*)(ws + OFF_W1T);
  unsigned short* W2T  = (unsigned short*)(ws + OFF_W2T);
  float*          Beta = (float*)(ws + OFF_W1T);
  unsigned short* Q16  = (unsigned short*)(ws + OFF_Q16);
  unsigned short* K16  = (unsigned short*)(ws + OFF_K16);
  unsigned short* VT   = (unsigned short*)(ws + OFF_VT);
  unsigned short* WN16 = (unsigned short*)(ws + OFF_WN16);
  unsigned short* WB16 = (unsigned short*)(ws + OFF_WB16);
  unsigned short* WNF16= (unsigned short*)(ws + OFF_WNF);
  unsigned short* ObB  = (unsigned short*)(ws + OFF_OB);
  unsigned short* Wpre = (unsigned short*)(ws + OFF_WPRE);
  float*          Fc   = (float*)(ws + OFF_FC);
  unsigned short* Lbuf = (unsigned short*)(ws + OFF_L);
  unsigned short* Sbuf = (unsigned short*)(ws + OFF_L);
  unsigned short* CT   = (unsigned short*)(ws + OFF_CT);
  unsigned short* Gbuf = (unsigned short*)(ws + OFF_G);
  float*          MR   = (float*)(ws + OFF_MR);
  float*          LR   = (float*)(ws + OFF_LR);
  unsigned short* UI   = (unsigned short*)(ws + OFF_UI);
  unsigned short* U128 = (unsigned short*)(ws + OFF_U128);

  dim3 blk(256);
  // prep (transposes + x cast fused)
  prep_all<<<2560, blk, 0, stream>>>(Wq, Wk, Wv, Wo, Ww1, Ww2, x,
                                     WqT, WkT, WvT, WoT, W1T, W2T, xb);
  // Q,K,VT in one launch (128^2 tiles, glds staging)
  proj_big<<<384, blk, 0, stream>>>(xb, WqT, WkT, WvT, Q16, K16, VT);
  // beta/log_f operand (overlays WkT -> after proj_big)
  bfprep<<<256, blk, 0, stream>>>(Wb, Wf, BFT);
  // Wpre + BL in one launch (BL overlays WqT -> after proj_big)
  proj_small<<<dim3(2,32), blk, 0, stream>>>(xb, W1T, BFT, Wpre, BL);
  // WNF = Wpre @ W2T
  gemm_nt<0><<<dim3(16,32), blk, 0, stream>>>(Wpre, W2T, WNF16, 2048, 1024, 64);
  // beta/logsigmoid/cumsum fused (Beta overlays W1T -> after proj_small)
  bgfc<<<32, blk, 0, stream>>>(BL, delta, Beta, Fc);
  wnorm2<<<2048, blk, 0, stream>>>(WNF16, Beta, WN16, WB16);
  // L and G (both stored NEGATED) in one fused launch
  pairLG<<<dim3(36 * 32), blk, 0, stream>>>(WN16, Q16, WB16, Lbuf, Gbuf);
  // triangular solve: 64-inverses -> 128-inverses -> 8 MFMA band steps
  inv64<<<dim3(16,32), blk, 0, stream>>>(Lbuf, UI);
  u128build<<<dim3(8,32), blk, 0, stream>>>(Lbuf, UI, U128);
  for (int ib = 0; ib < 8; ++ib)
    solve128<<<dim3(ib + 1, 32), blk, 0, stream>>>(WN16, K16, Lbuf, U128, CT, ib);
  // S = QK^T + Gneg C (sorted band grid; reuses L region)
  score128s<<<dim3(36 * 32), blk, 0, stream>>>(Q16, K16, Gbuf, CT, Sbuf);
  // softmax stats + PV
  rowstat<<<dim3(256,32), blk, 0, stream>>>(Sbuf, Fc, MR, LR);
  pv_kernel<<<dim3(512), blk, 0, stream>>>(Sbuf, VT, Fc, MR, LR, ObB);
  // output projection (f32 out)
  gemm_nt<1><<<dim3(16,32), blk, 0, stream>>>(ObB, WoT, d_out, 2048, 1024, 1024);
}

// Round 8
// 316.107 us; speedup vs baseline: 12.9002x; 1.0677x over previous
//
#include <hip/hip_runtime.h>
#include <hip/hip_bf16.h>

#define DEV static __device__ __forceinline__

constexpr float SM_SCALE = 0.125f;   // hd^-0.5, hd=64

typedef __attribute__((ext_vector_type(8))) short s16x8;
typedef __attribute__((ext_vector_type(8))) unsigned short u16x8;
typedef __attribute__((ext_vector_type(4))) unsigned short u16x4;
typedef __attribute__((ext_vector_type(4))) float f32x4;

DEV float bf2f(unsigned short u) {
  union { unsigned int i; float f; } v; v.i = ((unsigned int)u) << 16; return v.f;
}
DEV unsigned short f2bf(float f) {
  union { float f; unsigned int i; } v; v.f = f;
  unsigned int r = v.i + 0x7fffu + ((v.i >> 16) & 1u);
  return (unsigned short)(r >> 16);
}
DEV void tri_unrank(int r, int& k, int& i) {
  k = (int)((sqrtf(8.f * r + 1.f) - 1.f) * 0.5f);
  while (k * (k + 1) / 2 > r) --k;
  while ((k + 1) * (k + 2) / 2 <= r) ++k;
  i = r - k * (k + 1) / 2;
}
// async global->LDS, 16B per lane; dest must be wave-linear (base + lane*16)
DEV void glds16(const void* g, void* l) {
  __builtin_amdgcn_global_load_lds(
      (const __attribute__((address_space(1))) void*)g,
      (__attribute__((address_space(3))) void*)l, 16, 0, 0);
}

// ---------- workspace layout (bytes) ----------
constexpr size_t OFF_XB   = 0;                       // 4MB xb bf16 [2048][1024]
constexpr size_t OFF_WQT  = 4194304;                 // 2MB; reused as BL (f32 2048x64)
constexpr size_t OFF_BL   = 4194304;
constexpr size_t OFF_WKT  = 6291456;                 // 2MB
constexpr size_t OFF_WVT  = 8388608;
constexpr size_t OFF_WOT  = 10485760;
constexpr size_t OFF_W1C  = 12582912;                // 128KB bf16 Ww1 cast (1024x64)
constexpr size_t OFF_W2T  = 12713984;                // 128KB
constexpr size_t OFF_BETA = 12582912;                // reuse W1C after wfuse
constexpr size_t OFF_Q16  = 12845056;                // 4MB bf16 2048x1024
constexpr size_t OFF_K16  = 17039360;                // 4MB
constexpr size_t OFF_VT   = 21233664;                // 4MB  VT[b][64h*d][1024n]
constexpr size_t OFF_WN16 = 25427968;                // 4MB; holds WfusedT until wnorm2
constexpr size_t OFF_WB16 = 29622272;                // 4MB
constexpr size_t OFF_WNF  = 33816576;                // 4MB (reused as Ob)
constexpr size_t OFF_OB   = 33816576;
constexpr size_t OFF_BFT  = 38010880;                // 128KB bf16 (64x1024) [ex-WPRE slot]
constexpr size_t OFF_FC   = 38273024;                // 128KB
constexpr size_t OFF_L    = 38404096;                // 64MB, stores -L (reused as S)
constexpr size_t OFF_CT   = 105512960;               // 64MB
constexpr size_t OFF_G    = 172621824;               // 64MB, stores -G
constexpr size_t OFF_MR   = 239730688;               // 128KB f32 [32][1024]
constexpr size_t OFF_LR   = 239861760;               // 128KB
constexpr size_t OFF_UI   = 239992832;               // 4MB bf16 [32][16][64][64]
constexpr size_t OFF_U128 = 244187136;               // 8MB bf16 [32][8][128][128]
constexpr size_t OFF_B256 = 252575744;               // 4MB bf16 [32][4][128][128]

// ================= fused prep: transposes + casts + BFT; grid 2128 =================
__global__ __launch_bounds__(256) void prep_all(
    const float* __restrict__ W0, const float* __restrict__ W1,
    const float* __restrict__ W2, const float* __restrict__ W3,
    const float* __restrict__ Ww1, const float* __restrict__ Ww2,
    const float* __restrict__ x, const float* __restrict__ Wb,
    const float* __restrict__ Wf,
    unsigned short* __restrict__ D0, unsigned short* __restrict__ D1,
    unsigned short* __restrict__ D2, unsigned short* __restrict__ D3,
    unsigned short* __restrict__ W1c, unsigned short* __restrict__ W2T,
    unsigned short* __restrict__ xb, unsigned short* __restrict__ BFT) {
  int bidx = blockIdx.x;
  int t = threadIdx.x;
  if (bidx >= 2096) {                      // BFT build (32 blocks)
    int e0 = ((bidx - 2096) * 256 + t) * 8;
    int j = e0 >> 10, i0 = e0 & 1023;
    u16x8 o;
#pragma unroll
    for (int e = 0; e < 8; ++e) {
      int i = i0 + e;
      float v = 0.f;
      if (j < 16) v = Wb[i * 16 + j];
      else if (j < 32) v = Wf[i * 16 + (j - 16)];
      o[e] = f2bf(v);
    }
    *(u16x8*)(BFT + e0) = o;
    return;
  }
  if (bidx >= 2064) {                      // W1 cast (32 blocks)
    int i = ((bidx - 2064) * 256 + t) * 8;
    float4 a = *(const float4*)(Ww1 + i);
    float4 b = *(const float4*)(Ww1 + i + 4);
    u16x8 o;
    o[0] = f2bf(a.x); o[1] = f2bf(a.y); o[2] = f2bf(a.z); o[3] = f2bf(a.w);
    o[4] = f2bf(b.x); o[5] = f2bf(b.y); o[6] = f2bf(b.z); o[7] = f2bf(b.w);
    *(u16x8*)(W1c + i) = o;
    return;
  }
  if (bidx >= 1040) {                      // x cast (1024 blocks)
    int i = ((bidx - 1040) * 256 + t) * 8;
    float4 a = *(const float4*)(x + i);
    float4 b = *(const float4*)(x + i + 4);
    u16x8 o;
    o[0] = f2bf(a.x); o[1] = f2bf(a.y); o[2] = f2bf(a.z); o[3] = f2bf(a.w);
    o[4] = f2bf(b.x); o[5] = f2bf(b.y); o[6] = f2bf(b.z); o[7] = f2bf(b.w);
    *(u16x8*)(xb + i) = o;
    return;
  }
  const float* src; unsigned short* dst; int R, C, c0, r0;
  if (bidx >= 1024) {                      // W2T transpose (16 blocks)
    src = Ww2; dst = W2T; R = 64; C = 1024;
    c0 = (bidx - 1024) * 64; r0 = 0;
  } else {
    int z = bidx >> 8, xy = bidx & 255;
    src = z == 0 ? W0 : z == 1 ? W1 : z == 2 ? W2 : W3;
    dst = z == 0 ? D0 : z == 1 ? D1 : z == 2 ? D2 : D3;
    R = 1024; C = 1024;
    c0 = (xy & 15) * 64; r0 = (xy >> 4) * 64;
  }
  __shared__ float tile[64 * 65];
#pragma unroll
  for (int i = 0; i < 16; ++i) {
    int lin = t + i * 256; int r = lin >> 6, c = lin & 63;
    tile[r * 65 + c] = src[(size_t)(r0 + r) * C + c0 + c];
  }
  __syncthreads();
#pragma unroll
  for (int i = 0; i < 16; ++i) {
    int lin = t + i * 256; int c = lin >> 6, r = lin & 63;
    dst[(size_t)(c0 + c) * R + r0 + r] = f2bf(tile[r * 65 + c]);
  }
}

// beta + log_sigmoid + cumsum fused; grid 32 (bh)
__global__ __launch_bounds__(256) void bgfc(const float* __restrict__ BL,
    const float* __restrict__ delta, float* __restrict__ Beta, float* __restrict__ Fc) {
  int bh = blockIdx.x;
  int b = bh >> 4, h = bh & 15;
  int t = threadIdx.x;
  __shared__ float buf[1024];
  __shared__ float tsum[256];
  float dh = delta[h];
#pragma unroll
  for (int i = 0; i < 4; ++i) {
    int n = t + i * 256;
    int row = (b << 10) + n;
    float braw = BL[row * 64 + h];
    Beta[row * 16 + h] = 2.f / (1.f + __expf(-braw));
    float lraw = BL[row * 64 + 16 + h] + dh;
    buf[n] = (lraw >= 0.f) ? -log1pf(__expf(-lraw)) : (lraw - log1pf(__expf(lraw)));
  }
  __syncthreads();
  float loc[4]; float run = 0.f;
#pragma unroll
  for (int i = 0; i < 4; ++i) { run += buf[t * 4 + i]; loc[i] = run; }
  tsum[t] = run;
  __syncthreads();
  for (int off = 1; off < 256; off <<= 1) {
    float add = (t >= off) ? tsum[t - off] : 0.f;
    __syncthreads();
    tsum[t] += add;
    __syncthreads();
  }
  float excl = tsum[t] - run;
#pragma unroll
  for (int i = 0; i < 4; ++i) Fc[bh * 1024 + t * 4 + i] = excl + loc[i];
}

// ================= mega projection: Q,K (128^2) + VT + WNF, 512 blocks =================
__global__ __launch_bounds__(256) void proj_big(const unsigned short* __restrict__ xb,
    const unsigned short* __restrict__ WqT, const unsigned short* __restrict__ WkT,
    const unsigned short* __restrict__ WvT, const unsigned short* __restrict__ WfT,
    unsigned short* __restrict__ Q16, unsigned short* __restrict__ K16,
    unsigned short* __restrict__ VT, unsigned short* __restrict__ WNF) {
  int idx = blockIdx.x;
  const unsigned short *A, *BT; unsigned short* out; int m0, n0;
  if (idx < 256) {
    int my = idx >> 4, nx = idx & 15;
    m0 = my * 128; A = xb;
    if (nx < 8) { BT = WqT; out = Q16; n0 = nx * 128; }
    else { BT = WkT; out = K16; n0 = (nx - 8) * 128; }
  } else if (idx < 384) {
    int r = idx - 256; int bz = r >> 6; int rem = r & 63;
    m0 = (rem >> 3) * 128; n0 = (rem & 7) * 128;
    A = WvT; BT = xb + ((size_t)bz << 20); out = VT + ((size_t)bz << 20);
  } else {
    int r2 = idx - 384;
    m0 = (r2 >> 3) * 128; n0 = (r2 & 7) * 128;
    A = xb; BT = WfT; out = WNF;
  }
  int t = threadIdx.x;
  int w = t >> 6, l = t & 63;
  int wr = w >> 1, wc = w & 1;
  int fr = l & 15, fq = l >> 4;
  __shared__ unsigned short As[128 * 64];
  __shared__ unsigned short Bs[128 * 64];
  f32x4 acc[4][4];
#pragma unroll
  for (int m = 0; m < 4; ++m)
#pragma unroll
    for (int c = 0; c < 4; ++c) acc[m][c] = (f32x4){0.f, 0.f, 0.f, 0.f};
  for (int k0 = 0; k0 < 1024; k0 += 64) {
    __syncthreads();
#pragma unroll
    for (int i = 0; i < 4; ++i) {
      int cid = t + i * 256;
      int row = cid >> 3, ch = cid & 7;
      int chs = ch ^ (row & 7);
      glds16(A + (size_t)(m0 + row) * 1024 + k0 + chs * 8, (char*)As + cid * 16);
      glds16(BT + (size_t)(n0 + row) * 1024 + k0 + chs * 8, (char*)Bs + cid * 16);
    }
    __syncthreads();
#pragma unroll
    for (int kh = 0; kh < 2; ++kh) {
      s16x8 af[4], bfv[4];
#pragma unroll
      for (int m = 0; m < 4; ++m) {
        int ra = wr * 64 + 16 * m + fr;
        af[m] = *(const s16x8*)((char*)As + (((ra << 7) + (kh << 6) + (fq << 4)) ^ ((ra & 7) << 4)));
      }
#pragma unroll
      for (int c = 0; c < 4; ++c) {
        int rb = wc * 64 + 16 * c + fr;
        bfv[c] = *(const s16x8*)((char*)Bs + (((rb << 7) + (kh << 6) + (fq << 4)) ^ ((rb & 7) << 4)));
      }
#pragma unroll
      for (int m = 0; m < 4; ++m)
#pragma unroll
        for (int c = 0; c < 4; ++c)
          acc[m][c] = __builtin_amdgcn_mfma_f32_16x16x32_bf16(af[m], bfv[c], acc[m][c], 0, 0, 0);
    }
  }
#pragma unroll
  for (int m = 0; m < 4; ++m) {
#pragma unroll
    for (int c = 0; c < 4; ++c) {
      int col = n0 + wc * 64 + 16 * c + fr;
#pragma unroll
      for (int r = 0; r < 4; ++r) {
        int grow = m0 + wr * 64 + 16 * m + fq * 4 + r;
        out[(size_t)grow * 1024 + col] = f2bf(acc[m][c][r]);
      }
    }
  }
}

// ================= 64-tile bf16 NT GEMM =================
template<int F32OUT>
__global__ __launch_bounds__(256) void gemm_nt(const unsigned short* __restrict__ A,
    const unsigned short* __restrict__ BT, void* __restrict__ out,
    int M, int N, int K) {
  __shared__ unsigned short As[64 * 64];
  __shared__ unsigned short Bs[64 * 64];
  int m0 = blockIdx.y * 64, n0 = blockIdx.x * 64;
  int t = threadIdx.x;
  int w = t >> 6, l = t & 63, fr = l & 15;
  int koB = (l >> 4) * 16;
  f32x4 acc[4];
#pragma unroll
  for (int c = 0; c < 4; ++c) acc[c] = (f32x4){0.f, 0.f, 0.f, 0.f};
  for (int k0 = 0; k0 < K; k0 += 64) {
    __syncthreads();
#pragma unroll
    for (int i = 0; i < 2; ++i) {
      int cid = t + i * 256;
      int row = cid >> 3, ch = cid & 7;
      int chs = ch ^ (row & 7);
      glds16(A + (size_t)(m0 + row) * K + k0 + chs * 8, (char*)As + cid * 16);
      glds16(BT + (size_t)(n0 + row) * K + k0 + chs * 8, (char*)Bs + cid * 16);
    }
    __syncthreads();
#pragma unroll
    for (int kh = 0; kh < 2; ++kh) {
      int ra = 16 * w + fr;
      s16x8 a = *(const s16x8*)((char*)As + (((ra << 7) + (kh << 6) + koB) ^ ((ra & 7) << 4)));
#pragma unroll
      for (int c = 0; c < 4; ++c) {
        int rb = 16 * c + fr;
        s16x8 bb = *(const s16x8*)((char*)Bs + (((rb << 7) + (kh << 6) + koB) ^ ((rb & 7) << 4)));
        acc[c] = __builtin_amdgcn_mfma_f32_16x16x32_bf16(a, bb, acc[c], 0, 0, 0);
      }
    }
  }
  int rbase = m0 + 16 * w + ((l >> 4) << 2);
#pragma unroll
  for (int c = 0; c < 4; ++c) {
    int col = n0 + 16 * c + fr;
#pragma unroll
    for (int r = 0; r < 4; ++r) {
      if (F32OUT) ((float*)out)[(size_t)(rbase + r) * N + col] = acc[c][r];
      else ((unsigned short*)out)[(size_t)(rbase + r) * N + col] = f2bf(acc[c][r]);
    }
  }
}

// ================= w normalize + beta-scale =================
__global__ __launch_bounds__(256) void wnorm2(const unsigned short* __restrict__ WNF,
    const float* __restrict__ Beta, unsigned short* __restrict__ WN,
    unsigned short* __restrict__ WB) {
  int row = blockIdx.x;
  int wave = threadIdx.x >> 6, lane = threadIdx.x & 63;
#pragma unroll
  for (int i = 0; i < 4; ++i) {
    int hh = wave * 4 + i;
    size_t idx = ((size_t)row << 10) + hh * 64 + lane;
    float v = bf2f(WNF[idx]);
    float ss = v * v;
#pragma unroll
    for (int off = 1; off < 64; off <<= 1) ss += __shfl_xor(ss, off);
    float wn = v * rsqrtf(ss + 1e-6f);
    WN[idx] = f2bf(wn);
    WB[idx] = f2bf(wn * Beta[row * 16 + hh]);
  }
}

// ================= pair fused: writes NEGATED L and G =================
__global__ __launch_bounds__(256) void pairLG(const unsigned short* __restrict__ WN,
    const unsigned short* __restrict__ Q, const unsigned short* __restrict__ WB,
    unsigned short* __restrict__ Lg, unsigned short* __restrict__ Gg) {
  int idx = blockIdx.x;
  int bh = idx & 31, r0r = idx >> 5;
  int tb2, jb2; tri_unrank(r0r, tb2, jb2);
  int b = bh >> 4, h = bh & 15;
  int m0 = tb2 * 128, n0 = jb2 * 128;
  int t = threadIdx.x;
  int w = t >> 6, l = t & 63;
  int wr = w >> 1, wc = w & 1;
  int fr = l & 15, fq = l >> 4;
  __shared__ unsigned short As[128 * 64];
  __shared__ unsigned short Bs[128 * 64];
  const unsigned short* WNb = WN + ((size_t)b << 20) + h * 64;
  const unsigned short* Qb  = Q + ((size_t)b << 20) + h * 64;
  const unsigned short* WBb = WB + ((size_t)b << 20) + h * 64;
  size_t base = (size_t)bh << 20;
#pragma unroll
  for (int i = 0; i < 4; ++i) {
    int cid = t + i * 256;
    int row = cid >> 3, ch = cid & 7;
    int chs = ch ^ (row & 7);
    glds16(WNb + ((size_t)(m0 + row) << 10) + chs * 8, (char*)As + cid * 16);
    glds16(WBb + ((size_t)(n0 + row) << 10) + chs * 8, (char*)Bs + cid * 16);
  }
  __syncthreads();
  for (int pass = 0; pass < 2; ++pass) {
    f32x4 acc[4][4];
#pragma unroll
    for (int m = 0; m < 4; ++m)
#pragma unroll
      for (int c = 0; c < 4; ++c) acc[m][c] = (f32x4){0.f, 0.f, 0.f, 0.f};
#pragma unroll
    for (int kh = 0; kh < 2; ++kh) {
      s16x8 af[4], bfv[4];
#pragma unroll
      for (int m = 0; m < 4; ++m) {
        int ra = wr * 64 + 16 * m + fr;
        af[m] = *(const s16x8*)((char*)As + (((ra << 7) + (kh << 6) + (fq << 4)) ^ ((ra & 7) << 4)));
      }
#pragma unroll
      for (int c = 0; c < 4; ++c) {
        int rb = wc * 64 + 16 * c + fr;
        bfv[c] = *(const s16x8*)((char*)Bs + (((rb << 7) + (kh << 6) + (fq << 4)) ^ ((rb & 7) << 4)));
      }
#pragma unroll
      for (int m = 0; m < 4; ++m)
#pragma unroll
        for (int c = 0; c < 4; ++c)
          acc[m][c] = __builtin_amdgcn_mfma_f32_16x16x32_bf16(af[m], bfv[c], acc[m][c], 0, 0, 0);
    }
    unsigned short* dst = pass ? Gg : Lg;
#pragma unroll
    for (int m = 0; m < 4; ++m) {
#pragma unroll
      for (int c = 0; c < 4; ++c) {
        int gj = n0 + wc * 64 + 16 * c + fr;
#pragma unroll
        for (int r = 0; r < 4; ++r) {
          int gi = m0 + wr * 64 + 16 * m + fq * 4 + r;
          bool keep = pass ? (gj <= gi) : (gj < gi);
          dst[base + ((size_t)gi << 10) + gj] = f2bf(keep ? -acc[m][c][r] : 0.f);
        }
      }
    }
    if (pass == 0) {
      __syncthreads();
#pragma unroll
      for (int i = 0; i < 4; ++i) {
        int cid = t + i * 256;
        int row = cid >> 3, ch = cid & 7;
        int chs = ch ^ (row & 7);
        glds16(Qb + ((size_t)(m0 + row) << 10) + chs * 8, (char*)As + cid * 16);
      }
      __syncthreads();
    }
  }
}

// ================= score: S = Q K^T + Gneg @ C, sorted 1D grid =================
__global__ __launch_bounds__(256) void score128s(const unsigned short* __restrict__ Q,
    const unsigned short* __restrict__ Kk, const unsigned short* __restrict__ G,
    const unsigned short* __restrict__ CT, unsigned short* __restrict__ Sg) {
  int idx = blockIdx.x;
  int bh = idx & 31, r0r = idx >> 5;
  int k, i; tri_unrank(r0r, k, i);
  int tb2 = (7 - k) + i, jb2 = i;
  int b = bh >> 4, h = bh & 15;
  int m0 = tb2 * 128, n0 = jb2 * 128;
  int t = threadIdx.x;
  int w = t >> 6, l = t & 63;
  int wr = w >> 1, wc = w & 1;
  int fr = l & 15, fq = l >> 4;
  __shared__ unsigned short As[128 * 64];
  __shared__ unsigned short Bs[128 * 64];
  size_t base = (size_t)bh << 20;
  const unsigned short* Qb_ = Q + ((size_t)b << 20) + h * 64;
  const unsigned short* Kb_ = Kk + ((size_t)b << 20) + h * 64;
  const unsigned short* Gb_ = G + base;
  const unsigned short* Cb_ = CT + base;
  int kbase = jb2 * 128;
  int nsteps = 1 + (tb2 - jb2 + 1) * 2;
  f32x4 acc[4][4];
#pragma unroll
  for (int m = 0; m < 4; ++m)
#pragma unroll
    for (int c = 0; c < 4; ++c) acc[m][c] = (f32x4){0.f, 0.f, 0.f, 0.f};
  for (int step = 0; step < nsteps; ++step) {
    const unsigned short* pa; const unsigned short* pb; int koff;
    if (step == 0) { pa = Qb_; pb = Kb_; koff = 0; }
    else { pa = Gb_; pb = Cb_; koff = kbase + (step - 1) * 64; }
    __syncthreads();
#pragma unroll
    for (int i2 = 0; i2 < 4; ++i2) {
      int cid = t + i2 * 256;
      int row = cid >> 3, ch = cid & 7;
      int chs = ch ^ (row & 7);
      glds16(pa + ((size_t)(m0 + row) << 10) + koff + chs * 8, (char*)As + cid * 16);
      glds16(pb + ((size_t)(n0 + row) << 10) + koff + chs * 8, (char*)Bs + cid * 16);
    }
    __syncthreads();
#pragma unroll
    for (int kh = 0; kh < 2; ++kh) {
      s16x8 af[4], bfv[4];
#pragma unroll
      for (int m = 0; m < 4; ++m) {
        int ra = wr * 64 + 16 * m + fr;
        af[m] = *(const s16x8*)((char*)As + (((ra << 7) + (kh << 6) + (fq << 4)) ^ ((ra & 7) << 4)));
      }
#pragma unroll
      for (int c = 0; c < 4; ++c) {
        int rb = wc * 64 + 16 * c + fr;
        bfv[c] = *(const s16x8*)((char*)Bs + (((rb << 7) + (kh << 6) + (fq << 4)) ^ ((rb & 7) << 4)));
      }
#pragma unroll
      for (int m = 0; m < 4; ++m)
#pragma unroll
        for (int c = 0; c < 4; ++c)
          acc[m][c] = __builtin_amdgcn_mfma_f32_16x16x32_bf16(af[m], bfv[c], acc[m][c], 0, 0, 0);
    }
  }
#pragma unroll
  for (int m = 0; m < 4; ++m) {
#pragma unroll
    for (int c = 0; c < 4; ++c) {
      int gj = n0 + wc * 64 + 16 * c + fr;
#pragma unroll
      for (int r = 0; r < 4; ++r) {
        int gi = m0 + wr * 64 + 16 * m + fq * 4 + r;
        Sg[base + ((size_t)gi << 10) + gj] = f2bf(acc[m][c][r]);
      }
    }
  }
}

// ================= inv64: U = (I + Ldiag)^-1 (Lb holds -L); grid (16,32) =================
__global__ __launch_bounds__(256) void inv64(const unsigned short* __restrict__ Lb,
    unsigned short* __restrict__ UI) {
  int ib = blockIdx.x, bh = blockIdx.y;
  int t = threadIdx.x;
  int s0 = ib * 64;
  size_t base = (size_t)bh << 20;
  __shared__ float LD[64 * 65];
  __shared__ unsigned short us[64 * 66];
#pragma unroll
  for (int i = 0; i < 16; ++i) {
    int lin = t + i * 256; int s = lin >> 6, r = lin & 63;
    LD[s * 65 + r] = -bf2f(Lb[base + ((size_t)(s0 + s) << 10) + s0 + r]);   // +L
  }
  __syncthreads();
  if (t < 64) {
    float cc[64];
#pragma unroll
    for (int s = 0; s < 64; ++s) cc[s] = (s == t) ? 1.f : 0.f;
#pragma unroll
    for (int r = 0; r < 63; ++r) {
      float val = cc[r];
#pragma unroll
      for (int s = r + 1; s < 64; ++s) cc[s] -= LD[s * 65 + r] * val;
    }
#pragma unroll
    for (int s = 0; s < 64; ++s) us[s * 66 + t] = f2bf(cc[s]);
  }
  __syncthreads();
  size_t ubase = ((size_t)(bh * 16 + ib)) << 12;
#pragma unroll
  for (int i = 0; i < 16; ++i) {
    int lin = t + i * 256; int s = lin >> 6, j = lin & 63;
    UI[ubase + s * 64 + j] = us[s * 66 + j];
  }
}

// ================= u128build: U128 = [[Ua,0],[-Uc L_BA Ua, Uc]] (Lb = -L); grid (8,32) =================
__global__ __launch_bounds__(256) void u128build(const unsigned short* __restrict__ Lb,
    const unsigned short* __restrict__ UI, unsigned short* __restrict__ U128) {
  int ib = blockIdx.x, bh = blockIdx.y;
  int t = threadIdx.x, w = t >> 6, l = t & 63, fr = l & 15, fq = l >> 4;
  int s0 = ib * 128;
  size_t base = (size_t)bh << 20;
  const unsigned short* Ua = UI + (((size_t)(bh * 16 + 2 * ib)) << 12);
  const unsigned short* Uc = UI + (((size_t)(bh * 16 + 2 * ib + 1)) << 12);
  unsigned short* Uo = U128 + (((size_t)(bh * 8 + ib)) << 14);
  __shared__ unsigned short UaT[64 * 64];
  __shared__ unsigned short T1T[64 * 64];
#pragma unroll
  for (int i = 0; i < 2; ++i) {
    int cid = t + i * 256;
    int s = cid >> 3, ch = cid & 7;
    u16x8 v = *(const u16x8*)(Ua + s * 64 + ch * 8);
#pragma unroll
    for (int e = 0; e < 8; ++e) {
      int j = ch * 8 + e;
      int byt = ((j << 7) + (s << 1)) ^ ((j & 7) << 4);
      *(unsigned short*)((char*)UaT + byt) = v[e];
    }
  }
#pragma unroll
  for (int i = 0; i < 8; ++i) {
    int cid = t + i * 256;
    int row = cid >> 4, ch = cid & 15;
    if (row < 64) {
      if (ch < 8) *(u16x8*)(Uo + row * 128 + ch * 8) = *(const u16x8*)(Ua + row * 64 + ch * 8);
      else { u16x8 z = {0,0,0,0,0,0,0,0}; *(u16x8*)(Uo + row * 128 + ch * 8) = z; }
    } else if (ch >= 8) {
      *(u16x8*)(Uo + row * 128 + ch * 8) = *(const u16x8*)(Uc + (row - 64) * 64 + (ch - 8) * 8);
    }
  }
  __syncthreads();
  f32x4 a1[4];
#pragma unroll
  for (int c = 0; c < 4; ++c) a1[c] = (f32x4){0.f, 0.f, 0.f, 0.f};
#pragma unroll
  for (int kc = 0; kc < 2; ++kc) {
    s16x8 af = *(const s16x8*)(Lb + base + ((size_t)(s0 + 64 + 16 * w + fr) << 10) + s0 + kc * 32 + fq * 8);
#pragma unroll
    for (int c = 0; c < 4; ++c) {
      int j = 16 * c + fr;
      s16x8 bb = *(const s16x8*)((char*)UaT + (((j << 7) + (kc << 6) + (fq << 4)) ^ ((j & 7) << 4)));
      a1[c] = __builtin_amdgcn_mfma_f32_16x16x32_bf16(af, bb, a1[c], 0, 0, 0);
    }
  }
#pragma unroll
  for (int c = 0; c < 4; ++c) {
    int gj = 16 * c + fr;
    int sb = 16 * w + fq * 4;
    u16x4 pk;
#pragma unroll
    for (int r = 0; r < 4; ++r) pk[r] = f2bf(a1[c][r]);
    *(u16x4*)((char*)T1T + (((gj << 7) + (sb << 1)) ^ ((gj & 7) << 4))) = pk;
  }
  __syncthreads();
  f32x4 a2[4];
#pragma unroll
  for (int c = 0; c < 4; ++c) a2[c] = (f32x4){0.f, 0.f, 0.f, 0.f};
#pragma unroll
  for (int kc = 0; kc < 2; ++kc) {
    s16x8 af = *(const s16x8*)(Uc + (16 * w + fr) * 64 + kc * 32 + fq * 8);
#pragma unroll
    for (int c = 0; c < 4; ++c) {
      int j = 16 * c + fr;
      s16x8 bb = *(const s16x8*)((char*)T1T + (((j << 7) + (kc << 6) + (fq << 4)) ^ ((j & 7) << 4)));
      a2[c] = __builtin_amdgcn_mfma_f32_16x16x32_bf16(af, bb, a2[c], 0, 0, 0);
    }
  }
#pragma unroll
  for (int c = 0; c < 4; ++c) {
    int gj = 16 * c + fr;
#pragma unroll
    for (int r = 0; r < 4; ++r)
      Uo[(64 + 16 * w + fq * 4 + r) * 128 + gj] = f2bf(a2[c][r]);
  }
}

// ================= u256build: B256 = Uc128 @ (Lneg_BA @ Ua128); grid (4,32) =================
__global__ __launch_bounds__(256) void u256build(const unsigned short* __restrict__ Lb,
    const unsigned short* __restrict__ U128, unsigned short* __restrict__ B256) {
  int qb = blockIdx.x, bh = blockIdx.y;
  int t = threadIdx.x, w = t >> 6, l = t & 63, fr = l & 15, fq = l >> 4;
  int s0 = qb * 256;
  size_t base = (size_t)bh << 20;
  const unsigned short* Ua = U128 + (((size_t)(bh * 8 + 2 * qb)) << 14);
  const unsigned short* Uc = U128 + (((size_t)(bh * 8 + 2 * qb + 1)) << 14);
  unsigned short* out = B256 + (((size_t)(bh * 4 + qb)) << 14);
  __shared__ unsigned short UaT[16384];   // 128x128, 256B rows, XOR (j&15)<<4
  __shared__ unsigned short T1T[16384];
#pragma unroll
  for (int i = 0; i < 8; ++i) {
    int cid = t + i * 256;                // 0..2047
    int s = cid >> 4, ch = cid & 15;
    u16x8 v = *(const u16x8*)(Ua + s * 128 + ch * 8);
#pragma unroll
    for (int e = 0; e < 8; ++e) {
      int j = ch * 8 + e;
      int byt = ((j << 8) + (s << 1)) ^ ((j & 15) << 4);
      *(unsigned short*)((char*)UaT + byt) = v[e];
    }
  }
  __syncthreads();
  // T1 = Lneg_BA @ Ua
  f32x4 a1[2][8];
#pragma unroll
  for (int m = 0; m < 2; ++m)
#pragma unroll
    for (int c = 0; c < 8; ++c) a1[m][c] = (f32x4){0.f, 0.f, 0.f, 0.f};
#pragma unroll
  for (int kc = 0; kc < 4; ++kc) {
    s16x8 af[2];
#pragma unroll
    for (int m = 0; m < 2; ++m)
      af[m] = *(const s16x8*)(Lb + base + ((size_t)(s0 + 128 + 32 * w + 16 * m + fr) << 10) + s0 + kc * 32 + fq * 8);
#pragma unroll
    for (int c = 0; c < 8; ++c) {
      int j = 16 * c + fr;
      s16x8 bb = *(const s16x8*)((char*)UaT + (((j << 8) + (kc << 6) + (fq << 4)) ^ ((j & 15) << 4)));
#pragma unroll
      for (int m = 0; m < 2; ++m)
        a1[m][c] = __builtin_amdgcn_mfma_f32_16x16x32_bf16(af[m], bb, a1[m][c], 0, 0, 0);
    }
  }
#pragma unroll
  for (int m = 0; m < 2; ++m) {
#pragma unroll
    for (int c = 0; c < 8; ++c) {
      int col = 16 * c + fr;
      int row0 = 32 * w + 16 * m + fq * 4;
      u16x4 pk;
#pragma unroll
      for (int r = 0; r < 4; ++r) pk[r] = f2bf(a1[m][c][r]);
      int byt = ((col << 8) + (row0 << 1)) ^ ((col & 15) << 4);
      *(u16x4*)((char*)T1T + byt) = pk;
    }
  }
  __syncthreads();
  // B256 = Uc @ T1
  f32x4 a2[2][8];
#pragma unroll
  for (int m = 0; m < 2; ++m)
#pragma unroll
    for (int c = 0; c < 8; ++c) a2[m][c] = (f32x4){0.f, 0.f, 0.f, 0.f};
#pragma unroll
  for (int kc = 0; kc < 4; ++kc) {
    s16x8 af[2];
#pragma unroll
    for (int m = 0; m < 2; ++m)
      af[m] = *(const s16x8*)(Uc + (32 * w + 16 * m + fr) * 128 + kc * 32 + fq * 8);
#pragma unroll
    for (int c = 0; c < 8; ++c) {
      int j = 16 * c + fr;
      s16x8 bb = *(const s16x8*)((char*)T1T + (((j << 8) + (kc << 6) + (fq << 4)) ^ ((j & 15) << 4)));
#pragma unroll
      for (int m = 0; m < 2; ++m)
        a2[m][c] = __builtin_amdgcn_mfma_f32_16x16x32_bf16(af[m], bb, a2[m][c], 0, 0, 0);
    }
  }
#pragma unroll
  for (int m = 0; m < 2; ++m) {
#pragma unroll
    for (int c = 0; c < 8; ++c) {
      int col = 16 * c + fr;
#pragma unroll
      for (int r = 0; r < 4; ++r)
        out[(32 * w + 16 * m + fq * 4 + r) * 128 + col] = f2bf(a2[m][c][r]);
    }
  }
}

// ================= solve256: 256-row band step; band GEMM + 3-piece inverse apply =================
__global__ __launch_bounds__(256) void solve256(const unsigned short* __restrict__ WN,
    const unsigned short* __restrict__ Kk, const unsigned short* __restrict__ Lb,
    const unsigned short* __restrict__ U128, const unsigned short* __restrict__ B256,
    unsigned short* __restrict__ CT, int ib) {
  int jb = blockIdx.x, bh = blockIdx.y;     // jb: 128-wide col slab, 0..2ib+1
  int b = bh >> 4, h = bh & 15;
  int t = threadIdx.x, w = t >> 6, l = t & 63, fr = l & 15, fq = l >> 4;
  int s0 = ib * 256, j0 = jb * 128;
  size_t base = (size_t)bh << 20;
  __shared__ unsigned short sh[32768];      // 64KB
  unsigned short* As = sh;                  // 256x64 (32KB)
  unsigned short* Bs = sh + 16384;          // 128x64 (16KB)
  unsigned short* rT = sh;                  // [128 j][256 s] (64KB), aliases
  const unsigned short* Wb_ = WN + ((size_t)b << 20) + h * 64;
  const unsigned short* Kb_ = Kk + ((size_t)b << 20) + h * 64;

  // ---- band: rect(256 s x 128 j) = W K^T - sum L*C ----
  f32x4 acc[4][8];
#pragma unroll
  for (int m = 0; m < 4; ++m)
#pragma unroll
    for (int c = 0; c < 8; ++c) acc[m][c] = (f32x4){0.f, 0.f, 0.f, 0.f};
  int nst = 1 + 4 * ib - 2 * jb; if (nst < 1) nst = 1;
  for (int st = 0; st < nst; ++st) {
    __syncthreads();
    int rb = 2 * jb + st - 1;
#pragma unroll
    for (int i = 0; i < 8; ++i) {
      int cid = t + i * 256;
      int row = cid >> 3, ch = cid & 7;
      int chs = ch ^ (row & 7);
      const unsigned short* ga = (st == 0)
        ? Wb_ + ((size_t)(s0 + row) << 10) + chs * 8
        : Lb + base + ((size_t)(s0 + row) << 10) + rb * 64 + chs * 8;
      glds16(ga, (char*)As + cid * 16);
    }
#pragma unroll
    for (int i = 0; i < 4; ++i) {
      int cid = t + i * 256;
      int row = cid >> 3, ch = cid & 7;
      int chs = ch ^ (row & 7);
      const unsigned short* gb = (st == 0)
        ? Kb_ + ((size_t)(j0 + row) << 10) + chs * 8
        : CT + base + ((size_t)(j0 + row) << 10) + rb * 64 + chs * 8;
      glds16(gb, (char*)Bs + cid * 16);
    }
    __syncthreads();
#pragma unroll
    for (int kh = 0; kh < 2; ++kh) {
      s16x8 af[4], bfv[8];
#pragma unroll
      for (int m = 0; m < 4; ++m) {
        int ra = 64 * w + 16 * m + fr;
        af[m] = *(const s16x8*)((char*)As + (((ra << 7) + (kh << 6) + (fq << 4)) ^ ((ra & 7) << 4)));
      }
#pragma unroll
      for (int c = 0; c < 8; ++c) {
        int rb2 = 16 * c + fr;
        bfv[c] = *(const s16x8*)((char*)Bs + (((rb2 << 7) + (kh << 6) + (fq << 4)) ^ ((rb2 & 7) << 4)));
      }
#pragma unroll
      for (int m = 0; m < 4; ++m)
#pragma unroll
        for (int c = 0; c < 8; ++c)
          acc[m][c] = __builtin_amdgcn_mfma_f32_16x16x32_bf16(af[m], bfv[c], acc[m][c], 0, 0, 0);
    }
  }
  __syncthreads();
  // ---- write rectT [j][s] (512B rows, XOR (j&15)<<4), mask j >= s ----
#pragma unroll
  for (int m = 0; m < 4; ++m) {
#pragma unroll
    for (int c = 0; c < 8; ++c) {
      int sl0 = 64 * w + 16 * m + fq * 4;
      int jl = 16 * c + fr;
      u16x4 pk;
#pragma unroll
      for (int r = 0; r < 4; ++r) {
        float v = acc[m][c][r];
        if (j0 + jl >= s0 + sl0 + r) v = 0.f;
        pk[r] = f2bf(v);
      }
      int byt = ((jl << 9) + (sl0 << 1)) ^ ((jl & 15) << 4);
      *(u16x4*)((char*)rT + byt) = pk;
    }
  }
  __syncthreads();
  // ---- apply: C = U256 @ rect via pieces [Ua,0; B256,Uc] ----
  const unsigned short* Ua = U128 + (((size_t)(bh * 8 + 2 * ib)) << 14);
  const unsigned short* Uc = U128 + (((size_t)(bh * 8 + 2 * ib + 1)) << 14);
  const unsigned short* Bm = B256 + (((size_t)(bh * 4 + ib)) << 14);
#pragma unroll
  for (int m = 0; m < 4; ++m)
#pragma unroll
    for (int c = 0; c < 8; ++c) acc[m][c] = (f32x4){0.f, 0.f, 0.f, 0.f};
  int nkc = (w < 2) ? 4 : 8;
  for (int kc = 0; kc < nkc; ++kc) {
    const unsigned short* src; int arow;
    if (w < 2) { src = Ua; arow = 64 * w; }
    else { src = (kc < 4) ? Bm : Uc; arow = 64 * (w - 2); }
    s16x8 uf[4];
#pragma unroll
    for (int m = 0; m < 4; ++m)
      uf[m] = *(const s16x8*)(src + (arow + 16 * m + fr) * 128 + (kc & 3) * 32 + fq * 8);
#pragma unroll
    for (int c = 0; c < 8; ++c) {
      int jl = 16 * c + fr;
      s16x8 bb = *(const s16x8*)((char*)rT + (((jl << 9) + (kc << 6) + (fq << 4)) ^ ((jl & 15) << 4)));
#pragma unroll
      for (int m = 0; m < 4; ++m)
        acc[m][c] = __builtin_amdgcn_mfma_f32_16x16x32_bf16(uf[m], bb, acc[m][c], 0, 0, 0);
    }
  }
#pragma unroll
  for (int m = 0; m < 4; ++m) {
#pragma unroll
    for (int c = 0; c < 8; ++c) {
      int jl = 16 * c + fr;
      int sb = 64 * w + 16 * m + fq * 4;
      u16x4 pk;
#pragma unroll
      for (int r = 0; r < 4; ++r) pk[r] = f2bf(acc[m][c][r]);
      *(u16x4*)(CT + base + ((size_t)(j0 + jl) << 10) + s0 + sb) = pk;
    }
  }
}

// ================= rowstat: m,l per row =================
__global__ __launch_bounds__(256) void rowstat(const unsigned short* __restrict__ S,
    const float* __restrict__ Fc, float* __restrict__ MR, float* __restrict__ LR) {
  int bh = blockIdx.y;
  int t = blockIdx.x * 4 + (threadIdx.x >> 6);
  int l = threadIdx.x & 63;
  size_t base = (size_t)bh << 20;
  const unsigned short* srow = S + base + ((size_t)t << 10);
  float vals[16]; float vmax = -1e30f;
#pragma unroll
  for (int i = 0; i < 2; ++i) {
    int c0 = i * 512 + l * 8;
    u16x8 sv = *(const u16x8*)(srow + c0);
    float4 f0 = *(const float4*)(Fc + bh * 1024 + c0);
    float4 f1 = *(const float4*)(Fc + bh * 1024 + c0 + 4);
#pragma unroll
    for (int e = 0; e < 8; ++e) {
      float fc = e < 4 ? ((const float*)&f0)[e] : ((const float*)&f1)[e - 4];
      float v = (c0 + e <= t) ? bf2f(sv[e]) * SM_SCALE - fc : -1e30f;
      vals[i * 8 + e] = v; vmax = fmaxf(vmax, v);
    }
  }
#pragma unroll
  for (int o = 1; o < 64; o <<= 1) vmax = fmaxf(vmax, __shfl_xor(vmax, o));
  float sum = 0.f;
#pragma unroll
  for (int e = 0; e < 16; ++e) sum += __expf(vals[e] - vmax);
#pragma unroll
  for (int o = 1; o < 64; o <<= 1) sum += __shfl_xor(sum, o);
  if (l == 0) { MR[bh * 1024 + t] = vmax; LR[bh * 1024 + t] = sum; }
}

// ================= pv: O = P @ V with on-the-fly P; sorted 1D grid (512) =================
__global__ __launch_bounds__(256) void pv_kernel(const unsigned short* __restrict__ S,
    const unsigned short* __restrict__ VT, const float* __restrict__ Fc,
    const float* __restrict__ MR, const float* __restrict__ LR,
    unsigned short* __restrict__ Ob) {
  int idx = blockIdx.x;
  int bh = idx & 31, rank = idx >> 5;
  int tb = 15 - rank;
  int b = bh >> 4, h = bh & 15;
  int t0 = tb * 64;
  int t = threadIdx.x, w = t >> 6, l = t & 63, fr = l & 15, fq = l >> 4;
  __shared__ unsigned short Pl[64 * 64];
  size_t base = (size_t)bh << 20;
  f32x4 acc[4];
#pragma unroll
  for (int c = 0; c < 4; ++c) acc[c] = (f32x4){0.f,0.f,0.f,0.f};
  for (int jb = 0; jb <= tb; ++jb) {
    int j0 = jb * 64;
    __syncthreads();
#pragma unroll
    for (int i = 0; i < 2; ++i) {
      int cid = t + i * 256;
      int row = cid >> 3, ch = cid & 7;
      int grow = t0 + row;
      u16x8 sv = *(const u16x8*)(S + base + ((size_t)grow << 10) + j0 + ch * 8);
      float4 f0 = *(const float4*)(Fc + bh * 1024 + j0 + ch * 8);
      float4 f1 = *(const float4*)(Fc + bh * 1024 + j0 + ch * 8 + 4);
      float m = MR[bh * 1024 + grow];
      u16x8 pv;
#pragma unroll
      for (int e = 0; e < 8; ++e) {
        float fc = e < 4 ? ((const float*)&f0)[e] : ((const float*)&f1)[e - 4];
        float p = __expf(bf2f(sv[e]) * SM_SCALE - fc - m);
        if (jb == tb && ch * 8 + e > row) p = 0.f;
        pv[e] = f2bf(p);
      }
      int byt = ((row << 7) + (ch << 4)) ^ ((row & 7) << 4);
      *(u16x8*)((char*)Pl + byt) = pv;
    }
    __syncthreads();
#pragma unroll
    for (int kh = 0; kh < 2; ++kh) {
      int ra = 16 * w + fr;
      s16x8 a = *(const s16x8*)((char*)Pl + (((ra << 7) + (kh << 6) + (fq << 4)) ^ ((ra & 7) << 4)));
#pragma unroll
      for (int c = 0; c < 4; ++c) {
        s16x8 bb = *(const s16x8*)(VT + ((size_t)bh * 64 + 16 * c + fr) * 1024 + j0 + kh * 32 + fq * 8);
        acc[c] = __builtin_amdgcn_mfma_f32_16x16x32_bf16(a, bb, acc[c], 0, 0, 0);
      }
    }
  }
  float inv[4];
#pragma unroll
  for (int r = 0; r < 4; ++r) inv[r] = 1.f / LR[bh * 1024 + t0 + 16 * w + fq * 4 + r];
#pragma unroll
  for (int c = 0; c < 4; ++c) {
#pragma unroll
    for (int r = 0; r < 4; ++r) {
      int grow = t0 + 16 * w + fq * 4 + r;
      Ob[((size_t)(b * 1024) + grow) * 1024 + h * 64 + 16 * c + fr] = f2bf(acc[c][r] * inv[r]);
    }
  }
}

extern "C" void kernel_launch(void* const* d_in, const int* in_sizes, int n_in,
                              void* d_out, int out_size, void* d_ws, size_t ws_size,
                              hipStream_t stream) {
  const float* x    = (const float*)d_in[0];
  const float* Wq   = (const float*)d_in[1];
  const float* Wk   = (const float*)d_in[2];
  const float* Wv   = (const float*)d_in[3];
  const float* Wo   = (const float*)d_in[4];
  const float* Ww1  = (const float*)d_in[5];
  const float* Ww2  = (const float*)d_in[6];
  const float* Wb   = (const float*)d_in[7];
  const float* Wf   = (const float*)d_in[8];
  const float* delta= (const float*)d_in[9];

  char* ws = (char*)d_ws;
  unsigned short* xb   = (unsigned short*)(ws + OFF_XB);
  unsigned short* WqT  = (unsigned short*)(ws + OFF_WQT);
  float*          BL   = (float*)(ws + OFF_BL);
  unsigned short* WkT  = (unsigned short*)(ws + OFF_WKT);
  unsigned short* WvT  = (unsigned short*)(ws + OFF_WVT);
  unsigned short* WoT  = (unsigned short*)(ws + OFF_WOT);
  unsigned short* W1c  = (unsigned short*)(ws + OFF_W1C);
  unsigned short* W2T  = (unsigned short*)(ws + OFF_W2T);
  float*          Beta = (float*)(ws + OFF_BETA);
  unsigned short* Q16  = (unsigned short*)(ws + OFF_Q16);
  unsigned short* K16  = (unsigned short*)(ws + OFF_K16);
  unsigned short* VT   = (unsigned short*)(ws + OFF_VT);
  unsigned short* WN16 = (unsigned short*)(ws + OFF_WN16);   // WfusedT, then WN
  unsigned short* WB16 = (unsigned short*)(ws + OFF_WB16);
  unsigned short* WNF16= (unsigned short*)(ws + OFF_WNF);
  unsigned short* ObB  = (unsigned short*)(ws + OFF_OB);
  unsigned short* BFT  = (unsigned short*)(ws + OFF_BFT);
  float*          Fc   = (float*)(ws + OFF_FC);
  unsigned short* Lbuf = (unsigned short*)(ws + OFF_L);
  unsigned short* Sbuf = (unsigned short*)(ws + OFF_L);
  unsigned short* CT   = (unsigned short*)(ws + OFF_CT);
  unsigned short* Gbuf = (unsigned short*)(ws + OFF_G);
  float*          MR   = (float*)(ws + OFF_MR);
  float*          LR   = (float*)(ws + OFF_LR);
  unsigned short* UI   = (unsigned short*)(ws + OFF_UI);
  unsigned short* U128 = (unsigned short*)(ws + OFF_U128);
  unsigned short* B256 = (unsigned short*)(ws + OFF_B256);

  dim3 blk(256);
  // prep (all transposes + casts + BFT)
  prep_all<<<2128, blk, 0, stream>>>(Wq, Wk, Wv, Wo, Ww1, Ww2, x, Wb, Wf,
                                     WqT, WkT, WvT, WoT, W1c, W2T, xb, BFT);
  // WfusedT = W2T @ W1c^T  (rank-64 fold; lives in WN16 region until wnorm2)
  gemm_nt<0><<<dim3(16,16), blk, 0, stream>>>(W2T, W1c, WN16, 1024, 1024, 64);
  // Q, K, VT, WNF in one 512-block launch
  proj_big<<<512, blk, 0, stream>>>(xb, WqT, WkT, WvT, WN16, Q16, K16, VT, WNF16);
  // BL = xb @ BFT^T (f32; overlays WqT -> after proj_big)
  gemm_nt<1><<<dim3(1,32), blk, 0, stream>>>(xb, BFT, BL, 2048, 64, 1024);
  // beta/logsigmoid/cumsum fused (Beta overlays W1c -> after wfuse)
  bgfc<<<32, blk, 0, stream>>>(BL, delta, Beta, Fc);
  wnorm2<<<2048, blk, 0, stream>>>(WNF16, Beta, WN16, WB16);
  // L and G (both stored NEGATED)
  pairLG<<<dim3(36 * 32), blk, 0, stream>>>(WN16, Q16, WB16, Lbuf, Gbuf);
  // triangular solve: 64-inv -> 128-inv -> 256 off-diag piece -> 4 band steps
  inv64<<<dim3(16,32), blk, 0, stream>>>(Lbuf, UI);
  u128build<<<dim3(8,32), blk, 0, stream>>>(Lbuf, UI, U128);
  u256build<<<dim3(4,32), blk, 0, stream>>>(Lbuf, U128, B256);
  for (int ib = 0; ib < 4; ++ib)
    solve256<<<dim3(2 * ib + 2, 32), blk, 0, stream>>>(WN16, K16, Lbuf, U128, B256, CT, ib);
  // S = QK^T + Gneg C (sorted band grid; reuses L region)
  score128s<<<dim3(36 * 32), blk, 0, stream>>>(Q16, K16, Gbuf, CT, Sbuf);
  // softmax stats + PV
  rowstat<<<dim3(256,32), blk, 0, stream>>>(Sbuf, Fc, MR, LR);
  pv_kernel<<<dim3(512), blk, 0, stream>>>(Sbuf, VT, Fc, MR, LR, ObB);
  // output projection (f32 out)
  gemm_nt<1><<<dim3(16,32), blk, 0, stream>>>(ObB, WoT, d_out, 2048, 1024, 1024);
}

// Round 9
// 306.567 us; speedup vs baseline: 13.3017x; 1.0311x over previous
//
#include <hip/hip_runtime.h>
#include <hip/hip_bf16.h>

#define DEV static __device__ __forceinline__

constexpr float SM_SCALE = 0.125f;   // hd^-0.5, hd=64

typedef __attribute__((ext_vector_type(8))) short s16x8;
typedef __attribute__((ext_vector_type(8))) unsigned short u16x8;
typedef __attribute__((ext_vector_type(4))) unsigned short u16x4;
typedef __attribute__((ext_vector_type(4))) float f32x4;

DEV float bf2f(unsigned short u) {
  union { unsigned int i; float f; } v; v.i = ((unsigned int)u) << 16; return v.f;
}
DEV unsigned short f2bf(float f) {
  union { float f; unsigned int i; } v; v.f = f;
  unsigned int r = v.i + 0x7fffu + ((v.i >> 16) & 1u);
  return (unsigned short)(r >> 16);
}
DEV void tri_unrank(int r, int& k, int& i) {
  k = (int)((sqrtf(8.f * r + 1.f) - 1.f) * 0.5f);
  while (k * (k + 1) / 2 > r) --k;
  while ((k + 1) * (k + 2) / 2 <= r) ++k;
  i = r - k * (k + 1) / 2;
}
// async global->LDS, 16B per lane; dest must be wave-linear (base + lane*16)
DEV void glds16(const void* g, void* l) {
  __builtin_amdgcn_global_load_lds(
      (const __attribute__((address_space(1))) void*)g,
      (__attribute__((address_space(3))) void*)l, 16, 0, 0);
}

// ---------- workspace layout (bytes) ----------
constexpr size_t OFF_XB   = 0;                       // 4MB xb bf16 [2048][1024]
constexpr size_t OFF_WQT  = 4194304;                 // 2MB
constexpr size_t OFF_WKT  = 6291456;                 // 2MB
constexpr size_t OFF_WVT  = 8388608;
constexpr size_t OFF_WOT  = 10485760;
constexpr size_t OFF_W1C  = 12582912;                // 128KB bf16 Ww1 cast (1024x64)
constexpr size_t OFF_W2T  = 12713984;                // 128KB
constexpr size_t OFF_BETA = 12582912;                // reuse W1C after wfuse
constexpr size_t OFF_Q16  = 12845056;                // 4MB bf16 2048x1024
constexpr size_t OFF_K16  = 17039360;                // 4MB
constexpr size_t OFF_VT   = 21233664;                // 4MB  VT[b][64h*d][1024n]
constexpr size_t OFF_WN16 = 25427968;                // 4MB; holds WfusedT until wnorm2
constexpr size_t OFF_WB16 = 29622272;                // 4MB
constexpr size_t OFF_WNF  = 33816576;                // 4MB (reused as Ob)
constexpr size_t OFF_OB   = 33816576;
constexpr size_t OFF_BFT  = 38010880;                // 256KB bf16 (128x1024)
constexpr size_t OFF_FC   = 38273024;                // 128KB
constexpr size_t OFF_L    = 38404096;                // 64MB, stores -L (reused as S)
constexpr size_t OFF_CT   = 105512960;               // 64MB
constexpr size_t OFF_G    = 172621824;               // 64MB, stores -G
constexpr size_t OFF_BL   = 239730688;               // 512KB f32 2048x64 (ex MR/LR/UI)
constexpr size_t OFF_U128 = 244187136;               // 8MB bf16 [32][8][128][128]
constexpr size_t OFF_B256 = 252575744;               // 4MB bf16 [32][4][128][128]

// ================= fused prep: transposes + casts + BFT(128 rows); grid 2160 =================
__global__ __launch_bounds__(256) void prep_all(
    const float* __restrict__ W0, const float* __restrict__ W1,
    const float* __restrict__ W2, const float* __restrict__ W3,
    const float* __restrict__ Ww1, const float* __restrict__ Ww2,
    const float* __restrict__ x, const float* __restrict__ Wb,
    const float* __restrict__ Wf,
    unsigned short* __restrict__ D0, unsigned short* __restrict__ D1,
    unsigned short* __restrict__ D2, unsigned short* __restrict__ D3,
    unsigned short* __restrict__ W1c, unsigned short* __restrict__ W2T,
    unsigned short* __restrict__ xb, unsigned short* __restrict__ BFT) {
  int bidx = blockIdx.x;
  int t = threadIdx.x;
  if (bidx >= 2096) {                      // BFT build (64 blocks, 128x1024)
    int e0 = ((bidx - 2096) * 256 + t) * 8;
    int j = e0 >> 10, i0 = e0 & 1023;
    u16x8 o;
#pragma unroll
    for (int e = 0; e < 8; ++e) {
      int i = i0 + e;
      float v = 0.f;
      if (j < 16) v = Wb[i * 16 + j];
      else if (j < 32) v = Wf[i * 16 + (j - 16)];
      o[e] = f2bf(v);
    }
    *(u16x8*)(BFT + e0) = o;
    return;
  }
  if (bidx >= 2064) {                      // W1 cast (32 blocks)
    int i = ((bidx - 2064) * 256 + t) * 8;
    float4 a = *(const float4*)(Ww1 + i);
    float4 b = *(const float4*)(Ww1 + i + 4);
    u16x8 o;
    o[0] = f2bf(a.x); o[1] = f2bf(a.y); o[2] = f2bf(a.z); o[3] = f2bf(a.w);
    o[4] = f2bf(b.x); o[5] = f2bf(b.y); o[6] = f2bf(b.z); o[7] = f2bf(b.w);
    *(u16x8*)(W1c + i) = o;
    return;
  }
  if (bidx >= 1040) {                      // x cast (1024 blocks)
    int i = ((bidx - 1040) * 256 + t) * 8;
    float4 a = *(const float4*)(x + i);
    float4 b = *(const float4*)(x + i + 4);
    u16x8 o;
    o[0] = f2bf(a.x); o[1] = f2bf(a.y); o[2] = f2bf(a.z); o[3] = f2bf(a.w);
    o[4] = f2bf(b.x); o[5] = f2bf(b.y); o[6] = f2bf(b.z); o[7] = f2bf(b.w);
    *(u16x8*)(xb + i) = o;
    return;
  }
  const float* src; unsigned short* dst; int R, C, c0, r0;
  if (bidx >= 1024) {                      // W2T transpose (16 blocks)
    src = Ww2; dst = W2T; R = 64; C = 1024;
    c0 = (bidx - 1024) * 64; r0 = 0;
  } else {
    int z = bidx >> 8, xy = bidx & 255;
    src = z == 0 ? W0 : z == 1 ? W1 : z == 2 ? W2 : W3;
    dst = z == 0 ? D0 : z == 1 ? D1 : z == 2 ? D2 : D3;
    R = 1024; C = 1024;
    c0 = (xy & 15) * 64; r0 = (xy >> 4) * 64;
  }
  __shared__ float tile[64 * 65];
#pragma unroll
  for (int i = 0; i < 16; ++i) {
    int lin = t + i * 256; int r = lin >> 6, c = lin & 63;
    tile[r * 65 + c] = src[(size_t)(r0 + r) * C + c0 + c];
  }
  __syncthreads();
#pragma unroll
  for (int i = 0; i < 16; ++i) {
    int lin = t + i * 256; int c = lin >> 6, r = lin & 63;
    dst[(size_t)(c0 + c) * R + r0 + r] = f2bf(tile[r * 65 + c]);
  }
}

// beta + log_sigmoid + cumsum fused; grid 32 (bh)
__global__ __launch_bounds__(256) void bgfc(const float* __restrict__ BL,
    const float* __restrict__ delta, float* __restrict__ Beta, float* __restrict__ Fc) {
  int bh = blockIdx.x;
  int b = bh >> 4, h = bh & 15;
  int t = threadIdx.x;
  __shared__ float buf[1024];
  __shared__ float tsum[256];
  float dh = delta[h];
#pragma unroll
  for (int i = 0; i < 4; ++i) {
    int n = t + i * 256;
    int row = (b << 10) + n;
    float braw = BL[row * 64 + h];
    Beta[row * 16 + h] = 2.f / (1.f + __expf(-braw));
    float lraw = BL[row * 64 + 16 + h] + dh;
    buf[n] = (lraw >= 0.f) ? -log1pf(__expf(-lraw)) : (lraw - log1pf(__expf(lraw)));
  }
  __syncthreads();
  float loc[4]; float run = 0.f;
#pragma unroll
  for (int i = 0; i < 4; ++i) { run += buf[t * 4 + i]; loc[i] = run; }
  tsum[t] = run;
  __syncthreads();
  for (int off = 1; off < 256; off <<= 1) {
    float add = (t >= off) ? tsum[t - off] : 0.f;
    __syncthreads();
    tsum[t] += add;
    __syncthreads();
  }
  float excl = tsum[t] - run;
#pragma unroll
  for (int i = 0; i < 4; ++i) Fc[bh * 1024 + t * 4 + i] = excl + loc[i];
}

// ================= mega projection: Q,K + VT + WNF + BL, 528 blocks =================
__global__ __launch_bounds__(256) void proj_big(const unsigned short* __restrict__ xb,
    const unsigned short* __restrict__ WqT, const unsigned short* __restrict__ WkT,
    const unsigned short* __restrict__ WvT, const unsigned short* __restrict__ WfT,
    const unsigned short* __restrict__ BFT,
    unsigned short* __restrict__ Q16, unsigned short* __restrict__ K16,
    unsigned short* __restrict__ VT, unsigned short* __restrict__ WNF,
    float* __restrict__ BL) {
  int idx = blockIdx.x;
  const unsigned short *A, *BT; unsigned short* out = nullptr; int m0, n0;
  int mode = 0;                  // 0: bf16 full; 1: BL f32 (cols<64)
  if (idx < 256) {
    int my = idx >> 4, nx = idx & 15;
    m0 = my * 128; A = xb;
    if (nx < 8) { BT = WqT; out = Q16; n0 = nx * 128; }
    else { BT = WkT; out = K16; n0 = (nx - 8) * 128; }
  } else if (idx < 384) {
    int r = idx - 256; int bz = r >> 6; int rem = r & 63;
    m0 = (rem >> 3) * 128; n0 = (rem & 7) * 128;
    A = WvT; BT = xb + ((size_t)bz << 20); out = VT + ((size_t)bz << 20);
  } else if (idx < 512) {
    int r2 = idx - 384;
    m0 = (r2 >> 3) * 128; n0 = (r2 & 7) * 128;
    A = xb; BT = WfT; out = WNF;
  } else {
    m0 = (idx - 512) * 128; n0 = 0;
    A = xb; BT = BFT; mode = 1;
  }
  int t = threadIdx.x;
  int w = t >> 6, l = t & 63;
  int wr = w >> 1, wc = w & 1;
  int fr = l & 15, fq = l >> 4;
  __shared__ unsigned short As[128 * 64];
  __shared__ unsigned short Bs[128 * 64];
  f32x4 acc[4][4];
#pragma unroll
  for (int m = 0; m < 4; ++m)
#pragma unroll
    for (int c = 0; c < 4; ++c) acc[m][c] = (f32x4){0.f, 0.f, 0.f, 0.f};
  for (int k0 = 0; k0 < 1024; k0 += 64) {
    __syncthreads();
#pragma unroll
    for (int i = 0; i < 4; ++i) {
      int cid = t + i * 256;
      int row = cid >> 3, ch = cid & 7;
      int chs = ch ^ (row & 7);
      glds16(A + (size_t)(m0 + row) * 1024 + k0 + chs * 8, (char*)As + cid * 16);
      glds16(BT + (size_t)(n0 + row) * 1024 + k0 + chs * 8, (char*)Bs + cid * 16);
    }
    __syncthreads();
#pragma unroll
    for (int kh = 0; kh < 2; ++kh) {
      s16x8 af[4], bfv[4];
#pragma unroll
      for (int m = 0; m < 4; ++m) {
        int ra = wr * 64 + 16 * m + fr;
        af[m] = *(const s16x8*)((char*)As + (((ra << 7) + (kh << 6) + (fq << 4)) ^ ((ra & 7) << 4)));
      }
#pragma unroll
      for (int c = 0; c < 4; ++c) {
        int rb = wc * 64 + 16 * c + fr;
        bfv[c] = *(const s16x8*)((char*)Bs + (((rb << 7) + (kh << 6) + (fq << 4)) ^ ((rb & 7) << 4)));
      }
#pragma unroll
      for (int m = 0; m < 4; ++m)
#pragma unroll
        for (int c = 0; c < 4; ++c)
          acc[m][c] = __builtin_amdgcn_mfma_f32_16x16x32_bf16(af[m], bfv[c], acc[m][c], 0, 0, 0);
    }
  }
#pragma unroll
  for (int m = 0; m < 4; ++m) {
#pragma unroll
    for (int c = 0; c < 4; ++c) {
      int col = n0 + wc * 64 + 16 * c + fr;
#pragma unroll
      for (int r = 0; r < 4; ++r) {
        int grow = m0 + wr * 64 + 16 * m + fq * 4 + r;
        if (mode == 0) out[(size_t)grow * 1024 + col] = f2bf(acc[m][c][r]);
        else if (col < 64) BL[(size_t)grow * 64 + col] = acc[m][c][r];
      }
    }
  }
}

// ================= 64-tile bf16 NT GEMM =================
template<int F32OUT>
__global__ __launch_bounds__(256) void gemm_nt(const unsigned short* __restrict__ A,
    const unsigned short* __restrict__ BT, void* __restrict__ out,
    int M, int N, int K) {
  __shared__ unsigned short As[64 * 64];
  __shared__ unsigned short Bs[64 * 64];
  int m0 = blockIdx.y * 64, n0 = blockIdx.x * 64;
  int t = threadIdx.x;
  int w = t >> 6, l = t & 63, fr = l & 15;
  int koB = (l >> 4) * 16;
  f32x4 acc[4];
#pragma unroll
  for (int c = 0; c < 4; ++c) acc[c] = (f32x4){0.f, 0.f, 0.f, 0.f};
  for (int k0 = 0; k0 < K; k0 += 64) {
    __syncthreads();
#pragma unroll
    for (int i = 0; i < 2; ++i) {
      int cid = t + i * 256;
      int row = cid >> 3, ch = cid & 7;
      int chs = ch ^ (row & 7);
      glds16(A + (size_t)(m0 + row) * K + k0 + chs * 8, (char*)As + cid * 16);
      glds16(BT + (size_t)(n0 + row) * K + k0 + chs * 8, (char*)Bs + cid * 16);
    }
    __syncthreads();
#pragma unroll
    for (int kh = 0; kh < 2; ++kh) {
      int ra = 16 * w + fr;
      s16x8 a = *(const s16x8*)((char*)As + (((ra << 7) + (kh << 6) + koB) ^ ((ra & 7) << 4)));
#pragma unroll
      for (int c = 0; c < 4; ++c) {
        int rb = 16 * c + fr;
        s16x8 bb = *(const s16x8*)((char*)Bs + (((rb << 7) + (kh << 6) + koB) ^ ((rb & 7) << 4)));
        acc[c] = __builtin_amdgcn_mfma_f32_16x16x32_bf16(a, bb, acc[c], 0, 0, 0);
      }
    }
  }
  int rbase = m0 + 16 * w + ((l >> 4) << 2);
#pragma unroll
  for (int c = 0; c < 4; ++c) {
    int col = n0 + 16 * c + fr;
#pragma unroll
    for (int r = 0; r < 4; ++r) {
      if (F32OUT) ((float*)out)[(size_t)(rbase + r) * N + col] = acc[c][r];
      else ((unsigned short*)out)[(size_t)(rbase + r) * N + col] = f2bf(acc[c][r]);
    }
  }
}

// ================= w normalize + beta-scale =================
__global__ __launch_bounds__(256) void wnorm2(const unsigned short* __restrict__ WNF,
    const float* __restrict__ Beta, unsigned short* __restrict__ WN,
    unsigned short* __restrict__ WB) {
  int row = blockIdx.x;
  int wave = threadIdx.x >> 6, lane = threadIdx.x & 63;
#pragma unroll
  for (int i = 0; i < 4; ++i) {
    int hh = wave * 4 + i;
    size_t idx = ((size_t)row << 10) + hh * 64 + lane;
    float v = bf2f(WNF[idx]);
    float ss = v * v;
#pragma unroll
    for (int off = 1; off < 64; off <<= 1) ss += __shfl_xor(ss, off);
    float wn = v * rsqrtf(ss + 1e-6f);
    WN[idx] = f2bf(wn);
    WB[idx] = f2bf(wn * Beta[row * 16 + hh]);
  }
}

// ================= pair fused: writes NEGATED L and G =================
__global__ __launch_bounds__(256) void pairLG(const unsigned short* __restrict__ WN,
    const unsigned short* __restrict__ Q, const unsigned short* __restrict__ WB,
    unsigned short* __restrict__ Lg, unsigned short* __restrict__ Gg) {
  int idx = blockIdx.x;
  int bh = idx & 31, r0r = idx >> 5;
  int tb2, jb2; tri_unrank(r0r, tb2, jb2);
  int b = bh >> 4, h = bh & 15;
  int m0 = tb2 * 128, n0 = jb2 * 128;
  int t = threadIdx.x;
  int w = t >> 6, l = t & 63;
  int wr = w >> 1, wc = w & 1;
  int fr = l & 15, fq = l >> 4;
  __shared__ unsigned short As[128 * 64];
  __shared__ unsigned short Bs[128 * 64];
  const unsigned short* WNb = WN + ((size_t)b << 20) + h * 64;
  const unsigned short* Qb  = Q + ((size_t)b << 20) + h * 64;
  const unsigned short* WBb = WB + ((size_t)b << 20) + h * 64;
  size_t base = (size_t)bh << 20;
#pragma unroll
  for (int i = 0; i < 4; ++i) {
    int cid = t + i * 256;
    int row = cid >> 3, ch = cid & 7;
    int chs = ch ^ (row & 7);
    glds16(WNb + ((size_t)(m0 + row) << 10) + chs * 8, (char*)As + cid * 16);
    glds16(WBb + ((size_t)(n0 + row) << 10) + chs * 8, (char*)Bs + cid * 16);
  }
  __syncthreads();
  for (int pass = 0; pass < 2; ++pass) {
    f32x4 acc[4][4];
#pragma unroll
    for (int m = 0; m < 4; ++m)
#pragma unroll
      for (int c = 0; c < 4; ++c) acc[m][c] = (f32x4){0.f, 0.f, 0.f, 0.f};
#pragma unroll
    for (int kh = 0; kh < 2; ++kh) {
      s16x8 af[4], bfv[4];
#pragma unroll
      for (int m = 0; m < 4; ++m) {
        int ra = wr * 64 + 16 * m + fr;
        af[m] = *(const s16x8*)((char*)As + (((ra << 7) + (kh << 6) + (fq << 4)) ^ ((ra & 7) << 4)));
      }
#pragma unroll
      for (int c = 0; c < 4; ++c) {
        int rb = wc * 64 + 16 * c + fr;
        bfv[c] = *(const s16x8*)((char*)Bs + (((rb << 7) + (kh << 6) + (fq << 4)) ^ ((rb & 7) << 4)));
      }
#pragma unroll
      for (int m = 0; m < 4; ++m)
#pragma unroll
        for (int c = 0; c < 4; ++c)
          acc[m][c] = __builtin_amdgcn_mfma_f32_16x16x32_bf16(af[m], bfv[c], acc[m][c], 0, 0, 0);
    }
    unsigned short* dst = pass ? Gg : Lg;
#pragma unroll
    for (int m = 0; m < 4; ++m) {
#pragma unroll
      for (int c = 0; c < 4; ++c) {
        int gj = n0 + wc * 64 + 16 * c + fr;
#pragma unroll
        for (int r = 0; r < 4; ++r) {
          int gi = m0 + wr * 64 + 16 * m + fq * 4 + r;
          bool keep = pass ? (gj <= gi) : (gj < gi);
          dst[base + ((size_t)gi << 10) + gj] = f2bf(keep ? -acc[m][c][r] : 0.f);
        }
      }
    }
    if (pass == 0) {
      __syncthreads();
#pragma unroll
      for (int i = 0; i < 4; ++i) {
        int cid = t + i * 256;
        int row = cid >> 3, ch = cid & 7;
        int chs = ch ^ (row & 7);
        glds16(Qb + ((size_t)(m0 + row) << 10) + chs * 8, (char*)As + cid * 16);
      }
      __syncthreads();
    }
  }
}

// ================= score: S = Q K^T + Gneg @ C, sorted 1D grid =================
__global__ __launch_bounds__(256) void score128s(const unsigned short* __restrict__ Q,
    const unsigned short* __restrict__ Kk, const unsigned short* __restrict__ G,
    const unsigned short* __restrict__ CT, unsigned short* __restrict__ Sg) {
  int idx = blockIdx.x;
  int bh = idx & 31, r0r = idx >> 5;
  int k, i; tri_unrank(r0r, k, i);
  int tb2 = (7 - k) + i, jb2 = i;
  int b = bh >> 4, h = bh & 15;
  int m0 = tb2 * 128, n0 = jb2 * 128;
  int t = threadIdx.x;
  int w = t >> 6, l = t & 63;
  int wr = w >> 1, wc = w & 1;
  int fr = l & 15, fq = l >> 4;
  __shared__ unsigned short As[128 * 64];
  __shared__ unsigned short Bs[128 * 64];
  size_t base = (size_t)bh << 20;
  const unsigned short* Qb_ = Q + ((size_t)b << 20) + h * 64;
  const unsigned short* Kb_ = Kk + ((size_t)b << 20) + h * 64;
  const unsigned short* Gb_ = G + base;
  const unsigned short* Cb_ = CT + base;
  int kbase = jb2 * 128;
  int nsteps = 1 + (tb2 - jb2 + 1) * 2;
  f32x4 acc[4][4];
#pragma unroll
  for (int m = 0; m < 4; ++m)
#pragma unroll
    for (int c = 0; c < 4; ++c) acc[m][c] = (f32x4){0.f, 0.f, 0.f, 0.f};
  for (int step = 0; step < nsteps; ++step) {
    const unsigned short* pa; const unsigned short* pb; int koff;
    if (step == 0) { pa = Qb_; pb = Kb_; koff = 0; }
    else { pa = Gb_; pb = Cb_; koff = kbase + (step - 1) * 64; }
    __syncthreads();
#pragma unroll
    for (int i2 = 0; i2 < 4; ++i2) {
      int cid = t + i2 * 256;
      int row = cid >> 3, ch = cid & 7;
      int chs = ch ^ (row & 7);
      glds16(pa + ((size_t)(m0 + row) << 10) + koff + chs * 8, (char*)As + cid * 16);
      glds16(pb + ((size_t)(n0 + row) << 10) + koff + chs * 8, (char*)Bs + cid * 16);
    }
    __syncthreads();
#pragma unroll
    for (int kh = 0; kh < 2; ++kh) {
      s16x8 af[4], bfv[4];
#pragma unroll
      for (int m = 0; m < 4; ++m) {
        int ra = wr * 64 + 16 * m + fr;
        af[m] = *(const s16x8*)((char*)As + (((ra << 7) + (kh << 6) + (fq << 4)) ^ ((ra & 7) << 4)));
      }
#pragma unroll
      for (int c = 0; c < 4; ++c) {
        int rb = wc * 64 + 16 * c + fr;
        bfv[c] = *(const s16x8*)((char*)Bs + (((rb << 7) + (kh << 6) + (fq << 4)) ^ ((rb & 7) << 4)));
      }
#pragma unroll
      for (int m = 0; m < 4; ++m)
#pragma unroll
        for (int c = 0; c < 4; ++c)
          acc[m][c] = __builtin_amdgcn_mfma_f32_16x16x32_bf16(af[m], bfv[c], acc[m][c], 0, 0, 0);
    }
  }
#pragma unroll
  for (int m = 0; m < 4; ++m) {
#pragma unroll
    for (int c = 0; c < 4; ++c) {
      int gj = n0 + wc * 64 + 16 * c + fr;
#pragma unroll
      for (int r = 0; r < 4; ++r) {
        int gi = m0 + wr * 64 + 16 * m + fq * 4 + r;
        Sg[base + ((size_t)gi << 10) + gj] = f2bf(acc[m][c][r]);
      }
    }
  }
}

// ================= invbuild: 2x inv64 + U128 assembly in one block; grid (8,32) =================
__global__ __launch_bounds__(256) void invbuild(const unsigned short* __restrict__ Lb,
    unsigned short* __restrict__ U128) {
  int ib = blockIdx.x, bh = blockIdx.y;
  int t = threadIdx.x, w = t >> 6, l = t & 63, fr = l & 15, fq = l >> 4;
  int s0 = ib * 128;
  size_t base = (size_t)bh << 20;
  unsigned short* Uo = U128 + (((size_t)(bh * 8 + ib)) << 14);
  __shared__ float LD[2][64 * 65];          // 33.3KB (+L)
  __shared__ unsigned short UaR[64 * 72];   // 9KB row-major, pad 8
  __shared__ unsigned short UcR[64 * 72];
  __shared__ unsigned short UaT[64 * 64];   // 8KB swizzled transposed
  __shared__ unsigned short T1T[64 * 64];
  // load both diagonal 64-blocks of +L
#pragma unroll
  for (int i = 0; i < 32; ++i) {
    int lin = t + i * 256;                  // 0..8191
    int blk = lin >> 12, s = (lin >> 6) & 63, r = lin & 63;
    LD[blk][s * 65 + r] = -bf2f(Lb[base + ((size_t)(s0 + blk * 64 + s) << 10) + s0 + blk * 64 + r]);
  }
  __syncthreads();
  if (t < 128) {                             // 2 parallel substitution chains
    int blk = t >> 6, j = t & 63;
    const float* ld = LD[blk];
    float cc[64];
#pragma unroll
    for (int s = 0; s < 64; ++s) cc[s] = (s == j) ? 1.f : 0.f;
#pragma unroll
    for (int r = 0; r < 63; ++r) {
      float val = cc[r];
#pragma unroll
      for (int s = r + 1; s < 64; ++s) cc[s] -= ld[s * 65 + r] * val;
    }
    if (blk == 0) {
#pragma unroll
      for (int s = 0; s < 64; ++s) {
        unsigned short v = f2bf(cc[s]);
        UaR[s * 72 + j] = v;
        *(unsigned short*)((char*)UaT + (((j << 7) + (s << 1)) ^ ((j & 7) << 4))) = v;
      }
    } else {
#pragma unroll
      for (int s = 0; s < 64; ++s) UcR[s * 72 + j] = f2bf(cc[s]);
    }
  }
  __syncthreads();
  // copy-out: top [Ua | 0]; bottom-right Uc
#pragma unroll
  for (int i = 0; i < 8; ++i) {
    int cid = t + i * 256;
    int row = cid >> 4, ch = cid & 15;
    u16x8 v = {0, 0, 0, 0, 0, 0, 0, 0};
    if (row < 64) {
      if (ch < 8) {
#pragma unroll
        for (int e = 0; e < 8; ++e) v[e] = UaR[row * 72 + ch * 8 + e];
      }
      *(u16x8*)(Uo + row * 128 + ch * 8) = v;
    } else if (ch >= 8) {
#pragma unroll
      for (int e = 0; e < 8; ++e) v[e] = UcR[(row - 64) * 72 + (ch - 8) * 8 + e];
      *(u16x8*)(Uo + row * 128 + ch * 8) = v;
    }
  }
  // T1 = Lneg_BA @ Ua
  f32x4 a1[4];
#pragma unroll
  for (int c = 0; c < 4; ++c) a1[c] = (f32x4){0.f, 0.f, 0.f, 0.f};
#pragma unroll
  for (int kc = 0; kc < 2; ++kc) {
    s16x8 af = *(const s16x8*)(Lb + base + ((size_t)(s0 + 64 + 16 * w + fr) << 10) + s0 + kc * 32 + fq * 8);
#pragma unroll
    for (int c = 0; c < 4; ++c) {
      int j = 16 * c + fr;
      s16x8 bb = *(const s16x8*)((char*)UaT + (((j << 7) + (kc << 6) + (fq << 4)) ^ ((j & 7) << 4)));
      a1[c] = __builtin_amdgcn_mfma_f32_16x16x32_bf16(af, bb, a1[c], 0, 0, 0);
    }
  }
#pragma unroll
  for (int c = 0; c < 4; ++c) {
    int gj = 16 * c + fr;
    int sb = 16 * w + fq * 4;
    u16x4 pk;
#pragma unroll
    for (int r = 0; r < 4; ++r) pk[r] = f2bf(a1[c][r]);
    *(u16x4*)((char*)T1T + (((gj << 7) + (sb << 1)) ^ ((gj & 7) << 4))) = pk;
  }
  __syncthreads();
  // B128 = Uc @ T1 (= -Uc L_BA Ua since Lb negated)
  f32x4 a2[4];
#pragma unroll
  for (int c = 0; c < 4; ++c) a2[c] = (f32x4){0.f, 0.f, 0.f, 0.f};
#pragma unroll
  for (int kc = 0; kc < 2; ++kc) {
    s16x8 af = *(const s16x8*)(UcR + (16 * w + fr) * 72 + kc * 32 + fq * 8);
#pragma unroll
    for (int c = 0; c < 4; ++c) {
      int j = 16 * c + fr;
      s16x8 bb = *(const s16x8*)((char*)T1T + (((j << 7) + (kc << 6) + (fq << 4)) ^ ((j & 7) << 4)));
      a2[c] = __builtin_amdgcn_mfma_f32_16x16x32_bf16(af, bb, a2[c], 0, 0, 0);
    }
  }
#pragma unroll
  for (int c = 0; c < 4; ++c) {
    int gj = 16 * c + fr;
#pragma unroll
    for (int r = 0; r < 4; ++r)
      Uo[(64 + 16 * w + fq * 4 + r) * 128 + gj] = f2bf(a2[c][r]);
  }
}

// ================= u256build: B256 = Uc128 @ (Lneg_BA @ Ua128); grid (4,32) =================
__global__ __launch_bounds__(256) void u256build(const unsigned short* __restrict__ Lb,
    const unsigned short* __restrict__ U128, unsigned short* __restrict__ B256) {
  int qb = blockIdx.x, bh = blockIdx.y;
  int t = threadIdx.x, w = t >> 6, l = t & 63, fr = l & 15, fq = l >> 4;
  int s0 = qb * 256;
  size_t base = (size_t)bh << 20;
  const unsigned short* Ua = U128 + (((size_t)(bh * 8 + 2 * qb)) << 14);
  const unsigned short* Uc = U128 + (((size_t)(bh * 8 + 2 * qb + 1)) << 14);
  unsigned short* out = B256 + (((size_t)(bh * 4 + qb)) << 14);
  __shared__ unsigned short UaT[16384];   // 128x128, 256B rows, XOR (j&15)<<4
  __shared__ unsigned short T1T[16384];
#pragma unroll
  for (int i = 0; i < 8; ++i) {
    int cid = t + i * 256;
    int s = cid >> 4, ch = cid & 15;
    u16x8 v = *(const u16x8*)(Ua + s * 128 + ch * 8);
#pragma unroll
    for (int e = 0; e < 8; ++e) {
      int j = ch * 8 + e;
      int byt = ((j << 8) + (s << 1)) ^ ((j & 15) << 4);
      *(unsigned short*)((char*)UaT + byt) = v[e];
    }
  }
  __syncthreads();
  f32x4 a1[2][8];
#pragma unroll
  for (int m = 0; m < 2; ++m)
#pragma unroll
    for (int c = 0; c < 8; ++c) a1[m][c] = (f32x4){0.f, 0.f, 0.f, 0.f};
#pragma unroll
  for (int kc = 0; kc < 4; ++kc) {
    s16x8 af[2];
#pragma unroll
    for (int m = 0; m < 2; ++m)
      af[m] = *(const s16x8*)(Lb + base + ((size_t)(s0 + 128 + 32 * w + 16 * m + fr) << 10) + s0 + kc * 32 + fq * 8);
#pragma unroll
    for (int c = 0; c < 8; ++c) {
      int j = 16 * c + fr;
      s16x8 bb = *(const s16x8*)((char*)UaT + (((j << 8) + (kc << 6) + (fq << 4)) ^ ((j & 15) << 4)));
#pragma unroll
      for (int m = 0; m < 2; ++m)
        a1[m][c] = __builtin_amdgcn_mfma_f32_16x16x32_bf16(af[m], bb, a1[m][c], 0, 0, 0);
    }
  }
#pragma unroll
  for (int m = 0; m < 2; ++m) {
#pragma unroll
    for (int c = 0; c < 8; ++c) {
      int col = 16 * c + fr;
      int row0 = 32 * w + 16 * m + fq * 4;
      u16x4 pk;
#pragma unroll
      for (int r = 0; r < 4; ++r) pk[r] = f2bf(a1[m][c][r]);
      int byt = ((col << 8) + (row0 << 1)) ^ ((col & 15) << 4);
      *(u16x4*)((char*)T1T + byt) = pk;
    }
  }
  __syncthreads();
  f32x4 a2[2][8];
#pragma unroll
  for (int m = 0; m < 2; ++m)
#pragma unroll
    for (int c = 0; c < 8; ++c) a2[m][c] = (f32x4){0.f, 0.f, 0.f, 0.f};
#pragma unroll
  for (int kc = 0; kc < 4; ++kc) {
    s16x8 af[2];
#pragma unroll
    for (int m = 0; m < 2; ++m)
      af[m] = *(const s16x8*)(Uc + (32 * w + 16 * m + fr) * 128 + kc * 32 + fq * 8);
#pragma unroll
    for (int c = 0; c < 8; ++c) {
      int j = 16 * c + fr;
      s16x8 bb = *(const s16x8*)((char*)T1T + (((j << 8) + (kc << 6) + (fq << 4)) ^ ((j & 15) << 4)));
#pragma unroll
      for (int m = 0; m < 2; ++m)
        a2[m][c] = __builtin_amdgcn_mfma_f32_16x16x32_bf16(af[m], bb, a2[m][c], 0, 0, 0);
    }
  }
#pragma unroll
  for (int m = 0; m < 2; ++m) {
#pragma unroll
    for (int c = 0; c < 8; ++c) {
      int col = 16 * c + fr;
#pragma unroll
      for (int r = 0; r < 4; ++r)
        out[(32 * w + 16 * m + fq * 4 + r) * 128 + col] = f2bf(a2[m][c][r]);
    }
  }
}

// ================= solve256: 256-row band step; band GEMM + 3-piece inverse apply =================
__global__ __launch_bounds__(256) void solve256(const unsigned short* __restrict__ WN,
    const unsigned short* __restrict__ Kk, const unsigned short* __restrict__ Lb,
    const unsigned short* __restrict__ U128, const unsigned short* __restrict__ B256,
    unsigned short* __restrict__ CT, int ib) {
  int jb = blockIdx.x, bh = blockIdx.y;
  int b = bh >> 4, h = bh & 15;
  int t = threadIdx.x, w = t >> 6, l = t & 63, fr = l & 15, fq = l >> 4;
  int s0 = ib * 256, j0 = jb * 128;
  size_t base = (size_t)bh << 20;
  __shared__ unsigned short sh[32768];
  unsigned short* As = sh;
  unsigned short* Bs = sh + 16384;
  unsigned short* rT = sh;
  const unsigned short* Wb_ = WN + ((size_t)b << 20) + h * 64;
  const unsigned short* Kb_ = Kk + ((size_t)b << 20) + h * 64;

  f32x4 acc[4][8];
#pragma unroll
  for (int m = 0; m < 4; ++m)
#pragma unroll
    for (int c = 0; c < 8; ++c) acc[m][c] = (f32x4){0.f, 0.f, 0.f, 0.f};
  int nst = 1 + 4 * ib - 2 * jb; if (nst < 1) nst = 1;
  for (int st = 0; st < nst; ++st) {
    __syncthreads();
    int rb = 2 * jb + st - 1;
#pragma unroll
    for (int i = 0; i < 8; ++i) {
      int cid = t + i * 256;
      int row = cid >> 3, ch = cid & 7;
      int chs = ch ^ (row & 7);
      const unsigned short* ga = (st == 0)
        ? Wb_ + ((size_t)(s0 + row) << 10) + chs * 8
        : Lb + base + ((size_t)(s0 + row) << 10) + rb * 64 + chs * 8;
      glds16(ga, (char*)As + cid * 16);
    }
#pragma unroll
    for (int i = 0; i < 4; ++i) {
      int cid = t + i * 256;
      int row = cid >> 3, ch = cid & 7;
      int chs = ch ^ (row & 7);
      const unsigned short* gb = (st == 0)
        ? Kb_ + ((size_t)(j0 + row) << 10) + chs * 8
        : CT + base + ((size_t)(j0 + row) << 10) + rb * 64 + chs * 8;
      glds16(gb, (char*)Bs + cid * 16);
    }
    __syncthreads();
#pragma unroll
    for (int kh = 0; kh < 2; ++kh) {
      s16x8 af[4], bfv[8];
#pragma unroll
      for (int m = 0; m < 4; ++m) {
        int ra = 64 * w + 16 * m + fr;
        af[m] = *(const s16x8*)((char*)As + (((ra << 7) + (kh << 6) + (fq << 4)) ^ ((ra & 7) << 4)));
      }
#pragma unroll
      for (int c = 0; c < 8; ++c) {
        int rb2 = 16 * c + fr;
        bfv[c] = *(const s16x8*)((char*)Bs + (((rb2 << 7) + (kh << 6) + (fq << 4)) ^ ((rb2 & 7) << 4)));
      }
#pragma unroll
      for (int m = 0; m < 4; ++m)
#pragma unroll
        for (int c = 0; c < 8; ++c)
          acc[m][c] = __builtin_amdgcn_mfma_f32_16x16x32_bf16(af[m], bfv[c], acc[m][c], 0, 0, 0);
    }
  }
  __syncthreads();
#pragma unroll
  for (int m = 0; m < 4; ++m) {
#pragma unroll
    for (int c = 0; c < 8; ++c) {
      int sl0 = 64 * w + 16 * m + fq * 4;
      int jl = 16 * c + fr;
      u16x4 pk;
#pragma unroll
      for (int r = 0; r < 4; ++r) {
        float v = acc[m][c][r];
        if (j0 + jl >= s0 + sl0 + r) v = 0.f;
        pk[r] = f2bf(v);
      }
      int byt = ((jl << 9) + (sl0 << 1)) ^ ((jl & 15) << 4);
      *(u16x4*)((char*)rT + byt) = pk;
    }
  }
  __syncthreads();
  const unsigned short* Ua = U128 + (((size_t)(bh * 8 + 2 * ib)) << 14);
  const unsigned short* Uc = U128 + (((size_t)(bh * 8 + 2 * ib + 1)) << 14);
  const unsigned short* Bm = B256 + (((size_t)(bh * 4 + ib)) << 14);
#pragma unroll
  for (int m = 0; m < 4; ++m)
#pragma unroll
    for (int c = 0; c < 8; ++c) acc[m][c] = (f32x4){0.f, 0.f, 0.f, 0.f};
  int nkc = (w < 2) ? 4 : 8;
  for (int kc = 0; kc < nkc; ++kc) {
    const unsigned short* src; int arow;
    if (w < 2) { src = Ua; arow = 64 * w; }
    else { src = (kc < 4) ? Bm : Uc; arow = 64 * (w - 2); }
    s16x8 uf[4];
#pragma unroll
    for (int m = 0; m < 4; ++m)
      uf[m] = *(const s16x8*)(src + (arow + 16 * m + fr) * 128 + (kc & 3) * 32 + fq * 8);
#pragma unroll
    for (int c = 0; c < 8; ++c) {
      int jl = 16 * c + fr;
      s16x8 bb = *(const s16x8*)((char*)rT + (((jl << 9) + (kc << 6) + (fq << 4)) ^ ((jl & 15) << 4)));
#pragma unroll
      for (int m = 0; m < 4; ++m)
        acc[m][c] = __builtin_amdgcn_mfma_f32_16x16x32_bf16(uf[m], bb, acc[m][c], 0, 0, 0);
    }
  }
#pragma unroll
  for (int m = 0; m < 4; ++m) {
#pragma unroll
    for (int c = 0; c < 8; ++c) {
      int jl = 16 * c + fr;
      int sb = 64 * w + 16 * m + fq * 4;
      u16x4 pk;
#pragma unroll
      for (int r = 0; r < 4; ++r) pk[r] = f2bf(acc[m][c][r]);
      *(u16x4*)(CT + base + ((size_t)(j0 + jl) << 10) + s0 + sb) = pk;
    }
  }
}

// ================= pv: online-softmax + P @ V; sorted 1D grid (512) =================
__global__ __launch_bounds__(256) void pv_kernel(const unsigned short* __restrict__ S,
    const unsigned short* __restrict__ VT, const float* __restrict__ Fc,
    unsigned short* __restrict__ Ob) {
  int idx = blockIdx.x;
  int bh = idx & 31, rank = idx >> 5;
  int tb = 15 - rank;
  int b = bh >> 4, h = bh & 15;
  int t0 = tb * 64;
  int t = threadIdx.x, w = t >> 6, l = t & 63, fr = l & 15, fq = l >> 4;
  __shared__ unsigned short Pl[64 * 64];
  __shared__ float mrow[64], lrow[64], crow[64];
  if (t < 64) { mrow[t] = -1e30f; lrow[t] = 0.f; }
  size_t base = (size_t)bh << 20;
  f32x4 acc[4];
#pragma unroll
  for (int c = 0; c < 4; ++c) acc[c] = (f32x4){0.f,0.f,0.f,0.f};
  for (int jb = 0; jb <= tb; ++jb) {
    int j0 = jb * 64;
    __syncthreads();                       // Pl reuse + crow settle + init
    // ---- step 1: load S, logits, tile row-max (8-thread groups share a row) ----
    float vals[2][8], tmax[2];
#pragma unroll
    for (int i = 0; i < 2; ++i) {
      int cid = t + i * 256;
      int row = cid >> 3, ch = cid & 7;
      int grow = t0 + row;
      u16x8 sv = *(const u16x8*)(S + base + ((size_t)grow << 10) + j0 + ch * 8);
      float4 f0 = *(const float4*)(Fc + bh * 1024 + j0 + ch * 8);
      float4 f1 = *(const float4*)(Fc + bh * 1024 + j0 + ch * 8 + 4);
      float tm = -1e30f;
#pragma unroll
      for (int e = 0; e < 8; ++e) {
        float fc = e < 4 ? ((const float*)&f0)[e] : ((const float*)&f1)[e - 4];
        float v = bf2f(sv[e]) * SM_SCALE - fc;
        if (jb == tb && ch * 8 + e > row) v = -1e30f;
        vals[i][e] = v; tm = fmaxf(tm, v);
      }
      tm = fmaxf(tm, __shfl_xor(tm, 1));
      tm = fmaxf(tm, __shfl_xor(tm, 2));
      tm = fmaxf(tm, __shfl_xor(tm, 4));
      tmax[i] = tm;
    }
    // ---- step 2: row owners update m, scale, partial l ----
    if ((t & 7) == 0) {
#pragma unroll
      for (int i = 0; i < 2; ++i) {
        int row = (t >> 3) + i * 32;
        float mo = mrow[row];
        float mn = fmaxf(mo, tmax[i]);
        float sc = __expf(mo - mn);
        crow[row] = sc; mrow[row] = mn;
        lrow[row] *= sc;
      }
    }
    __syncthreads();
    // ---- step 3: P = exp(vals - m), write LDS, accumulate l ----
    float ps[2];
#pragma unroll
    for (int i = 0; i < 2; ++i) {
      int cid = t + i * 256;
      int row = cid >> 3, ch = cid & 7;
      float mn = mrow[row];
      u16x8 pv;
      float psum = 0.f;
#pragma unroll
      for (int e = 0; e < 8; ++e) {
        float p = __expf(vals[i][e] - mn);
        psum += p; pv[e] = f2bf(p);
      }
      int byt = ((row << 7) + (ch << 4)) ^ ((row & 7) << 4);
      *(u16x8*)((char*)Pl + byt) = pv;
      psum += __shfl_xor(psum, 1);
      psum += __shfl_xor(psum, 2);
      psum += __shfl_xor(psum, 4);
      ps[i] = psum;
    }
    if ((t & 7) == 0) {
      lrow[t >> 3] += ps[0];
      lrow[(t >> 3) + 32] += ps[1];
    }
    __syncthreads();
    // ---- step 4: rescale O, PV MFMA ----
    float cr[4];
#pragma unroll
    for (int r = 0; r < 4; ++r) cr[r] = crow[16 * w + fq * 4 + r];
#pragma unroll
    for (int c = 0; c < 4; ++c)
#pragma unroll
      for (int r = 0; r < 4; ++r) acc[c][r] *= cr[r];
#pragma unroll
    for (int kh = 0; kh < 2; ++kh) {
      int ra = 16 * w + fr;
      s16x8 a = *(const s16x8*)((char*)Pl + (((ra << 7) + (kh << 6) + (fq << 4)) ^ ((ra & 7) << 4)));
#pragma unroll
      for (int c = 0; c < 4; ++c) {
        s16x8 bb = *(const s16x8*)(VT + ((size_t)bh * 64 + 16 * c + fr) * 1024 + j0 + kh * 32 + fq * 8);
        acc[c] = __builtin_amdgcn_mfma_f32_16x16x32_bf16(a, bb, acc[c], 0, 0, 0);
      }
    }
  }
  __syncthreads();
  float inv[4];
#pragma unroll
  for (int r = 0; r < 4; ++r) inv[r] = 1.f / lrow[16 * w + fq * 4 + r];
#pragma unroll
  for (int c = 0; c < 4; ++c) {
#pragma unroll
    for (int r = 0; r < 4; ++r) {
      int grow = t0 + 16 * w + fq * 4 + r;
      Ob[((size_t)(b * 1024) + grow) * 1024 + h * 64 + 16 * c + fr] = f2bf(acc[c][r] * inv[r]);
    }
  }
}

extern "C" void kernel_launch(void* const* d_in, const int* in_sizes, int n_in,
                              void* d_out, int out_size, void* d_ws, size_t ws_size,
                              hipStream_t stream) {
  const float* x    = (const float*)d_in[0];
  const float* Wq   = (const float*)d_in[1];
  const float* Wk   = (const float*)d_in[2];
  const float* Wv   = (const float*)d_in[3];
  const float* Wo   = (const float*)d_in[4];
  const float* Ww1  = (const float*)d_in[5];
  const float* Ww2  = (const float*)d_in[6];
  const float* Wb   = (const float*)d_in[7];
  const float* Wf   = (const float*)d_in[8];
  const float* delta= (const float*)d_in[9];

  char* ws = (char*)d_ws;
  unsigned short* xb   = (unsigned short*)(ws + OFF_XB);
  unsigned short* WqT  = (unsigned short*)(ws + OFF_WQT);
  unsigned short* WkT  = (unsigned short*)(ws + OFF_WKT);
  unsigned short* WvT  = (unsigned short*)(ws + OFF_WVT);
  unsigned short* WoT  = (unsigned short*)(ws + OFF_WOT);
  unsigned short* W1c  = (unsigned short*)(ws + OFF_W1C);
  unsigned short* W2T  = (unsigned short*)(ws + OFF_W2T);
  float*          Beta = (float*)(ws + OFF_BETA);
  unsigned short* Q16  = (unsigned short*)(ws + OFF_Q16);
  unsigned short* K16  = (unsigned short*)(ws + OFF_K16);
  unsigned short* VT   = (unsigned short*)(ws + OFF_VT);
  unsigned short* WN16 = (unsigned short*)(ws + OFF_WN16);
  unsigned short* WB16 = (unsigned short*)(ws + OFF_WB16);
  unsigned short* WNF16= (unsigned short*)(ws + OFF_WNF);
  unsigned short* ObB  = (unsigned short*)(ws + OFF_OB);
  unsigned short* BFT  = (unsigned short*)(ws + OFF_BFT);
  float*          Fc   = (float*)(ws + OFF_FC);
  unsigned short* Lbuf = (unsigned short*)(ws + OFF_L);
  unsigned short* Sbuf = (unsigned short*)(ws + OFF_L);
  unsigned short* CT   = (unsigned short*)(ws + OFF_CT);
  unsigned short* Gbuf = (unsigned short*)(ws + OFF_G);
  float*          BL   = (float*)(ws + OFF_BL);
  unsigned short* U128 = (unsigned short*)(ws + OFF_U128);
  unsigned short* B256 = (unsigned short*)(ws + OFF_B256);

  dim3 blk(256);
  // prep (all transposes + casts + BFT 128-row)
  prep_all<<<2160, blk, 0, stream>>>(Wq, Wk, Wv, Wo, Ww1, Ww2, x, Wb, Wf,
                                     WqT, WkT, WvT, WoT, W1c, W2T, xb, BFT);
  // WfusedT = W2T @ W1c^T (rank-64 fold; lives in WN16 region until wnorm2)
  gemm_nt<0><<<dim3(16,16), blk, 0, stream>>>(W2T, W1c, WN16, 1024, 1024, 64);
  // Q, K, VT, WNF, BL in one 528-block launch
  proj_big<<<528, blk, 0, stream>>>(xb, WqT, WkT, WvT, WN16, BFT,
                                    Q16, K16, VT, WNF16, BL);
  // beta/logsigmoid/cumsum fused
  bgfc<<<32, blk, 0, stream>>>(BL, delta, Beta, Fc);
  wnorm2<<<2048, blk, 0, stream>>>(WNF16, Beta, WN16, WB16);
  // L and G (both stored NEGATED)
  pairLG<<<dim3(36 * 32), blk, 0, stream>>>(WN16, Q16, WB16, Lbuf, Gbuf);
  // triangular solve: fused inverses -> 256 off-diag piece -> 4 band steps
  invbuild<<<dim3(8,32), blk, 0, stream>>>(Lbuf, U128);
  u256build<<<dim3(4,32), blk, 0, stream>>>(Lbuf, U128, B256);
  for (int ib = 0; ib < 4; ++ib)
    solve256<<<dim3(2 * ib + 2, 32), blk, 0, stream>>>(WN16, K16, Lbuf, U128, B256, CT, ib);
  // S = QK^T + Gneg C (sorted band grid; reuses L region)
  score128s<<<dim3(36 * 32), blk, 0, stream>>>(Q16, K16, Gbuf, CT, Sbuf);
  // online softmax + PV (rowstat fused away)
  pv_kernel<<<dim3(512), blk, 0, stream>>>(Sbuf, VT, Fc, ObB);
  // output projection (f32 out)
  gemm_nt<1><<<dim3(16,32), blk, 0, stream>>>(ObB, WoT, d_out, 2048, 1024, 1024);
}

// Round 11
// 297.424 us; speedup vs baseline: 13.7106x; 1.0307x over previous
//
#include <hip/hip_runtime.h>
#include <hip/hip_bf16.h>

#define DEV static __device__ __forceinline__

constexpr float SM_SCALE = 0.125f;   // hd^-0.5, hd=64

typedef __attribute__((ext_vector_type(8))) short s16x8;
typedef __attribute__((ext_vector_type(8))) unsigned short u16x8;
typedef __attribute__((ext_vector_type(4))) unsigned short u16x4;
typedef __attribute__((ext_vector_type(4))) float f32x4;

DEV float bf2f(unsigned short u) {
  union { unsigned int i; float f; } v; v.i = ((unsigned int)u) << 16; return v.f;
}
DEV unsigned short f2bf(float f) {
  union { float f; unsigned int i; } v; v.f = f;
  unsigned int r = v.i + 0x7fffu + ((v.i >> 16) & 1u);
  return (unsigned short)(r >> 16);
}
DEV void tri_unrank(int r, int& k, int& i) {
  k = (int)((sqrtf(8.f * r + 1.f) - 1.f) * 0.5f);
  while (k * (k + 1) / 2 > r) --k;
  while ((k + 1) * (k + 2) / 2 <= r) ++k;
  i = r - k * (k + 1) / 2;
}
// async global->LDS, 16B per lane; dest must be wave-linear (base + lane*16)
DEV void glds16(const void* g, void* l) {
  __builtin_amdgcn_global_load_lds(
      (const __attribute__((address_space(1))) void*)g,
      (__attribute__((address_space(3))) void*)l, 16, 0, 0);
}
DEV void pipe_drain_barrier() {
  asm volatile("s_waitcnt vmcnt(0)" ::: "memory");
  __builtin_amdgcn_s_barrier();
}

// ---------- workspace layout (bytes) ----------
constexpr size_t OFF_XB   = 0;                       // 4MB xb bf16 [2048][1024]
constexpr size_t OFF_WQT  = 4194304;                 // 2MB
constexpr size_t OFF_WKT  = 6291456;                 // 2MB
constexpr size_t OFF_WVT  = 8388608;
constexpr size_t OFF_WOT  = 10485760;
constexpr size_t OFF_W1C  = 12582912;                // 128KB bf16 Ww1 cast (1024x64)
constexpr size_t OFF_W2T  = 12713984;                // 128KB
constexpr size_t OFF_BETA = 12582912;                // reuse W1C after wfuse
constexpr size_t OFF_Q16  = 12845056;                // 4MB bf16 2048x1024
constexpr size_t OFF_K16  = 17039360;                // 4MB
constexpr size_t OFF_VT   = 21233664;                // 4MB  VT[b][64h*d][1024n]
constexpr size_t OFF_WN16 = 25427968;                // 4MB; holds WfusedT until wnorm2
constexpr size_t OFF_WB16 = 29622272;                // 4MB
constexpr size_t OFF_WNF  = 33816576;                // 4MB (reused as Ob)
constexpr size_t OFF_OB   = 33816576;
constexpr size_t OFF_BFT  = 38010880;                // 256KB bf16 (128x1024)
constexpr size_t OFF_FC   = 38273024;                // 128KB
constexpr size_t OFF_L    = 38404096;                // 64MB, stores -L (reused as S)
constexpr size_t OFF_CT   = 105512960;               // 64MB
constexpr size_t OFF_G    = 172621824;               // 64MB, stores -G
constexpr size_t OFF_BL   = 239730688;               // 512KB f32 2048x64
constexpr size_t OFF_U128 = 244187136;               // 8MB bf16 [32][8][128][128]
constexpr size_t OFF_B256 = 252575744;               // 4MB bf16 [32][4][128][128]

// ================= fused prep: transposes + casts + BFT(128 rows); grid 2160 =================
__global__ __launch_bounds__(256) void prep_all(
    const float* __restrict__ W0, const float* __restrict__ W1,
    const float* __restrict__ W2, const float* __restrict__ W3,
    const float* __restrict__ Ww1, const float* __restrict__ Ww2,
    const float* __restrict__ x, const float* __restrict__ Wb,
    const float* __restrict__ Wf,
    unsigned short* __restrict__ D0, unsigned short* __restrict__ D1,
    unsigned short* __restrict__ D2, unsigned short* __restrict__ D3,
    unsigned short* __restrict__ W1c, unsigned short* __restrict__ W2T,
    unsigned short* __restrict__ xb, unsigned short* __restrict__ BFT) {
  int bidx = blockIdx.x;
  int t = threadIdx.x;
  if (bidx >= 2096) {                      // BFT build (64 blocks, 128x1024)
    int e0 = ((bidx - 2096) * 256 + t) * 8;
    int j = e0 >> 10, i0 = e0 & 1023;
    u16x8 o;
#pragma unroll
    for (int e = 0; e < 8; ++e) {
      int i = i0 + e;
      float v = 0.f;
      if (j < 16) v = Wb[i * 16 + j];
      else if (j < 32) v = Wf[i * 16 + (j - 16)];
      o[e] = f2bf(v);
    }
    *(u16x8*)(BFT + e0) = o;
    return;
  }
  if (bidx >= 2064) {                      // W1 cast (32 blocks)
    int i = ((bidx - 2064) * 256 + t) * 8;
    float4 a = *(const float4*)(Ww1 + i);
    float4 b = *(const float4*)(Ww1 + i + 4);
    u16x8 o;
    o[0] = f2bf(a.x); o[1] = f2bf(a.y); o[2] = f2bf(a.z); o[3] = f2bf(a.w);
    o[4] = f2bf(b.x); o[5] = f2bf(b.y); o[6] = f2bf(b.z); o[7] = f2bf(b.w);
    *(u16x8*)(W1c + i) = o;
    return;
  }
  if (bidx >= 1040) {                      // x cast (1024 blocks)
    int i = ((bidx - 1040) * 256 + t) * 8;
    float4 a = *(const float4*)(x + i);
    float4 b = *(const float4*)(x + i + 4);
    u16x8 o;
    o[0] = f2bf(a.x); o[1] = f2bf(a.y); o[2] = f2bf(a.z); o[3] = f2bf(a.w);
    o[4] = f2bf(b.x); o[5] = f2bf(b.y); o[6] = f2bf(b.z); o[7] = f2bf(b.w);
    *(u16x8*)(xb + i) = o;
    return;
  }
  const float* src; unsigned short* dst; int R, C, c0, r0;
  if (bidx >= 1024) {                      // W2T transpose (16 blocks)
    src = Ww2; dst = W2T; R = 64; C = 1024;
    c0 = (bidx - 1024) * 64; r0 = 0;
  } else {
    int z = bidx >> 8, xy = bidx & 255;
    src = z == 0 ? W0 : z == 1 ? W1 : z == 2 ? W2 : W3;
    dst = z == 0 ? D0 : z == 1 ? D1 : z == 2 ? D2 : D3;
    R = 1024; C = 1024;
    c0 = (xy & 15) * 64; r0 = (xy >> 4) * 64;
  }
  __shared__ float tile[64 * 65];
#pragma unroll
  for (int i = 0; i < 16; ++i) {
    int lin = t + i * 256; int r = lin >> 6, c = lin & 63;
    tile[r * 65 + c] = src[(size_t)(r0 + r) * C + c0 + c];
  }
  __syncthreads();
#pragma unroll
  for (int i = 0; i < 16; ++i) {
    int lin = t + i * 256; int c = lin >> 6, r = lin & 63;
    dst[(size_t)(c0 + c) * R + r0 + r] = f2bf(tile[r * 65 + c]);
  }
}

// beta + log_sigmoid + cumsum fused; grid 32 (bh)
__global__ __launch_bounds__(256) void bgfc(const float* __restrict__ BL,
    const float* __restrict__ delta, float* __restrict__ Beta, float* __restrict__ Fc) {
  int bh = blockIdx.x;
  int b = bh >> 4, h = bh & 15;
  int t = threadIdx.x;
  __shared__ float buf[1024];
  __shared__ float tsum[256];
  float dh = delta[h];
#pragma unroll
  for (int i = 0; i < 4; ++i) {
    int n = t + i * 256;
    int row = (b << 10) + n;
    float braw = BL[row * 64 + h];
    Beta[row * 16 + h] = 2.f / (1.f + __expf(-braw));
    float lraw = BL[row * 64 + 16 + h] + dh;
    buf[n] = (lraw >= 0.f) ? -log1pf(__expf(-lraw)) : (lraw - log1pf(__expf(lraw)));
  }
  __syncthreads();
  float loc[4]; float run = 0.f;
#pragma unroll
  for (int i = 0; i < 4; ++i) { run += buf[t * 4 + i]; loc[i] = run; }
  tsum[t] = run;
  __syncthreads();
  for (int off = 1; off < 256; off <<= 1) {
    float add = (t >= off) ? tsum[t - off] : 0.f;
    __syncthreads();
    tsum[t] += add;
    __syncthreads();
  }
  float excl = tsum[t] - run;
#pragma unroll
  for (int i = 0; i < 4; ++i) Fc[bh * 1024 + t * 4 + i] = excl + loc[i];
}

// ================= mega projection: Q,K + VT + WNF + BL, 528 blocks; 2-phase pipeline =================
__global__ __launch_bounds__(256) void proj_big(const unsigned short* __restrict__ xb,
    const unsigned short* __restrict__ WqT, const unsigned short* __restrict__ WkT,
    const unsigned short* __restrict__ WvT, const unsigned short* __restrict__ WfT,
    const unsigned short* __restrict__ BFT,
    unsigned short* __restrict__ Q16, unsigned short* __restrict__ K16,
    unsigned short* __restrict__ VT, unsigned short* __restrict__ WNF,
    float* __restrict__ BL) {
  int idx = blockIdx.x;
  const unsigned short *A, *BT; unsigned short* out = nullptr; int m0, n0;
  int mode = 0;
  if (idx < 256) {
    int my = idx >> 4, nx = idx & 15;
    m0 = my * 128; A = xb;
    if (nx < 8) { BT = WqT; out = Q16; n0 = nx * 128; }
    else { BT = WkT; out = K16; n0 = (nx - 8) * 128; }
  } else if (idx < 384) {
    int r = idx - 256; int bz = r >> 6; int rem = r & 63;
    m0 = (rem >> 3) * 128; n0 = (rem & 7) * 128;
    A = WvT; BT = xb + ((size_t)bz << 20); out = VT + ((size_t)bz << 20);
  } else if (idx < 512) {
    int r2 = idx - 384;
    m0 = (r2 >> 3) * 128; n0 = (r2 & 7) * 128;
    A = xb; BT = WfT; out = WNF;
  } else {
    m0 = (idx - 512) * 128; n0 = 0;
    A = xb; BT = BFT; mode = 1;
  }
  int t = threadIdx.x;
  int w = t >> 6, l = t & 63;
  int wr = w >> 1, wc = w & 1;
  int fr = l & 15, fq = l >> 4;
  __shared__ unsigned short As[2 * 8192];
  __shared__ unsigned short Bs[2 * 8192];
  f32x4 acc[4][4];
#pragma unroll
  for (int m = 0; m < 4; ++m)
#pragma unroll
    for (int c = 0; c < 4; ++c) acc[m][c] = (f32x4){0.f, 0.f, 0.f, 0.f};

#define STAGE_PB(buf, k0) {                                             \
  _Pragma("unroll")                                                     \
  for (int i = 0; i < 4; ++i) {                                         \
    int cid = t + i * 256;                                              \
    int row = cid >> 3, ch = cid & 7;                                   \
    int chs = ch ^ (row & 7);                                           \
    glds16(A + (size_t)(m0 + row) * 1024 + (k0) + chs * 8, (char*)(As + (buf) * 8192) + cid * 16); \
    glds16(BT + (size_t)(n0 + row) * 1024 + (k0) + chs * 8, (char*)(Bs + (buf) * 8192) + cid * 16); \
  } }

  STAGE_PB(0, 0);
  pipe_drain_barrier();
  int cur = 0;
  for (int kt = 0; kt < 16; ++kt) {
    if (kt < 15) STAGE_PB(cur ^ 1, (kt + 1) * 64);
    const char* Ab = (const char*)(As + cur * 8192);
    const char* Bb = (const char*)(Bs + cur * 8192);
    __builtin_amdgcn_s_setprio(1);
#pragma unroll
    for (int kh = 0; kh < 2; ++kh) {
      s16x8 af[4], bfv[4];
#pragma unroll
      for (int m = 0; m < 4; ++m) {
        int ra = wr * 64 + 16 * m + fr;
        af[m] = *(const s16x8*)(Ab + (((ra << 7) + (kh << 6) + (fq << 4)) ^ ((ra & 7) << 4)));
      }
#pragma unroll
      for (int c = 0; c < 4; ++c) {
        int rb = wc * 64 + 16 * c + fr;
        bfv[c] = *(const s16x8*)(Bb + (((rb << 7) + (kh << 6) + (fq << 4)) ^ ((rb & 7) << 4)));
      }
#pragma unroll
      for (int m = 0; m < 4; ++m)
#pragma unroll
        for (int c = 0; c < 4; ++c)
          acc[m][c] = __builtin_amdgcn_mfma_f32_16x16x32_bf16(af[m], bfv[c], acc[m][c], 0, 0, 0);
    }
    __builtin_amdgcn_s_setprio(0);
    pipe_drain_barrier();
    cur ^= 1;
  }
#undef STAGE_PB
#pragma unroll
  for (int m = 0; m < 4; ++m) {
#pragma unroll
    for (int c = 0; c < 4; ++c) {
      int col = n0 + wc * 64 + 16 * c + fr;
#pragma unroll
      for (int r = 0; r < 4; ++r) {
        int grow = m0 + wr * 64 + 16 * m + fq * 4 + r;
        if (mode == 0) out[(size_t)grow * 1024 + col] = f2bf(acc[m][c][r]);
        else if (col < 64) BL[(size_t)grow * 64 + col] = acc[m][c][r];
      }
    }
  }
}

// ================= 64-tile bf16 NT GEMM; 2-phase pipeline =================
template<int F32OUT>
__global__ __launch_bounds__(256) void gemm_nt(const unsigned short* __restrict__ A,
    const unsigned short* __restrict__ BT, void* __restrict__ out,
    int M, int N, int K) {
  __shared__ unsigned short As[2 * 4096];
  __shared__ unsigned short Bs[2 * 4096];
  int m0 = blockIdx.y * 64, n0 = blockIdx.x * 64;
  int t = threadIdx.x;
  int w = t >> 6, l = t & 63, fr = l & 15;
  int koB = (l >> 4) * 16;
  f32x4 acc[4];
#pragma unroll
  for (int c = 0; c < 4; ++c) acc[c] = (f32x4){0.f, 0.f, 0.f, 0.f};

#define STAGE_G(buf, k0) {                                              \
  _Pragma("unroll")                                                     \
  for (int i = 0; i < 2; ++i) {                                         \
    int cid = t + i * 256;                                              \
    int row = cid >> 3, ch = cid & 7;                                   \
    int chs = ch ^ (row & 7);                                           \
    glds16(A + (size_t)(m0 + row) * K + (k0) + chs * 8, (char*)(As + (buf) * 4096) + cid * 16); \
    glds16(BT + (size_t)(n0 + row) * K + (k0) + chs * 8, (char*)(Bs + (buf) * 4096) + cid * 16); \
  } }

  int nt = K >> 6;
  STAGE_G(0, 0);
  pipe_drain_barrier();
  int cur = 0;
  for (int kt = 0; kt < nt; ++kt) {
    if (kt + 1 < nt) STAGE_G(cur ^ 1, (kt + 1) * 64);
    const char* Ab = (const char*)(As + cur * 4096);
    const char* Bb = (const char*)(Bs + cur * 4096);
    __builtin_amdgcn_s_setprio(1);
#pragma unroll
    for (int kh = 0; kh < 2; ++kh) {
      int ra = 16 * w + fr;
      s16x8 a = *(const s16x8*)(Ab + (((ra << 7) + (kh << 6) + koB) ^ ((ra & 7) << 4)));
#pragma unroll
      for (int c = 0; c < 4; ++c) {
        int rb = 16 * c + fr;
        s16x8 bb = *(const s16x8*)(Bb + (((rb << 7) + (kh << 6) + koB) ^ ((rb & 7) << 4)));
        acc[c] = __builtin_amdgcn_mfma_f32_16x16x32_bf16(a, bb, acc[c], 0, 0, 0);
      }
    }
    __builtin_amdgcn_s_setprio(0);
    pipe_drain_barrier();
    cur ^= 1;
  }
#undef STAGE_G
  int rbase = m0 + 16 * w + ((l >> 4) << 2);
#pragma unroll
  for (int c = 0; c < 4; ++c) {
    int col = n0 + 16 * c + fr;
#pragma unroll
    for (int r = 0; r < 4; ++r) {
      if (F32OUT) ((float*)out)[(size_t)(rbase + r) * N + col] = acc[c][r];
      else ((unsigned short*)out)[(size_t)(rbase + r) * N + col] = f2bf(acc[c][r]);
    }
  }
}

// ================= w normalize + beta-scale =================
__global__ __launch_bounds__(256) void wnorm2(const unsigned short* __restrict__ WNF,
    const float* __restrict__ Beta, unsigned short* __restrict__ WN,
    unsigned short* __restrict__ WB) {
  int row = blockIdx.x;
  int wave = threadIdx.x >> 6, lane = threadIdx.x & 63;
#pragma unroll
  for (int i = 0; i < 4; ++i) {
    int hh = wave * 4 + i;
    size_t idx = ((size_t)row << 10) + hh * 64 + lane;
    float v = bf2f(WNF[idx]);
    float ss = v * v;
#pragma unroll
    for (int off = 1; off < 64; off <<= 1) ss += __shfl_xor(ss, off);
    float wn = v * rsqrtf(ss + 1e-6f);
    WN[idx] = f2bf(wn);
    WB[idx] = f2bf(wn * Beta[row * 16 + hh]);
  }
}

// ================= pair fused: writes NEGATED L and G =================
__global__ __launch_bounds__(256) void pairLG(const unsigned short* __restrict__ WN,
    const unsigned short* __restrict__ Q, const unsigned short* __restrict__ WB,
    unsigned short* __restrict__ Lg, unsigned short* __restrict__ Gg) {
  int idx = blockIdx.x;
  int bh = idx & 31, r0r = idx >> 5;
  int tb2, jb2; tri_unrank(r0r, tb2, jb2);
  int b = bh >> 4, h = bh & 15;
  int m0 = tb2 * 128, n0 = jb2 * 128;
  int t = threadIdx.x;
  int w = t >> 6, l = t & 63;
  int wr = w >> 1, wc = w & 1;
  int fr = l & 15, fq = l >> 4;
  __shared__ unsigned short As[128 * 64];
  __shared__ unsigned short Bs[128 * 64];
  const unsigned short* WNb = WN + ((size_t)b << 20) + h * 64;
  const unsigned short* Qb  = Q + ((size_t)b << 20) + h * 64;
  const unsigned short* WBb = WB + ((size_t)b << 20) + h * 64;
  size_t base = (size_t)bh << 20;
#pragma unroll
  for (int i = 0; i < 4; ++i) {
    int cid = t + i * 256;
    int row = cid >> 3, ch = cid & 7;
    int chs = ch ^ (row & 7);
    glds16(WNb + ((size_t)(m0 + row) << 10) + chs * 8, (char*)As + cid * 16);
    glds16(WBb + ((size_t)(n0 + row) << 10) + chs * 8, (char*)Bs + cid * 16);
  }
  __syncthreads();
  for (int pass = 0; pass < 2; ++pass) {
    f32x4 acc[4][4];
#pragma unroll
    for (int m = 0; m < 4; ++m)
#pragma unroll
      for (int c = 0; c < 4; ++c) acc[m][c] = (f32x4){0.f, 0.f, 0.f, 0.f};
#pragma unroll
    for (int kh = 0; kh < 2; ++kh) {
      s16x8 af[4], bfv[4];
#pragma unroll
      for (int m = 0; m < 4; ++m) {
        int ra = wr * 64 + 16 * m + fr;
        af[m] = *(const s16x8*)((char*)As + (((ra << 7) + (kh << 6) + (fq << 4)) ^ ((ra & 7) << 4)));
      }
#pragma unroll
      for (int c = 0; c < 4; ++c) {
        int rb = wc * 64 + 16 * c + fr;
        bfv[c] = *(const s16x8*)((char*)Bs + (((rb << 7) + (kh << 6) + (fq << 4)) ^ ((rb & 7) << 4)));
      }
#pragma unroll
      for (int m = 0; m < 4; ++m)
#pragma unroll
        for (int c = 0; c < 4; ++c)
          acc[m][c] = __builtin_amdgcn_mfma_f32_16x16x32_bf16(af[m], bfv[c], acc[m][c], 0, 0, 0);
    }
    unsigned short* dst = pass ? Gg : Lg;
#pragma unroll
    for (int m = 0; m < 4; ++m) {
#pragma unroll
      for (int c = 0; c < 4; ++c) {
        int gj = n0 + wc * 64 + 16 * c + fr;
#pragma unroll
        for (int r = 0; r < 4; ++r) {
          int gi = m0 + wr * 64 + 16 * m + fq * 4 + r;
          bool keep = pass ? (gj <= gi) : (gj < gi);
          dst[base + ((size_t)gi << 10) + gj] = f2bf(keep ? -acc[m][c][r] : 0.f);
        }
      }
    }
    if (pass == 0) {
      __syncthreads();
#pragma unroll
      for (int i = 0; i < 4; ++i) {
        int cid = t + i * 256;
        int row = cid >> 3, ch = cid & 7;
        int chs = ch ^ (row & 7);
        glds16(Qb + ((size_t)(m0 + row) << 10) + chs * 8, (char*)As + cid * 16);
      }
      __syncthreads();
    }
  }
}

// ================= score: S = Q K^T + Gneg @ C, sorted 1D grid; 2-phase pipeline =================
__global__ __launch_bounds__(256) void score128s(const unsigned short* __restrict__ Q,
    const unsigned short* __restrict__ Kk, const unsigned short* __restrict__ G,
    const unsigned short* __restrict__ CT, unsigned short* __restrict__ Sg) {
  int idx = blockIdx.x;
  int bh = idx & 31, r0r = idx >> 5;
  int k, i; tri_unrank(r0r, k, i);
  int tb2 = (7 - k) + i, jb2 = i;
  int b = bh >> 4, h = bh & 15;
  int m0 = tb2 * 128, n0 = jb2 * 128;
  int t = threadIdx.x;
  int w = t >> 6, l = t & 63;
  int wr = w >> 1, wc = w & 1;
  int fr = l & 15, fq = l >> 4;
  __shared__ unsigned short As[2 * 8192];
  __shared__ unsigned short Bs[2 * 8192];
  size_t base = (size_t)bh << 20;
  const unsigned short* Qb_ = Q + ((size_t)b << 20) + h * 64;
  const unsigned short* Kb_ = Kk + ((size_t)b << 20) + h * 64;
  const unsigned short* Gb_ = G + base;
  const unsigned short* Cb_ = CT + base;
  int kbase = jb2 * 128;
  int nsteps = 1 + (tb2 - jb2 + 1) * 2;
  f32x4 acc[4][4];
#pragma unroll
  for (int m = 0; m < 4; ++m)
#pragma unroll
    for (int c = 0; c < 4; ++c) acc[m][c] = (f32x4){0.f, 0.f, 0.f, 0.f};

#define STAGE_SC(buf, stp) {                                            \
  const unsigned short* pa; const unsigned short* pb; int koff;         \
  if ((stp) == 0) { pa = Qb_; pb = Kb_; koff = 0; }                     \
  else { pa = Gb_; pb = Cb_; koff = kbase + ((stp) - 1) * 64; }         \
  _Pragma("unroll")                                                     \
  for (int i2 = 0; i2 < 4; ++i2) {                                      \
    int cid = t + i2 * 256;                                             \
    int row = cid >> 3, ch = cid & 7;                                   \
    int chs = ch ^ (row & 7);                                           \
    glds16(pa + ((size_t)(m0 + row) << 10) + koff + chs * 8, (char*)(As + (buf) * 8192) + cid * 16); \
    glds16(pb + ((size_t)(n0 + row) << 10) + koff + chs * 8, (char*)(Bs + (buf) * 8192) + cid * 16); \
  } }

  STAGE_SC(0, 0);
  pipe_drain_barrier();
  int cur = 0;
  for (int step = 0; step < nsteps; ++step) {
    if (step + 1 < nsteps) STAGE_SC(cur ^ 1, step + 1);
    const char* Ab = (const char*)(As + cur * 8192);
    const char* Bb = (const char*)(Bs + cur * 8192);
    __builtin_amdgcn_s_setprio(1);
#pragma unroll
    for (int kh = 0; kh < 2; ++kh) {
      s16x8 af[4], bfv[4];
#pragma unroll
      for (int m = 0; m < 4; ++m) {
        int ra = wr * 64 + 16 * m + fr;
        af[m] = *(const s16x8*)(Ab + (((ra << 7) + (kh << 6) + (fq << 4)) ^ ((ra & 7) << 4)));
      }
#pragma unroll
      for (int c = 0; c < 4; ++c) {
        int rb = wc * 64 + 16 * c + fr;
        bfv[c] = *(const s16x8*)(Bb + (((rb << 7) + (kh << 6) + (fq << 4)) ^ ((rb & 7) << 4)));
      }
#pragma unroll
      for (int m = 0; m < 4; ++m)
#pragma unroll
        for (int c = 0; c < 4; ++c)
          acc[m][c] = __builtin_amdgcn_mfma_f32_16x16x32_bf16(af[m], bfv[c], acc[m][c], 0, 0, 0);
    }
    __builtin_amdgcn_s_setprio(0);
    pipe_drain_barrier();
    cur ^= 1;
  }
#undef STAGE_SC
#pragma unroll
  for (int m = 0; m < 4; ++m) {
#pragma unroll
    for (int c = 0; c < 4; ++c) {
      int gj = n0 + wc * 64 + 16 * c + fr;
#pragma unroll
      for (int r = 0; r < 4; ++r) {
        int gi = m0 + wr * 64 + 16 * m + fq * 4 + r;
        Sg[base + ((size_t)gi << 10) + gj] = f2bf(acc[m][c][r]);
      }
    }
  }
}

// ================= invbuild: 2x inv64 + U128 assembly in one block; grid (8,32) =================
__global__ __launch_bounds__(256) void invbuild(const unsigned short* __restrict__ Lb,
    unsigned short* __restrict__ U128) {
  int ib = blockIdx.x, bh = blockIdx.y;
  int t = threadIdx.x, w = t >> 6, l = t & 63, fr = l & 15, fq = l >> 4;
  int s0 = ib * 128;
  size_t base = (size_t)bh << 20;
  unsigned short* Uo = U128 + (((size_t)(bh * 8 + ib)) << 14);
  __shared__ float LD[2][64 * 65];
  __shared__ unsigned short UaR[64 * 72];
  __shared__ unsigned short UcR[64 * 72];
  __shared__ unsigned short UaT[64 * 64];
  __shared__ unsigned short T1T[64 * 64];
#pragma unroll
  for (int i = 0; i < 32; ++i) {
    int lin = t + i * 256;
    int blk = lin >> 12, s = (lin >> 6) & 63, r = lin & 63;
    LD[blk][s * 65 + r] = -bf2f(Lb[base + ((size_t)(s0 + blk * 64 + s) << 10) + s0 + blk * 64 + r]);
  }
  __syncthreads();
  if (t < 128) {
    int blk = t >> 6, j = t & 63;
    const float* ld = LD[blk];
    float cc[64];
#pragma unroll
    for (int s = 0; s < 64; ++s) cc[s] = (s == j) ? 1.f : 0.f;
#pragma unroll
    for (int r = 0; r < 63; ++r) {
      float val = cc[r];
#pragma unroll
      for (int s = r + 1; s < 64; ++s) cc[s] -= ld[s * 65 + r] * val;
    }
    if (blk == 0) {
#pragma unroll
      for (int s = 0; s < 64; ++s) {
        unsigned short v = f2bf(cc[s]);
        UaR[s * 72 + j] = v;
        *(unsigned short*)((char*)UaT + (((j << 7) + (s << 1)) ^ ((j & 7) << 4))) = v;
      }
    } else {
#pragma unroll
      for (int s = 0; s < 64; ++s) UcR[s * 72 + j] = f2bf(cc[s]);
    }
  }
  __syncthreads();
#pragma unroll
  for (int i = 0; i < 8; ++i) {
    int cid = t + i * 256;
    int row = cid >> 4, ch = cid & 15;
    u16x8 v = {0, 0, 0, 0, 0, 0, 0, 0};
    if (row < 64) {
      if (ch < 8) {
#pragma unroll
        for (int e = 0; e < 8; ++e) v[e] = UaR[row * 72 + ch * 8 + e];
      }
      *(u16x8*)(Uo + row * 128 + ch * 8) = v;
    } else if (ch >= 8) {
#pragma unroll
      for (int e = 0; e < 8; ++e) v[e] = UcR[(row - 64) * 72 + (ch - 8) * 8 + e];
      *(u16x8*)(Uo + row * 128 + ch * 8) = v;
    }
  }
  f32x4 a1[4];
#pragma unroll
  for (int c = 0; c < 4; ++c) a1[c] = (f32x4){0.f, 0.f, 0.f, 0.f};
#pragma unroll
  for (int kc = 0; kc < 2; ++kc) {
    s16x8 af = *(const s16x8*)(Lb + base + ((size_t)(s0 + 64 + 16 * w + fr) << 10) + s0 + kc * 32 + fq * 8);
#pragma unroll
    for (int c = 0; c < 4; ++c) {
      int j = 16 * c + fr;
      s16x8 bb = *(const s16x8*)((char*)UaT + (((j << 7) + (kc << 6) + (fq << 4)) ^ ((j & 7) << 4)));
      a1[c] = __builtin_amdgcn_mfma_f32_16x16x32_bf16(af, bb, a1[c], 0, 0, 0);
    }
  }
#pragma unroll
  for (int c = 0; c < 4; ++c) {
    int gj = 16 * c + fr;
    int sb = 16 * w + fq * 4;
    u16x4 pk;
#pragma unroll
    for (int r = 0; r < 4; ++r) pk[r] = f2bf(a1[c][r]);
    *(u16x4*)((char*)T1T + (((gj << 7) + (sb << 1)) ^ ((gj & 7) << 4))) = pk;
  }
  __syncthreads();
  f32x4 a2[4];
#pragma unroll
  for (int c = 0; c < 4; ++c) a2[c] = (f32x4){0.f, 0.f, 0.f, 0.f};
#pragma unroll
  for (int kc = 0; kc < 2; ++kc) {
    s16x8 af = *(const s16x8*)(UcR + (16 * w + fr) * 72 + kc * 32 + fq * 8);
#pragma unroll
    for (int c = 0; c < 4; ++c) {
      int j = 16 * c + fr;
      s16x8 bb = *(const s16x8*)((char*)T1T + (((j << 7) + (kc << 6) + (fq << 4)) ^ ((j & 7) << 4)));
      a2[c] = __builtin_amdgcn_mfma_f32_16x16x32_bf16(af, bb, a2[c], 0, 0, 0);
    }
  }
#pragma unroll
  for (int c = 0; c < 4; ++c) {
    int gj = 16 * c + fr;
#pragma unroll
    for (int r = 0; r < 4; ++r)
      Uo[(64 + 16 * w + fq * 4 + r) * 128 + gj] = f2bf(a2[c][r]);
  }
}

// ================= u256build: B256 = Uc128 @ (Lneg_BA @ Ua128); grid (4,32) =================
__global__ __launch_bounds__(256) void u256build(const unsigned short* __restrict__ Lb,
    const unsigned short* __restrict__ U128, unsigned short* __restrict__ B256) {
  int qb = blockIdx.x, bh = blockIdx.y;
  int t = threadIdx.x, w = t >> 6, l = t & 63, fr = l & 15, fq = l >> 4;
  int s0 = qb * 256;
  size_t base = (size_t)bh << 20;
  const unsigned short* Ua = U128 + (((size_t)(bh * 8 + 2 * qb)) << 14);
  const unsigned short* Uc = U128 + (((size_t)(bh * 8 + 2 * qb + 1)) << 14);
  unsigned short* out = B256 + (((size_t)(bh * 4 + qb)) << 14);
  __shared__ unsigned short UaT[16384];
  __shared__ unsigned short T1T[16384];
#pragma unroll
  for (int i = 0; i < 8; ++i) {
    int cid = t + i * 256;
    int s = cid >> 4, ch = cid & 15;
    u16x8 v = *(const u16x8*)(Ua + s * 128 + ch * 8);
#pragma unroll
    for (int e = 0; e < 8; ++e) {
      int j = ch * 8 + e;
      int byt = ((j << 8) + (s << 1)) ^ ((j & 15) << 4);
      *(unsigned short*)((char*)UaT + byt) = v[e];
    }
  }
  __syncthreads();
  f32x4 a1[2][8];
#pragma unroll
  for (int m = 0; m < 2; ++m)
#pragma unroll
    for (int c = 0; c < 8; ++c) a1[m][c] = (f32x4){0.f, 0.f, 0.f, 0.f};
#pragma unroll
  for (int kc = 0; kc < 4; ++kc) {
    s16x8 af[2];
#pragma unroll
    for (int m = 0; m < 2; ++m)
      af[m] = *(const s16x8*)(Lb + base + ((size_t)(s0 + 128 + 32 * w + 16 * m + fr) << 10) + s0 + kc * 32 + fq * 8);
#pragma unroll
    for (int c = 0; c < 8; ++c) {
      int j = 16 * c + fr;
      s16x8 bb = *(const s16x8*)((char*)UaT + (((j << 8) + (kc << 6) + (fq << 4)) ^ ((j & 15) << 4)));
#pragma unroll
      for (int m = 0; m < 2; ++m)
        a1[m][c] = __builtin_amdgcn_mfma_f32_16x16x32_bf16(af[m], bb, a1[m][c], 0, 0, 0);
    }
  }
#pragma unroll
  for (int m = 0; m < 2; ++m) {
#pragma unroll
    for (int c = 0; c < 8; ++c) {
      int col = 16 * c + fr;
      int row0 = 32 * w + 16 * m + fq * 4;
      u16x4 pk;
#pragma unroll
      for (int r = 0; r < 4; ++r) pk[r] = f2bf(a1[m][c][r]);
      int byt = ((col << 8) + (row0 << 1)) ^ ((col & 15) << 4);
      *(u16x4*)((char*)T1T + byt) = pk;
    }
  }
  __syncthreads();
  f32x4 a2[2][8];
#pragma unroll
  for (int m = 0; m < 2; ++m)
#pragma unroll
    for (int c = 0; c < 8; ++c) a2[m][c] = (f32x4){0.f, 0.f, 0.f, 0.f};
#pragma unroll
  for (int kc = 0; kc < 4; ++kc) {
    s16x8 af[2];
#pragma unroll
    for (int m = 0; m < 2; ++m)
      af[m] = *(const s16x8*)(Uc + (32 * w + 16 * m + fr) * 128 + kc * 32 + fq * 8);
#pragma unroll
    for (int c = 0; c < 8; ++c) {
      int j = 16 * c + fr;
      s16x8 bb = *(const s16x8*)((char*)T1T + (((j << 8) + (kc << 6) + (fq << 4)) ^ ((j & 15) << 4)));
#pragma unroll
      for (int m = 0; m < 2; ++m)
        a2[m][c] = __builtin_amdgcn_mfma_f32_16x16x32_bf16(af[m], bb, a2[m][c], 0, 0, 0);
    }
  }
#pragma unroll
  for (int m = 0; m < 2; ++m) {
#pragma unroll
    for (int c = 0; c < 8; ++c) {
      int col = 16 * c + fr;
#pragma unroll
      for (int r = 0; r < 4; ++r)
        out[(32 * w + 16 * m + fq * 4 + r) * 128 + col] = f2bf(a2[m][c][r]);
    }
  }
}

// ================= solve256: 256-row band step; pipelined band GEMM + 3-piece apply =================
__global__ __launch_bounds__(256) void solve256(const unsigned short* __restrict__ WN,
    const unsigned short* __restrict__ Kk, const unsigned short* __restrict__ Lb,
    const unsigned short* __restrict__ U128, const unsigned short* __restrict__ B256,
    unsigned short* __restrict__ CT, int ib) {
  int jb = blockIdx.x, bh = blockIdx.y;
  int b = bh >> 4, h = bh & 15;
  int t = threadIdx.x, w = t >> 6, l = t & 63, fr = l & 15, fq = l >> 4;
  int s0 = ib * 256, j0 = jb * 128;
  size_t base = (size_t)bh << 20;
  __shared__ unsigned short sh[49152];      // 96KB: As[2] @0/16384, Bs[2] @32768/40960; rT aliases @0
  unsigned short* rT = sh;
  const unsigned short* Wb_ = WN + ((size_t)b << 20) + h * 64;
  const unsigned short* Kb_ = Kk + ((size_t)b << 20) + h * 64;

  f32x4 acc[4][8];
#pragma unroll
  for (int m = 0; m < 4; ++m)
#pragma unroll
    for (int c = 0; c < 8; ++c) acc[m][c] = (f32x4){0.f, 0.f, 0.f, 0.f};
  int nst = 1 + 4 * ib - 2 * jb; if (nst < 1) nst = 1;

#define STAGE_SV(buf, stp) {                                            \
  int rb = 2 * jb + (stp) - 1;                                          \
  _Pragma("unroll")                                                     \
  for (int i = 0; i < 8; ++i) {                                         \
    int cid = t + i * 256;                                              \
    int row = cid >> 3, ch = cid & 7;                                   \
    int chs = ch ^ (row & 7);                                           \
    const unsigned short* ga = ((stp) == 0)                             \
      ? Wb_ + ((size_t)(s0 + row) << 10) + chs * 8                      \
      : Lb + base + ((size_t)(s0 + row) << 10) + rb * 64 + chs * 8;     \
    glds16(ga, (char*)(sh + (buf) * 16384) + cid * 16);                 \
  }                                                                     \
  _Pragma("unroll")                                                     \
  for (int i = 0; i < 4; ++i) {                                         \
    int cid = t + i * 256;                                              \
    int row = cid >> 3, ch = cid & 7;                                   \
    int chs = ch ^ (row & 7);                                           \
    const unsigned short* gb = ((stp) == 0)                             \
      ? Kb_ + ((size_t)(j0 + row) << 10) + chs * 8                      \
      : CT + base + ((size_t)(j0 + row) << 10) + rb * 64 + chs * 8;     \
    glds16(gb, (char*)(sh + 32768 + (buf) * 8192) + cid * 16);          \
  } }

  STAGE_SV(0, 0);
  pipe_drain_barrier();
  int cur = 0;
  for (int st = 0; st < nst; ++st) {
    if (st + 1 < nst) STAGE_SV(cur ^ 1, st + 1);
    const char* Ab = (const char*)(sh + cur * 16384);
    const char* Bb = (const char*)(sh + 32768 + cur * 8192);
    __builtin_amdgcn_s_setprio(1);
#pragma unroll
    for (int kh = 0; kh < 2; ++kh) {
      s16x8 af[4], bfv[8];
#pragma unroll
      for (int m = 0; m < 4; ++m) {
        int ra = 64 * w + 16 * m + fr;
        af[m] = *(const s16x8*)(Ab + (((ra << 7) + (kh << 6) + (fq << 4)) ^ ((ra & 7) << 4)));
      }
#pragma unroll
      for (int c = 0; c < 8; ++c) {
        int rb2 = 16 * c + fr;
        bfv[c] = *(const s16x8*)(Bb + (((rb2 << 7) + (kh << 6) + (fq << 4)) ^ ((rb2 & 7) << 4)));
      }
#pragma unroll
      for (int m = 0; m < 4; ++m)
#pragma unroll
        for (int c = 0; c < 8; ++c)
          acc[m][c] = __builtin_amdgcn_mfma_f32_16x16x32_bf16(af[m], bfv[c], acc[m][c], 0, 0, 0);
    }
    __builtin_amdgcn_s_setprio(0);
    pipe_drain_barrier();
    cur ^= 1;
  }
#undef STAGE_SV
  // write rectT [j][s] (512B rows, XOR (j&15)<<4), mask j >= s
#pragma unroll
  for (int m = 0; m < 4; ++m) {
#pragma unroll
    for (int c = 0; c < 8; ++c) {
      int sl0 = 64 * w + 16 * m + fq * 4;
      int jl = 16 * c + fr;
      u16x4 pk;
#pragma unroll
      for (int r = 0; r < 4; ++r) {
        float v = acc[m][c][r];
        if (j0 + jl >= s0 + sl0 + r) v = 0.f;
        pk[r] = f2bf(v);
      }
      int byt = ((jl << 9) + (sl0 << 1)) ^ ((jl & 15) << 4);
      *(u16x4*)((char*)rT + byt) = pk;
    }
  }
  __syncthreads();
  const unsigned short* Ua = U128 + (((size_t)(bh * 8 + 2 * ib)) << 14);
  const unsigned short* Uc = U128 + (((size_t)(bh * 8 + 2 * ib + 1)) << 14);
  const unsigned short* Bm = B256 + (((size_t)(bh * 4 + ib)) << 14);
#pragma unroll
  for (int m = 0; m < 4; ++m)
#pragma unroll
    for (int c = 0; c < 8; ++c) acc[m][c] = (f32x4){0.f, 0.f, 0.f, 0.f};
  int nkc = (w < 2) ? 4 : 8;
  for (int kc = 0; kc < nkc; ++kc) {
    const unsigned short* src; int arow;
    if (w < 2) { src = Ua; arow = 64 * w; }
    else { src = (kc < 4) ? Bm : Uc; arow = 64 * (w - 2); }
    s16x8 uf[4];
#pragma unroll
    for (int m = 0; m < 4; ++m)
      uf[m] = *(const s16x8*)(src + (arow + 16 * m + fr) * 128 + (kc & 3) * 32 + fq * 8);
#pragma unroll
    for (int c = 0; c < 8; ++c) {
      int jl = 16 * c + fr;
      s16x8 bb = *(const s16x8*)((char*)rT + (((jl << 9) + (kc << 6) + (fq << 4)) ^ ((jl & 15) << 4)));
#pragma unroll
      for (int m = 0; m < 4; ++m)
        acc[m][c] = __builtin_amdgcn_mfma_f32_16x16x32_bf16(uf[m], bb, acc[m][c], 0, 0, 0);
    }
  }
#pragma unroll
  for (int m = 0; m < 4; ++m) {
#pragma unroll
    for (int c = 0; c < 8; ++c) {
      int jl = 16 * c + fr;
      int sb = 64 * w + 16 * m + fq * 4;
      u16x4 pk;
#pragma unroll
      for (int r = 0; r < 4; ++r) pk[r] = f2bf(acc[m][c][r]);
      *(u16x4*)(CT + base + ((size_t)(j0 + jl) << 10) + s0 + sb) = pk;
    }
  }
}

// ================= pv: online-softmax + P @ V; sorted 1D grid (512) =================
__global__ __launch_bounds__(256) void pv_kernel(const unsigned short* __restrict__ S,
    const unsigned short* __restrict__ VT, const float* __restrict__ Fc,
    unsigned short* __restrict__ Ob) {
  int idx = blockIdx.x;
  int bh = idx & 31, rank = idx >> 5;
  int tb = 15 - rank;
  int b = bh >> 4, h = bh & 15;
  int t0 = tb * 64;
  int t = threadIdx.x, w = t >> 6, l = t & 63, fr = l & 15, fq = l >> 4;
  __shared__ unsigned short Pl[64 * 64];
  __shared__ float mrow[64], lrow[64], crow[64];
  if (t < 64) { mrow[t] = -1e30f; lrow[t] = 0.f; }
  size_t base = (size_t)bh << 20;
  f32x4 acc[4];
#pragma unroll
  for (int c = 0; c < 4; ++c) acc[c] = (f32x4){0.f,0.f,0.f,0.f};
  for (int jb = 0; jb <= tb; ++jb) {
    int j0 = jb * 64;
    __syncthreads();
    float vals[2][8], tmax[2];
#pragma unroll
    for (int i = 0; i < 2; ++i) {
      int cid = t + i * 256;
      int row = cid >> 3, ch = cid & 7;
      int grow = t0 + row;
      u16x8 sv = *(const u16x8*)(S + base + ((size_t)grow << 10) + j0 + ch * 8);
      float4 f0 = *(const float4*)(Fc + bh * 1024 + j0 + ch * 8);
      float4 f1 = *(const float4*)(Fc + bh * 1024 + j0 + ch * 8 + 4);
      float tm = -1e30f;
#pragma unroll
      for (int e = 0; e < 8; ++e) {
        float fc = e < 4 ? ((const float*)&f0)[e] : ((const float*)&f1)[e - 4];
        float v = bf2f(sv[e]) * SM_SCALE - fc;
        if (jb == tb && ch * 8 + e > row) v = -1e30f;
        vals[i][e] = v; tm = fmaxf(tm, v);
      }
      tm = fmaxf(tm, __shfl_xor(tm, 1));
      tm = fmaxf(tm, __shfl_xor(tm, 2));
      tm = fmaxf(tm, __shfl_xor(tm, 4));
      tmax[i] = tm;
    }
    if ((t & 7) == 0) {
#pragma unroll
      for (int i = 0; i < 2; ++i) {
        int row = (t >> 3) + i * 32;
        float mo = mrow[row];
        float mn = fmaxf(mo, tmax[i]);
        float sc = __expf(mo - mn);
        crow[row] = sc; mrow[row] = mn;
        lrow[row] *= sc;
      }
    }
    __syncthreads();
    float ps[2];
#pragma unroll
    for (int i = 0; i < 2; ++i) {
      int cid = t + i * 256;
      int row = cid >> 3, ch = cid & 7;
      float mn = mrow[row];
      u16x8 pv;
      float psum = 0.f;
#pragma unroll
      for (int e = 0; e < 8; ++e) {
        float p = __expf(vals[i][e] - mn);
        psum += p; pv[e] = f2bf(p);
      }
      int byt = ((row << 7) + (ch << 4)) ^ ((row & 7) << 4);
      *(u16x8*)((char*)Pl + byt) = pv;
      psum += __shfl_xor(psum, 1);
      psum += __shfl_xor(psum, 2);
      psum += __shfl_xor(psum, 4);
      ps[i] = psum;
    }
    if ((t & 7) == 0) {
      lrow[t >> 3] += ps[0];
      lrow[(t >> 3) + 32] += ps[1];
    }
    __syncthreads();
    float cr[4];
#pragma unroll
    for (int r = 0; r < 4; ++r) cr[r] = crow[16 * w + fq * 4 + r];
#pragma unroll
    for (int c = 0; c < 4; ++c)
#pragma unroll
      for (int r = 0; r < 4; ++r) acc[c][r] *= cr[r];
#pragma unroll
    for (int kh = 0; kh < 2; ++kh) {
      int ra = 16 * w + fr;
      s16x8 a = *(const s16x8*)((char*)Pl + (((ra << 7) + (kh << 6) + (fq << 4)) ^ ((ra & 7) << 4)));
#pragma unroll
      for (int c = 0; c < 4; ++c) {
        s16x8 bb = *(const s16x8*)(VT + ((size_t)bh * 64 + 16 * c + fr) * 1024 + j0 + kh * 32 + fq * 8);
        acc[c] = __builtin_amdgcn_mfma_f32_16x16x32_bf16(a, bb, acc[c], 0, 0, 0);
      }
    }
  }
  __syncthreads();
  float inv[4];
#pragma unroll
  for (int r = 0; r < 4; ++r) inv[r] = 1.f / lrow[16 * w + fq * 4 + r];
#pragma unroll
  for (int c = 0; c < 4; ++c) {
#pragma unroll
    for (int r = 0; r < 4; ++r) {
      int grow = t0 + 16 * w + fq * 4 + r;
      Ob[((size_t)(b * 1024) + grow) * 1024 + h * 64 + 16 * c + fr] = f2bf(acc[c][r] * inv[r]);
    }
  }
}

extern "C" void kernel_launch(void* const* d_in, const int* in_sizes, int n_in,
                              void* d_out, int out_size, void* d_ws, size_t ws_size,
                              hipStream_t stream) {
  const float* x    = (const float*)d_in[0];
  const float* Wq   = (const float*)d_in[1];
  const float* Wk   = (const float*)d_in[2];
  const float* Wv   = (const float*)d_in[3];
  const float* Wo   = (const float*)d_in[4];
  const float* Ww1  = (const float*)d_in[5];
  const float* Ww2  = (const float*)d_in[6];
  const float* Wb   = (const float*)d_in[7];
  const float* Wf   = (const float*)d_in[8];
  const float* delta= (const float*)d_in[9];

  char* ws = (char*)d_ws;
  unsigned short* xb   = (unsigned short*)(ws + OFF_XB);
  unsigned short* WqT  = (unsigned short*)(ws + OFF_WQT);
  unsigned short* WkT  = (unsigned short*)(ws + OFF_WKT);
  unsigned short* WvT  = (unsigned short*)(ws + OFF_WVT);
  unsigned short* WoT  = (unsigned short*)(ws + OFF_WOT);
  unsigned short* W1c  = (unsigned short*)(ws + OFF_W1C);
  unsigned short* W2T  = (unsigned short*)(ws + OFF_W2T);
  float*          Beta = (float*)(ws + OFF_BETA);
  unsigned short* Q16  = (unsigned short*)(ws + OFF_Q16);
  unsigned short* K16  = (unsigned short*)(ws + OFF_K16);
  unsigned short* VT   = (unsigned short*)(ws + OFF_VT);
  unsigned short* WN16 = (unsigned short*)(ws + OFF_WN16);
  unsigned short* WB16 = (unsigned short*)(ws + OFF_WB16);
  unsigned short* WNF16= (unsigned short*)(ws + OFF_WNF);
  unsigned short* ObB  = (unsigned short*)(ws + OFF_OB);
  unsigned short* BFT  = (unsigned short*)(ws + OFF_BFT);
  float*          Fc   = (float*)(ws + OFF_FC);
  unsigned short* Lbuf = (unsigned short*)(ws + OFF_L);
  unsigned short* Sbuf = (unsigned short*)(ws + OFF_L);
  unsigned short* CT   = (unsigned short*)(ws + OFF_CT);
  unsigned short* Gbuf = (unsigned short*)(ws + OFF_G);
  float*          BL   = (float*)(ws + OFF_BL);
  unsigned short* U128 = (unsigned short*)(ws + OFF_U128);
  unsigned short* B256 = (unsigned short*)(ws + OFF_B256);

  dim3 blk(256);
  // prep (all transposes + casts + BFT 128-row)
  prep_all<<<2160, blk, 0, stream>>>(Wq, Wk, Wv, Wo, Ww1, Ww2, x, Wb, Wf,
                                     WqT, WkT, WvT, WoT, W1c, W2T, xb, BFT);
  // WfusedT = W2T @ W1c^T (rank-64 fold; lives in WN16 region until wnorm2)
  gemm_nt<0><<<dim3(16,16), blk, 0, stream>>>(W2T, W1c, WN16, 1024, 1024, 64);
  // Q, K, VT, WNF, BL in one 528-block launch (2-phase pipelined)
  proj_big<<<528, blk, 0, stream>>>(xb, WqT, WkT, WvT, WN16, BFT,
                                    Q16, K16, VT, WNF16, BL);
  // beta/logsigmoid/cumsum fused
  bgfc<<<32, blk, 0, stream>>>(BL, delta, Beta, Fc);
  wnorm2<<<2048, blk, 0, stream>>>(WNF16, Beta, WN16, WB16);
  // L and G (both stored NEGATED)
  pairLG<<<dim3(36 * 32), blk, 0, stream>>>(WN16, Q16, WB16, Lbuf, Gbuf);
  // triangular solve: fused inverses -> 256 off-diag piece -> 4 band steps
  invbuild<<<dim3(8,32), blk, 0, stream>>>(Lbuf, U128);
  u256build<<<dim3(4,32), blk, 0, stream>>>(Lbuf, U128, B256);
  for (int ib = 0; ib < 4; ++ib)
    solve256<<<dim3(2 * ib + 2, 32), blk, 0, stream>>>(WN16, K16, Lbuf, U128, B256, CT, ib);
  // S = QK^T + Gneg C (sorted band grid; reuses L region; pipelined)
  score128s<<<dim3(36 * 32), blk, 0, stream>>>(Q16, K16, Gbuf, CT, Sbuf);
  // online softmax + PV
  pv_kernel<<<dim3(512), blk, 0, stream>>>(Sbuf, VT, Fc, ObB);
  // output projection (f32 out; pipelined)
  gemm_nt<1><<<dim3(16,32), blk, 0, stream>>>(ObB, WoT, d_out, 2048, 1024, 1024);
}

// Round 12
// 290.457 us; speedup vs baseline: 14.0395x; 1.0240x over previous
//
#include <hip/hip_runtime.h>
#include <hip/hip_bf16.h>

#define DEV static __device__ __forceinline__

constexpr float SM_SCALE = 0.125f;   // hd^-0.5, hd=64

typedef __attribute__((ext_vector_type(8))) short s16x8;
typedef __attribute__((ext_vector_type(8))) unsigned short u16x8;
typedef __attribute__((ext_vector_type(4))) unsigned short u16x4;
typedef __attribute__((ext_vector_type(4))) float f32x4;

DEV float bf2f(unsigned short u) {
  union { unsigned int i; float f; } v; v.i = ((unsigned int)u) << 16; return v.f;
}
DEV unsigned short f2bf(float f) {
  union { float f; unsigned int i; } v; v.f = f;
  unsigned int r = v.i + 0x7fffu + ((v.i >> 16) & 1u);
  return (unsigned short)(r >> 16);
}
DEV void tri_unrank(int r, int& k, int& i) {
  k = (int)((sqrtf(8.f * r + 1.f) - 1.f) * 0.5f);
  while (k * (k + 1) / 2 > r) --k;
  while ((k + 1) * (k + 2) / 2 <= r) ++k;
  i = r - k * (k + 1) / 2;
}
// async global->LDS, 16B per lane; dest must be wave-linear (base + lane*16)
DEV void glds16(const void* g, void* l) {
  __builtin_amdgcn_global_load_lds(
      (const __attribute__((address_space(1))) void*)g,
      (__attribute__((address_space(3))) void*)l, 16, 0, 0);
}
DEV void pipe_drain_barrier() {
  asm volatile("s_waitcnt vmcnt(0)" ::: "memory");
  __builtin_amdgcn_s_barrier();
}

// ---------- workspace layout (bytes) ----------
constexpr size_t OFF_XB   = 0;                       // 4MB xb bf16 [2048][1024]
constexpr size_t OFF_WQT  = 4194304;                 // 2MB
constexpr size_t OFF_WKT  = 6291456;                 // 2MB
constexpr size_t OFF_WVT  = 8388608;
constexpr size_t OFF_WOT  = 10485760;
constexpr size_t OFF_W1C  = 12582912;                // 128KB bf16 Ww1 cast (1024x64)
constexpr size_t OFF_W2T  = 12713984;                // 128KB
constexpr size_t OFF_BETA = 12582912;                // reuse W1C after wfuse
constexpr size_t OFF_Q16  = 12845056;                // 4MB bf16 2048x1024
constexpr size_t OFF_K16  = 17039360;                // 4MB
constexpr size_t OFF_VT   = 21233664;                // 4MB  VT[b][64h*d][1024n]
constexpr size_t OFF_WN16 = 25427968;                // 4MB; holds WfusedT until wnorm2
constexpr size_t OFF_WB16 = 29622272;                // 4MB
constexpr size_t OFF_WNF  = 33816576;                // 4MB (reused as Ob)
constexpr size_t OFF_OB   = 33816576;
constexpr size_t OFF_BFT  = 38010880;                // 256KB bf16 (128x1024)
constexpr size_t OFF_FC   = 38273024;                // 128KB
constexpr size_t OFF_L    = 38404096;                // 64MB, stores -L (reused as S)
constexpr size_t OFF_CT   = 105512960;               // 64MB
constexpr size_t OFF_G    = 172621824;               // 64MB, stores -G
constexpr size_t OFF_BL   = 239730688;               // 512KB f32 2048x64
constexpr size_t OFF_U128 = 244187136;               // 8MB bf16 [32][8][128][128]
constexpr size_t OFF_B256 = 252575744;               // 4MB bf16 [32][4][128][128]

// ================= fused prep: transposes + casts + BFT(128 rows); grid 2160 =================
__global__ __launch_bounds__(256) void prep_all(
    const float* __restrict__ W0, const float* __restrict__ W1,
    const float* __restrict__ W2, const float* __restrict__ W3,
    const float* __restrict__ Ww1, const float* __restrict__ Ww2,
    const float* __restrict__ x, const float* __restrict__ Wb,
    const float* __restrict__ Wf,
    unsigned short* __restrict__ D0, unsigned short* __restrict__ D1,
    unsigned short* __restrict__ D2, unsigned short* __restrict__ D3,
    unsigned short* __restrict__ W1c, unsigned short* __restrict__ W2T,
    unsigned short* __restrict__ xb, unsigned short* __restrict__ BFT) {
  int bidx = blockIdx.x;
  int t = threadIdx.x;
  if (bidx >= 2096) {                      // BFT build (64 blocks, 128x1024)
    int e0 = ((bidx - 2096) * 256 + t) * 8;
    int j = e0 >> 10, i0 = e0 & 1023;
    u16x8 o;
#pragma unroll
    for (int e = 0; e < 8; ++e) {
      int i = i0 + e;
      float v = 0.f;
      if (j < 16) v = Wb[i * 16 + j];
      else if (j < 32) v = Wf[i * 16 + (j - 16)];
      o[e] = f2bf(v);
    }
    *(u16x8*)(BFT + e0) = o;
    return;
  }
  if (bidx >= 2064) {                      // W1 cast (32 blocks)
    int i = ((bidx - 2064) * 256 + t) * 8;
    float4 a = *(const float4*)(Ww1 + i);
    float4 b = *(const float4*)(Ww1 + i + 4);
    u16x8 o;
    o[0] = f2bf(a.x); o[1] = f2bf(a.y); o[2] = f2bf(a.z); o[3] = f2bf(a.w);
    o[4] = f2bf(b.x); o[5] = f2bf(b.y); o[6] = f2bf(b.z); o[7] = f2bf(b.w);
    *(u16x8*)(W1c + i) = o;
    return;
  }
  if (bidx >= 1040) {                      // x cast (1024 blocks)
    int i = ((bidx - 1040) * 256 + t) * 8;
    float4 a = *(const float4*)(x + i);
    float4 b = *(const float4*)(x + i + 4);
    u16x8 o;
    o[0] = f2bf(a.x); o[1] = f2bf(a.y); o[2] = f2bf(a.z); o[3] = f2bf(a.w);
    o[4] = f2bf(b.x); o[5] = f2bf(b.y); o[6] = f2bf(b.z); o[7] = f2bf(b.w);
    *(u16x8*)(xb + i) = o;
    return;
  }
  const float* src; unsigned short* dst; int R, C, c0, r0;
  if (bidx >= 1024) {                      // W2T transpose (16 blocks)
    src = Ww2; dst = W2T; R = 64; C = 1024;
    c0 = (bidx - 1024) * 64; r0 = 0;
  } else {
    int z = bidx >> 8, xy = bidx & 255;
    src = z == 0 ? W0 : z == 1 ? W1 : z == 2 ? W2 : W3;
    dst = z == 0 ? D0 : z == 1 ? D1 : z == 2 ? D2 : D3;
    R = 1024; C = 1024;
    c0 = (xy & 15) * 64; r0 = (xy >> 4) * 64;
  }
  __shared__ float tile[64 * 65];
#pragma unroll
  for (int i = 0; i < 16; ++i) {
    int lin = t + i * 256; int r = lin >> 6, c = lin & 63;
    tile[r * 65 + c] = src[(size_t)(r0 + r) * C + c0 + c];
  }
  __syncthreads();
#pragma unroll
  for (int i = 0; i < 16; ++i) {
    int lin = t + i * 256; int c = lin >> 6, r = lin & 63;
    dst[(size_t)(c0 + c) * R + r0 + r] = f2bf(tile[r * 65 + c]);
  }
}

// beta + log_sigmoid + cumsum fused; grid 32 (bh)
__global__ __launch_bounds__(256) void bgfc(const float* __restrict__ BL,
    const float* __restrict__ delta, float* __restrict__ Beta, float* __restrict__ Fc) {
  int bh = blockIdx.x;
  int b = bh >> 4, h = bh & 15;
  int t = threadIdx.x;
  __shared__ float buf[1024];
  __shared__ float tsum[256];
  float dh = delta[h];
#pragma unroll
  for (int i = 0; i < 4; ++i) {
    int n = t + i * 256;
    int row = (b << 10) + n;
    float braw = BL[row * 64 + h];
    Beta[row * 16 + h] = 2.f / (1.f + __expf(-braw));
    float lraw = BL[row * 64 + 16 + h] + dh;
    buf[n] = (lraw >= 0.f) ? -log1pf(__expf(-lraw)) : (lraw - log1pf(__expf(lraw)));
  }
  __syncthreads();
  float loc[4]; float run = 0.f;
#pragma unroll
  for (int i = 0; i < 4; ++i) { run += buf[t * 4 + i]; loc[i] = run; }
  tsum[t] = run;
  __syncthreads();
  for (int off = 1; off < 256; off <<= 1) {
    float add = (t >= off) ? tsum[t - off] : 0.f;
    __syncthreads();
    tsum[t] += add;
    __syncthreads();
  }
  float excl = tsum[t] - run;
#pragma unroll
  for (int i = 0; i < 4; ++i) Fc[bh * 1024 + t * 4 + i] = excl + loc[i];
}

// ================= mega projection: Q,K + VT + WNF + BL, 528 blocks; 2-phase pipeline =================
__global__ __launch_bounds__(256) void proj_big(const unsigned short* __restrict__ xb,
    const unsigned short* __restrict__ WqT, const unsigned short* __restrict__ WkT,
    const unsigned short* __restrict__ WvT, const unsigned short* __restrict__ WfT,
    const unsigned short* __restrict__ BFT,
    unsigned short* __restrict__ Q16, unsigned short* __restrict__ K16,
    unsigned short* __restrict__ VT, unsigned short* __restrict__ WNF,
    float* __restrict__ BL) {
  int idx = blockIdx.x;
  const unsigned short *A, *BT; unsigned short* out = nullptr; int m0, n0;
  int mode = 0;
  if (idx < 256) {
    int my = idx >> 4, nx = idx & 15;
    m0 = my * 128; A = xb;
    if (nx < 8) { BT = WqT; out = Q16; n0 = nx * 128; }
    else { BT = WkT; out = K16; n0 = (nx - 8) * 128; }
  } else if (idx < 384) {
    int r = idx - 256; int bz = r >> 6; int rem = r & 63;
    m0 = (rem >> 3) * 128; n0 = (rem & 7) * 128;
    A = WvT; BT = xb + ((size_t)bz << 20); out = VT + ((size_t)bz << 20);
  } else if (idx < 512) {
    int r2 = idx - 384;
    m0 = (r2 >> 3) * 128; n0 = (r2 & 7) * 128;
    A = xb; BT = WfT; out = WNF;
  } else {
    m0 = (idx - 512) * 128; n0 = 0;
    A = xb; BT = BFT; mode = 1;
  }
  int t = threadIdx.x;
  int w = t >> 6, l = t & 63;
  int wr = w >> 1, wc = w & 1;
  int fr = l & 15, fq = l >> 4;
  __shared__ unsigned short As[2 * 8192];
  __shared__ unsigned short Bs[2 * 8192];
  f32x4 acc[4][4];
#pragma unroll
  for (int m = 0; m < 4; ++m)
#pragma unroll
    for (int c = 0; c < 4; ++c) acc[m][c] = (f32x4){0.f, 0.f, 0.f, 0.f};

#define STAGE_PB(buf, k0) {                                             \
  _Pragma("unroll")                                                     \
  for (int i = 0; i < 4; ++i) {                                         \
    int cid = t + i * 256;                                              \
    int row = cid >> 3, ch = cid & 7;                                   \
    int chs = ch ^ (row & 7);                                           \
    glds16(A + (size_t)(m0 + row) * 1024 + (k0) + chs * 8, (char*)(As + (buf) * 8192) + cid * 16); \
    glds16(BT + (size_t)(n0 + row) * 1024 + (k0) + chs * 8, (char*)(Bs + (buf) * 8192) + cid * 16); \
  } }

  STAGE_PB(0, 0);
  pipe_drain_barrier();
  int cur = 0;
  for (int kt = 0; kt < 16; ++kt) {
    if (kt < 15) STAGE_PB(cur ^ 1, (kt + 1) * 64);
    const char* Ab = (const char*)(As + cur * 8192);
    const char* Bb = (const char*)(Bs + cur * 8192);
    __builtin_amdgcn_s_setprio(1);
#pragma unroll
    for (int kh = 0; kh < 2; ++kh) {
      s16x8 af[4], bfv[4];
#pragma unroll
      for (int m = 0; m < 4; ++m) {
        int ra = wr * 64 + 16 * m + fr;
        af[m] = *(const s16x8*)(Ab + (((ra << 7) + (kh << 6) + (fq << 4)) ^ ((ra & 7) << 4)));
      }
#pragma unroll
      for (int c = 0; c < 4; ++c) {
        int rb = wc * 64 + 16 * c + fr;
        bfv[c] = *(const s16x8*)(Bb + (((rb << 7) + (kh << 6) + (fq << 4)) ^ ((rb & 7) << 4)));
      }
#pragma unroll
      for (int m = 0; m < 4; ++m)
#pragma unroll
        for (int c = 0; c < 4; ++c)
          acc[m][c] = __builtin_amdgcn_mfma_f32_16x16x32_bf16(af[m], bfv[c], acc[m][c], 0, 0, 0);
    }
    __builtin_amdgcn_s_setprio(0);
    pipe_drain_barrier();
    cur ^= 1;
  }
#undef STAGE_PB
#pragma unroll
  for (int m = 0; m < 4; ++m) {
#pragma unroll
    for (int c = 0; c < 4; ++c) {
      int col = n0 + wc * 64 + 16 * c + fr;
#pragma unroll
      for (int r = 0; r < 4; ++r) {
        int grow = m0 + wr * 64 + 16 * m + fq * 4 + r;
        if (mode == 0) out[(size_t)grow * 1024 + col] = f2bf(acc[m][c][r]);
        else if (col < 64) BL[(size_t)grow * 64 + col] = acc[m][c][r];
      }
    }
  }
}

// ================= 64-tile bf16 NT GEMM; 2-phase pipeline =================
template<int F32OUT>
__global__ __launch_bounds__(256) void gemm_nt(const unsigned short* __restrict__ A,
    const unsigned short* __restrict__ BT, void* __restrict__ out,
    int M, int N, int K) {
  __shared__ unsigned short As[2 * 4096];
  __shared__ unsigned short Bs[2 * 4096];
  int m0 = blockIdx.y * 64, n0 = blockIdx.x * 64;
  int t = threadIdx.x;
  int w = t >> 6, l = t & 63, fr = l & 15;
  int koB = (l >> 4) * 16;
  f32x4 acc[4];
#pragma unroll
  for (int c = 0; c < 4; ++c) acc[c] = (f32x4){0.f, 0.f, 0.f, 0.f};

#define STAGE_G(buf, k0) {                                              \
  _Pragma("unroll")                                                     \
  for (int i = 0; i < 2; ++i) {                                         \
    int cid = t + i * 256;                                              \
    int row = cid >> 3, ch = cid & 7;                                   \
    int chs = ch ^ (row & 7);                                           \
    glds16(A + (size_t)(m0 + row) * K + (k0) + chs * 8, (char*)(As + (buf) * 4096) + cid * 16); \
    glds16(BT + (size_t)(n0 + row) * K + (k0) + chs * 8, (char*)(Bs + (buf) * 4096) + cid * 16); \
  } }

  int nt = K >> 6;
  STAGE_G(0, 0);
  pipe_drain_barrier();
  int cur = 0;
  for (int kt = 0; kt < nt; ++kt) {
    if (kt + 1 < nt) STAGE_G(cur ^ 1, (kt + 1) * 64);
    const char* Ab = (const char*)(As + cur * 4096);
    const char* Bb = (const char*)(Bs + cur * 4096);
    __builtin_amdgcn_s_setprio(1);
#pragma unroll
    for (int kh = 0; kh < 2; ++kh) {
      int ra = 16 * w + fr;
      s16x8 a = *(const s16x8*)(Ab + (((ra << 7) + (kh << 6) + koB) ^ ((ra & 7) << 4)));
#pragma unroll
      for (int c = 0; c < 4; ++c) {
        int rb = 16 * c + fr;
        s16x8 bb = *(const s16x8*)(Bb + (((rb << 7) + (kh << 6) + koB) ^ ((rb & 7) << 4)));
        acc[c] = __builtin_amdgcn_mfma_f32_16x16x32_bf16(a, bb, acc[c], 0, 0, 0);
      }
    }
    __builtin_amdgcn_s_setprio(0);
    pipe_drain_barrier();
    cur ^= 1;
  }
#undef STAGE_G
  int rbase = m0 + 16 * w + ((l >> 4) << 2);
#pragma unroll
  for (int c = 0; c < 4; ++c) {
    int col = n0 + 16 * c + fr;
#pragma unroll
    for (int r = 0; r < 4; ++r) {
      if (F32OUT) ((float*)out)[(size_t)(rbase + r) * N + col] = acc[c][r];
      else ((unsigned short*)out)[(size_t)(rbase + r) * N + col] = f2bf(acc[c][r]);
    }
  }
}

// ================= w normalize + beta-scale =================
__global__ __launch_bounds__(256) void wnorm2(const unsigned short* __restrict__ WNF,
    const float* __restrict__ Beta, unsigned short* __restrict__ WN,
    unsigned short* __restrict__ WB) {
  int row = blockIdx.x;
  int wave = threadIdx.x >> 6, lane = threadIdx.x & 63;
#pragma unroll
  for (int i = 0; i < 4; ++i) {
    int hh = wave * 4 + i;
    size_t idx = ((size_t)row << 10) + hh * 64 + lane;
    float v = bf2f(WNF[idx]);
    float ss = v * v;
#pragma unroll
    for (int off = 1; off < 64; off <<= 1) ss += __shfl_xor(ss, off);
    float wn = v * rsqrtf(ss + 1e-6f);
    WN[idx] = f2bf(wn);
    WB[idx] = f2bf(wn * Beta[row * 16 + hh]);
  }
}

// ================= pair fused: writes NEGATED L and G =================
__global__ __launch_bounds__(256) void pairLG(const unsigned short* __restrict__ WN,
    const unsigned short* __restrict__ Q, const unsigned short* __restrict__ WB,
    unsigned short* __restrict__ Lg, unsigned short* __restrict__ Gg) {
  int idx = blockIdx.x;
  int bh = idx & 31, r0r = idx >> 5;
  int tb2, jb2; tri_unrank(r0r, tb2, jb2);
  int b = bh >> 4, h = bh & 15;
  int m0 = tb2 * 128, n0 = jb2 * 128;
  int t = threadIdx.x;
  int w = t >> 6, l = t & 63;
  int wr = w >> 1, wc = w & 1;
  int fr = l & 15, fq = l >> 4;
  __shared__ unsigned short As[128 * 64];
  __shared__ unsigned short Bs[128 * 64];
  const unsigned short* WNb = WN + ((size_t)b << 20) + h * 64;
  const unsigned short* Qb  = Q + ((size_t)b << 20) + h * 64;
  const unsigned short* WBb = WB + ((size_t)b << 20) + h * 64;
  size_t base = (size_t)bh << 20;
#pragma unroll
  for (int i = 0; i < 4; ++i) {
    int cid = t + i * 256;
    int row = cid >> 3, ch = cid & 7;
    int chs = ch ^ (row & 7);
    glds16(WNb + ((size_t)(m0 + row) << 10) + chs * 8, (char*)As + cid * 16);
    glds16(WBb + ((size_t)(n0 + row) << 10) + chs * 8, (char*)Bs + cid * 16);
  }
  __syncthreads();
  for (int pass = 0; pass < 2; ++pass) {
    f32x4 acc[4][4];
#pragma unroll
    for (int m = 0; m < 4; ++m)
#pragma unroll
      for (int c = 0; c < 4; ++c) acc[m][c] = (f32x4){0.f, 0.f, 0.f, 0.f};
#pragma unroll
    for (int kh = 0; kh < 2; ++kh) {
      s16x8 af[4], bfv[4];
#pragma unroll
      for (int m = 0; m < 4; ++m) {
        int ra = wr * 64 + 16 * m + fr;
        af[m] = *(const s16x8*)((char*)As + (((ra << 7) + (kh << 6) + (fq << 4)) ^ ((ra & 7) << 4)));
      }
#pragma unroll
      for (int c = 0; c < 4; ++c) {
        int rb = wc * 64 + 16 * c + fr;
        bfv[c] = *(const s16x8*)((char*)Bs + (((rb << 7) + (kh << 6) + (fq << 4)) ^ ((rb & 7) << 4)));
      }
#pragma unroll
      for (int m = 0; m < 4; ++m)
#pragma unroll
        for (int c = 0; c < 4; ++c)
          acc[m][c] = __builtin_amdgcn_mfma_f32_16x16x32_bf16(af[m], bfv[c], acc[m][c], 0, 0, 0);
    }
    unsigned short* dst = pass ? Gg : Lg;
#pragma unroll
    for (int m = 0; m < 4; ++m) {
#pragma unroll
      for (int c = 0; c < 4; ++c) {
        int gj = n0 + wc * 64 + 16 * c + fr;
#pragma unroll
        for (int r = 0; r < 4; ++r) {
          int gi = m0 + wr * 64 + 16 * m + fq * 4 + r;
          bool keep = pass ? (gj <= gi) : (gj < gi);
          dst[base + ((size_t)gi << 10) + gj] = f2bf(keep ? -acc[m][c][r] : 0.f);
        }
      }
    }
    if (pass == 0) {
      __syncthreads();
#pragma unroll
      for (int i = 0; i < 4; ++i) {
        int cid = t + i * 256;
        int row = cid >> 3, ch = cid & 7;
        int chs = ch ^ (row & 7);
        glds16(Qb + ((size_t)(m0 + row) << 10) + chs * 8, (char*)As + cid * 16);
      }
      __syncthreads();
    }
  }
}

// ================= score: S = Q K^T + Gneg @ C, sorted 1D grid; 2-phase pipeline =================
__global__ __launch_bounds__(256) void score128s(const unsigned short* __restrict__ Q,
    const unsigned short* __restrict__ Kk, const unsigned short* __restrict__ G,
    const unsigned short* __restrict__ CT, unsigned short* __restrict__ Sg) {
  int idx = blockIdx.x;
  int bh = idx & 31, r0r = idx >> 5;
  int k, i; tri_unrank(r0r, k, i);
  int tb2 = (7 - k) + i, jb2 = i;
  int b = bh >> 4, h = bh & 15;
  int m0 = tb2 * 128, n0 = jb2 * 128;
  int t = threadIdx.x;
  int w = t >> 6, l = t & 63;
  int wr = w >> 1, wc = w & 1;
  int fr = l & 15, fq = l >> 4;
  __shared__ unsigned short As[2 * 8192];
  __shared__ unsigned short Bs[2 * 8192];
  size_t base = (size_t)bh << 20;
  const unsigned short* Qb_ = Q + ((size_t)b << 20) + h * 64;
  const unsigned short* Kb_ = Kk + ((size_t)b << 20) + h * 64;
  const unsigned short* Gb_ = G + base;
  const unsigned short* Cb_ = CT + base;
  int kbase = jb2 * 128;
  int nsteps = 1 + (tb2 - jb2 + 1) * 2;
  f32x4 acc[4][4];
#pragma unroll
  for (int m = 0; m < 4; ++m)
#pragma unroll
    for (int c = 0; c < 4; ++c) acc[m][c] = (f32x4){0.f, 0.f, 0.f, 0.f};

#define STAGE_SC(buf, stp) {                                            \
  const unsigned short* pa; const unsigned short* pb; int koff;         \
  if ((stp) == 0) { pa = Qb_; pb = Kb_; koff = 0; }                     \
  else { pa = Gb_; pb = Cb_; koff = kbase + ((stp) - 1) * 64; }         \
  _Pragma("unroll")                                                     \
  for (int i2 = 0; i2 < 4; ++i2) {                                      \
    int cid = t + i2 * 256;                                             \
    int row = cid >> 3, ch = cid & 7;                                   \
    int chs = ch ^ (row & 7);                                           \
    glds16(pa + ((size_t)(m0 + row) << 10) + koff + chs * 8, (char*)(As + (buf) * 8192) + cid * 16); \
    glds16(pb + ((size_t)(n0 + row) << 10) + koff + chs * 8, (char*)(Bs + (buf) * 8192) + cid * 16); \
  } }

  STAGE_SC(0, 0);
  pipe_drain_barrier();
  int cur = 0;
  for (int step = 0; step < nsteps; ++step) {
    if (step + 1 < nsteps) STAGE_SC(cur ^ 1, step + 1);
    const char* Ab = (const char*)(As + cur * 8192);
    const char* Bb = (const char*)(Bs + cur * 8192);
    __builtin_amdgcn_s_setprio(1);
#pragma unroll
    for (int kh = 0; kh < 2; ++kh) {
      s16x8 af[4], bfv[4];
#pragma unroll
      for (int m = 0; m < 4; ++m) {
        int ra = wr * 64 + 16 * m + fr;
        af[m] = *(const s16x8*)(Ab + (((ra << 7) + (kh << 6) + (fq << 4)) ^ ((ra & 7) << 4)));
      }
#pragma unroll
      for (int c = 0; c < 4; ++c) {
        int rb = wc * 64 + 16 * c + fr;
        bfv[c] = *(const s16x8*)(Bb + (((rb << 7) + (kh << 6) + (fq << 4)) ^ ((rb & 7) << 4)));
      }
#pragma unroll
      for (int m = 0; m < 4; ++m)
#pragma unroll
        for (int c = 0; c < 4; ++c)
          acc[m][c] = __builtin_amdgcn_mfma_f32_16x16x32_bf16(af[m], bfv[c], acc[m][c], 0, 0, 0);
    }
    __builtin_amdgcn_s_setprio(0);
    pipe_drain_barrier();
    cur ^= 1;
  }
#undef STAGE_SC
#pragma unroll
  for (int m = 0; m < 4; ++m) {
#pragma unroll
    for (int c = 0; c < 4; ++c) {
      int gj = n0 + wc * 64 + 16 * c + fr;
#pragma unroll
      for (int r = 0; r < 4; ++r) {
        int gi = m0 + wr * 64 + 16 * m + fq * 4 + r;
        Sg[base + ((size_t)gi << 10) + gj] = f2bf(acc[m][c][r]);
      }
    }
  }
}

// ================= invbuild: 2x inv64 + U128 assembly in one block; grid (8,32) =================
__global__ __launch_bounds__(256) void invbuild(const unsigned short* __restrict__ Lb,
    unsigned short* __restrict__ U128) {
  int ib = blockIdx.x, bh = blockIdx.y;
  int t = threadIdx.x, w = t >> 6, l = t & 63, fr = l & 15, fq = l >> 4;
  int s0 = ib * 128;
  size_t base = (size_t)bh << 20;
  unsigned short* Uo = U128 + (((size_t)(bh * 8 + ib)) << 14);
  __shared__ float LD[2][64 * 65];
  __shared__ unsigned short UaR[64 * 72];
  __shared__ unsigned short UcR[64 * 72];
  __shared__ unsigned short UaT[64 * 64];
  __shared__ unsigned short T1T[64 * 64];
#pragma unroll
  for (int i = 0; i < 32; ++i) {
    int lin = t + i * 256;
    int blk = lin >> 12, s = (lin >> 6) & 63, r = lin & 63;
    LD[blk][s * 65 + r] = -bf2f(Lb[base + ((size_t)(s0 + blk * 64 + s) << 10) + s0 + blk * 64 + r]);
  }
  __syncthreads();
  if (t < 128) {
    int blk = t >> 6, j = t & 63;
    const float* ld = LD[blk];
    float cc[64];
#pragma unroll
    for (int s = 0; s < 64; ++s) cc[s] = (s == j) ? 1.f : 0.f;
#pragma unroll
    for (int r = 0; r < 63; ++r) {
      float val = cc[r];
#pragma unroll
      for (int s = r + 1; s < 64; ++s) cc[s] -= ld[s * 65 + r] * val;
    }
    if (blk == 0) {
#pragma unroll
      for (int s = 0; s < 64; ++s) {
        unsigned short v = f2bf(cc[s]);
        UaR[s * 72 + j] = v;
        *(unsigned short*)((char*)UaT + (((j << 7) + (s << 1)) ^ ((j & 7) << 4))) = v;
      }
    } else {
#pragma unroll
      for (int s = 0; s < 64; ++s) UcR[s * 72 + j] = f2bf(cc[s]);
    }
  }
  __syncthreads();
#pragma unroll
  for (int i = 0; i < 8; ++i) {
    int cid = t + i * 256;
    int row = cid >> 4, ch = cid & 15;
    u16x8 v = {0, 0, 0, 0, 0, 0, 0, 0};
    if (row < 64) {
      if (ch < 8) {
#pragma unroll
        for (int e = 0; e < 8; ++e) v[e] = UaR[row * 72 + ch * 8 + e];
      }
      *(u16x8*)(Uo + row * 128 + ch * 8) = v;
    } else if (ch >= 8) {
#pragma unroll
      for (int e = 0; e < 8; ++e) v[e] = UcR[(row - 64) * 72 + (ch - 8) * 8 + e];
      *(u16x8*)(Uo + row * 128 + ch * 8) = v;
    }
  }
  f32x4 a1[4];
#pragma unroll
  for (int c = 0; c < 4; ++c) a1[c] = (f32x4){0.f, 0.f, 0.f, 0.f};
#pragma unroll
  for (int kc = 0; kc < 2; ++kc) {
    s16x8 af = *(const s16x8*)(Lb + base + ((size_t)(s0 + 64 + 16 * w + fr) << 10) + s0 + kc * 32 + fq * 8);
#pragma unroll
    for (int c = 0; c < 4; ++c) {
      int j = 16 * c + fr;
      s16x8 bb = *(const s16x8*)((char*)UaT + (((j << 7) + (kc << 6) + (fq << 4)) ^ ((j & 7) << 4)));
      a1[c] = __builtin_amdgcn_mfma_f32_16x16x32_bf16(af, bb, a1[c], 0, 0, 0);
    }
  }
#pragma unroll
  for (int c = 0; c < 4; ++c) {
    int gj = 16 * c + fr;
    int sb = 16 * w + fq * 4;
    u16x4 pk;
#pragma unroll
    for (int r = 0; r < 4; ++r) pk[r] = f2bf(a1[c][r]);
    *(u16x4*)((char*)T1T + (((gj << 7) + (sb << 1)) ^ ((gj & 7) << 4))) = pk;
  }
  __syncthreads();
  f32x4 a2[4];
#pragma unroll
  for (int c = 0; c < 4; ++c) a2[c] = (f32x4){0.f, 0.f, 0.f, 0.f};
#pragma unroll
  for (int kc = 0; kc < 2; ++kc) {
    s16x8 af = *(const s16x8*)(UcR + (16 * w + fr) * 72 + kc * 32 + fq * 8);
#pragma unroll
    for (int c = 0; c < 4; ++c) {
      int j = 16 * c + fr;
      s16x8 bb = *(const s16x8*)((char*)T1T + (((j << 7) + (kc << 6) + (fq << 4)) ^ ((j & 7) << 4)));
      a2[c] = __builtin_amdgcn_mfma_f32_16x16x32_bf16(af, bb, a2[c], 0, 0, 0);
    }
  }
#pragma unroll
  for (int c = 0; c < 4; ++c) {
    int gj = 16 * c + fr;
#pragma unroll
    for (int r = 0; r < 4; ++r)
      Uo[(64 + 16 * w + fq * 4 + r) * 128 + gj] = f2bf(a2[c][r]);
  }
}

// ================= u256build: B256 = Uc128 @ (Lneg_BA @ Ua128); grid (4,32) =================
__global__ __launch_bounds__(256) void u256build(const unsigned short* __restrict__ Lb,
    const unsigned short* __restrict__ U128, unsigned short* __restrict__ B256) {
  int qb = blockIdx.x, bh = blockIdx.y;
  int t = threadIdx.x, w = t >> 6, l = t & 63, fr = l & 15, fq = l >> 4;
  int s0 = qb * 256;
  size_t base = (size_t)bh << 20;
  const unsigned short* Ua = U128 + (((size_t)(bh * 8 + 2 * qb)) << 14);
  const unsigned short* Uc = U128 + (((size_t)(bh * 8 + 2 * qb + 1)) << 14);
  unsigned short* out = B256 + (((size_t)(bh * 4 + qb)) << 14);
  __shared__ unsigned short UaT[16384];
  __shared__ unsigned short T1T[16384];
#pragma unroll
  for (int i = 0; i < 8; ++i) {
    int cid = t + i * 256;
    int s = cid >> 4, ch = cid & 15;
    u16x8 v = *(const u16x8*)(Ua + s * 128 + ch * 8);
#pragma unroll
    for (int e = 0; e < 8; ++e) {
      int j = ch * 8 + e;
      int byt = ((j << 8) + (s << 1)) ^ ((j & 15) << 4);
      *(unsigned short*)((char*)UaT + byt) = v[e];
    }
  }
  __syncthreads();
  f32x4 a1[2][8];
#pragma unroll
  for (int m = 0; m < 2; ++m)
#pragma unroll
    for (int c = 0; c < 8; ++c) a1[m][c] = (f32x4){0.f, 0.f, 0.f, 0.f};
#pragma unroll
  for (int kc = 0; kc < 4; ++kc) {
    s16x8 af[2];
#pragma unroll
    for (int m = 0; m < 2; ++m)
      af[m] = *(const s16x8*)(Lb + base + ((size_t)(s0 + 128 + 32 * w + 16 * m + fr) << 10) + s0 + kc * 32 + fq * 8);
#pragma unroll
    for (int c = 0; c < 8; ++c) {
      int j = 16 * c + fr;
      s16x8 bb = *(const s16x8*)((char*)UaT + (((j << 8) + (kc << 6) + (fq << 4)) ^ ((j & 15) << 4)));
#pragma unroll
      for (int m = 0; m < 2; ++m)
        a1[m][c] = __builtin_amdgcn_mfma_f32_16x16x32_bf16(af[m], bb, a1[m][c], 0, 0, 0);
    }
  }
#pragma unroll
  for (int m = 0; m < 2; ++m) {
#pragma unroll
    for (int c = 0; c < 8; ++c) {
      int col = 16 * c + fr;
      int row0 = 32 * w + 16 * m + fq * 4;
      u16x4 pk;
#pragma unroll
      for (int r = 0; r < 4; ++r) pk[r] = f2bf(a1[m][c][r]);
      int byt = ((col << 8) + (row0 << 1)) ^ ((col & 15) << 4);
      *(u16x4*)((char*)T1T + byt) = pk;
    }
  }
  __syncthreads();
  f32x4 a2[2][8];
#pragma unroll
  for (int m = 0; m < 2; ++m)
#pragma unroll
    for (int c = 0; c < 8; ++c) a2[m][c] = (f32x4){0.f, 0.f, 0.f, 0.f};
#pragma unroll
  for (int kc = 0; kc < 4; ++kc) {
    s16x8 af[2];
#pragma unroll
    for (int m = 0; m < 2; ++m)
      af[m] = *(const s16x8*)(Uc + (32 * w + 16 * m + fr) * 128 + kc * 32 + fq * 8);
#pragma unroll
    for (int c = 0; c < 8; ++c) {
      int j = 16 * c + fr;
      s16x8 bb = *(const s16x8*)((char*)T1T + (((j << 8) + (kc << 6) + (fq << 4)) ^ ((j & 15) << 4)));
#pragma unroll
      for (int m = 0; m < 2; ++m)
        a2[m][c] = __builtin_amdgcn_mfma_f32_16x16x32_bf16(af[m], bb, a2[m][c], 0, 0, 0);
    }
  }
#pragma unroll
  for (int m = 0; m < 2; ++m) {
#pragma unroll
    for (int c = 0; c < 8; ++c) {
      int col = 16 * c + fr;
#pragma unroll
      for (int r = 0; r < 4; ++r)
        out[(32 * w + 16 * m + fq * 4 + r) * 128 + col] = f2bf(a2[m][c][r]);
    }
  }
}

// ================= solve256: 256-row band step; pipelined band GEMM + 3-piece apply =================
__global__ __launch_bounds__(256) void solve256(const unsigned short* __restrict__ WN,
    const unsigned short* __restrict__ Kk, const unsigned short* __restrict__ Lb,
    const unsigned short* __restrict__ U128, const unsigned short* __restrict__ B256,
    unsigned short* __restrict__ CT, int ib) {
  int jb = blockIdx.x, bh = blockIdx.y;
  int b = bh >> 4, h = bh & 15;
  int t = threadIdx.x, w = t >> 6, l = t & 63, fr = l & 15, fq = l >> 4;
  int s0 = ib * 256, j0 = jb * 128;
  size_t base = (size_t)bh << 20;
  __shared__ unsigned short sh[49152];      // 96KB: As[2] @0/16384, Bs[2] @32768/40960; rT aliases @0
  unsigned short* rT = sh;
  const unsigned short* Wb_ = WN + ((size_t)b << 20) + h * 64;
  const unsigned short* Kb_ = Kk + ((size_t)b << 20) + h * 64;

  f32x4 acc[4][8];
#pragma unroll
  for (int m = 0; m < 4; ++m)
#pragma unroll
    for (int c = 0; c < 8; ++c) acc[m][c] = (f32x4){0.f, 0.f, 0.f, 0.f};
  int nst = 1 + 4 * ib - 2 * jb; if (nst < 1) nst = 1;

#define STAGE_SV(buf, stp) {                                            \
  int rb = 2 * jb + (stp) - 1;                                          \
  _Pragma("unroll")                                                     \
  for (int i = 0; i < 8; ++i) {                                         \
    int cid = t + i * 256;                                              \
    int row = cid >> 3, ch = cid & 7;                                   \
    int chs = ch ^ (row & 7);                                           \
    const unsigned short* ga = ((stp) == 0)                             \
      ? Wb_ + ((size_t)(s0 + row) << 10) + chs * 8                      \
      : Lb + base + ((size_t)(s0 + row) << 10) + rb * 64 + chs * 8;     \
    glds16(ga, (char*)(sh + (buf) * 16384) + cid * 16);                 \
  }                                                                     \
  _Pragma("unroll")                                                     \
  for (int i = 0; i < 4; ++i) {                                         \
    int cid = t + i * 256;                                              \
    int row = cid >> 3, ch = cid & 7;                                   \
    int chs = ch ^ (row & 7);                                           \
    const unsigned short* gb = ((stp) == 0)                             \
      ? Kb_ + ((size_t)(j0 + row) << 10) + chs * 8                      \
      : CT + base + ((size_t)(j0 + row) << 10) + rb * 64 + chs * 8;     \
    glds16(gb, (char*)(sh + 32768 + (buf) * 8192) + cid * 16);          \
  } }

  STAGE_SV(0, 0);
  pipe_drain_barrier();
  int cur = 0;
  for (int st = 0; st < nst; ++st) {
    if (st + 1 < nst) STAGE_SV(cur ^ 1, st + 1);
    const char* Ab = (const char*)(sh + cur * 16384);
    const char* Bb = (const char*)(sh + 32768 + cur * 8192);
    __builtin_amdgcn_s_setprio(1);
#pragma unroll
    for (int kh = 0; kh < 2; ++kh) {
      s16x8 af[4], bfv[8];
#pragma unroll
      for (int m = 0; m < 4; ++m) {
        int ra = 64 * w + 16 * m + fr;
        af[m] = *(const s16x8*)(Ab + (((ra << 7) + (kh << 6) + (fq << 4)) ^ ((ra & 7) << 4)));
      }
#pragma unroll
      for (int c = 0; c < 8; ++c) {
        int rb2 = 16 * c + fr;
        bfv[c] = *(const s16x8*)(Bb + (((rb2 << 7) + (kh << 6) + (fq << 4)) ^ ((rb2 & 7) << 4)));
      }
#pragma unroll
      for (int m = 0; m < 4; ++m)
#pragma unroll
        for (int c = 0; c < 8; ++c)
          acc[m][c] = __builtin_amdgcn_mfma_f32_16x16x32_bf16(af[m], bfv[c], acc[m][c], 0, 0, 0);
    }
    __builtin_amdgcn_s_setprio(0);
    pipe_drain_barrier();
    cur ^= 1;
  }
#undef STAGE_SV
  // write rectT [j][s] (512B rows, XOR (j&15)<<4), mask j >= s
#pragma unroll
  for (int m = 0; m < 4; ++m) {
#pragma unroll
    for (int c = 0; c < 8; ++c) {
      int sl0 = 64 * w + 16 * m + fq * 4;
      int jl = 16 * c + fr;
      u16x4 pk;
#pragma unroll
      for (int r = 0; r < 4; ++r) {
        float v = acc[m][c][r];
        if (j0 + jl >= s0 + sl0 + r) v = 0.f;
        pk[r] = f2bf(v);
      }
      int byt = ((jl << 9) + (sl0 << 1)) ^ ((jl & 15) << 4);
      *(u16x4*)((char*)rT + byt) = pk;
    }
  }
  __syncthreads();
  const unsigned short* Ua = U128 + (((size_t)(bh * 8 + 2 * ib)) << 14);
  const unsigned short* Uc = U128 + (((size_t)(bh * 8 + 2 * ib + 1)) << 14);
  const unsigned short* Bm = B256 + (((size_t)(bh * 4 + ib)) << 14);
#pragma unroll
  for (int m = 0; m < 4; ++m)
#pragma unroll
    for (int c = 0; c < 8; ++c) acc[m][c] = (f32x4){0.f, 0.f, 0.f, 0.f};
  int nkc = (w < 2) ? 4 : 8;
  for (int kc = 0; kc < nkc; ++kc) {
    const unsigned short* src; int arow;
    if (w < 2) { src = Ua; arow = 64 * w; }
    else { src = (kc < 4) ? Bm : Uc; arow = 64 * (w - 2); }
    s16x8 uf[4];
#pragma unroll
    for (int m = 0; m < 4; ++m)
      uf[m] = *(const s16x8*)(src + (arow + 16 * m + fr) * 128 + (kc & 3) * 32 + fq * 8);
#pragma unroll
    for (int c = 0; c < 8; ++c) {
      int jl = 16 * c + fr;
      s16x8 bb = *(const s16x8*)((char*)rT + (((jl << 9) + (kc << 6) + (fq << 4)) ^ ((jl & 15) << 4)));
#pragma unroll
      for (int m = 0; m < 4; ++m)
        acc[m][c] = __builtin_amdgcn_mfma_f32_16x16x32_bf16(uf[m], bb, acc[m][c], 0, 0, 0);
    }
  }
#pragma unroll
  for (int m = 0; m < 4; ++m) {
#pragma unroll
    for (int c = 0; c < 8; ++c) {
      int jl = 16 * c + fr;
      int sb = 64 * w + 16 * m + fq * 4;
      u16x4 pk;
#pragma unroll
      for (int r = 0; r < 4; ++r) pk[r] = f2bf(acc[m][c][r]);
      *(u16x4*)(CT + base + ((size_t)(j0 + jl) << 10) + s0 + sb) = pk;
    }
  }
}

// ================= pv: online-softmax + P @ V; wave-independent (no barriers) =================
__global__ __launch_bounds__(256) void pv_kernel(const unsigned short* __restrict__ S,
    const unsigned short* __restrict__ VT, const float* __restrict__ Fc,
    unsigned short* __restrict__ Ob) {
  int idx = blockIdx.x;
  int bh = idx & 31, rank = idx >> 5;
  int tb = 15 - rank;
  int b = bh >> 4, h = bh & 15;
  int t0 = tb * 64;
  int t = threadIdx.x, w = t >> 6, l = t & 63, fr = l & 15, fq = l >> 4;
  int g = l >> 3, ch = l & 7;              // 8-lane row group / col chunk
  __shared__ unsigned short Pl[4][16 * 64];   // per-wave 2KB region
  size_t base = (size_t)bh << 20;
  // per-lane stats for the 2 rows this 8-lane group owns (rows g and g+8 of wave's 16)
  float m0 = -1e30f, m1 = -1e30f, l0 = 0.f, l1 = 0.f;
  f32x4 acc[4];
#pragma unroll
  for (int c = 0; c < 4; ++c) acc[c] = (f32x4){0.f,0.f,0.f,0.f};
  for (int jb = 0; jb <= tb; ++jb) {
    int j0 = jb * 64;
    float sc[2];
#pragma unroll
    for (int i = 0; i < 2; ++i) {
      int row16 = g + i * 8;               // 0..15 within wave's rows
      int row64 = 16 * w + row16;          // 0..63 within tile
      int grow = t0 + row64;
      u16x8 sv = *(const u16x8*)(S + base + ((size_t)grow << 10) + j0 + ch * 8);
      float4 f0 = *(const float4*)(Fc + bh * 1024 + j0 + ch * 8);
      float4 f1 = *(const float4*)(Fc + bh * 1024 + j0 + ch * 8 + 4);
      float vals[8];
      float tm = -1e30f;
#pragma unroll
      for (int e = 0; e < 8; ++e) {
        float fc = e < 4 ? ((const float*)&f0)[e] : ((const float*)&f1)[e - 4];
        float v = bf2f(sv[e]) * SM_SCALE - fc;
        if (jb == tb && ch * 8 + e > row64) v = -1e30f;
        vals[e] = v; tm = fmaxf(tm, v);
      }
      tm = fmaxf(tm, __shfl_xor(tm, 1));
      tm = fmaxf(tm, __shfl_xor(tm, 2));
      tm = fmaxf(tm, __shfl_xor(tm, 4));
      float mo = i ? m1 : m0;
      float mn = fmaxf(mo, tm);
      float s = __expf(mo - mn);
      u16x8 pv;
      float psum = 0.f;
#pragma unroll
      for (int e = 0; e < 8; ++e) {
        float p = __expf(vals[e] - mn);
        psum += p; pv[e] = f2bf(p);
      }
      int byt = ((row16 << 7) + (ch << 4)) ^ ((row16 & 7) << 4);
      *(u16x8*)((char*)Pl[w] + byt) = pv;
      psum += __shfl_xor(psum, 1);
      psum += __shfl_xor(psum, 2);
      psum += __shfl_xor(psum, 4);
      if (i) { m1 = mn; l1 = l1 * s + psum; } else { m0 = mn; l0 = l0 * s + psum; }
      sc[i] = s;
    }
    __builtin_amdgcn_wave_barrier();       // pin P writes before reads (wave-local)
    // rescale O: lane needs sc for rows fq*4+r; broadcast from owner group lane
    float cr[4];
#pragma unroll
    for (int r = 0; r < 4; ++r) {
      int rho = fq * 4 + r;                // 0..15
      int src = (rho & 7) * 8;
      float v0 = __shfl(sc[0], src);
      float v1 = __shfl(sc[1], src);
      cr[r] = (rho < 8) ? v0 : v1;
    }
#pragma unroll
    for (int c = 0; c < 4; ++c)
#pragma unroll
      for (int r = 0; r < 4; ++r) acc[c][r] *= cr[r];
#pragma unroll
    for (int kh = 0; kh < 2; ++kh) {
      s16x8 a = *(const s16x8*)((char*)Pl[w] + (((fr << 7) + (kh << 6) + (fq << 4)) ^ ((fr & 7) << 4)));
#pragma unroll
      for (int c = 0; c < 4; ++c) {
        s16x8 bb = *(const s16x8*)(VT + ((size_t)bh * 64 + 16 * c + fr) * 1024 + j0 + kh * 32 + fq * 8);
        acc[c] = __builtin_amdgcn_mfma_f32_16x16x32_bf16(a, bb, acc[c], 0, 0, 0);
      }
    }
    __builtin_amdgcn_wave_barrier();       // Pl consumed before next-iter overwrite
  }
  // final normalize: lane needs l for rows fq*4+r
  float inv[4];
#pragma unroll
  for (int r = 0; r < 4; ++r) {
    int rho = fq * 4 + r;
    int src = (rho & 7) * 8;
    float v0 = __shfl(l0, src);
    float v1 = __shfl(l1, src);
    inv[r] = 1.f / ((rho < 8) ? v0 : v1);
  }
#pragma unroll
  for (int c = 0; c < 4; ++c) {
#pragma unroll
    for (int r = 0; r < 4; ++r) {
      int grow = t0 + 16 * w + fq * 4 + r;
      Ob[((size_t)(b * 1024) + grow) * 1024 + h * 64 + 16 * c + fr] = f2bf(acc[c][r] * inv[r]);
    }
  }
}

extern "C" void kernel_launch(void* const* d_in, const int* in_sizes, int n_in,
                              void* d_out, int out_size, void* d_ws, size_t ws_size,
                              hipStream_t stream) {
  const float* x    = (const float*)d_in[0];
  const float* Wq   = (const float*)d_in[1];
  const float* Wk   = (const float*)d_in[2];
  const float* Wv   = (const float*)d_in[3];
  const float* Wo   = (const float*)d_in[4];
  const float* Ww1  = (const float*)d_in[5];
  const float* Ww2  = (const float*)d_in[6];
  const float* Wb   = (const float*)d_in[7];
  const float* Wf   = (const float*)d_in[8];
  const float* delta= (const float*)d_in[9];

  char* ws = (char*)d_ws;
  unsigned short* xb   = (unsigned short*)(ws + OFF_XB);
  unsigned short* WqT  = (unsigned short*)(ws + OFF_WQT);
  unsigned short* WkT  = (unsigned short*)(ws + OFF_WKT);
  unsigned short* WvT  = (unsigned short*)(ws + OFF_WVT);
  unsigned short* WoT  = (unsigned short*)(ws + OFF_WOT);
  unsigned short* W1c  = (unsigned short*)(ws + OFF_W1C);
  unsigned short* W2T  = (unsigned short*)(ws + OFF_W2T);
  float*          Beta = (float*)(ws + OFF_BETA);
  unsigned short* Q16  = (unsigned short*)(ws + OFF_Q16);
  unsigned short* K16  = (unsigned short*)(ws + OFF_K16);
  unsigned short* VT   = (unsigned short*)(ws + OFF_VT);
  unsigned short* WN16 = (unsigned short*)(ws + OFF_WN16);
  unsigned short* WB16 = (unsigned short*)(ws + OFF_WB16);
  unsigned short* WNF16= (unsigned short*)(ws + OFF_WNF);
  unsigned short* ObB  = (unsigned short*)(ws + OFF_OB);
  unsigned short* BFT  = (unsigned short*)(ws + OFF_BFT);
  float*          Fc   = (float*)(ws + OFF_FC);
  unsigned short* Lbuf = (unsigned short*)(ws + OFF_L);
  unsigned short* Sbuf = (unsigned short*)(ws + OFF_L);
  unsigned short* CT   = (unsigned short*)(ws + OFF_CT);
  unsigned short* Gbuf = (unsigned short*)(ws + OFF_G);
  float*          BL   = (float*)(ws + OFF_BL);
  unsigned short* U128 = (unsigned short*)(ws + OFF_U128);
  unsigned short* B256 = (unsigned short*)(ws + OFF_B256);

  dim3 blk(256);
  // prep (all transposes + casts + BFT 128-row)
  prep_all<<<2160, blk, 0, stream>>>(Wq, Wk, Wv, Wo, Ww1, Ww2, x, Wb, Wf,
                                     WqT, WkT, WvT, WoT, W1c, W2T, xb, BFT);
  // WfusedT = W2T @ W1c^T (rank-64 fold; lives in WN16 region until wnorm2)
  gemm_nt<0><<<dim3(16,16), blk, 0, stream>>>(W2T, W1c, WN16, 1024, 1024, 64);
  // Q, K, VT, WNF, BL in one 528-block launch (2-phase pipelined)
  proj_big<<<528, blk, 0, stream>>>(xb, WqT, WkT, WvT, WN16, BFT,
                                    Q16, K16, VT, WNF16, BL);
  // beta/logsigmoid/cumsum fused
  bgfc<<<32, blk, 0, stream>>>(BL, delta, Beta, Fc);
  wnorm2<<<2048, blk, 0, stream>>>(WNF16, Beta, WN16, WB16);
  // L and G (both stored NEGATED)
  pairLG<<<dim3(36 * 32), blk, 0, stream>>>(WN16, Q16, WB16, Lbuf, Gbuf);
  // triangular solve: fused inverses -> 256 off-diag piece -> 4 band steps
  invbuild<<<dim3(8,32), blk, 0, stream>>>(Lbuf, U128);
  u256build<<<dim3(4,32), blk, 0, stream>>>(Lbuf, U128, B256);
  for (int ib = 0; ib < 4; ++ib)
    solve256<<<dim3(2 * ib + 2, 32), blk, 0, stream>>>(WN16, K16, Lbuf, U128, B256, CT, ib);
  // S = QK^T + Gneg C (sorted band grid; reuses L region; pipelined)
  score128s<<<dim3(36 * 32), blk, 0, stream>>>(Q16, K16, Gbuf, CT, Sbuf);
  // online softmax + PV (wave-independent)
  pv_kernel<<<dim3(512), blk, 0, stream>>>(Sbuf, VT, Fc, ObB);
  // output projection (f32 out; pipelined)
  gemm_nt<1><<<dim3(16,32), blk, 0, stream>>>(ObB, WoT, d_out, 2048, 1024, 1024);
}

// Round 13
// 288.993 us; speedup vs baseline: 14.1106x; 1.0051x over previous
//
#include <hip/hip_runtime.h>
#include <hip/hip_bf16.h>

#define DEV static __device__ __forceinline__

constexpr float SM_SCALE = 0.125f;   // hd^-0.5, hd=64

typedef __attribute__((ext_vector_type(8))) short s16x8;
typedef __attribute__((ext_vector_type(8))) unsigned short u16x8;
typedef __attribute__((ext_vector_type(4))) unsigned short u16x4;
typedef __attribute__((ext_vector_type(4))) float f32x4;

DEV float bf2f(unsigned short u) {
  union { unsigned int i; float f; } v; v.i = ((unsigned int)u) << 16; return v.f;
}
DEV unsigned short f2bf(float f) {
  union { float f; unsigned int i; } v; v.f = f;
  unsigned int r = v.i + 0x7fffu + ((v.i >> 16) & 1u);
  return (unsigned short)(r >> 16);
}
DEV void tri_unrank(int r, int& k, int& i) {
  k = (int)((sqrtf(8.f * r + 1.f) - 1.f) * 0.5f);
  while (k * (k + 1) / 2 > r) --k;
  while ((k + 1) * (k + 2) / 2 <= r) ++k;
  i = r - k * (k + 1) / 2;
}
// async global->LDS, 16B per lane; dest must be wave-linear (base + lane*16)
DEV void glds16(const void* g, void* l) {
  __builtin_amdgcn_global_load_lds(
      (const __attribute__((address_space(1))) void*)g,
      (__attribute__((address_space(3))) void*)l, 16, 0, 0);
}
DEV void pipe_drain_barrier() {
  asm volatile("s_waitcnt vmcnt(0)" ::: "memory");
  __builtin_amdgcn_s_barrier();
}

// ---------- workspace layout (bytes) ----------
constexpr size_t OFF_XB   = 0;                       // 4MB xb bf16 [2048][1024]
constexpr size_t OFF_WQT  = 4194304;                 // 2MB
constexpr size_t OFF_WKT  = 6291456;                 // 2MB
constexpr size_t OFF_WVT  = 8388608;
constexpr size_t OFF_WOT  = 10485760;
constexpr size_t OFF_W1C  = 12582912;                // 128KB bf16 Ww1 cast (1024x64)
constexpr size_t OFF_W2T  = 12713984;                // 128KB
constexpr size_t OFF_BETA = 12582912;                // reuse W1C after wfuse
constexpr size_t OFF_Q16  = 12845056;                // 4MB bf16 2048x1024
constexpr size_t OFF_K16  = 17039360;                // 4MB
constexpr size_t OFF_VT   = 21233664;                // 4MB  VT[b][64h*d][1024n]
constexpr size_t OFF_WN16 = 25427968;                // 4MB; holds WfusedT until wnorm2
constexpr size_t OFF_WB16 = 29622272;                // 4MB
constexpr size_t OFF_WNF  = 33816576;                // 4MB (reused as Ob)
constexpr size_t OFF_OB   = 33816576;
constexpr size_t OFF_BFT  = 38010880;                // 256KB bf16 (128x1024)
constexpr size_t OFF_FC   = 38273024;                // 128KB
constexpr size_t OFF_L    = 38404096;                // 64MB, stores -L (reused as S)
constexpr size_t OFF_CT   = 105512960;               // 64MB
constexpr size_t OFF_G    = 172621824;               // 64MB, stores -G
constexpr size_t OFF_BL   = 239730688;               // 512KB f32 2048x64
constexpr size_t OFF_U128 = 244187136;               // 8MB bf16 [32][8][128][128]
constexpr size_t OFF_B256 = 252575744;               // 4MB bf16 [32][4][128][128]

// ================= fused prep: transposes + casts + BFT(128 rows); grid 2160 =================
__global__ __launch_bounds__(256) void prep_all(
    const float* __restrict__ W0, const float* __restrict__ W1,
    const float* __restrict__ W2, const float* __restrict__ W3,
    const float* __restrict__ Ww1, const float* __restrict__ Ww2,
    const float* __restrict__ x, const float* __restrict__ Wb,
    const float* __restrict__ Wf,
    unsigned short* __restrict__ D0, unsigned short* __restrict__ D1,
    unsigned short* __restrict__ D2, unsigned short* __restrict__ D3,
    unsigned short* __restrict__ W1c, unsigned short* __restrict__ W2T,
    unsigned short* __restrict__ xb, unsigned short* __restrict__ BFT) {
  int bidx = blockIdx.x;
  int t = threadIdx.x;
  if (bidx >= 2096) {                      // BFT build (64 blocks, 128x1024)
    int e0 = ((bidx - 2096) * 256 + t) * 8;
    int j = e0 >> 10, i0 = e0 & 1023;
    u16x8 o;
#pragma unroll
    for (int e = 0; e < 8; ++e) {
      int i = i0 + e;
      float v = 0.f;
      if (j < 16) v = Wb[i * 16 + j];
      else if (j < 32) v = Wf[i * 16 + (j - 16)];
      o[e] = f2bf(v);
    }
    *(u16x8*)(BFT + e0) = o;
    return;
  }
  if (bidx >= 2064) {                      // W1 cast (32 blocks)
    int i = ((bidx - 2064) * 256 + t) * 8;
    float4 a = *(const float4*)(Ww1 + i);
    float4 b = *(const float4*)(Ww1 + i + 4);
    u16x8 o;
    o[0] = f2bf(a.x); o[1] = f2bf(a.y); o[2] = f2bf(a.z); o[3] = f2bf(a.w);
    o[4] = f2bf(b.x); o[5] = f2bf(b.y); o[6] = f2bf(b.z); o[7] = f2bf(b.w);
    *(u16x8*)(W1c + i) = o;
    return;
  }
  if (bidx >= 1040) {                      // x cast (1024 blocks)
    int i = ((bidx - 1040) * 256 + t) * 8;
    float4 a = *(const float4*)(x + i);
    float4 b = *(const float4*)(x + i + 4);
    u16x8 o;
    o[0] = f2bf(a.x); o[1] = f2bf(a.y); o[2] = f2bf(a.z); o[3] = f2bf(a.w);
    o[4] = f2bf(b.x); o[5] = f2bf(b.y); o[6] = f2bf(b.z); o[7] = f2bf(b.w);
    *(u16x8*)(xb + i) = o;
    return;
  }
  const float* src; unsigned short* dst; int R, C, c0, r0;
  if (bidx >= 1024) {                      // W2T transpose (16 blocks)
    src = Ww2; dst = W2T; R = 64; C = 1024;
    c0 = (bidx - 1024) * 64; r0 = 0;
  } else {
    int z = bidx >> 8, xy = bidx & 255;
    src = z == 0 ? W0 : z == 1 ? W1 : z == 2 ? W2 : W3;
    dst = z == 0 ? D0 : z == 1 ? D1 : z == 2 ? D2 : D3;
    R = 1024; C = 1024;
    c0 = (xy & 15) * 64; r0 = (xy >> 4) * 64;
  }
  __shared__ float tile[64 * 65];
#pragma unroll
  for (int i = 0; i < 16; ++i) {
    int lin = t + i * 256; int r = lin >> 6, c = lin & 63;
    tile[r * 65 + c] = src[(size_t)(r0 + r) * C + c0 + c];
  }
  __syncthreads();
#pragma unroll
  for (int i = 0; i < 16; ++i) {
    int lin = t + i * 256; int c = lin >> 6, r = lin & 63;
    dst[(size_t)(c0 + c) * R + r0 + r] = f2bf(tile[r * 65 + c]);
  }
}

// beta + log_sigmoid + cumsum fused; grid 32 (bh)
__global__ __launch_bounds__(256) void bgfc(const float* __restrict__ BL,
    const float* __restrict__ delta, float* __restrict__ Beta, float* __restrict__ Fc) {
  int bh = blockIdx.x;
  int b = bh >> 4, h = bh & 15;
  int t = threadIdx.x;
  __shared__ float buf[1024];
  __shared__ float tsum[256];
  float dh = delta[h];
#pragma unroll
  for (int i = 0; i < 4; ++i) {
    int n = t + i * 256;
    int row = (b << 10) + n;
    float braw = BL[row * 64 + h];
    Beta[row * 16 + h] = 2.f / (1.f + __expf(-braw));
    float lraw = BL[row * 64 + 16 + h] + dh;
    buf[n] = (lraw >= 0.f) ? -log1pf(__expf(-lraw)) : (lraw - log1pf(__expf(lraw)));
  }
  __syncthreads();
  float loc[4]; float run = 0.f;
#pragma unroll
  for (int i = 0; i < 4; ++i) { run += buf[t * 4 + i]; loc[i] = run; }
  tsum[t] = run;
  __syncthreads();
  for (int off = 1; off < 256; off <<= 1) {
    float add = (t >= off) ? tsum[t - off] : 0.f;
    __syncthreads();
    tsum[t] += add;
    __syncthreads();
  }
  float excl = tsum[t] - run;
#pragma unroll
  for (int i = 0; i < 4; ++i) Fc[bh * 1024 + t * 4 + i] = excl + loc[i];
}

// ================= mega projection: Q,K + VT + WNF + BL; XCD-grouped 528 blocks =================
__global__ __launch_bounds__(256) void proj_big(const unsigned short* __restrict__ xb,
    const unsigned short* __restrict__ WqT, const unsigned short* __restrict__ WkT,
    const unsigned short* __restrict__ WvT, const unsigned short* __restrict__ WfT,
    const unsigned short* __restrict__ BFT,
    unsigned short* __restrict__ Q16, unsigned short* __restrict__ K16,
    unsigned short* __restrict__ VT, unsigned short* __restrict__ WNF,
    float* __restrict__ BL) {
  int sg = blockIdx.x;                       // 528 = 8 * 66 exactly
  int virt = (sg % 8) * 66 + (sg / 8);       // bijective chunked XCD swizzle
  const unsigned short *A, *BT; unsigned short* out = nullptr; int m0, n0;
  int mode = 0;
  if (virt < 256) {                          // Q/K: 16my x 16nx in 4x4 groups, 2x2 supergroups
    int g = virt >> 4, in = virt & 15;
    int ssb = g >> 2, gin = g & 3;
    int mb = (ssb >> 1) * 2 + (gin >> 1);
    int nb = (ssb & 1) * 2 + (gin & 1);
    int my = mb * 4 + (in >> 2);
    int nx = nb * 4 + (in & 3);
    m0 = my * 128; A = xb;
    if (nx < 8) { BT = WqT; out = Q16; n0 = nx * 128; }
    else { BT = WkT; out = K16; n0 = (nx - 8) * 128; }
  } else if (virt < 384) {                   // VT: per batch 8x8 in 4x4 groups
    int r = virt - 256; int bz = r >> 6; int rr = r & 63;
    int g = rr >> 4, in = rr & 15;
    int my = (g >> 1) * 4 + (in >> 2);
    int nx = (g & 1) * 4 + (in & 3);
    m0 = my * 128; n0 = nx * 128;
    A = WvT; BT = xb + ((size_t)bz << 20); out = VT + ((size_t)bz << 20);
  } else if (virt < 512) {                   // WNF: 16my x 8nx in 4x4 groups
    int r = virt - 384;
    int g = r >> 4, in = r & 15;
    int my = (g >> 1) * 4 + (in >> 2);
    int nx = (g & 1) * 4 + (in & 3);
    m0 = my * 128; n0 = nx * 128;
    A = xb; BT = WfT; out = WNF;
  } else {
    m0 = (virt - 512) * 128; n0 = 0;
    A = xb; BT = BFT; mode = 1;
  }
  int t = threadIdx.x;
  int w = t >> 6, l = t & 63;
  int wr = w >> 1, wc = w & 1;
  int fr = l & 15, fq = l >> 4;
  __shared__ unsigned short As[2 * 8192];
  __shared__ unsigned short Bs[2 * 8192];
  f32x4 acc[4][4];
#pragma unroll
  for (int m = 0; m < 4; ++m)
#pragma unroll
    for (int c = 0; c < 4; ++c) acc[m][c] = (f32x4){0.f, 0.f, 0.f, 0.f};

#define STAGE_PB(buf, k0) {                                             \
  _Pragma("unroll")                                                     \
  for (int i = 0; i < 4; ++i) {                                         \
    int cid = t + i * 256;                                              \
    int row = cid >> 3, ch = cid & 7;                                   \
    int chs = ch ^ (row & 7);                                           \
    glds16(A + (size_t)(m0 + row) * 1024 + (k0) + chs * 8, (char*)(As + (buf) * 8192) + cid * 16); \
    glds16(BT + (size_t)(n0 + row) * 1024 + (k0) + chs * 8, (char*)(Bs + (buf) * 8192) + cid * 16); \
  } }

  STAGE_PB(0, 0);
  pipe_drain_barrier();
  int cur = 0;
  for (int kt = 0; kt < 16; ++kt) {
    if (kt < 15) STAGE_PB(cur ^ 1, (kt + 1) * 64);
    const char* Ab = (const char*)(As + cur * 8192);
    const char* Bb = (const char*)(Bs + cur * 8192);
    __builtin_amdgcn_s_setprio(1);
#pragma unroll
    for (int kh = 0; kh < 2; ++kh) {
      s16x8 af[4], bfv[4];
#pragma unroll
      for (int m = 0; m < 4; ++m) {
        int ra = wr * 64 + 16 * m + fr;
        af[m] = *(const s16x8*)(Ab + (((ra << 7) + (kh << 6) + (fq << 4)) ^ ((ra & 7) << 4)));
      }
#pragma unroll
      for (int c = 0; c < 4; ++c) {
        int rb = wc * 64 + 16 * c + fr;
        bfv[c] = *(const s16x8*)(Bb + (((rb << 7) + (kh << 6) + (fq << 4)) ^ ((rb & 7) << 4)));
      }
#pragma unroll
      for (int m = 0; m < 4; ++m)
#pragma unroll
        for (int c = 0; c < 4; ++c)
          acc[m][c] = __builtin_amdgcn_mfma_f32_16x16x32_bf16(af[m], bfv[c], acc[m][c], 0, 0, 0);
    }
    __builtin_amdgcn_s_setprio(0);
    pipe_drain_barrier();
    cur ^= 1;
  }
#undef STAGE_PB
#pragma unroll
  for (int m = 0; m < 4; ++m) {
#pragma unroll
    for (int c = 0; c < 4; ++c) {
      int col = n0 + wc * 64 + 16 * c + fr;
#pragma unroll
      for (int r = 0; r < 4; ++r) {
        int grow = m0 + wr * 64 + 16 * m + fq * 4 + r;
        if (mode == 0) out[(size_t)grow * 1024 + col] = f2bf(acc[m][c][r]);
        else if (col < 64) BL[(size_t)grow * 64 + col] = acc[m][c][r];
      }
    }
  }
}

// ================= 64-tile bf16 NT GEMM; 2-phase pipeline =================
template<int F32OUT>
__global__ __launch_bounds__(256) void gemm_nt(const unsigned short* __restrict__ A,
    const unsigned short* __restrict__ BT, void* __restrict__ out,
    int M, int N, int K) {
  __shared__ unsigned short As[2 * 4096];
  __shared__ unsigned short Bs[2 * 4096];
  int m0 = blockIdx.y * 64, n0 = blockIdx.x * 64;
  int t = threadIdx.x;
  int w = t >> 6, l = t & 63, fr = l & 15;
  int koB = (l >> 4) * 16;
  f32x4 acc[4];
#pragma unroll
  for (int c = 0; c < 4; ++c) acc[c] = (f32x4){0.f, 0.f, 0.f, 0.f};

#define STAGE_G(buf, k0) {                                              \
  _Pragma("unroll")                                                     \
  for (int i = 0; i < 2; ++i) {                                         \
    int cid = t + i * 256;                                              \
    int row = cid >> 3, ch = cid & 7;                                   \
    int chs = ch ^ (row & 7);                                           \
    glds16(A + (size_t)(m0 + row) * K + (k0) + chs * 8, (char*)(As + (buf) * 4096) + cid * 16); \
    glds16(BT + (size_t)(n0 + row) * K + (k0) + chs * 8, (char*)(Bs + (buf) * 4096) + cid * 16); \
  } }

  int nt = K >> 6;
  STAGE_G(0, 0);
  pipe_drain_barrier();
  int cur = 0;
  for (int kt = 0; kt < nt; ++kt) {
    if (kt + 1 < nt) STAGE_G(cur ^ 1, (kt + 1) * 64);
    const char* Ab = (const char*)(As + cur * 4096);
    const char* Bb = (const char*)(Bs + cur * 4096);
    __builtin_amdgcn_s_setprio(1);
#pragma unroll
    for (int kh = 0; kh < 2; ++kh) {
      int ra = 16 * w + fr;
      s16x8 a = *(const s16x8*)(Ab + (((ra << 7) + (kh << 6) + koB) ^ ((ra & 7) << 4)));
#pragma unroll
      for (int c = 0; c < 4; ++c) {
        int rb = 16 * c + fr;
        s16x8 bb = *(const s16x8*)(Bb + (((rb << 7) + (kh << 6) + koB) ^ ((rb & 7) << 4)));
        acc[c] = __builtin_amdgcn_mfma_f32_16x16x32_bf16(a, bb, acc[c], 0, 0, 0);
      }
    }
    __builtin_amdgcn_s_setprio(0);
    pipe_drain_barrier();
    cur ^= 1;
  }
#undef STAGE_G
  int rbase = m0 + 16 * w + ((l >> 4) << 2);
#pragma unroll
  for (int c = 0; c < 4; ++c) {
    int col = n0 + 16 * c + fr;
#pragma unroll
    for (int r = 0; r < 4; ++r) {
      if (F32OUT) ((float*)out)[(size_t)(rbase + r) * N + col] = acc[c][r];
      else ((unsigned short*)out)[(size_t)(rbase + r) * N + col] = f2bf(acc[c][r]);
    }
  }
}

// ================= output projection: 64-tile, XCD-grouped 512 blocks, f32 out =================
__global__ __launch_bounds__(256) void gemm_outproj(const unsigned short* __restrict__ A,
    const unsigned short* __restrict__ BT, float* __restrict__ out) {
  int sg = blockIdx.x;                       // 512 = 8 * 64 exactly
  int virt = (sg & 7) * 64 + (sg >> 3);      // each XCD: one 8x8 panel group (2MB WS)
  int g = virt >> 6, in = virt & 63;
  int my = (g >> 1) * 8 + (in >> 3);         // 0..31
  int nx = (g & 1) * 8 + (in & 7);           // 0..15
  int m0 = my * 64, n0 = nx * 64;
  const int K = 1024, N = 1024;
  __shared__ unsigned short As[2 * 4096];
  __shared__ unsigned short Bs[2 * 4096];
  int t = threadIdx.x;
  int w = t >> 6, l = t & 63, fr = l & 15;
  int koB = (l >> 4) * 16;
  f32x4 acc[4];
#pragma unroll
  for (int c = 0; c < 4; ++c) acc[c] = (f32x4){0.f, 0.f, 0.f, 0.f};

#define STAGE_O(buf, k0) {                                              \
  _Pragma("unroll")                                                     \
  for (int i = 0; i < 2; ++i) {                                         \
    int cid = t + i * 256;                                              \
    int row = cid >> 3, ch = cid & 7;                                   \
    int chs = ch ^ (row & 7);                                           \
    glds16(A + (size_t)(m0 + row) * K + (k0) + chs * 8, (char*)(As + (buf) * 4096) + cid * 16); \
    glds16(BT + (size_t)(n0 + row) * K + (k0) + chs * 8, (char*)(Bs + (buf) * 4096) + cid * 16); \
  } }

  STAGE_O(0, 0);
  pipe_drain_barrier();
  int cur = 0;
  for (int kt = 0; kt < 16; ++kt) {
    if (kt + 1 < 16) STAGE_O(cur ^ 1, (kt + 1) * 64);
    const char* Ab = (const char*)(As + cur * 4096);
    const char* Bb = (const char*)(Bs + cur * 4096);
    __builtin_amdgcn_s_setprio(1);
#pragma unroll
    for (int kh = 0; kh < 2; ++kh) {
      int ra = 16 * w + fr;
      s16x8 a = *(const s16x8*)(Ab + (((ra << 7) + (kh << 6) + koB) ^ ((ra & 7) << 4)));
#pragma unroll
      for (int c = 0; c < 4; ++c) {
        int rb = 16 * c + fr;
        s16x8 bb = *(const s16x8*)(Bb + (((rb << 7) + (kh << 6) + koB) ^ ((rb & 7) << 4)));
        acc[c] = __builtin_amdgcn_mfma_f32_16x16x32_bf16(a, bb, acc[c], 0, 0, 0);
      }
    }
    __builtin_amdgcn_s_setprio(0);
    pipe_drain_barrier();
    cur ^= 1;
  }
#undef STAGE_O
  int rbase = m0 + 16 * w + ((l >> 4) << 2);
#pragma unroll
  for (int c = 0; c < 4; ++c) {
    int col = n0 + 16 * c + fr;
#pragma unroll
    for (int r = 0; r < 4; ++r)
      out[(size_t)(rbase + r) * N + col] = acc[c][r];
  }
}

// ================= w normalize + beta-scale =================
__global__ __launch_bounds__(256) void wnorm2(const unsigned short* __restrict__ WNF,
    const float* __restrict__ Beta, unsigned short* __restrict__ WN,
    unsigned short* __restrict__ WB) {
  int row = blockIdx.x;
  int wave = threadIdx.x >> 6, lane = threadIdx.x & 63;
#pragma unroll
  for (int i = 0; i < 4; ++i) {
    int hh = wave * 4 + i;
    size_t idx = ((size_t)row << 10) + hh * 64 + lane;
    float v = bf2f(WNF[idx]);
    float ss = v * v;
#pragma unroll
    for (int off = 1; off < 64; off <<= 1) ss += __shfl_xor(ss, off);
    float wn = v * rsqrtf(ss + 1e-6f);
    WN[idx] = f2bf(wn);
    WB[idx] = f2bf(wn * Beta[row * 16 + hh]);
  }
}

// ================= pair fused: writes NEGATED L and G =================
__global__ __launch_bounds__(256) void pairLG(const unsigned short* __restrict__ WN,
    const unsigned short* __restrict__ Q, const unsigned short* __restrict__ WB,
    unsigned short* __restrict__ Lg, unsigned short* __restrict__ Gg) {
  int idx = blockIdx.x;
  int bh = idx & 31, r0r = idx >> 5;
  int tb2, jb2; tri_unrank(r0r, tb2, jb2);
  int b = bh >> 4, h = bh & 15;
  int m0 = tb2 * 128, n0 = jb2 * 128;
  int t = threadIdx.x;
  int w = t >> 6, l = t & 63;
  int wr = w >> 1, wc = w & 1;
  int fr = l & 15, fq = l >> 4;
  __shared__ unsigned short As[128 * 64];
  __shared__ unsigned short Bs[128 * 64];
  const unsigned short* WNb = WN + ((size_t)b << 20) + h * 64;
  const unsigned short* Qb  = Q + ((size_t)b << 20) + h * 64;
  const unsigned short* WBb = WB + ((size_t)b << 20) + h * 64;
  size_t base = (size_t)bh << 20;
#pragma unroll
  for (int i = 0; i < 4; ++i) {
    int cid = t + i * 256;
    int row = cid >> 3, ch = cid & 7;
    int chs = ch ^ (row & 7);
    glds16(WNb + ((size_t)(m0 + row) << 10) + chs * 8, (char*)As + cid * 16);
    glds16(WBb + ((size_t)(n0 + row) << 10) + chs * 8, (char*)Bs + cid * 16);
  }
  __syncthreads();
  for (int pass = 0; pass < 2; ++pass) {
    f32x4 acc[4][4];
#pragma unroll
    for (int m = 0; m < 4; ++m)
#pragma unroll
      for (int c = 0; c < 4; ++c) acc[m][c] = (f32x4){0.f, 0.f, 0.f, 0.f};
#pragma unroll
    for (int kh = 0; kh < 2; ++kh) {
      s16x8 af[4], bfv[4];
#pragma unroll
      for (int m = 0; m < 4; ++m) {
        int ra = wr * 64 + 16 * m + fr;
        af[m] = *(const s16x8*)((char*)As + (((ra << 7) + (kh << 6) + (fq << 4)) ^ ((ra & 7) << 4)));
      }
#pragma unroll
      for (int c = 0; c < 4; ++c) {
        int rb = wc * 64 + 16 * c + fr;
        bfv[c] = *(const s16x8*)((char*)Bs + (((rb << 7) + (kh << 6) + (fq << 4)) ^ ((rb & 7) << 4)));
      }
#pragma unroll
      for (int m = 0; m < 4; ++m)
#pragma unroll
        for (int c = 0; c < 4; ++c)
          acc[m][c] = __builtin_amdgcn_mfma_f32_16x16x32_bf16(af[m], bfv[c], acc[m][c], 0, 0, 0);
    }
    unsigned short* dst = pass ? Gg : Lg;
#pragma unroll
    for (int m = 0; m < 4; ++m) {
#pragma unroll
      for (int c = 0; c < 4; ++c) {
        int gj = n0 + wc * 64 + 16 * c + fr;
#pragma unroll
        for (int r = 0; r < 4; ++r) {
          int gi = m0 + wr * 64 + 16 * m + fq * 4 + r;
          bool keep = pass ? (gj <= gi) : (gj < gi);
          dst[base + ((size_t)gi << 10) + gj] = f2bf(keep ? -acc[m][c][r] : 0.f);
        }
      }
    }
    if (pass == 0) {
      __syncthreads();
#pragma unroll
      for (int i = 0; i < 4; ++i) {
        int cid = t + i * 256;
        int row = cid >> 3, ch = cid & 7;
        int chs = ch ^ (row & 7);
        glds16(Qb + ((size_t)(m0 + row) << 10) + chs * 8, (char*)As + cid * 16);
      }
      __syncthreads();
    }
  }
}

// ================= score: S = Q K^T + Gneg @ C, sorted 1D grid; 2-phase pipeline =================
__global__ __launch_bounds__(256) void score128s(const unsigned short* __restrict__ Q,
    const unsigned short* __restrict__ Kk, const unsigned short* __restrict__ G,
    const unsigned short* __restrict__ CT, unsigned short* __restrict__ Sg) {
  int idx = blockIdx.x;
  int bh = idx & 31, r0r = idx >> 5;
  int k, i; tri_unrank(r0r, k, i);
  int tb2 = (7 - k) + i, jb2 = i;
  int b = bh >> 4, h = bh & 15;
  int m0 = tb2 * 128, n0 = jb2 * 128;
  int t = threadIdx.x;
  int w = t >> 6, l = t & 63;
  int wr = w >> 1, wc = w & 1;
  int fr = l & 15, fq = l >> 4;
  __shared__ unsigned short As[2 * 8192];
  __shared__ unsigned short Bs[2 * 8192];
  size_t base = (size_t)bh << 20;
  const unsigned short* Qb_ = Q + ((size_t)b << 20) + h * 64;
  const unsigned short* Kb_ = Kk + ((size_t)b << 20) + h * 64;
  const unsigned short* Gb_ = G + base;
  const unsigned short* Cb_ = CT + base;
  int kbase = jb2 * 128;
  int nsteps = 1 + (tb2 - jb2 + 1) * 2;
  f32x4 acc[4][4];
#pragma unroll
  for (int m = 0; m < 4; ++m)
#pragma unroll
    for (int c = 0; c < 4; ++c) acc[m][c] = (f32x4){0.f, 0.f, 0.f, 0.f};

#define STAGE_SC(buf, stp) {                                            \
  const unsigned short* pa; const unsigned short* pb; int koff;         \
  if ((stp) == 0) { pa = Qb_; pb = Kb_; koff = 0; }                     \
  else { pa = Gb_; pb = Cb_; koff = kbase + ((stp) - 1) * 64; }         \
  _Pragma("unroll")                                                     \
  for (int i2 = 0; i2 < 4; ++i2) {                                      \
    int cid = t + i2 * 256;                                             \
    int row = cid >> 3, ch = cid & 7;                                   \
    int chs = ch ^ (row & 7);                                           \
    glds16(pa + ((size_t)(m0 + row) << 10) + koff + chs * 8, (char*)(As + (buf) * 8192) + cid * 16); \
    glds16(pb + ((size_t)(n0 + row) << 10) + koff + chs * 8, (char*)(Bs + (buf) * 8192) + cid * 16); \
  } }

  STAGE_SC(0, 0);
  pipe_drain_barrier();
  int cur = 0;
  for (int step = 0; step < nsteps; ++step) {
    if (step + 1 < nsteps) STAGE_SC(cur ^ 1, step + 1);
    const char* Ab = (const char*)(As + cur * 8192);
    const char* Bb = (const char*)(Bs + cur * 8192);
    __builtin_amdgcn_s_setprio(1);
#pragma unroll
    for (int kh = 0; kh < 2; ++kh) {
      s16x8 af[4], bfv[4];
#pragma unroll
      for (int m = 0; m < 4; ++m) {
        int ra = wr * 64 + 16 * m + fr;
        af[m] = *(const s16x8*)(Ab + (((ra << 7) + (kh << 6) + (fq << 4)) ^ ((ra & 7) << 4)));
      }
#pragma unroll
      for (int c = 0; c < 4; ++c) {
        int rb = wc * 64 + 16 * c + fr;
        bfv[c] = *(const s16x8*)(Bb + (((rb << 7) + (kh << 6) + (fq << 4)) ^ ((rb & 7) << 4)));
      }
#pragma unroll
      for (int m = 0; m < 4; ++m)
#pragma unroll
        for (int c = 0; c < 4; ++c)
          acc[m][c] = __builtin_amdgcn_mfma_f32_16x16x32_bf16(af[m], bfv[c], acc[m][c], 0, 0, 0);
    }
    __builtin_amdgcn_s_setprio(0);
    pipe_drain_barrier();
    cur ^= 1;
  }
#undef STAGE_SC
#pragma unroll
  for (int m = 0; m < 4; ++m) {
#pragma unroll
    for (int c = 0; c < 4; ++c) {
      int gj = n0 + wc * 64 + 16 * c + fr;
#pragma unroll
      for (int r = 0; r < 4; ++r) {
        int gi = m0 + wr * 64 + 16 * m + fq * 4 + r;
        Sg[base + ((size_t)gi << 10) + gj] = f2bf(acc[m][c][r]);
      }
    }
  }
}

// ================= invbuild: 2x inv64 + U128 assembly in one block; grid (8,32) =================
__global__ __launch_bounds__(256) void invbuild(const unsigned short* __restrict__ Lb,
    unsigned short* __restrict__ U128) {
  int ib = blockIdx.x, bh = blockIdx.y;
  int t = threadIdx.x, w = t >> 6, l = t & 63, fr = l & 15, fq = l >> 4;
  int s0 = ib * 128;
  size_t base = (size_t)bh << 20;
  unsigned short* Uo = U128 + (((size_t)(bh * 8 + ib)) << 14);
  __shared__ float LD[2][64 * 65];
  __shared__ unsigned short UaR[64 * 72];
  __shared__ unsigned short UcR[64 * 72];
  __shared__ unsigned short UaT[64 * 64];
  __shared__ unsigned short T1T[64 * 64];
#pragma unroll
  for (int i = 0; i < 32; ++i) {
    int lin = t + i * 256;
    int blk = lin >> 12, s = (lin >> 6) & 63, r = lin & 63;
    LD[blk][s * 65 + r] = -bf2f(Lb[base + ((size_t)(s0 + blk * 64 + s) << 10) + s0 + blk * 64 + r]);
  }
  __syncthreads();
  if (t < 128) {
    int blk = t >> 6, j = t & 63;
    const float* ld = LD[blk];
    float cc[64];
#pragma unroll
    for (int s = 0; s < 64; ++s) cc[s] = (s == j) ? 1.f : 0.f;
#pragma unroll
    for (int r = 0; r < 63; ++r) {
      float val = cc[r];
#pragma unroll
      for (int s = r + 1; s < 64; ++s) cc[s] -= ld[s * 65 + r] * val;
    }
    if (blk == 0) {
#pragma unroll
      for (int s = 0; s < 64; ++s) {
        unsigned short v = f2bf(cc[s]);
        UaR[s * 72 + j] = v;
        *(unsigned short*)((char*)UaT + (((j << 7) + (s << 1)) ^ ((j & 7) << 4))) = v;
      }
    } else {
#pragma unroll
      for (int s = 0; s < 64; ++s) UcR[s * 72 + j] = f2bf(cc[s]);
    }
  }
  __syncthreads();
#pragma unroll
  for (int i = 0; i < 8; ++i) {
    int cid = t + i * 256;
    int row = cid >> 4, ch = cid & 15;
    u16x8 v = {0, 0, 0, 0, 0, 0, 0, 0};
    if (row < 64) {
      if (ch < 8) {
#pragma unroll
        for (int e = 0; e < 8; ++e) v[e] = UaR[row * 72 + ch * 8 + e];
      }
      *(u16x8*)(Uo + row * 128 + ch * 8) = v;
    } else if (ch >= 8) {
#pragma unroll
      for (int e = 0; e < 8; ++e) v[e] = UcR[(row - 64) * 72 + (ch - 8) * 8 + e];
      *(u16x8*)(Uo + row * 128 + ch * 8) = v;
    }
  }
  f32x4 a1[4];
#pragma unroll
  for (int c = 0; c < 4; ++c) a1[c] = (f32x4){0.f, 0.f, 0.f, 0.f};
#pragma unroll
  for (int kc = 0; kc < 2; ++kc) {
    s16x8 af = *(const s16x8*)(Lb + base + ((size_t)(s0 + 64 + 16 * w + fr) << 10) + s0 + kc * 32 + fq * 8);
#pragma unroll
    for (int c = 0; c < 4; ++c) {
      int j = 16 * c + fr;
      s16x8 bb = *(const s16x8*)((char*)UaT + (((j << 7) + (kc << 6) + (fq << 4)) ^ ((j & 7) << 4)));
      a1[c] = __builtin_amdgcn_mfma_f32_16x16x32_bf16(af, bb, a1[c], 0, 0, 0);
    }
  }
#pragma unroll
  for (int c = 0; c < 4; ++c) {
    int gj = 16 * c + fr;
    int sb = 16 * w + fq * 4;
    u16x4 pk;
#pragma unroll
    for (int r = 0; r < 4; ++r) pk[r] = f2bf(a1[c][r]);
    *(u16x4*)((char*)T1T + (((gj << 7) + (sb << 1)) ^ ((gj & 7) << 4))) = pk;
  }
  __syncthreads();
  f32x4 a2[4];
#pragma unroll
  for (int c = 0; c < 4; ++c) a2[c] = (f32x4){0.f, 0.f, 0.f, 0.f};
#pragma unroll
  for (int kc = 0; kc < 2; ++kc) {
    s16x8 af = *(const s16x8*)(UcR + (16 * w + fr) * 72 + kc * 32 + fq * 8);
#pragma unroll
    for (int c = 0; c < 4; ++c) {
      int j = 16 * c + fr;
      s16x8 bb = *(const s16x8*)((char*)T1T + (((j << 7) + (kc << 6) + (fq << 4)) ^ ((j & 7) << 4)));
      a2[c] = __builtin_amdgcn_mfma_f32_16x16x32_bf16(af, bb, a2[c], 0, 0, 0);
    }
  }
#pragma unroll
  for (int c = 0; c < 4; ++c) {
    int gj = 16 * c + fr;
#pragma unroll
    for (int r = 0; r < 4; ++r)
      Uo[(64 + 16 * w + fq * 4 + r) * 128 + gj] = f2bf(a2[c][r]);
  }
}

// ================= u256build: B256 = Uc128 @ (Lneg_BA @ Ua128); grid (4,32) =================
__global__ __launch_bounds__(256) void u256build(const unsigned short* __restrict__ Lb,
    const unsigned short* __restrict__ U128, unsigned short* __restrict__ B256) {
  int qb = blockIdx.x, bh = blockIdx.y;
  int t = threadIdx.x, w = t >> 6, l = t & 63, fr = l & 15, fq = l >> 4;
  int s0 = qb * 256;
  size_t base = (size_t)bh << 20;
  const unsigned short* Ua = U128 + (((size_t)(bh * 8 + 2 * qb)) << 14);
  const unsigned short* Uc = U128 + (((size_t)(bh * 8 + 2 * qb + 1)) << 14);
  unsigned short* out = B256 + (((size_t)(bh * 4 + qb)) << 14);
  __shared__ unsigned short UaT[16384];
  __shared__ unsigned short T1T[16384];
#pragma unroll
  for (int i = 0; i < 8; ++i) {
    int cid = t + i * 256;
    int s = cid >> 4, ch = cid & 15;
    u16x8 v = *(const u16x8*)(Ua + s * 128 + ch * 8);
#pragma unroll
    for (int e = 0; e < 8; ++e) {
      int j = ch * 8 + e;
      int byt = ((j << 8) + (s << 1)) ^ ((j & 15) << 4);
      *(unsigned short*)((char*)UaT + byt) = v[e];
    }
  }
  __syncthreads();
  f32x4 a1[2][8];
#pragma unroll
  for (int m = 0; m < 2; ++m)
#pragma unroll
    for (int c = 0; c < 8; ++c) a1[m][c] = (f32x4){0.f, 0.f, 0.f, 0.f};
#pragma unroll
  for (int kc = 0; kc < 4; ++kc) {
    s16x8 af[2];
#pragma unroll
    for (int m = 0; m < 2; ++m)
      af[m] = *(const s16x8*)(Lb + base + ((size_t)(s0 + 128 + 32 * w + 16 * m + fr) << 10) + s0 + kc * 32 + fq * 8);
#pragma unroll
    for (int c = 0; c < 8; ++c) {
      int j = 16 * c + fr;
      s16x8 bb = *(const s16x8*)((char*)UaT + (((j << 8) + (kc << 6) + (fq << 4)) ^ ((j & 15) << 4)));
#pragma unroll
      for (int m = 0; m < 2; ++m)
        a1[m][c] = __builtin_amdgcn_mfma_f32_16x16x32_bf16(af[m], bb, a1[m][c], 0, 0, 0);
    }
  }
#pragma unroll
  for (int m = 0; m < 2; ++m) {
#pragma unroll
    for (int c = 0; c < 8; ++c) {
      int col = 16 * c + fr;
      int row0 = 32 * w + 16 * m + fq * 4;
      u16x4 pk;
#pragma unroll
      for (int r = 0; r < 4; ++r) pk[r] = f2bf(a1[m][c][r]);
      int byt = ((col << 8) + (row0 << 1)) ^ ((col & 15) << 4);
      *(u16x4*)((char*)T1T + byt) = pk;
    }
  }
  __syncthreads();
  f32x4 a2[2][8];
#pragma unroll
  for (int m = 0; m < 2; ++m)
#pragma unroll
    for (int c = 0; c < 8; ++c) a2[m][c] = (f32x4){0.f, 0.f, 0.f, 0.f};
#pragma unroll
  for (int kc = 0; kc < 4; ++kc) {
    s16x8 af[2];
#pragma unroll
    for (int m = 0; m < 2; ++m)
      af[m] = *(const s16x8*)(Uc + (32 * w + 16 * m + fr) * 128 + kc * 32 + fq * 8);
#pragma unroll
    for (int c = 0; c < 8; ++c) {
      int j = 16 * c + fr;
      s16x8 bb = *(const s16x8*)((char*)T1T + (((j << 8) + (kc << 6) + (fq << 4)) ^ ((j & 15) << 4)));
#pragma unroll
      for (int m = 0; m < 2; ++m)
        a2[m][c] = __builtin_amdgcn_mfma_f32_16x16x32_bf16(af[m], bb, a2[m][c], 0, 0, 0);
    }
  }
#pragma unroll
  for (int m = 0; m < 2; ++m) {
#pragma unroll
    for (int c = 0; c < 8; ++c) {
      int col = 16 * c + fr;
#pragma unroll
      for (int r = 0; r < 4; ++r)
        out[(32 * w + 16 * m + fq * 4 + r) * 128 + col] = f2bf(a2[m][c][r]);
    }
  }
}

// ================= solve256: 256-row band step; pipelined band GEMM + 3-piece apply =================
__global__ __launch_bounds__(256) void solve256(const unsigned short* __restrict__ WN,
    const unsigned short* __restrict__ Kk, const unsigned short* __restrict__ Lb,
    const unsigned short* __restrict__ U128, const unsigned short* __restrict__ B256,
    unsigned short* __restrict__ CT, int ib) {
  int jb = blockIdx.x, bh = blockIdx.y;
  int b = bh >> 4, h = bh & 15;
  int t = threadIdx.x, w = t >> 6, l = t & 63, fr = l & 15, fq = l >> 4;
  int s0 = ib * 256, j0 = jb * 128;
  size_t base = (size_t)bh << 20;
  __shared__ unsigned short sh[49152];      // 96KB: As[2] @0/16384, Bs[2] @32768/40960; rT aliases @0
  unsigned short* rT = sh;
  const unsigned short* Wb_ = WN + ((size_t)b << 20) + h * 64;
  const unsigned short* Kb_ = Kk + ((size_t)b << 20) + h * 64;

  f32x4 acc[4][8];
#pragma unroll
  for (int m = 0; m < 4; ++m)
#pragma unroll
    for (int c = 0; c < 8; ++c) acc[m][c] = (f32x4){0.f, 0.f, 0.f, 0.f};
  int nst = 1 + 4 * ib - 2 * jb; if (nst < 1) nst = 1;

#define STAGE_SV(buf, stp) {                                            \
  int rb = 2 * jb + (stp) - 1;                                          \
  _Pragma("unroll")                                                     \
  for (int i = 0; i < 8; ++i) {                                         \
    int cid = t + i * 256;                                              \
    int row = cid >> 3, ch = cid & 7;                                   \
    int chs = ch ^ (row & 7);                                           \
    const unsigned short* ga = ((stp) == 0)                             \
      ? Wb_ + ((size_t)(s0 + row) << 10) + chs * 8                      \
      : Lb + base + ((size_t)(s0 + row) << 10) + rb * 64 + chs * 8;     \
    glds16(ga, (char*)(sh + (buf) * 16384) + cid * 16);                 \
  }                                                                     \
  _Pragma("unroll")                                                     \
  for (int i = 0; i < 4; ++i) {                                         \
    int cid = t + i * 256;                                              \
    int row = cid >> 3, ch = cid & 7;                                   \
    int chs = ch ^ (row & 7);                                           \
    const unsigned short* gb = ((stp) == 0)                             \
      ? Kb_ + ((size_t)(j0 + row) << 10) + chs * 8                      \
      : CT + base + ((size_t)(j0 + row) << 10) + rb * 64 + chs * 8;     \
    glds16(gb, (char*)(sh + 32768 + (buf) * 8192) + cid * 16);          \
  } }

  STAGE_SV(0, 0);
  pipe_drain_barrier();
  int cur = 0;
  for (int st = 0; st < nst; ++st) {
    if (st + 1 < nst) STAGE_SV(cur ^ 1, st + 1);
    const char* Ab = (const char*)(sh + cur * 16384);
    const char* Bb = (const char*)(sh + 32768 + cur * 8192);
    __builtin_amdgcn_s_setprio(1);
#pragma unroll
    for (int kh = 0; kh < 2; ++kh) {
      s16x8 af[4], bfv[8];
#pragma unroll
      for (int m = 0; m < 4; ++m) {
        int ra = 64 * w + 16 * m + fr;
        af[m] = *(const s16x8*)(Ab + (((ra << 7) + (kh << 6) + (fq << 4)) ^ ((ra & 7) << 4)));
      }
#pragma unroll
      for (int c = 0; c < 8; ++c) {
        int rb2 = 16 * c + fr;
        bfv[c] = *(const s16x8*)(Bb + (((rb2 << 7) + (kh << 6) + (fq << 4)) ^ ((rb2 & 7) << 4)));
      }
#pragma unroll
      for (int m = 0; m < 4; ++m)
#pragma unroll
        for (int c = 0; c < 8; ++c)
          acc[m][c] = __builtin_amdgcn_mfma_f32_16x16x32_bf16(af[m], bfv[c], acc[m][c], 0, 0, 0);
    }
    __builtin_amdgcn_s_setprio(0);
    pipe_drain_barrier();
    cur ^= 1;
  }
#undef STAGE_SV
  // write rectT [j][s] (512B rows, XOR (j&15)<<4), mask j >= s
#pragma unroll
  for (int m = 0; m < 4; ++m) {
#pragma unroll
    for (int c = 0; c < 8; ++c) {
      int sl0 = 64 * w + 16 * m + fq * 4;
      int jl = 16 * c + fr;
      u16x4 pk;
#pragma unroll
      for (int r = 0; r < 4; ++r) {
        float v = acc[m][c][r];
        if (j0 + jl >= s0 + sl0 + r) v = 0.f;
        pk[r] = f2bf(v);
      }
      int byt = ((jl << 9) + (sl0 << 1)) ^ ((jl & 15) << 4);
      *(u16x4*)((char*)rT + byt) = pk;
    }
  }
  __syncthreads();
  const unsigned short* Ua = U128 + (((size_t)(bh * 8 + 2 * ib)) << 14);
  const unsigned short* Uc = U128 + (((size_t)(bh * 8 + 2 * ib + 1)) << 14);
  const unsigned short* Bm = B256 + (((size_t)(bh * 4 + ib)) << 14);
#pragma unroll
  for (int m = 0; m < 4; ++m)
#pragma unroll
    for (int c = 0; c < 8; ++c) acc[m][c] = (f32x4){0.f, 0.f, 0.f, 0.f};
  int nkc = (w < 2) ? 4 : 8;
  for (int kc = 0; kc < nkc; ++kc) {
    const unsigned short* src; int arow;
    if (w < 2) { src = Ua; arow = 64 * w; }
    else { src = (kc < 4) ? Bm : Uc; arow = 64 * (w - 2); }
    s16x8 uf[4];
#pragma unroll
    for (int m = 0; m < 4; ++m)
      uf[m] = *(const s16x8*)(src + (arow + 16 * m + fr) * 128 + (kc & 3) * 32 + fq * 8);
#pragma unroll
    for (int c = 0; c < 8; ++c) {
      int jl = 16 * c + fr;
      s16x8 bb = *(const s16x8*)((char*)rT + (((jl << 9) + (kc << 6) + (fq << 4)) ^ ((jl & 15) << 4)));
#pragma unroll
      for (int m = 0; m < 4; ++m)
        acc[m][c] = __builtin_amdgcn_mfma_f32_16x16x32_bf16(uf[m], bb, acc[m][c], 0, 0, 0);
    }
  }
#pragma unroll
  for (int m = 0; m < 4; ++m) {
#pragma unroll
    for (int c = 0; c < 8; ++c) {
      int jl = 16 * c + fr;
      int sb = 64 * w + 16 * m + fq * 4;
      u16x4 pk;
#pragma unroll
      for (int r = 0; r < 4; ++r) pk[r] = f2bf(acc[m][c][r]);
      *(u16x4*)(CT + base + ((size_t)(j0 + jl) << 10) + s0 + sb) = pk;
    }
  }
}

// ================= pv: online-softmax + P @ V; wave-independent (no barriers) =================
__global__ __launch_bounds__(256) void pv_kernel(const unsigned short* __restrict__ S,
    const unsigned short* __restrict__ VT, const float* __restrict__ Fc,
    unsigned short* __restrict__ Ob) {
  int idx = blockIdx.x;
  int bh = idx & 31, rank = idx >> 5;
  int tb = 15 - rank;
  int b = bh >> 4, h = bh & 15;
  int t0 = tb * 64;
  int t = threadIdx.x, w = t >> 6, l = t & 63, fr = l & 15, fq = l >> 4;
  int g = l >> 3, ch = l & 7;              // 8-lane row group / col chunk
  __shared__ unsigned short Pl[4][16 * 64];   // per-wave 2KB region
  size_t base = (size_t)bh << 20;
  float m0 = -1e30f, m1 = -1e30f, l0 = 0.f, l1 = 0.f;
  f32x4 acc[4];
#pragma unroll
  for (int c = 0; c < 4; ++c) acc[c] = (f32x4){0.f,0.f,0.f,0.f};
  for (int jb = 0; jb <= tb; ++jb) {
    int j0 = jb * 64;
    float sc[2];
#pragma unroll
    for (int i = 0; i < 2; ++i) {
      int row16 = g + i * 8;
      int row64 = 16 * w + row16;
      int grow = t0 + row64;
      u16x8 sv = *(const u16x8*)(S + base + ((size_t)grow << 10) + j0 + ch * 8);
      float4 f0 = *(const float4*)(Fc + bh * 1024 + j0 + ch * 8);
      float4 f1 = *(const float4*)(Fc + bh * 1024 + j0 + ch * 8 + 4);
      float vals[8];
      float tm = -1e30f;
#pragma unroll
      for (int e = 0; e < 8; ++e) {
        float fc = e < 4 ? ((const float*)&f0)[e] : ((const float*)&f1)[e - 4];
        float v = bf2f(sv[e]) * SM_SCALE - fc;
        if (jb == tb && ch * 8 + e > row64) v = -1e30f;
        vals[e] = v; tm = fmaxf(tm, v);
      }
      tm = fmaxf(tm, __shfl_xor(tm, 1));
      tm = fmaxf(tm, __shfl_xor(tm, 2));
      tm = fmaxf(tm, __shfl_xor(tm, 4));
      float mo = i ? m1 : m0;
      float mn = fmaxf(mo, tm);
      float s = __expf(mo - mn);
      u16x8 pv;
      float psum = 0.f;
#pragma unroll
      for (int e = 0; e < 8; ++e) {
        float p = __expf(vals[e] - mn);
        psum += p; pv[e] = f2bf(p);
      }
      int byt = ((row16 << 7) + (ch << 4)) ^ ((row16 & 7) << 4);
      *(u16x8*)((char*)Pl[w] + byt) = pv;
      psum += __shfl_xor(psum, 1);
      psum += __shfl_xor(psum, 2);
      psum += __shfl_xor(psum, 4);
      if (i) { m1 = mn; l1 = l1 * s + psum; } else { m0 = mn; l0 = l0 * s + psum; }
      sc[i] = s;
    }
    __builtin_amdgcn_wave_barrier();
    float cr[4];
#pragma unroll
    for (int r = 0; r < 4; ++r) {
      int rho = fq * 4 + r;
      int src = (rho & 7) * 8;
      float v0 = __shfl(sc[0], src);
      float v1 = __shfl(sc[1], src);
      cr[r] = (rho < 8) ? v0 : v1;
    }
#pragma unroll
    for (int c = 0; c < 4; ++c)
#pragma unroll
      for (int r = 0; r < 4; ++r) acc[c][r] *= cr[r];
#pragma unroll
    for (int kh = 0; kh < 2; ++kh) {
      s16x8 a = *(const s16x8*)((char*)Pl[w] + (((fr << 7) + (kh << 6) + (fq << 4)) ^ ((fr & 7) << 4)));
#pragma unroll
      for (int c = 0; c < 4; ++c) {
        s16x8 bb = *(const s16x8*)(VT + ((size_t)bh * 64 + 16 * c + fr) * 1024 + j0 + kh * 32 + fq * 8);
        acc[c] = __builtin_amdgcn_mfma_f32_16x16x32_bf16(a, bb, acc[c], 0, 0, 0);
      }
    }
    __builtin_amdgcn_wave_barrier();
  }
  float inv[4];
#pragma unroll
  for (int r = 0; r < 4; ++r) {
    int rho = fq * 4 + r;
    int src = (rho & 7) * 8;
    float v0 = __shfl(l0, src);
    float v1 = __shfl(l1, src);
    inv[r] = 1.f / ((rho < 8) ? v0 : v1);
  }
#pragma unroll
  for (int c = 0; c < 4; ++c) {
#pragma unroll
    for (int r = 0; r < 4; ++r) {
      int grow = t0 + 16 * w + fq * 4 + r;
      Ob[((size_t)(b * 1024) + grow) * 1024 + h * 64 + 16 * c + fr] = f2bf(acc[c][r] * inv[r]);
    }
  }
}

extern "C" void kernel_launch(void* const* d_in, const int* in_sizes, int n_in,
                              void* d_out, int out_size, void* d_ws, size_t ws_size,
                              hipStream_t stream) {
  const float* x    = (const float*)d_in[0];
  const float* Wq   = (const float*)d_in[1];
  const float* Wk   = (const float*)d_in[2];
  const float* Wv   = (const float*)d_in[3];
  const float* Wo   = (const float*)d_in[4];
  const float* Ww1  = (const float*)d_in[5];
  const float* Ww2  = (const float*)d_in[6];
  const float* Wb   = (const float*)d_in[7];
  const float* Wf   = (const float*)d_in[8];
  const float* delta= (const float*)d_in[9];

  char* ws = (char*)d_ws;
  unsigned short* xb   = (unsigned short*)(ws + OFF_XB);
  unsigned short* WqT  = (unsigned short*)(ws + OFF_WQT);
  unsigned short* WkT  = (unsigned short*)(ws + OFF_WKT);
  unsigned short* WvT  = (unsigned short*)(ws + OFF_WVT);
  unsigned short* WoT  = (unsigned short*)(ws + OFF_WOT);
  unsigned short* W1c  = (unsigned short*)(ws + OFF_W1C);
  unsigned short* W2T  = (unsigned short*)(ws + OFF_W2T);
  float*          Beta = (float*)(ws + OFF_BETA);
  unsigned short* Q16  = (unsigned short*)(ws + OFF_Q16);
  unsigned short* K16  = (unsigned short*)(ws + OFF_K16);
  unsigned short* VT   = (unsigned short*)(ws + OFF_VT);
  unsigned short* WN16 = (unsigned short*)(ws + OFF_WN16);
  unsigned short* WB16 = (unsigned short*)(ws + OFF_WB16);
  unsigned short* WNF16= (unsigned short*)(ws + OFF_WNF);
  unsigned short* ObB  = (unsigned short*)(ws + OFF_OB);
  unsigned short* BFT  = (unsigned short*)(ws + OFF_BFT);
  float*          Fc   = (float*)(ws + OFF_FC);
  unsigned short* Lbuf = (unsigned short*)(ws + OFF_L);
  unsigned short* Sbuf = (unsigned short*)(ws + OFF_L);
  unsigned short* CT   = (unsigned short*)(ws + OFF_CT);
  unsigned short* Gbuf = (unsigned short*)(ws + OFF_G);
  float*          BL   = (float*)(ws + OFF_BL);
  unsigned short* U128 = (unsigned short*)(ws + OFF_U128);
  unsigned short* B256 = (unsigned short*)(ws + OFF_B256);

  dim3 blk(256);
  // prep (all transposes + casts + BFT 128-row)
  prep_all<<<2160, blk, 0, stream>>>(Wq, Wk, Wv, Wo, Ww1, Ww2, x, Wb, Wf,
                                     WqT, WkT, WvT, WoT, W1c, W2T, xb, BFT);
  // WfusedT = W2T @ W1c^T (rank-64 fold; lives in WN16 region until wnorm2)
  gemm_nt<0><<<dim3(16,16), blk, 0, stream>>>(W2T, W1c, WN16, 1024, 1024, 64);
  // Q, K, VT, WNF, BL in one 528-block launch (XCD-grouped, pipelined)
  proj_big<<<528, blk, 0, stream>>>(xb, WqT, WkT, WvT, WN16, BFT,
                                    Q16, K16, VT, WNF16, BL);
  // beta/logsigmoid/cumsum fused
  bgfc<<<32, blk, 0, stream>>>(BL, delta, Beta, Fc);
  wnorm2<<<2048, blk, 0, stream>>>(WNF16, Beta, WN16, WB16);
  // L and G (both stored NEGATED)
  pairLG<<<dim3(36 * 32), blk, 0, stream>>>(WN16, Q16, WB16, Lbuf, Gbuf);
  // triangular solve: fused inverses -> 256 off-diag piece -> 4 band steps
  invbuild<<<dim3(8,32), blk, 0, stream>>>(Lbuf, U128);
  u256build<<<dim3(4,32), blk, 0, stream>>>(Lbuf, U128, B256);
  for (int ib = 0; ib < 4; ++ib)
    solve256<<<dim3(2 * ib + 2, 32), blk, 0, stream>>>(WN16, K16, Lbuf, U128, B256, CT, ib);
  // S = QK^T + Gneg C (sorted band grid; reuses L region; pipelined)
  score128s<<<dim3(36 * 32), blk, 0, stream>>>(Q16, K16, Gbuf, CT, Sbuf);
  // online softmax + PV (wave-independent)
  pv_kernel<<<dim3(512), blk, 0, stream>>>(Sbuf, VT, Fc, ObB);
  // output projection (f32 out; XCD-grouped, pipelined)
  gemm_outproj<<<512, blk, 0, stream>>>(ObB, WoT, (float*)d_out);
}